// Round 5
// baseline (913.736 us; speedup 1.0000x reference)
//
#include <hip/hip_runtime.h>
#include <hip/hip_bf16.h>
#include <math.h>

// Sizes fixed by the problem: B=2, T=2048, D=1024, F=4096, H=8, DH=128.
#define BSZ 2
#define TLEN 2048
#define DDIM 1024
#define FDIM 4096
#define HHEADS 8
#define DHEAD 128
#define NC 32   // chunks per sequence
#define CS 64   // chunk size (CS*NC == TLEN)

typedef __bf16 bf16x8 __attribute__((ext_vector_type(8)));
typedef float f32x4 __attribute__((ext_vector_type(4)));

__device__ __forceinline__ float silu_f(float x) {
    return x / (1.0f + expf(-x));
}

__device__ __forceinline__ void load_lds16(const void* g, void* l) {
    __builtin_amdgcn_global_load_lds(
        (const __attribute__((address_space(1))) void*)g,
        (__attribute__((address_space(3))) void*)l, 16, 0, 0);
}

__device__ __forceinline__ unsigned short bf16_bits(float f) {
    __hip_bfloat16 h = __float2bfloat16(f);
    return *reinterpret_cast<unsigned short*>(&h);
}

__device__ __forceinline__ float bfbits2f(unsigned short u) {
    union { unsigned int i; float f; } c;
    c.i = ((unsigned int)u) << 16;
    return c.f;
}

__device__ __forceinline__ uint4 pack8_bf16(const float* f) {
    union { unsigned short u[8]; uint4 v; } r;
#pragma unroll
    for (int i = 0; i < 8; ++i) r.u[i] = bf16_bits(f[i]);
    return r.v;
}

// ---------------- RMSNorm: one block (256 thr) per row of 1024; bf16 out -----
struct alignas(8) bh4 { __hip_bfloat16 a, b, c, d; };

__global__ __launch_bounds__(256) void rmsnorm_k(const float* __restrict__ in,
                                                 __hip_bfloat16* __restrict__ out) {
    const long row = blockIdx.x;
    const int tid = threadIdx.x;
    const float4 x = *(const float4*)(in + row * DDIM + tid * 4);
    float ss = x.x * x.x + x.y * x.y + x.z * x.z + x.w * x.w;
    ss += __shfl_xor(ss, 1);
    ss += __shfl_xor(ss, 2);
    ss += __shfl_xor(ss, 4);
    ss += __shfl_xor(ss, 8);
    ss += __shfl_xor(ss, 16);
    ss += __shfl_xor(ss, 32);
    __shared__ float wsum[4];
    if ((tid & 63) == 0) wsum[tid >> 6] = ss;
    __syncthreads();
    const float tot = wsum[0] + wsum[1] + wsum[2] + wsum[3];
    const float sc = rsqrtf(tot * (1.0f / (float)DDIM) + 1e-6f);
    bh4 y;
    y.a = __float2bfloat16(x.x * sc);
    y.b = __float2bfloat16(x.y * sc);
    y.c = __float2bfloat16(x.z * sc);
    y.d = __float2bfloat16(x.w * sc);
    *(bh4*)(out + row * DDIM + tid * 4) = y;
}

// ------------- transpose + f32->bf16: W[K,N] -> Wt[N,K] -------------
__global__ __launch_bounds__(256) void transpose_cvt(const float* __restrict__ W,
                                                     __hip_bfloat16* __restrict__ Wt,
                                                     int K, int N) {
    __shared__ float t[32][33];
    const int n0 = blockIdx.x * 32, k0 = blockIdx.y * 32;
    const int tx = threadIdx.x & 31, ty = threadIdx.x >> 5;  // ty 0..7
#pragma unroll
    for (int i = 0; i < 4; ++i)
        t[ty * 4 + i][tx] = W[(long)(k0 + ty * 4 + i) * N + n0 + tx];
    __syncthreads();
#pragma unroll
    for (int i = 0; i < 4; ++i)
        Wt[(long)(n0 + ty * 4 + i) * K + k0 + tx] = __float2bfloat16(t[tx][ty * 4 + i]);
}

// ---------------- bf16 MFMA GEMM: C[M,N] = A[M,K] @ Bt[N,K]^T -------
// MODE 0: f32 out. MODE 1: f32 out + f32 resid. MODE 2: bf16 out.
template <int MODE>
__global__ __launch_bounds__(256) void gemm_bf16(const __hip_bfloat16* __restrict__ A,
                                                 const __hip_bfloat16* __restrict__ Bt,
                                                 const float* __restrict__ resid,
                                                 void* __restrict__ Cout,
                                                 int M, int N, int K) {
    __shared__ __align__(16) short As[128 * 32];
    __shared__ __align__(16) short Bs[128 * 32];
    const int tid = threadIdx.x;
    const int w = tid >> 6, l = tid & 63;
    const int m0 = blockIdx.y * 128, n0 = blockIdx.x * 128;
    const int srow = (w << 4) + (l >> 2);
    const int skcol = (l & 3) * 8;
    const int wr = w >> 1, wc = w & 1;
    const int fr = l & 15;
    const int fkB = (l >> 4) * 16;

    f32x4 acc[4][4];
#pragma unroll
    for (int m = 0; m < 4; ++m)
#pragma unroll
        for (int n = 0; n < 4; ++n) acc[m][n] = (f32x4)0.0f;

    const __hip_bfloat16* Abase = A + (long)m0 * K + skcol;
    const __hip_bfloat16* Bbase = Bt + (long)n0 * K + skcol;

    for (int k0 = 0; k0 < K; k0 += 32) {
#pragma unroll
        for (int j = 0; j < 2; ++j) {
            const int row = srow + j * 64;
            load_lds16(Abase + (long)row * K + k0, (char*)As + w * 1024 + j * 4096);
            load_lds16(Bbase + (long)row * K + k0, (char*)Bs + w * 1024 + j * 4096);
        }
        __syncthreads();
        bf16x8 av[4], bv[4];
#pragma unroll
        for (int m = 0; m < 4; ++m) {
            av[m] = *(const bf16x8*)((char*)As + (wr * 64 + m * 16 + fr) * 64 + fkB);
            bv[m] = *(const bf16x8*)((char*)Bs + (wc * 64 + m * 16 + fr) * 64 + fkB);
        }
#pragma unroll
        for (int m = 0; m < 4; ++m)
#pragma unroll
            for (int n = 0; n < 4; ++n)
                acc[m][n] = __builtin_amdgcn_mfma_f32_16x16x32_bf16(av[m], bv[n], acc[m][n], 0, 0, 0);
        __syncthreads();
    }

    const int r0 = (l >> 4) * 4;
    const int cc = l & 15;
#pragma unroll
    for (int m = 0; m < 4; ++m) {
#pragma unroll
        for (int r = 0; r < 4; ++r) {
            const long row = m0 + wr * 64 + m * 16 + r0 + r;
            const long colb = n0 + wc * 64 + cc;
            if (MODE == 2) {
                __hip_bfloat16* cb = (__hip_bfloat16*)Cout + row * N + colb;
#pragma unroll
                for (int n = 0; n < 4; ++n)
                    cb[n * 16] = __float2bfloat16(acc[m][n][r]);
            } else {
                float* cp = (float*)Cout + row * N + colb;
                const float* rp = resid + row * N + colb;
#pragma unroll
                for (int n = 0; n < 4; ++n) {
                    float v = acc[m][n][r];
                    if (MODE == 1) v += rp[n * 16];
                    cp[n * 16] = v;
                }
            }
        }
    }
}

// ---- dual-B MFMA GEMM for SwiGLU: H = bf16( silu(A@Wg^T) * (A@Wu^T) ) ------
__global__ __launch_bounds__(256) void gemm_gateup_bf16(const __hip_bfloat16* __restrict__ A,
                                                        const __hip_bfloat16* __restrict__ Bg,
                                                        const __hip_bfloat16* __restrict__ Bu,
                                                        __hip_bfloat16* __restrict__ Hb,
                                                        int M, int N, int K) {
    __shared__ __align__(16) short As[128 * 32];
    __shared__ __align__(16) short Bgs[128 * 32];
    __shared__ __align__(16) short Bus[128 * 32];
    const int tid = threadIdx.x;
    const int w = tid >> 6, l = tid & 63;
    const int m0 = blockIdx.y * 128, n0 = blockIdx.x * 128;
    const int srow = (w << 4) + (l >> 2);
    const int skcol = (l & 3) * 8;
    const int wr = w >> 1, wc = w & 1;
    const int fr = l & 15;
    const int fkB = (l >> 4) * 16;

    f32x4 accg[4][4], accu[4][4];
#pragma unroll
    for (int m = 0; m < 4; ++m)
#pragma unroll
        for (int n = 0; n < 4; ++n) { accg[m][n] = (f32x4)0.0f; accu[m][n] = (f32x4)0.0f; }

    const __hip_bfloat16* Abase = A + (long)m0 * K + skcol;
    const __hip_bfloat16* Bgb = Bg + (long)n0 * K + skcol;
    const __hip_bfloat16* Bub = Bu + (long)n0 * K + skcol;

    for (int k0 = 0; k0 < K; k0 += 32) {
#pragma unroll
        for (int j = 0; j < 2; ++j) {
            const int row = srow + j * 64;
            load_lds16(Abase + (long)row * K + k0, (char*)As + w * 1024 + j * 4096);
            load_lds16(Bgb + (long)row * K + k0, (char*)Bgs + w * 1024 + j * 4096);
            load_lds16(Bub + (long)row * K + k0, (char*)Bus + w * 1024 + j * 4096);
        }
        __syncthreads();
        bf16x8 av[4], bgv[4], buv[4];
#pragma unroll
        for (int m = 0; m < 4; ++m) {
            av[m] = *(const bf16x8*)((char*)As + (wr * 64 + m * 16 + fr) * 64 + fkB);
            bgv[m] = *(const bf16x8*)((char*)Bgs + (wc * 64 + m * 16 + fr) * 64 + fkB);
            buv[m] = *(const bf16x8*)((char*)Bus + (wc * 64 + m * 16 + fr) * 64 + fkB);
        }
#pragma unroll
        for (int m = 0; m < 4; ++m)
#pragma unroll
            for (int n = 0; n < 4; ++n) {
                accg[m][n] = __builtin_amdgcn_mfma_f32_16x16x32_bf16(av[m], bgv[n], accg[m][n], 0, 0, 0);
                accu[m][n] = __builtin_amdgcn_mfma_f32_16x16x32_bf16(av[m], buv[n], accu[m][n], 0, 0, 0);
            }
        __syncthreads();
    }

    const int r0 = (l >> 4) * 4;
    const int cc = l & 15;
#pragma unroll
    for (int m = 0; m < 4; ++m) {
#pragma unroll
        for (int r = 0; r < 4; ++r) {
            const long row = m0 + wr * 64 + m * 16 + r0 + r;
            __hip_bfloat16* hp = Hb + row * N + n0 + wc * 64 + cc;
#pragma unroll
            for (int n = 0; n < 4; ++n)
                hp[n * 16] = __float2bfloat16(silu_f(accg[m][n][r]) * accu[m][n][r]);
        }
    }
}

// ------- beta/alpha: inline rmsnorm (scale folds out of the dot) -------
__global__ __launch_bounds__(64) void ba_kernel(const float* __restrict__ x,
                                                const float* __restrict__ wb,
                                                const float* __restrict__ wg,
                                                float* __restrict__ beta,
                                                float* __restrict__ alpha) {
    const long row = blockIdx.x;
    const int tid = threadIdx.x;
    const int o = tid >> 2;
    const int p = tid & 3;
    const float* w = (o < 8) ? (wb + o) : (wg + (o - 8));
    const float* xr = x + row * DDIM + p * 256;
    const float* wr = w + (long)(p * 256) * HHEADS;
    float acc = 0.0f, ss = 0.0f;
#pragma unroll 8
    for (int i = 0; i < 256; ++i) {
        const float xv = xr[i];
        ss = fmaf(xv, xv, ss);
        acc = fmaf(xv, wr[(long)i * HHEADS], acc);
    }
    acc += __shfl_xor(acc, 1);
    acc += __shfl_xor(acc, 2);
    ss += __shfl_xor(ss, 1);
    ss += __shfl_xor(ss, 2);
    if (p == 0) {
        const float sc = rsqrtf(ss * (1.0f / (float)DDIM) + 1e-6f);
        const float val = 1.0f / (1.0f + expf(-acc * sc));
        if (o < 8) beta[row * HHEADS + o] = val;
        else       alpha[row * HHEADS + (o - 8)] = val;
    }
}

// ------- post-projection (bf16 in-place): silu + l2norm on q,k; silu on v ----
__global__ __launch_bounds__(64) void postqkv(__hip_bfloat16* __restrict__ q,
                                              __hip_bfloat16* __restrict__ k,
                                              __hip_bfloat16* __restrict__ v) {
    const long r = blockIdx.x;
    const int tid = threadIdx.x;
    {
        unsigned int* qp = (unsigned int*)(q + r * DHEAD + tid * 2);
        const unsigned int wbits = *qp;
        float y0 = silu_f(bfbits2f(wbits & 0xffff));
        float y1 = silu_f(bfbits2f(wbits >> 16));
        float ss = y0 * y0 + y1 * y1;
        ss += __shfl_xor(ss, 1);  ss += __shfl_xor(ss, 2);
        ss += __shfl_xor(ss, 4);  ss += __shfl_xor(ss, 8);
        ss += __shfl_xor(ss, 16); ss += __shfl_xor(ss, 32);
        const float sc = rsqrtf(ss + 1e-6f);
        *qp = (unsigned int)bf16_bits(y0 * sc) | ((unsigned int)bf16_bits(y1 * sc) << 16);
    }
    {
        unsigned int* kp = (unsigned int*)(k + r * DHEAD + tid * 2);
        const unsigned int wbits = *kp;
        float y0 = silu_f(bfbits2f(wbits & 0xffff));
        float y1 = silu_f(bfbits2f(wbits >> 16));
        float ss = y0 * y0 + y1 * y1;
        ss += __shfl_xor(ss, 1);  ss += __shfl_xor(ss, 2);
        ss += __shfl_xor(ss, 4);  ss += __shfl_xor(ss, 8);
        ss += __shfl_xor(ss, 16); ss += __shfl_xor(ss, 32);
        const float sc = rsqrtf(ss + 1e-6f);
        *kp = (unsigned int)bf16_bits(y0 * sc) | ((unsigned int)bf16_bits(y1 * sc) << 16);
    }
    {
        unsigned int* vp = (unsigned int*)(v + r * DHEAD + tid * 2);
        const unsigned int wbits = *vp;
        *vp = (unsigned int)bf16_bits(silu_f(bfbits2f(wbits & 0xffff)))
            | ((unsigned int)bf16_bits(silu_f(bfbits2f(wbits >> 16))) << 16);
    }
}

// ============ Chunked gated delta rule (log-space decay) ============
// G_t = sum_{s<=t} log(a_s) within chunk; ratio(t,s)=exp(G_t-G_s)<=1 for s<=t.
//   dv = dv0 + R @ S0,   R = -Tinv @ diag(b_s e^{G_s}) @ K   (precomputed)
//   dv0 = Tinv @ (b (.) v)                                    (precomputed)
//   o_t = e^{G_t} (S0^T q_t) + (M @ dv)_t                     (M precomputed)
//   S_end = e^{G63} S0 + K^T @ diag(e^{G63-G_t}) dv

// --------- Phase A (parallel over bh x chunk): G, M, R, K^T, dv0 ------------
__global__ __launch_bounds__(256) void chunk_prep(
    const __hip_bfloat16* __restrict__ kb, const __hip_bfloat16* __restrict__ qb,
    const __hip_bfloat16* __restrict__ vb, const float* __restrict__ betab,
    const float* __restrict__ alphab, float* __restrict__ Gcum,
    __hip_bfloat16* __restrict__ Rg, __hip_bfloat16* __restrict__ Ktg,
    __hip_bfloat16* __restrict__ dvX, __hip_bfloat16* __restrict__ Mmat)
{
    const int bh = blockIdx.x >> 5;
    const int c  = blockIdx.x & 31;
    const int b = bh >> 3, h = bh & 7;
    const int tid = threadIdx.x;

    __shared__ __align__(16) __hip_bfloat16 tA[64][136];   // k chunk
    __shared__ __align__(16) __hip_bfloat16 tB[64][136];   // q chunk, later b*v
    __shared__ __hip_bfloat16 Wl[64][66];
    __shared__ float Ti[64][65];
    __shared__ float sa[64], sb_[64], sG[64], swB[64];

    const long row0 = (long)b * TLEN + (long)c * CS;
    const long chnk = (long)bh * NC + c;

    if (tid < 64) {
        sa[tid]  = alphab[(row0 + tid) * HHEADS + h];
        sb_[tid] = betab[(row0 + tid) * HHEADS + h];
    }
    // load k,q chunks (bf16 direct copies)
    {
        const int r = tid >> 2;
        const int d0 = (tid & 3) * 32;
        const uint4* kp = (const uint4*)(kb + (row0 + r) * DDIM + h * DHEAD + d0);
        const uint4* qp = (const uint4*)(qb + (row0 + r) * DDIM + h * DHEAD + d0);
#pragma unroll
        for (int i = 0; i < 4; ++i) {
            *(uint4*)&tA[r][d0 + i * 8] = kp[i];
            *(uint4*)&tB[r][d0 + i * 8] = qp[i];
        }
    }
    __syncthreads();
    if (tid == 0) {
        float run = 0.0f;
        for (int t = 0; t < CS; ++t) { run += logf(sa[t]); sG[t] = run; }
    }
    __syncthreads();
    if (tid < 64) {
        Gcum[chnk * CS + tid] = sG[tid];
        swB[tid] = sb_[tid] * expf(sG[tid]);
    }
    __syncthreads();

    // W[t][s] (s<t) and M[t][s] (s<=t)
    {
        const int t = tid >> 2;
        const int s0 = (tid & 3) * 16;
        float accW[16], accM[16];
#pragma unroll
        for (int i = 0; i < 16; ++i) { accW[i] = 0.0f; accM[i] = 0.0f; }
        for (int d = 0; d < DHEAD; ++d) {
            const float at = __bfloat162float(tA[t][d]);
            const float bt = __bfloat162float(tB[t][d]);
#pragma unroll
            for (int i = 0; i < 16; ++i) {
                const float ks = __bfloat162float(tA[s0 + i][d]);
                accW[i] = fmaf(at, ks, accW[i]);
                accM[i] = fmaf(bt, ks, accM[i]);
            }
        }
        const float btc = sb_[t], Gt = sG[t];
        float mrow[16];
#pragma unroll
        for (int i = 0; i < 16; ++i) {
            const int s = s0 + i;
            const float ratio = (s <= t) ? expf(Gt - sG[s]) : 0.0f;  // <= 1
            Wl[t][s] = __float2bfloat16((s < t) ? btc * ratio * accW[i] : 0.0f);
            mrow[i] = ratio * accM[i];
        }
        __hip_bfloat16* mp = Mmat + (chnk * CS + t) * CS + s0;
        *(uint4*)(mp)     = pack8_bf16(&mrow[0]);
        *(uint4*)(mp + 8) = pack8_bf16(&mrow[8]);
    }
    __syncthreads();

    // Ti = (I+W)^-1 via forward elimination
    {
        const int t = tid >> 2, j0 = (tid & 3) * 16;
#pragma unroll
        for (int i = 0; i < 16; ++i) Ti[t][j0 + i] = (t == j0 + i) ? 1.0f : 0.0f;
    }
    __syncthreads();
    for (int s = 0; s < CS - 1; ++s) {
        const int t = tid & 63, jq = tid >> 6;
        if (t > s) {
            const float wt = -__bfloat162float(Wl[t][s]);
            const int jlo = jq * 16;
            const int jhi = min(s, jlo + 15);
            for (int j = jlo; j <= jhi; ++j)
                Ti[t][j] = fmaf(wt, Ti[s][j], Ti[t][j]);
        }
        __syncthreads();
    }

    // R[t][kk] = -sum_s Ti[t][s] * swB[s] * K[s][kk]   (bf16 out)
    {
        const int t = tid >> 2, j0 = (tid & 3) * 32;
        float acc[32];
#pragma unroll
        for (int j = 0; j < 32; ++j) acc[j] = 0.0f;
        for (int s = 0; s <= t; ++s) {
            const float cf = -Ti[t][s] * swB[s];
#pragma unroll
            for (int j = 0; j < 32; ++j)
                acc[j] = fmaf(cf, __bfloat162float(tA[s][j0 + j]), acc[j]);
        }
        __hip_bfloat16* rp = Rg + (chnk * CS + t) * DHEAD + j0;
#pragma unroll
        for (int i = 0; i < 4; ++i)
            *(uint4*)(rp + i * 8) = pack8_bf16(&acc[i * 8]);
    }

    // K^T: Ktg[kk][t] = K[t][kk]
    {
        const int kk = tid >> 1;
        const int t0 = (tid & 1) * 32;
        __hip_bfloat16* kp = Ktg + (chnk * DHEAD + kk) * CS + t0;
        float f[8];
#pragma unroll
        for (int i = 0; i < 4; ++i) {
#pragma unroll
            for (int j2 = 0; j2 < 8; ++j2)
                f[j2] = __bfloat162float(tA[t0 + i * 8 + j2][kk]);
            *(uint4*)(kp + i * 8) = pack8_bf16(f);
        }
    }

    // load b*v into tB
    {
        const int r = tid >> 2, d0 = (tid & 3) * 32;
        const float br = sb_[r];
        const uint4* vp = (const uint4*)(vb + (row0 + r) * DDIM + h * DHEAD + d0);
#pragma unroll
        for (int i = 0; i < 4; ++i) {
            const uint4 vv = vp[i];
            const unsigned short* u = (const unsigned short*)&vv;
            float f[8];
#pragma unroll
            for (int j = 0; j < 8; ++j) f[j] = br * bfbits2f(u[j]);
            *(uint4*)&tB[r][d0 + i * 8] = pack8_bf16(f);
        }
    }
    __syncthreads();

    // dv0 = Ti @ (b*v) -> dvX (bf16)
    {
        const int t = tid >> 2, j0 = (tid & 3) * 32;
        float acc[32];
#pragma unroll
        for (int j = 0; j < 32; ++j) acc[j] = 0.0f;
        for (int s = 0; s < CS; ++s) {
            const float ti = Ti[t][s];
#pragma unroll
            for (int j = 0; j < 32; ++j)
                acc[j] = fmaf(ti, __bfloat162float(tB[s][j0 + j]), acc[j]);
        }
        __hip_bfloat16* dp = dvX + (chnk * CS + t) * DHEAD + j0;
#pragma unroll
        for (int i = 0; i < 4; ++i)
            *(uint4*)(dp + i * 8) = pack8_bf16(&acc[i * 8]);
    }
}

// --------- Phase B (sequential over chunks; MFMA; one block per bh) ----------
// LDS carve (bytes):
//   R[2]   : 0      + buf*17408   ([64][136] bf16)
//   Kt[2]  : 34816  + buf*18432   ([128][72] bf16)
//   dvT    : 71680                ([128][72] bf16)
//   Stl    : 90112                ([128][136] bf16, holds S^T: Stl[j][kk]=S[kk][j])
//   sG     : 124928               (f32[2][64])
//   ldsT   : overlay at 0         ([128][132] f32, init/final transpose)
#define SEQ_LDS_BYTES 125440

__global__ __launch_bounds__(256) void chunk_seq_mfma(
    const float* __restrict__ S0in, const float* __restrict__ Gcum,
    const __hip_bfloat16* __restrict__ Rg, const __hip_bfloat16* __restrict__ Ktg,
    __hip_bfloat16* __restrict__ dvX, __hip_bfloat16* __restrict__ Ssnap,
    float* __restrict__ Sout)
{
    const int bh = blockIdx.x;
    const int tid = threadIdx.x;
    const int w = tid >> 6;
    const int l = tid & 63;
    const int fr = l & 15;
    const int fk8 = (l >> 4) * 8;
    const int rq = (l >> 4) * 4;   // row-quad base within 16-tile

    __shared__ __align__(16) char smem[SEQ_LDS_BYTES];
    __hip_bfloat16* dvT = (__hip_bfloat16*)(smem + 71680);
    __hip_bfloat16* Stl = (__hip_bfloat16*)(smem + 90112);
    float* sG = (float*)(smem + 124928);
    float* ldsT = (float*)(smem);

    // ---- init: S0 [kk][j] -> ldsT f32; master regs (S^T) + Stl bf16 ----
    {
        const int kk = tid >> 1, j0 = (tid & 1) * 64;
        const float* sp = S0in + ((long)bh * 128 + kk) * 128 + j0;
        float* dst = ldsT + kk * 132 + j0;
#pragma unroll
        for (int i = 0; i < 16; ++i)
            *(float4*)(dst + i * 4) = ((const float4*)sp)[i];
    }
    __syncthreads();
    f32x4 SM[2][8];
#pragma unroll
    for (int mj = 0; mj < 2; ++mj)
#pragma unroll
        for (int nk = 0; nk < 8; ++nk) {
#pragma unroll
            for (int r = 0; r < 4; ++r) {
                const int j = w * 32 + mj * 16 + rq + r;
                const int kk = nk * 16 + fr;
                const float v = ldsT[kk * 132 + j];
                SM[mj][nk][r] = v;
                Stl[j * 136 + kk] = __float2bfloat16(v);
            }
        }
    __syncthreads();   // ldsT dead; Stl visible

    // ---- staging ----
    uint4 rreg[4], kreg[4];
    float greg = 0.0f;

#define SEQ_STAGE_LOAD(c_) do {                                                   \
        const long cb_ = (long)bh * NC + (c_);                                    \
        _Pragma("unroll")                                                         \
        for (int i_ = 0; i_ < 4; ++i_) {                                          \
            const int ur_ = (tid << 2) + i_;                                      \
            rreg[i_] = *(const uint4*)(Rg + (cb_ * CS + (ur_ >> 4)) * DHEAD + ((ur_ & 15) << 3)); \
            kreg[i_] = *(const uint4*)(Ktg + (cb_ * DHEAD + (ur_ >> 3)) * CS + ((ur_ & 7) << 3)); \
        }                                                                         \
        if (tid < 64) greg = Gcum[cb_ * CS + tid];                                \
    } while (0)

#define SEQ_STAGE_WRITE(bufi_) do {                                               \
        __hip_bfloat16* rb_ = (__hip_bfloat16*)(smem + (bufi_) * 17408);          \
        __hip_bfloat16* kb2_ = (__hip_bfloat16*)(smem + 34816 + (bufi_) * 18432); \
        _Pragma("unroll")                                                         \
        for (int i_ = 0; i_ < 4; ++i_) {                                          \
            const int ur_ = (tid << 2) + i_;                                      \
            *(uint4*)(rb_ + (ur_ >> 4) * 136 + ((ur_ & 15) << 3)) = rreg[i_];     \
            *(uint4*)(kb2_ + (ur_ >> 3) * 72 + ((ur_ & 7) << 3)) = kreg[i_];      \
        }                                                                         \
        if (tid < 64) sG[(bufi_) * 64 + tid] = greg;                              \
    } while (0)

    SEQ_STAGE_LOAD(0);
    SEQ_STAGE_WRITE(0);
    __syncthreads();

    for (int c = 0; c < NC; ++c) {
        const int cur = c & 1;
        const long chnk = (long)bh * NC + c;
        const __hip_bfloat16* Rl = (const __hip_bfloat16*)(smem + cur * 17408);
        const __hip_bfloat16* Ktl = (const __hip_bfloat16*)(smem + 34816 + cur * 18432);
        const float g63 = sG[cur * 64 + 63];
        const float a63 = expf(g63);

        // dv0 prefetch for this chunk (same addresses overwritten below)
        unsigned short d0r[32];
#pragma unroll
        for (int m = 0; m < 4; ++m)
#pragma unroll
            for (int r = 0; r < 4; ++r) {
                const int t = m * 16 + rq + r;
#pragma unroll
                for (int n = 0; n < 2; ++n) {
                    const int j = w * 32 + n * 16 + fr;
                    d0r[(m * 4 + r) * 2 + n] =
                        *(const unsigned short*)(dvX + (chnk * CS + t) * DHEAD + j);
                }
            }

        if (c + 1 < NC) SEQ_STAGE_LOAD(c + 1);

        // snapshot chunk-initial S^T -> Ssnap[chnk][j][kk] (coalesced)
        {
            const int j = tid >> 1, k0 = (tid & 1) * 64;
#pragma unroll
            for (int i = 0; i < 8; ++i) {
                const uint4 v = *(const uint4*)&Stl[j * 136 + k0 + i * 8];
                *(uint4*)(Ssnap + (chnk * 128 + j) * 128 + k0 + i * 8) = v;
            }
        }

        // ---- step A: dv = dv0 + R @ S   (acc[t-tiles][j-tiles]) ----
        f32x4 acc[4][2];
#pragma unroll
        for (int m = 0; m < 4; ++m)
#pragma unroll
            for (int n = 0; n < 2; ++n) acc[m][n] = (f32x4)0.0f;
#pragma unroll
        for (int ks = 0; ks < 4; ++ks) {
            bf16x8 bfrag[2];
#pragma unroll
            for (int n = 0; n < 2; ++n)
                bfrag[n] = *(const bf16x8*)&Stl[(w * 32 + n * 16 + fr) * 136 + ks * 32 + fk8];
#pragma unroll
            for (int m = 0; m < 4; ++m) {
                const bf16x8 afrag = *(const bf16x8*)&Rl[(m * 16 + fr) * 136 + ks * 32 + fk8];
#pragma unroll
                for (int n = 0; n < 2; ++n)
                    acc[m][n] = __builtin_amdgcn_mfma_f32_16x16x32_bf16(afrag, bfrag[n], acc[m][n], 0, 0, 0);
            }
        }
        // epi A: add dv0, store dv, write scaled dv^T to LDS
#pragma unroll
        for (int m = 0; m < 4; ++m)
#pragma unroll
            for (int r = 0; r < 4; ++r) {
                const int t = m * 16 + rq + r;
                const float rk = expf(g63 - sG[cur * 64 + t]);
#pragma unroll
                for (int n = 0; n < 2; ++n) {
                    const int j = w * 32 + n * 16 + fr;
                    const float dv = acc[m][n][r] + bfbits2f(d0r[(m * 4 + r) * 2 + n]);
                    *(unsigned short*)(dvX + (chnk * CS + t) * DHEAD + j) = bf16_bits(dv);
                    dvT[j * 72 + t] = __float2bfloat16(rk * dv);
                }
            }

        if (c + 1 < NC) SEQ_STAGE_WRITE(cur ^ 1);
        __syncthreads();   // dvT + staged next-chunk visible

        // ---- step B: S' = a63*S + K^T @ dvs   (master regs) ----
#pragma unroll
        for (int mj = 0; mj < 2; ++mj)
#pragma unroll
            for (int nk = 0; nk < 8; ++nk) SM[mj][nk] *= a63;
#pragma unroll
        for (int ks = 0; ks < 2; ++ks) {
            bf16x8 afrag[2];
#pragma unroll
            for (int mj = 0; mj < 2; ++mj)
                afrag[mj] = *(const bf16x8*)&dvT[(w * 32 + mj * 16 + fr) * 72 + ks * 32 + fk8];
#pragma unroll
            for (int nk = 0; nk < 8; ++nk) {
                const bf16x8 bfrag = *(const bf16x8*)&Ktl[(nk * 16 + fr) * 72 + ks * 32 + fk8];
#pragma unroll
                for (int mj = 0; mj < 2; ++mj)
                    SM[mj][nk] = __builtin_amdgcn_mfma_f32_16x16x32_bf16(afrag[mj], bfrag, SM[mj][nk], 0, 0, 0);
            }
        }
        // epi B: refresh bf16 mirror
#pragma unroll
        for (int mj = 0; mj < 2; ++mj)
#pragma unroll
            for (int nk = 0; nk < 8; ++nk)
#pragma unroll
                for (int r = 0; r < 4; ++r) {
                    const int j = w * 32 + mj * 16 + rq + r;
                    const int kk = nk * 16 + fr;
                    Stl[j * 136 + kk] = __float2bfloat16(SM[mj][nk][r]);
                }
        __syncthreads();   // Stl visible for next chunk
    }

    // ---- final: master (S^T) -> ldsT [kk][j] -> Sout [kk][j] coalesced ----
#pragma unroll
    for (int mj = 0; mj < 2; ++mj)
#pragma unroll
        for (int nk = 0; nk < 8; ++nk)
#pragma unroll
            for (int r = 0; r < 4; ++r) {
                const int j = w * 32 + mj * 16 + rq + r;
                const int kk = nk * 16 + fr;
                ldsT[kk * 132 + j] = SM[mj][nk][r];
            }
    __syncthreads();
    {
        const int kk = tid >> 1, j0 = (tid & 1) * 64;
        float* op = Sout + ((long)bh * 128 + kk) * 128 + j0;
#pragma unroll
        for (int i = 0; i < 16; ++i)
            *(float4*)(op + i * 4) = *(const float4*)&ldsT[kk * 132 + j0 + i * 4];
    }
#undef SEQ_STAGE_LOAD
#undef SEQ_STAGE_WRITE
}

// --------- Phase C (parallel): o = e^{G_t}*(q_t @ S0snap) + M @ dv ----------
// Ssnap layout: [chnk][j][kk] = S0^T
__global__ __launch_bounds__(256) void chunk_out(
    const __hip_bfloat16* __restrict__ qb, const float* __restrict__ Gcum,
    const __hip_bfloat16* __restrict__ dvX, const __hip_bfloat16* __restrict__ Ssnap,
    const __hip_bfloat16* __restrict__ Mmat, __hip_bfloat16* __restrict__ ob)
{
    const int bh = blockIdx.x >> 5;
    const int c  = blockIdx.x & 31;
    const int b = bh >> 3, h = bh & 7;
    const int tid = threadIdx.x;
    const long row0 = (long)b * TLEN + (long)c * CS;
    const long chnk = (long)bh * NC + c;

    __shared__ __align__(16) __hip_bfloat16 Ssn[128][136];   // [j][kk]
    __shared__ __align__(16) __hip_bfloat16 dvq[64][136];    // dv, later q
    __shared__ __align__(16) __hip_bfloat16 Ml[64][72];

    {
        const int j = tid >> 1;
        const int d0 = (tid & 1) * 64;
        const uint4* sp = (const uint4*)(Ssnap + (chnk * 128 + j) * 128 + d0);
#pragma unroll
        for (int i = 0; i < 8; ++i)
            *(uint4*)&Ssn[j][d0 + i * 8] = sp[i];
    }
    {
        const int t = tid >> 2;
        const int s0 = (tid & 3) * 32;
        const uint4* dp = (const uint4*)(dvX + (chnk * CS + t) * DHEAD + s0);
#pragma unroll
        for (int i = 0; i < 4; ++i)
            *(uint4*)&dvq[t][s0 + i * 8] = dp[i];
    }
    {
        const int t = tid >> 2;
        const int s0 = (tid & 3) * 16;
        const uint4* mp = (const uint4*)(Mmat + (chnk * CS + t) * CS + s0);
        *(uint4*)&Ml[t][s0]     = mp[0];
        *(uint4*)&Ml[t][s0 + 8] = mp[1];
    }
    __syncthreads();

    const int t = tid >> 2;
    const int j0l = (tid & 3) * 32;
    float acc[32];
#pragma unroll
    for (int j = 0; j < 32; ++j) acc[j] = 0.0f;

    // part 1: M @ dv
    for (int s = 0; s < CS; ++s) {
        const float m = __bfloat162float(Ml[t][s]);
#pragma unroll
        for (int j = 0; j < 32; ++j)
            acc[j] = fmaf(m, __bfloat162float(dvq[s][j0l + j]), acc[j]);
    }
    __syncthreads();

    // load q chunk into dvq
    {
        const int r = tid >> 2, d0 = (tid & 3) * 32;
        const uint4* qp = (const uint4*)(qb + (row0 + r) * DDIM + h * DHEAD + d0);
#pragma unroll
        for (int i = 0; i < 4; ++i)
            *(uint4*)&dvq[r][d0 + i * 8] = qp[i];
    }
    __syncthreads();

    // part 2: + e^{G_t} * (q_t @ S0)   with S0[kk][j] = Ssn[j][kk]
    const float At = expf(Gcum[chnk * CS + t]);
    for (int kk = 0; kk < 128; ++kk) {
        const float qv = At * __bfloat162float(dvq[t][kk]);
#pragma unroll
        for (int j = 0; j < 32; ++j)
            acc[j] = fmaf(qv, __bfloat162float(Ssn[j0l + j][kk]), acc[j]);
    }

    __hip_bfloat16* op = ob + (row0 + t) * DDIM + h * DHEAD + j0l;
#pragma unroll
    for (int i = 0; i < 4; ++i)
        *(uint4*)(op + i * 8) = pack8_bf16(&acc[i * 8]);
}

extern "C" void kernel_launch(void* const* d_in, const int* in_sizes, int n_in,
                              void* d_out, int out_size, void* d_ws, size_t ws_size,
                              hipStream_t stream) {
    const float* x     = (const float*)d_in[0];
    const float* S0    = (const float*)d_in[1];
    const float* wq    = (const float*)d_in[2];
    const float* wk    = (const float*)d_in[3];
    const float* wv    = (const float*)d_in[4];
    const float* wb    = (const float*)d_in[5];
    const float* wg    = (const float*)d_in[6];
    const float* wo    = (const float*)d_in[7];
    const float* wgate = (const float*)d_in[8];
    const float* wup   = (const float*)d_in[9];
    const float* wdown = (const float*)d_in[10];

    const int M = BSZ * TLEN;  // 4096 token rows

    float* out  = (float*)d_out;
    float* Sout = out + (long)M * DDIM;

    // Workspace layout, peak 76.5 MiB (proven budget: 81 MiB).
    char* w = (char*)d_ws;
    const size_t MB = 1u << 20;
    const size_t KB = 1u << 10;
    __hip_bfloat16* qbh   = (__hip_bfloat16*)(w + 0 * MB);             // QKV->chunk_out
    __hip_bfloat16* kbh   = (__hip_bfloat16*)(w + 8 * MB);             // QKV->chunk_prep
    __hip_bfloat16* vbh   = (__hip_bfloat16*)(w + 16 * MB);            // QKV->chunk_prep
    float*          beta  = (float*)(w + 24 * MB);                     // ->prep
    float*          alpha = (float*)(w + 24 * MB + 128 * KB);          // ->prep
    float*          Gcum  = (float*)(w + 24 * MB + 256 * KB);          // ->out
    __hip_bfloat16* Mmat  = (__hip_bfloat16*)(w + 24 * MB + 512 * KB); // prep->out (4MB)
    __hip_bfloat16* dvX   = (__hip_bfloat16*)(w + 28 * MB + 512 * KB); // prep->out (8MB)
    __hip_bfloat16* Rg    = (__hip_bfloat16*)(w + 36 * MB + 512 * KB); // prep->seq (8MB)
    __hip_bfloat16* xnb   = (__hip_bfloat16*)(w + 36 * MB + 512 * KB); // rms1->QKV (dead before Rg)
    __hip_bfloat16* Ktg   = (__hip_bfloat16*)(w + 44 * MB + 512 * KB); // prep->seq (8MB)
    __hip_bfloat16* Ssnap = (__hip_bfloat16*)(w + 52 * MB + 512 * KB); // seq->out (16MB)
    __hip_bfloat16* wqt   = (__hip_bfloat16*)(w + 68 * MB + 512 * KB); // ->QKV (2MB)
    __hip_bfloat16* wkt   = (__hip_bfloat16*)(w + 70 * MB + 512 * KB);
    __hip_bfloat16* wvt   = (__hip_bfloat16*)(w + 72 * MB + 512 * KB);
    __hip_bfloat16* wot   = (__hip_bfloat16*)(w + 74 * MB + 512 * KB); // ->GEMM4 (2MB), peak 76.5
    __hip_bfloat16* obufb = (__hip_bfloat16*)(w + 8 * MB);             // chunk_out->GEMM4 (kbh dead)
    __hip_bfloat16* xn2b  = (__hip_bfloat16*)(w + 8 * MB);             // rms2->gateup (obufb dead)
    __hip_bfloat16* wdt   = (__hip_bfloat16*)(w + 16 * MB);            // ->down (vbh dead)
    __hip_bfloat16* wgt   = (__hip_bfloat16*)(w + 24 * MB + 512 * KB); // after chunk_out (8MB)
    __hip_bfloat16* wut   = (__hip_bfloat16*)(w + 32 * MB + 512 * KB); // after chunk_out (8MB)
    __hip_bfloat16* Hb    = (__hip_bfloat16*)(w + 40 * MB + 512 * KB); // gateup->down (32MB)

    // 0) weight transpose+convert (W[K,N] -> Wt[N,K] bf16)
    transpose_cvt<<<dim3(DDIM / 32, DDIM / 32), 256, 0, stream>>>(wq, wqt, DDIM, DDIM);
    transpose_cvt<<<dim3(DDIM / 32, DDIM / 32), 256, 0, stream>>>(wk, wkt, DDIM, DDIM);
    transpose_cvt<<<dim3(DDIM / 32, DDIM / 32), 256, 0, stream>>>(wv, wvt, DDIM, DDIM);
    transpose_cvt<<<dim3(DDIM / 32, DDIM / 32), 256, 0, stream>>>(wo, wot, DDIM, DDIM);

    // 1) norms / gates
    rmsnorm_k<<<M, 256, 0, stream>>>(x, xnb);
    ba_kernel<<<M, 64, 0, stream>>>(x, wb, wg, beta, alpha);

    // 2) q/k/v projections (bf16 out)
    dim3 gP(DDIM / 128, M / 128);
    gemm_bf16<2><<<gP, 256, 0, stream>>>(xnb, wqt, nullptr, qbh, M, DDIM, DDIM);
    gemm_bf16<2><<<gP, 256, 0, stream>>>(xnb, wkt, nullptr, kbh, M, DDIM, DDIM);
    gemm_bf16<2><<<gP, 256, 0, stream>>>(xnb, wvt, nullptr, vbh, M, DDIM, DDIM);
    postqkv<<<M * HHEADS, 64, 0, stream>>>(qbh, kbh, vbh);

    // 3) chunked delta rule
    chunk_prep<<<16 * NC, 256, 0, stream>>>(kbh, qbh, vbh, beta, alpha, Gcum, Rg, Ktg, dvX, Mmat);
    chunk_seq_mfma<<<16, 256, 0, stream>>>(S0, Gcum, Rg, Ktg, dvX, Ssnap, Sout);
    chunk_out<<<16 * NC, 256, 0, stream>>>(qbh, Gcum, dvX, Ssnap, Mmat, obufb);

    // 4) x1 = x + o @ wo
    gemm_bf16<1><<<gP, 256, 0, stream>>>(obufb, wot, x, out, M, DDIM, DDIM);

    // 4b) remaining weight transposes into now-dead regions
    transpose_cvt<<<dim3(DDIM / 32, FDIM / 32), 256, 0, stream>>>(wdown, wdt, FDIM, DDIM);
    transpose_cvt<<<dim3(FDIM / 32, DDIM / 32), 256, 0, stream>>>(wgate, wgt, DDIM, FDIM);
    transpose_cvt<<<dim3(FDIM / 32, DDIM / 32), 256, 0, stream>>>(wup, wut, DDIM, FDIM);

    // 5) xn2 = rms_norm(x1)
    rmsnorm_k<<<M, 256, 0, stream>>>(out, xn2b);

    // 6) H = silu(xn2 @ w_gate) * (xn2 @ w_up)
    dim3 gGU(FDIM / 128, M / 128);
    gemm_gateup_bf16<<<gGU, 256, 0, stream>>>(xn2b, wgt, wut, Hb, M, FDIM, DDIM);

    // 7) x_out = x1 + H @ w_down
    dim3 gDN(DDIM / 128, M / 128);
    gemm_bf16<1><<<gDN, 256, 0, stream>>>(Hb, wdt, out, out, M, DDIM, FDIM);
}

// Round 6
// 779.233 us; speedup vs baseline: 1.1726x; 1.1726x over previous
//
#include <hip/hip_runtime.h>
#include <hip/hip_bf16.h>
#include <math.h>

// Sizes fixed by the problem: B=2, T=2048, D=1024, F=4096, H=8, DH=128.
#define BSZ 2
#define TLEN 2048
#define DDIM 1024
#define FDIM 4096
#define HHEADS 8
#define DHEAD 128
#define NC 32   // chunks per sequence
#define CS 64   // chunk size (CS*NC == TLEN)

typedef __bf16 bf16x8 __attribute__((ext_vector_type(8)));
typedef float f32x4 __attribute__((ext_vector_type(4)));

__device__ __forceinline__ float silu_f(float x) {
    return x / (1.0f + expf(-x));
}

__device__ __forceinline__ void load_lds16(const void* g, void* l) {
    __builtin_amdgcn_global_load_lds(
        (const __attribute__((address_space(1))) void*)g,
        (__attribute__((address_space(3))) void*)l, 16, 0, 0);
}

__device__ __forceinline__ unsigned short bf16_bits(float f) {
    __hip_bfloat16 h = __float2bfloat16(f);
    return *reinterpret_cast<unsigned short*>(&h);
}

__device__ __forceinline__ float bfbits2f(unsigned short u) {
    union { unsigned int i; float f; } c;
    c.i = ((unsigned int)u) << 16;
    return c.f;
}

__device__ __forceinline__ uint4 pack8_bf16(const float* f) {
    union { unsigned short u[8]; uint4 v; } r;
#pragma unroll
    for (int i = 0; i < 8; ++i) r.u[i] = bf16_bits(f[i]);
    return r.v;
}

// ---------------- RMSNorm: one block (256 thr) per row of 1024; bf16 out -----
struct alignas(8) bh4 { __hip_bfloat16 a, b, c, d; };

__global__ __launch_bounds__(256) void rmsnorm_k(const float* __restrict__ in,
                                                 __hip_bfloat16* __restrict__ out) {
    const long row = blockIdx.x;
    const int tid = threadIdx.x;
    const float4 x = *(const float4*)(in + row * DDIM + tid * 4);
    float ss = x.x * x.x + x.y * x.y + x.z * x.z + x.w * x.w;
    ss += __shfl_xor(ss, 1);
    ss += __shfl_xor(ss, 2);
    ss += __shfl_xor(ss, 4);
    ss += __shfl_xor(ss, 8);
    ss += __shfl_xor(ss, 16);
    ss += __shfl_xor(ss, 32);
    __shared__ float wsum[4];
    if ((tid & 63) == 0) wsum[tid >> 6] = ss;
    __syncthreads();
    const float tot = wsum[0] + wsum[1] + wsum[2] + wsum[3];
    const float sc = rsqrtf(tot * (1.0f / (float)DDIM) + 1e-6f);
    bh4 y;
    y.a = __float2bfloat16(x.x * sc);
    y.b = __float2bfloat16(x.y * sc);
    y.c = __float2bfloat16(x.z * sc);
    y.d = __float2bfloat16(x.w * sc);
    *(bh4*)(out + row * DDIM + tid * 4) = y;
}

// ------------- transpose + f32->bf16: W[K,N] -> Wt[N,K] -------------
__global__ __launch_bounds__(256) void transpose_cvt(const float* __restrict__ W,
                                                     __hip_bfloat16* __restrict__ Wt,
                                                     int K, int N) {
    __shared__ float t[32][33];
    const int n0 = blockIdx.x * 32, k0 = blockIdx.y * 32;
    const int tx = threadIdx.x & 31, ty = threadIdx.x >> 5;  // ty 0..7
#pragma unroll
    for (int i = 0; i < 4; ++i)
        t[ty * 4 + i][tx] = W[(long)(k0 + ty * 4 + i) * N + n0 + tx];
    __syncthreads();
#pragma unroll
    for (int i = 0; i < 4; ++i)
        Wt[(long)(n0 + ty * 4 + i) * K + k0 + tx] = __float2bfloat16(t[tx][ty * 4 + i]);
}

// ---------------- bf16 MFMA GEMM: C[M,N] = A[M,K] @ Bt[N,K]^T -------
// MODE 0: f32 out. MODE 1: f32 out + f32 resid. MODE 2: bf16 out.
template <int MODE>
__global__ __launch_bounds__(256) void gemm_bf16(const __hip_bfloat16* __restrict__ A,
                                                 const __hip_bfloat16* __restrict__ Bt,
                                                 const float* __restrict__ resid,
                                                 void* __restrict__ Cout,
                                                 int M, int N, int K) {
    __shared__ __align__(16) short As[128 * 32];
    __shared__ __align__(16) short Bs[128 * 32];
    const int tid = threadIdx.x;
    const int w = tid >> 6, l = tid & 63;
    const int m0 = blockIdx.y * 128, n0 = blockIdx.x * 128;
    const int srow = (w << 4) + (l >> 2);
    const int skcol = (l & 3) * 8;
    const int wr = w >> 1, wc = w & 1;
    const int fr = l & 15;
    const int fkB = (l >> 4) * 16;

    f32x4 acc[4][4];
#pragma unroll
    for (int m = 0; m < 4; ++m)
#pragma unroll
        for (int n = 0; n < 4; ++n) acc[m][n] = (f32x4)0.0f;

    const __hip_bfloat16* Abase = A + (long)m0 * K + skcol;
    const __hip_bfloat16* Bbase = Bt + (long)n0 * K + skcol;

    for (int k0 = 0; k0 < K; k0 += 32) {
#pragma unroll
        for (int j = 0; j < 2; ++j) {
            const int row = srow + j * 64;
            load_lds16(Abase + (long)row * K + k0, (char*)As + w * 1024 + j * 4096);
            load_lds16(Bbase + (long)row * K + k0, (char*)Bs + w * 1024 + j * 4096);
        }
        __syncthreads();
        bf16x8 av[4], bv[4];
#pragma unroll
        for (int m = 0; m < 4; ++m) {
            av[m] = *(const bf16x8*)((char*)As + (wr * 64 + m * 16 + fr) * 64 + fkB);
            bv[m] = *(const bf16x8*)((char*)Bs + (wc * 64 + m * 16 + fr) * 64 + fkB);
        }
#pragma unroll
        for (int m = 0; m < 4; ++m)
#pragma unroll
            for (int n = 0; n < 4; ++n)
                acc[m][n] = __builtin_amdgcn_mfma_f32_16x16x32_bf16(av[m], bv[n], acc[m][n], 0, 0, 0);
        __syncthreads();
    }

    const int r0 = (l >> 4) * 4;
    const int cc = l & 15;
#pragma unroll
    for (int m = 0; m < 4; ++m) {
#pragma unroll
        for (int r = 0; r < 4; ++r) {
            const long row = m0 + wr * 64 + m * 16 + r0 + r;
            const long colb = n0 + wc * 64 + cc;
            if (MODE == 2) {
                __hip_bfloat16* cb = (__hip_bfloat16*)Cout + row * N + colb;
#pragma unroll
                for (int n = 0; n < 4; ++n)
                    cb[n * 16] = __float2bfloat16(acc[m][n][r]);
            } else {
                float* cp = (float*)Cout + row * N + colb;
                const float* rp = resid + row * N + colb;
#pragma unroll
                for (int n = 0; n < 4; ++n) {
                    float v = acc[m][n][r];
                    if (MODE == 1) v += rp[n * 16];
                    cp[n * 16] = v;
                }
            }
        }
    }
}

// ---- dual-B MFMA GEMM for SwiGLU: H = bf16( silu(A@Wg^T) * (A@Wu^T) ) ------
__global__ __launch_bounds__(256) void gemm_gateup_bf16(const __hip_bfloat16* __restrict__ A,
                                                        const __hip_bfloat16* __restrict__ Bg,
                                                        const __hip_bfloat16* __restrict__ Bu,
                                                        __hip_bfloat16* __restrict__ Hb,
                                                        int M, int N, int K) {
    __shared__ __align__(16) short As[128 * 32];
    __shared__ __align__(16) short Bgs[128 * 32];
    __shared__ __align__(16) short Bus[128 * 32];
    const int tid = threadIdx.x;
    const int w = tid >> 6, l = tid & 63;
    const int m0 = blockIdx.y * 128, n0 = blockIdx.x * 128;
    const int srow = (w << 4) + (l >> 2);
    const int skcol = (l & 3) * 8;
    const int wr = w >> 1, wc = w & 1;
    const int fr = l & 15;
    const int fkB = (l >> 4) * 16;

    f32x4 accg[4][4], accu[4][4];
#pragma unroll
    for (int m = 0; m < 4; ++m)
#pragma unroll
        for (int n = 0; n < 4; ++n) { accg[m][n] = (f32x4)0.0f; accu[m][n] = (f32x4)0.0f; }

    const __hip_bfloat16* Abase = A + (long)m0 * K + skcol;
    const __hip_bfloat16* Bgb = Bg + (long)n0 * K + skcol;
    const __hip_bfloat16* Bub = Bu + (long)n0 * K + skcol;

    for (int k0 = 0; k0 < K; k0 += 32) {
#pragma unroll
        for (int j = 0; j < 2; ++j) {
            const int row = srow + j * 64;
            load_lds16(Abase + (long)row * K + k0, (char*)As + w * 1024 + j * 4096);
            load_lds16(Bgb + (long)row * K + k0, (char*)Bgs + w * 1024 + j * 4096);
            load_lds16(Bub + (long)row * K + k0, (char*)Bus + w * 1024 + j * 4096);
        }
        __syncthreads();
        bf16x8 av[4], bgv[4], buv[4];
#pragma unroll
        for (int m = 0; m < 4; ++m) {
            av[m] = *(const bf16x8*)((char*)As + (wr * 64 + m * 16 + fr) * 64 + fkB);
            bgv[m] = *(const bf16x8*)((char*)Bgs + (wc * 64 + m * 16 + fr) * 64 + fkB);
            buv[m] = *(const bf16x8*)((char*)Bus + (wc * 64 + m * 16 + fr) * 64 + fkB);
        }
#pragma unroll
        for (int m = 0; m < 4; ++m)
#pragma unroll
            for (int n = 0; n < 4; ++n) {
                accg[m][n] = __builtin_amdgcn_mfma_f32_16x16x32_bf16(av[m], bgv[n], accg[m][n], 0, 0, 0);
                accu[m][n] = __builtin_amdgcn_mfma_f32_16x16x32_bf16(av[m], buv[n], accu[m][n], 0, 0, 0);
            }
        __syncthreads();
    }

    const int r0 = (l >> 4) * 4;
    const int cc = l & 15;
#pragma unroll
    for (int m = 0; m < 4; ++m) {
#pragma unroll
        for (int r = 0; r < 4; ++r) {
            const long row = m0 + wr * 64 + m * 16 + r0 + r;
            __hip_bfloat16* hp = Hb + row * N + n0 + wc * 64 + cc;
#pragma unroll
            for (int n = 0; n < 4; ++n)
                hp[n * 16] = __float2bfloat16(silu_f(accg[m][n][r]) * accu[m][n][r]);
        }
    }
}

// ------- beta/alpha: inline rmsnorm (scale folds out of the dot) -------
__global__ __launch_bounds__(64) void ba_kernel(const float* __restrict__ x,
                                                const float* __restrict__ wb,
                                                const float* __restrict__ wg,
                                                float* __restrict__ beta,
                                                float* __restrict__ alpha) {
    const long row = blockIdx.x;
    const int tid = threadIdx.x;
    const int o = tid >> 2;
    const int p = tid & 3;
    const float* w = (o < 8) ? (wb + o) : (wg + (o - 8));
    const float* xr = x + row * DDIM + p * 256;
    const float* wr = w + (long)(p * 256) * HHEADS;
    float acc = 0.0f, ss = 0.0f;
#pragma unroll 8
    for (int i = 0; i < 256; ++i) {
        const float xv = xr[i];
        ss = fmaf(xv, xv, ss);
        acc = fmaf(xv, wr[(long)i * HHEADS], acc);
    }
    acc += __shfl_xor(acc, 1);
    acc += __shfl_xor(acc, 2);
    ss += __shfl_xor(ss, 1);
    ss += __shfl_xor(ss, 2);
    if (p == 0) {
        const float sc = rsqrtf(ss * (1.0f / (float)DDIM) + 1e-6f);
        const float val = 1.0f / (1.0f + expf(-acc * sc));
        if (o < 8) beta[row * HHEADS + o] = val;
        else       alpha[row * HHEADS + (o - 8)] = val;
    }
}

// ------- post-projection (bf16 in-place): silu + l2norm on q,k; silu on v ----
__global__ __launch_bounds__(64) void postqkv(__hip_bfloat16* __restrict__ q,
                                              __hip_bfloat16* __restrict__ k,
                                              __hip_bfloat16* __restrict__ v) {
    const long r = blockIdx.x;
    const int tid = threadIdx.x;
    {
        unsigned int* qp = (unsigned int*)(q + r * DHEAD + tid * 2);
        const unsigned int wbits = *qp;
        float y0 = silu_f(bfbits2f(wbits & 0xffff));
        float y1 = silu_f(bfbits2f(wbits >> 16));
        float ss = y0 * y0 + y1 * y1;
        ss += __shfl_xor(ss, 1);  ss += __shfl_xor(ss, 2);
        ss += __shfl_xor(ss, 4);  ss += __shfl_xor(ss, 8);
        ss += __shfl_xor(ss, 16); ss += __shfl_xor(ss, 32);
        const float sc = rsqrtf(ss + 1e-6f);
        *qp = (unsigned int)bf16_bits(y0 * sc) | ((unsigned int)bf16_bits(y1 * sc) << 16);
    }
    {
        unsigned int* kp = (unsigned int*)(k + r * DHEAD + tid * 2);
        const unsigned int wbits = *kp;
        float y0 = silu_f(bfbits2f(wbits & 0xffff));
        float y1 = silu_f(bfbits2f(wbits >> 16));
        float ss = y0 * y0 + y1 * y1;
        ss += __shfl_xor(ss, 1);  ss += __shfl_xor(ss, 2);
        ss += __shfl_xor(ss, 4);  ss += __shfl_xor(ss, 8);
        ss += __shfl_xor(ss, 16); ss += __shfl_xor(ss, 32);
        const float sc = rsqrtf(ss + 1e-6f);
        *kp = (unsigned int)bf16_bits(y0 * sc) | ((unsigned int)bf16_bits(y1 * sc) << 16);
    }
    {
        unsigned int* vp = (unsigned int*)(v + r * DHEAD + tid * 2);
        const unsigned int wbits = *vp;
        *vp = (unsigned int)bf16_bits(silu_f(bfbits2f(wbits & 0xffff)))
            | ((unsigned int)bf16_bits(silu_f(bfbits2f(wbits >> 16))) << 16);
    }
}

// ============ Chunked gated delta rule (log-space decay) ============
// G_t = sum_{s<=t} log(a_s) within chunk; ratio(t,s)=exp(G_t-G_s)<=1 for s<=t.
//   dv = dv0 + R @ S0,   R = -Tinv @ diag(b_s e^{G_s}) @ K   (precomputed)
//   dv0 = Tinv @ (b (.) v)                                    (precomputed)
//   o_t = e^{G_t} (S0^T q_t) + (M @ dv)_t                     (M precomputed)
//   S_end = e^{G63} S0 + K^T @ diag(e^{G63-G_t}) dv

// --------- Phase A (parallel over bh x chunk): G, M, R, K^T, dv0 ------------
__global__ __launch_bounds__(256) void chunk_prep(
    const __hip_bfloat16* __restrict__ kb, const __hip_bfloat16* __restrict__ qb,
    const __hip_bfloat16* __restrict__ vb, const float* __restrict__ betab,
    const float* __restrict__ alphab, float* __restrict__ Gcum,
    __hip_bfloat16* __restrict__ Rg, __hip_bfloat16* __restrict__ Ktg,
    __hip_bfloat16* __restrict__ dvX, __hip_bfloat16* __restrict__ Mmat)
{
    const int bh = blockIdx.x >> 5;
    const int c  = blockIdx.x & 31;
    const int b = bh >> 3, h = bh & 7;
    const int tid = threadIdx.x;

    __shared__ __align__(16) __hip_bfloat16 tA[64][136];   // k chunk
    __shared__ __align__(16) __hip_bfloat16 tB[64][136];   // q chunk, later b*v
    __shared__ __hip_bfloat16 Wl[64][66];
    __shared__ float Ti[64][65];
    __shared__ float sa[64], sb_[64], sG[64], swB[64];

    const long row0 = (long)b * TLEN + (long)c * CS;
    const long chnk = (long)bh * NC + c;

    if (tid < 64) {
        sa[tid]  = alphab[(row0 + tid) * HHEADS + h];
        sb_[tid] = betab[(row0 + tid) * HHEADS + h];
    }
    // load k,q chunks (bf16 direct copies)
    {
        const int r = tid >> 2;
        const int d0 = (tid & 3) * 32;
        const uint4* kp = (const uint4*)(kb + (row0 + r) * DDIM + h * DHEAD + d0);
        const uint4* qp = (const uint4*)(qb + (row0 + r) * DDIM + h * DHEAD + d0);
#pragma unroll
        for (int i = 0; i < 4; ++i) {
            *(uint4*)&tA[r][d0 + i * 8] = kp[i];
            *(uint4*)&tB[r][d0 + i * 8] = qp[i];
        }
    }
    __syncthreads();
    if (tid == 0) {
        float run = 0.0f;
        for (int t = 0; t < CS; ++t) { run += logf(sa[t]); sG[t] = run; }
    }
    __syncthreads();
    if (tid < 64) {
        Gcum[chnk * CS + tid] = sG[tid];
        swB[tid] = sb_[tid] * expf(sG[tid]);
    }
    __syncthreads();

    // W[t][s] (s<t) and M[t][s] (s<=t)
    {
        const int t = tid >> 2;
        const int s0 = (tid & 3) * 16;
        float accW[16], accM[16];
#pragma unroll
        for (int i = 0; i < 16; ++i) { accW[i] = 0.0f; accM[i] = 0.0f; }
        for (int d = 0; d < DHEAD; ++d) {
            const float at = __bfloat162float(tA[t][d]);
            const float bt = __bfloat162float(tB[t][d]);
#pragma unroll
            for (int i = 0; i < 16; ++i) {
                const float ks = __bfloat162float(tA[s0 + i][d]);
                accW[i] = fmaf(at, ks, accW[i]);
                accM[i] = fmaf(bt, ks, accM[i]);
            }
        }
        const float btc = sb_[t], Gt = sG[t];
        float mrow[16];
#pragma unroll
        for (int i = 0; i < 16; ++i) {
            const int s = s0 + i;
            const float ratio = (s <= t) ? expf(Gt - sG[s]) : 0.0f;  // <= 1
            Wl[t][s] = __float2bfloat16((s < t) ? btc * ratio * accW[i] : 0.0f);
            mrow[i] = ratio * accM[i];
        }
        __hip_bfloat16* mp = Mmat + (chnk * CS + t) * CS + s0;
        *(uint4*)(mp)     = pack8_bf16(&mrow[0]);
        *(uint4*)(mp + 8) = pack8_bf16(&mrow[8]);
    }
    __syncthreads();

    // Ti = (I+W)^-1 via forward elimination
    {
        const int t = tid >> 2, j0 = (tid & 3) * 16;
#pragma unroll
        for (int i = 0; i < 16; ++i) Ti[t][j0 + i] = (t == j0 + i) ? 1.0f : 0.0f;
    }
    __syncthreads();
    for (int s = 0; s < CS - 1; ++s) {
        const int t = tid & 63, jq = tid >> 6;
        if (t > s) {
            const float wt = -__bfloat162float(Wl[t][s]);
            const int jlo = jq * 16;
            const int jhi = min(s, jlo + 15);
            for (int j = jlo; j <= jhi; ++j)
                Ti[t][j] = fmaf(wt, Ti[s][j], Ti[t][j]);
        }
        __syncthreads();
    }

    // R[t][kk] = -sum_s Ti[t][s] * swB[s] * K[s][kk]   (bf16 out)
    {
        const int t = tid >> 2, j0 = (tid & 3) * 32;
        float acc[32];
#pragma unroll
        for (int j = 0; j < 32; ++j) acc[j] = 0.0f;
        for (int s = 0; s <= t; ++s) {
            const float cf = -Ti[t][s] * swB[s];
#pragma unroll
            for (int j = 0; j < 32; ++j)
                acc[j] = fmaf(cf, __bfloat162float(tA[s][j0 + j]), acc[j]);
        }
        __hip_bfloat16* rp = Rg + (chnk * CS + t) * DHEAD + j0;
#pragma unroll
        for (int i = 0; i < 4; ++i)
            *(uint4*)(rp + i * 8) = pack8_bf16(&acc[i * 8]);
    }

    // K^T: Ktg[kk][t] = K[t][kk]
    {
        const int kk = tid >> 1;
        const int t0 = (tid & 1) * 32;
        __hip_bfloat16* kp = Ktg + (chnk * DHEAD + kk) * CS + t0;
        float f[8];
#pragma unroll
        for (int i = 0; i < 4; ++i) {
#pragma unroll
            for (int j2 = 0; j2 < 8; ++j2)
                f[j2] = __bfloat162float(tA[t0 + i * 8 + j2][kk]);
            *(uint4*)(kp + i * 8) = pack8_bf16(f);
        }
    }

    // load b*v into tB
    {
        const int r = tid >> 2, d0 = (tid & 3) * 32;
        const float br = sb_[r];
        const uint4* vp = (const uint4*)(vb + (row0 + r) * DDIM + h * DHEAD + d0);
#pragma unroll
        for (int i = 0; i < 4; ++i) {
            const uint4 vv = vp[i];
            const unsigned short* u = (const unsigned short*)&vv;
            float f[8];
#pragma unroll
            for (int j = 0; j < 8; ++j) f[j] = br * bfbits2f(u[j]);
            *(uint4*)&tB[r][d0 + i * 8] = pack8_bf16(f);
        }
    }
    __syncthreads();

    // dv0 = Ti @ (b*v) -> dvX (bf16)
    {
        const int t = tid >> 2, j0 = (tid & 3) * 32;
        float acc[32];
#pragma unroll
        for (int j = 0; j < 32; ++j) acc[j] = 0.0f;
        for (int s = 0; s < CS; ++s) {
            const float ti = Ti[t][s];
#pragma unroll
            for (int j = 0; j < 32; ++j)
                acc[j] = fmaf(ti, __bfloat162float(tB[s][j0 + j]), acc[j]);
        }
        __hip_bfloat16* dp = dvX + (chnk * CS + t) * DHEAD + j0;
#pragma unroll
        for (int i = 0; i < 4; ++i)
            *(uint4*)(dp + i * 8) = pack8_bf16(&acc[i * 8]);
    }
}

// --------- Phase B: sequential over chunks; MFMA; 128 blocks ----------------
// Grid 16*SEQGV; bh = blockIdx.x & 15 (same-bh blocks share an XCD for L2
// reuse of R/Kt), g = blockIdx.x >> 4 selects 16 v-columns.
// Per block state: S[128 kk][16 j] as 2 MFMA C-fragments (8 f32/thread).
// LDS (bytes): R[2] 0/17408, Kt[2] 34816+18432*buf, dvT 71680 (16x72),
//              Stl 73984 (16x136, Stl[j][kk]), sG 78336 (2x64 f32). Total 78848.
#define SEQGV 8
#define SEQ_LDS_BYTES 78848

__global__ __launch_bounds__(256) void chunk_seq_mfma(
    const float* __restrict__ S0in, const float* __restrict__ Gcum,
    const __hip_bfloat16* __restrict__ Rg, const __hip_bfloat16* __restrict__ Ktg,
    __hip_bfloat16* __restrict__ dvX, __hip_bfloat16* __restrict__ Ssnap,
    float* __restrict__ Sout)
{
    const int bh = blockIdx.x & 15;
    const int g  = blockIdx.x >> 4;
    const int j0 = g * 16;
    const int tid = threadIdx.x;
    const int w = tid >> 6;
    const int l = tid & 63;
    const int fr = l & 15;
    const int fk8 = (l >> 4) * 8;
    const int rq = (l >> 4) * 4;

    __shared__ __align__(16) char smem[SEQ_LDS_BYTES];
    __hip_bfloat16* dvT = (__hip_bfloat16*)(smem + 71680);   // [16 j][72 t]
    __hip_bfloat16* Stl = (__hip_bfloat16*)(smem + 73984);   // [16 j][136 kk]
    float* sG = (float*)(smem + 78336);

    // ---- init: master S fragments (rows kk, cols j) + bf16 mirror S^T ----
    f32x4 SM[2];
#pragma unroll
    for (int mj = 0; mj < 2; ++mj) {
#pragma unroll
        for (int r = 0; r < 4; ++r) {
            const int kk = w * 32 + mj * 16 + rq + r;
            const float v = S0in[((long)bh * 128 + kk) * 128 + j0 + fr];
            SM[mj][r] = v;
            Stl[fr * 136 + kk] = __float2bfloat16(v);
        }
    }

    // ---- staging ----
    uint4 rreg[4], kreg[4];
    float greg = 0.0f;

#define SEQ_STAGE_LOAD(c_) do {                                                   \
        const long cb_ = (long)bh * NC + (c_);                                    \
        _Pragma("unroll")                                                         \
        for (int i_ = 0; i_ < 4; ++i_) {                                          \
            const int ur_ = (tid << 2) + i_;                                      \
            rreg[i_] = *(const uint4*)(Rg + (cb_ * CS + (ur_ >> 4)) * DHEAD + ((ur_ & 15) << 3)); \
            kreg[i_] = *(const uint4*)(Ktg + (cb_ * DHEAD + (ur_ >> 3)) * CS + ((ur_ & 7) << 3)); \
        }                                                                         \
        if (tid < 64) greg = Gcum[cb_ * CS + tid];                                \
    } while (0)

#define SEQ_STAGE_WRITE(bufi_) do {                                               \
        __hip_bfloat16* rb_ = (__hip_bfloat16*)(smem + (bufi_) * 17408);          \
        __hip_bfloat16* kb2_ = (__hip_bfloat16*)(smem + 34816 + (bufi_) * 18432); \
        _Pragma("unroll")                                                         \
        for (int i_ = 0; i_ < 4; ++i_) {                                          \
            const int ur_ = (tid << 2) + i_;                                      \
            *(uint4*)(rb_ + (ur_ >> 4) * 136 + ((ur_ & 15) << 3)) = rreg[i_];     \
            *(uint4*)(kb2_ + (ur_ >> 3) * 72 + ((ur_ & 7) << 3)) = kreg[i_];      \
        }                                                                         \
        if (tid < 64) sG[(bufi_) * 64 + tid] = greg;                              \
    } while (0)

    SEQ_STAGE_LOAD(0);
    SEQ_STAGE_WRITE(0);
    __syncthreads();

    for (int c = 0; c < NC; ++c) {
        const int cur = c & 1;
        const long chnk = (long)bh * NC + c;
        const __hip_bfloat16* Rl = (const __hip_bfloat16*)(smem + cur * 17408);
        const __hip_bfloat16* Ktl = (const __hip_bfloat16*)(smem + 34816 + cur * 18432);
        const float g63 = sG[cur * 64 + 63];
        const float a63 = expf(g63);

        // dv0 prefetch (this lane's 4 elements; same addresses overwritten below)
        unsigned short d0r[4];
#pragma unroll
        for (int r = 0; r < 4; ++r) {
            const int t = w * 16 + rq + r;
            d0r[r] = *(const unsigned short*)(dvX + (chnk * CS + t) * DHEAD + j0 + fr);
        }

        if (c + 1 < NC) SEQ_STAGE_LOAD(c + 1);

        // snapshot chunk-initial S^T slice -> Ssnap[chnk][j0+j][kk]
        {
            const int j = tid >> 4, k0 = (tid & 15) * 8;
            const uint4 v = *(const uint4*)&Stl[j * 136 + k0];
            *(uint4*)(Ssnap + (chnk * 128 + j0 + j) * 128 + k0) = v;
        }

        // ---- step A: dv[64 t][16 j] = dv0 + R @ S  (per wave: 1 t-tile) ----
        f32x4 acc = (f32x4)0.0f;
#pragma unroll
        for (int ks = 0; ks < 4; ++ks) {
            const bf16x8 bfrag = *(const bf16x8*)&Stl[fr * 136 + ks * 32 + fk8];
            const bf16x8 afrag = *(const bf16x8*)&Rl[(w * 16 + fr) * 136 + ks * 32 + fk8];
            acc = __builtin_amdgcn_mfma_f32_16x16x32_bf16(afrag, bfrag, acc, 0, 0, 0);
        }
        // epi A: add dv0, store dv (global), write scaled dv^T to LDS
#pragma unroll
        for (int r = 0; r < 4; ++r) {
            const int t = w * 16 + rq + r;
            const float rk = expf(g63 - sG[cur * 64 + t]);
            const float dv = acc[r] + bfbits2f(d0r[r]);
            *(unsigned short*)(dvX + (chnk * CS + t) * DHEAD + j0 + fr) = bf16_bits(dv);
            dvT[fr * 72 + t] = __float2bfloat16(rk * dv);
        }

        if (c + 1 < NC) SEQ_STAGE_WRITE(cur ^ 1);
        __syncthreads();   // dvT + next-chunk staging visible

        // ---- step B: S' = a63*S + K^T @ dvs  (per wave: 2 kk-tiles) ----
#pragma unroll
        for (int mj = 0; mj < 2; ++mj) SM[mj] *= a63;
#pragma unroll
        for (int ks = 0; ks < 2; ++ks) {
            const bf16x8 bfrag = *(const bf16x8*)&dvT[fr * 72 + ks * 32 + fk8];
#pragma unroll
            for (int mj = 0; mj < 2; ++mj) {
                const bf16x8 afrag = *(const bf16x8*)&Ktl[(w * 32 + mj * 16 + fr) * 72 + ks * 32 + fk8];
                SM[mj] = __builtin_amdgcn_mfma_f32_16x16x32_bf16(afrag, bfrag, SM[mj], 0, 0, 0);
            }
        }
        // epi B: refresh bf16 mirror
#pragma unroll
        for (int mj = 0; mj < 2; ++mj)
#pragma unroll
            for (int r = 0; r < 4; ++r) {
                const int kk = w * 32 + mj * 16 + rq + r;
                Stl[fr * 136 + kk] = __float2bfloat16(SM[mj][r]);
            }
        __syncthreads();   // Stl stable for next chunk's snapshot/step A
    }

    // ---- final state ----
#pragma unroll
    for (int mj = 0; mj < 2; ++mj)
#pragma unroll
        for (int r = 0; r < 4; ++r) {
            const int kk = w * 32 + mj * 16 + rq + r;
            Sout[((long)bh * 128 + kk) * 128 + j0 + fr] = SM[mj][r];
        }
#undef SEQ_STAGE_LOAD
#undef SEQ_STAGE_WRITE
}

// --------- Phase C (parallel): o = e^{G_t}*(q_t @ S0snap) + M @ dv ----------
// Ssnap layout: [chnk][j][kk] = S0^T
__global__ __launch_bounds__(256) void chunk_out(
    const __hip_bfloat16* __restrict__ qb, const float* __restrict__ Gcum,
    const __hip_bfloat16* __restrict__ dvX, const __hip_bfloat16* __restrict__ Ssnap,
    const __hip_bfloat16* __restrict__ Mmat, __hip_bfloat16* __restrict__ ob)
{
    const int bh = blockIdx.x >> 5;
    const int c  = blockIdx.x & 31;
    const int b = bh >> 3, h = bh & 7;
    const int tid = threadIdx.x;
    const long row0 = (long)b * TLEN + (long)c * CS;
    const long chnk = (long)bh * NC + c;

    __shared__ __align__(16) __hip_bfloat16 Ssn[128][136];   // [j][kk]
    __shared__ __align__(16) __hip_bfloat16 dvq[64][136];    // dv, later q
    __shared__ __align__(16) __hip_bfloat16 Ml[64][72];

    {
        const int j = tid >> 1;
        const int d0 = (tid & 1) * 64;
        const uint4* sp = (const uint4*)(Ssnap + (chnk * 128 + j) * 128 + d0);
#pragma unroll
        for (int i = 0; i < 8; ++i)
            *(uint4*)&Ssn[j][d0 + i * 8] = sp[i];
    }
    {
        const int t = tid >> 2;
        const int s0 = (tid & 3) * 32;
        const uint4* dp = (const uint4*)(dvX + (chnk * CS + t) * DHEAD + s0);
#pragma unroll
        for (int i = 0; i < 4; ++i)
            *(uint4*)&dvq[t][s0 + i * 8] = dp[i];
    }
    {
        const int t = tid >> 2;
        const int s0 = (tid & 3) * 16;
        const uint4* mp = (const uint4*)(Mmat + (chnk * CS + t) * CS + s0);
        *(uint4*)&Ml[t][s0]     = mp[0];
        *(uint4*)&Ml[t][s0 + 8] = mp[1];
    }
    __syncthreads();

    const int t = tid >> 2;
    const int j0l = (tid & 3) * 32;
    float acc[32];
#pragma unroll
    for (int j = 0; j < 32; ++j) acc[j] = 0.0f;

    // part 1: M @ dv
    for (int s = 0; s < CS; ++s) {
        const float m = __bfloat162float(Ml[t][s]);
#pragma unroll
        for (int j = 0; j < 32; ++j)
            acc[j] = fmaf(m, __bfloat162float(dvq[s][j0l + j]), acc[j]);
    }
    __syncthreads();

    // load q chunk into dvq
    {
        const int r = tid >> 2, d0 = (tid & 3) * 32;
        const uint4* qp = (const uint4*)(qb + (row0 + r) * DDIM + h * DHEAD + d0);
#pragma unroll
        for (int i = 0; i < 4; ++i)
            *(uint4*)&dvq[r][d0 + i * 8] = qp[i];
    }
    __syncthreads();

    // part 2: + e^{G_t} * (q_t @ S0)   with S0[kk][j] = Ssn[j][kk]
    const float At = expf(Gcum[chnk * CS + t]);
    for (int kk = 0; kk < 128; ++kk) {
        const float qv = At * __bfloat162float(dvq[t][kk]);
#pragma unroll
        for (int j = 0; j < 32; ++j)
            acc[j] = fmaf(qv, __bfloat162float(Ssn[j0l + j][kk]), acc[j]);
    }

    __hip_bfloat16* op = ob + (row0 + t) * DDIM + h * DHEAD + j0l;
#pragma unroll
    for (int i = 0; i < 4; ++i)
        *(uint4*)(op + i * 8) = pack8_bf16(&acc[i * 8]);
}

extern "C" void kernel_launch(void* const* d_in, const int* in_sizes, int n_in,
                              void* d_out, int out_size, void* d_ws, size_t ws_size,
                              hipStream_t stream) {
    const float* x     = (const float*)d_in[0];
    const float* S0    = (const float*)d_in[1];
    const float* wq    = (const float*)d_in[2];
    const float* wk    = (const float*)d_in[3];
    const float* wv    = (const float*)d_in[4];
    const float* wb    = (const float*)d_in[5];
    const float* wg    = (const float*)d_in[6];
    const float* wo    = (const float*)d_in[7];
    const float* wgate = (const float*)d_in[8];
    const float* wup   = (const float*)d_in[9];
    const float* wdown = (const float*)d_in[10];

    const int M = BSZ * TLEN;  // 4096 token rows

    float* out  = (float*)d_out;
    float* Sout = out + (long)M * DDIM;

    // Workspace layout, peak 76.5 MiB (proven budget: 81 MiB).
    char* w = (char*)d_ws;
    const size_t MB = 1u << 20;
    const size_t KB = 1u << 10;
    __hip_bfloat16* qbh   = (__hip_bfloat16*)(w + 0 * MB);             // QKV->chunk_out
    __hip_bfloat16* kbh   = (__hip_bfloat16*)(w + 8 * MB);             // QKV->chunk_prep
    __hip_bfloat16* vbh   = (__hip_bfloat16*)(w + 16 * MB);            // QKV->chunk_prep
    float*          beta  = (float*)(w + 24 * MB);                     // ->prep
    float*          alpha = (float*)(w + 24 * MB + 128 * KB);          // ->prep
    float*          Gcum  = (float*)(w + 24 * MB + 256 * KB);          // ->out
    __hip_bfloat16* Mmat  = (__hip_bfloat16*)(w + 24 * MB + 512 * KB); // prep->out (4MB)
    __hip_bfloat16* dvX   = (__hip_bfloat16*)(w + 28 * MB + 512 * KB); // prep->out (8MB)
    __hip_bfloat16* Rg    = (__hip_bfloat16*)(w + 36 * MB + 512 * KB); // prep->seq (8MB)
    __hip_bfloat16* xnb   = (__hip_bfloat16*)(w + 36 * MB + 512 * KB); // rms1->QKV (dead before Rg)
    __hip_bfloat16* Ktg   = (__hip_bfloat16*)(w + 44 * MB + 512 * KB); // prep->seq (8MB)
    __hip_bfloat16* Ssnap = (__hip_bfloat16*)(w + 52 * MB + 512 * KB); // seq->out (16MB)
    __hip_bfloat16* wqt   = (__hip_bfloat16*)(w + 68 * MB + 512 * KB); // ->QKV (2MB)
    __hip_bfloat16* wkt   = (__hip_bfloat16*)(w + 70 * MB + 512 * KB);
    __hip_bfloat16* wvt   = (__hip_bfloat16*)(w + 72 * MB + 512 * KB);
    __hip_bfloat16* wot   = (__hip_bfloat16*)(w + 74 * MB + 512 * KB); // ->GEMM4 (2MB), peak 76.5
    __hip_bfloat16* obufb = (__hip_bfloat16*)(w + 8 * MB);             // chunk_out->GEMM4 (kbh dead)
    __hip_bfloat16* xn2b  = (__hip_bfloat16*)(w + 8 * MB);             // rms2->gateup (obufb dead)
    __hip_bfloat16* wdt   = (__hip_bfloat16*)(w + 16 * MB);            // ->down (vbh dead)
    __hip_bfloat16* wgt   = (__hip_bfloat16*)(w + 24 * MB + 512 * KB); // after chunk_out (8MB)
    __hip_bfloat16* wut   = (__hip_bfloat16*)(w + 32 * MB + 512 * KB); // after chunk_out (8MB)
    __hip_bfloat16* Hb    = (__hip_bfloat16*)(w + 40 * MB + 512 * KB); // gateup->down (32MB)

    // 0) weight transpose+convert (W[K,N] -> Wt[N,K] bf16)
    transpose_cvt<<<dim3(DDIM / 32, DDIM / 32), 256, 0, stream>>>(wq, wqt, DDIM, DDIM);
    transpose_cvt<<<dim3(DDIM / 32, DDIM / 32), 256, 0, stream>>>(wk, wkt, DDIM, DDIM);
    transpose_cvt<<<dim3(DDIM / 32, DDIM / 32), 256, 0, stream>>>(wv, wvt, DDIM, DDIM);
    transpose_cvt<<<dim3(DDIM / 32, DDIM / 32), 256, 0, stream>>>(wo, wot, DDIM, DDIM);

    // 1) norms / gates
    rmsnorm_k<<<M, 256, 0, stream>>>(x, xnb);
    ba_kernel<<<M, 64, 0, stream>>>(x, wb, wg, beta, alpha);

    // 2) q/k/v projections (bf16 out)
    dim3 gP(DDIM / 128, M / 128);
    gemm_bf16<2><<<gP, 256, 0, stream>>>(xnb, wqt, nullptr, qbh, M, DDIM, DDIM);
    gemm_bf16<2><<<gP, 256, 0, stream>>>(xnb, wkt, nullptr, kbh, M, DDIM, DDIM);
    gemm_bf16<2><<<gP, 256, 0, stream>>>(xnb, wvt, nullptr, vbh, M, DDIM, DDIM);
    postqkv<<<M * HHEADS, 64, 0, stream>>>(qbh, kbh, vbh);

    // 3) chunked delta rule
    chunk_prep<<<16 * NC, 256, 0, stream>>>(kbh, qbh, vbh, beta, alpha, Gcum, Rg, Ktg, dvX, Mmat);
    chunk_seq_mfma<<<16 * SEQGV, 256, 0, stream>>>(S0, Gcum, Rg, Ktg, dvX, Ssnap, Sout);
    chunk_out<<<16 * NC, 256, 0, stream>>>(qbh, Gcum, dvX, Ssnap, Mmat, obufb);

    // 4) x1 = x + o @ wo
    gemm_bf16<1><<<gP, 256, 0, stream>>>(obufb, wot, x, out, M, DDIM, DDIM);

    // 4b) remaining weight transposes into now-dead regions
    transpose_cvt<<<dim3(DDIM / 32, FDIM / 32), 256, 0, stream>>>(wdown, wdt, FDIM, DDIM);
    transpose_cvt<<<dim3(FDIM / 32, DDIM / 32), 256, 0, stream>>>(wgate, wgt, DDIM, FDIM);
    transpose_cvt<<<dim3(FDIM / 32, DDIM / 32), 256, 0, stream>>>(wup, wut, DDIM, FDIM);

    // 5) xn2 = rms_norm(x1)
    rmsnorm_k<<<M, 256, 0, stream>>>(out, xn2b);

    // 6) H = silu(xn2 @ w_gate) * (xn2 @ w_up)
    dim3 gGU(FDIM / 128, M / 128);
    gemm_gateup_bf16<<<gGU, 256, 0, stream>>>(xn2b, wgt, wut, Hb, M, FDIM, DDIM);

    // 7) x_out = x1 + H @ w_down
    dim3 gDN(DDIM / 128, M / 128);
    gemm_bf16<1><<<gDN, 256, 0, stream>>>(Hb, wdt, out, out, M, DDIM, FDIM);
}

// Round 7
// 711.789 us; speedup vs baseline: 1.2837x; 1.0948x over previous
//
#include <hip/hip_runtime.h>
#include <hip/hip_bf16.h>
#include <math.h>

// Sizes fixed by the problem: B=2, T=2048, D=1024, F=4096, H=8, DH=128.
#define BSZ 2
#define TLEN 2048
#define DDIM 1024
#define FDIM 4096
#define HHEADS 8
#define DHEAD 128
#define NC 32   // chunks per sequence
#define CS 64   // chunk size (CS*NC == TLEN)

typedef __bf16 bf16x8 __attribute__((ext_vector_type(8)));
typedef float f32x4 __attribute__((ext_vector_type(4)));

__device__ __forceinline__ float silu_f(float x) {
    return x / (1.0f + expf(-x));
}

__device__ __forceinline__ void load_lds16(const void* g, void* l) {
    __builtin_amdgcn_global_load_lds(
        (const __attribute__((address_space(1))) void*)g,
        (__attribute__((address_space(3))) void*)l, 16, 0, 0);
}

__device__ __forceinline__ unsigned short bf16_bits(float f) {
    __hip_bfloat16 h = __float2bfloat16(f);
    return *reinterpret_cast<unsigned short*>(&h);
}

__device__ __forceinline__ float bfbits2f(unsigned short u) {
    union { unsigned int i; float f; } c;
    c.i = ((unsigned int)u) << 16;
    return c.f;
}

__device__ __forceinline__ uint4 pack8_bf16(const float* f) {
    union { unsigned short u[8]; uint4 v; } r;
#pragma unroll
    for (int i = 0; i < 8; ++i) r.u[i] = bf16_bits(f[i]);
    return r.v;
}

// ---------------- RMSNorm: one block (256 thr) per row of 1024; bf16 out -----
struct alignas(8) bh4 { __hip_bfloat16 a, b, c, d; };

__global__ __launch_bounds__(256) void rmsnorm_k(const float* __restrict__ in,
                                                 __hip_bfloat16* __restrict__ out) {
    const long row = blockIdx.x;
    const int tid = threadIdx.x;
    const float4 x = *(const float4*)(in + row * DDIM + tid * 4);
    float ss = x.x * x.x + x.y * x.y + x.z * x.z + x.w * x.w;
    ss += __shfl_xor(ss, 1);
    ss += __shfl_xor(ss, 2);
    ss += __shfl_xor(ss, 4);
    ss += __shfl_xor(ss, 8);
    ss += __shfl_xor(ss, 16);
    ss += __shfl_xor(ss, 32);
    __shared__ float wsum[4];
    if ((tid & 63) == 0) wsum[tid >> 6] = ss;
    __syncthreads();
    const float tot = wsum[0] + wsum[1] + wsum[2] + wsum[3];
    const float sc = rsqrtf(tot * (1.0f / (float)DDIM) + 1e-6f);
    bh4 y;
    y.a = __float2bfloat16(x.x * sc);
    y.b = __float2bfloat16(x.y * sc);
    y.c = __float2bfloat16(x.z * sc);
    y.d = __float2bfloat16(x.w * sc);
    *(bh4*)(out + row * DDIM + tid * 4) = y;
}

// ------------- transpose + f32->bf16: W[K,N] -> Wt[N,K] -------------
__global__ __launch_bounds__(256) void transpose_cvt(const float* __restrict__ W,
                                                     __hip_bfloat16* __restrict__ Wt,
                                                     int K, int N) {
    __shared__ float t[32][33];
    const int n0 = blockIdx.x * 32, k0 = blockIdx.y * 32;
    const int tx = threadIdx.x & 31, ty = threadIdx.x >> 5;  // ty 0..7
#pragma unroll
    for (int i = 0; i < 4; ++i)
        t[ty * 4 + i][tx] = W[(long)(k0 + ty * 4 + i) * N + n0 + tx];
    __syncthreads();
#pragma unroll
    for (int i = 0; i < 4; ++i)
        Wt[(long)(n0 + ty * 4 + i) * K + k0 + tx] = __float2bfloat16(t[tx][ty * 4 + i]);
}

// ---------------- bf16 MFMA GEMM: C[M,N] = A[M,K] @ Bt[N,K]^T -------
// MODE 0: f32 out. MODE 1: f32 out + f32 resid. MODE 2: bf16 out.
template <int MODE>
__global__ __launch_bounds__(256) void gemm_bf16(const __hip_bfloat16* __restrict__ A,
                                                 const __hip_bfloat16* __restrict__ Bt,
                                                 const float* __restrict__ resid,
                                                 void* __restrict__ Cout,
                                                 int M, int N, int K) {
    __shared__ __align__(16) short As[128 * 32];
    __shared__ __align__(16) short Bs[128 * 32];
    const int tid = threadIdx.x;
    const int w = tid >> 6, l = tid & 63;
    const int m0 = blockIdx.y * 128, n0 = blockIdx.x * 128;
    const int srow = (w << 4) + (l >> 2);
    const int skcol = (l & 3) * 8;
    const int wr = w >> 1, wc = w & 1;
    const int fr = l & 15;
    const int fkB = (l >> 4) * 16;

    f32x4 acc[4][4];
#pragma unroll
    for (int m = 0; m < 4; ++m)
#pragma unroll
        for (int n = 0; n < 4; ++n) acc[m][n] = (f32x4)0.0f;

    const __hip_bfloat16* Abase = A + (long)m0 * K + skcol;
    const __hip_bfloat16* Bbase = Bt + (long)n0 * K + skcol;

    for (int k0 = 0; k0 < K; k0 += 32) {
#pragma unroll
        for (int j = 0; j < 2; ++j) {
            const int row = srow + j * 64;
            load_lds16(Abase + (long)row * K + k0, (char*)As + w * 1024 + j * 4096);
            load_lds16(Bbase + (long)row * K + k0, (char*)Bs + w * 1024 + j * 4096);
        }
        __syncthreads();
        bf16x8 av[4], bv[4];
#pragma unroll
        for (int m = 0; m < 4; ++m) {
            av[m] = *(const bf16x8*)((char*)As + (wr * 64 + m * 16 + fr) * 64 + fkB);
            bv[m] = *(const bf16x8*)((char*)Bs + (wc * 64 + m * 16 + fr) * 64 + fkB);
        }
#pragma unroll
        for (int m = 0; m < 4; ++m)
#pragma unroll
            for (int n = 0; n < 4; ++n)
                acc[m][n] = __builtin_amdgcn_mfma_f32_16x16x32_bf16(av[m], bv[n], acc[m][n], 0, 0, 0);
        __syncthreads();
    }

    const int r0 = (l >> 4) * 4;
    const int cc = l & 15;
#pragma unroll
    for (int m = 0; m < 4; ++m) {
#pragma unroll
        for (int r = 0; r < 4; ++r) {
            const long row = m0 + wr * 64 + m * 16 + r0 + r;
            const long colb = n0 + wc * 64 + cc;
            if (MODE == 2) {
                __hip_bfloat16* cb = (__hip_bfloat16*)Cout + row * N + colb;
#pragma unroll
                for (int n = 0; n < 4; ++n)
                    cb[n * 16] = __float2bfloat16(acc[m][n][r]);
            } else {
                float* cp = (float*)Cout + row * N + colb;
                const float* rp = resid + row * N + colb;
#pragma unroll
                for (int n = 0; n < 4; ++n) {
                    float v = acc[m][n][r];
                    if (MODE == 1) v += rp[n * 16];
                    cp[n * 16] = v;
                }
            }
        }
    }
}

// ---- dual-B MFMA GEMM for SwiGLU: H = bf16( silu(A@Wg^T) * (A@Wu^T) ) ------
// Block tile 128x64, 4 waves (2x2), per wave 4x2 fragments per matrix.
// Accumulators: 2 * 4*2 * f32x4 = 64 AGPR (vs 128 before) -> 3 waves/SIMD.
__global__ __launch_bounds__(256) void gemm_gateup_bf16(const __hip_bfloat16* __restrict__ A,
                                                        const __hip_bfloat16* __restrict__ Bg,
                                                        const __hip_bfloat16* __restrict__ Bu,
                                                        __hip_bfloat16* __restrict__ Hb,
                                                        int M, int N, int K) {
    __shared__ __align__(16) short As[128 * 32];   // 8 KB
    __shared__ __align__(16) short Bgs[64 * 32];   // 4 KB
    __shared__ __align__(16) short Bus[64 * 32];   // 4 KB
    const int tid = threadIdx.x;
    const int w = tid >> 6, l = tid & 63;
    const int m0 = blockIdx.y * 128, n0 = blockIdx.x * 64;
    const int srow = (w << 4) + (l >> 2);   // 0..63 (+64 for A's second half)
    const int skcol = (l & 3) * 8;
    const int wr = w >> 1, wc = w & 1;
    const int fr = l & 15;
    const int fkB = (l >> 4) * 16;

    f32x4 accg[4][2], accu[4][2];
#pragma unroll
    for (int m = 0; m < 4; ++m)
#pragma unroll
        for (int n = 0; n < 2; ++n) { accg[m][n] = (f32x4)0.0f; accu[m][n] = (f32x4)0.0f; }

    const __hip_bfloat16* Abase = A + (long)m0 * K + skcol;
    const __hip_bfloat16* Bgb = Bg + (long)n0 * K + skcol;
    const __hip_bfloat16* Bub = Bu + (long)n0 * K + skcol;

    for (int k0 = 0; k0 < K; k0 += 32) {
        // A: 128 rows (2 chunks of 64); Bg/Bu: 64 rows (1 chunk each)
#pragma unroll
        for (int j = 0; j < 2; ++j)
            load_lds16(Abase + (long)(srow + j * 64) * K + k0, (char*)As + w * 1024 + j * 4096);
        load_lds16(Bgb + (long)srow * K + k0, (char*)Bgs + w * 1024);
        load_lds16(Bub + (long)srow * K + k0, (char*)Bus + w * 1024);
        __syncthreads();
        bf16x8 av[4], bgv[2], buv[2];
#pragma unroll
        for (int m = 0; m < 4; ++m)
            av[m] = *(const bf16x8*)((char*)As + (wr * 64 + m * 16 + fr) * 64 + fkB);
#pragma unroll
        for (int n = 0; n < 2; ++n) {
            bgv[n] = *(const bf16x8*)((char*)Bgs + (wc * 32 + n * 16 + fr) * 64 + fkB);
            buv[n] = *(const bf16x8*)((char*)Bus + (wc * 32 + n * 16 + fr) * 64 + fkB);
        }
#pragma unroll
        for (int m = 0; m < 4; ++m)
#pragma unroll
            for (int n = 0; n < 2; ++n) {
                accg[m][n] = __builtin_amdgcn_mfma_f32_16x16x32_bf16(av[m], bgv[n], accg[m][n], 0, 0, 0);
                accu[m][n] = __builtin_amdgcn_mfma_f32_16x16x32_bf16(av[m], buv[n], accu[m][n], 0, 0, 0);
            }
        __syncthreads();
    }

    const int r0 = (l >> 4) * 4;
    const int cc = l & 15;
#pragma unroll
    for (int m = 0; m < 4; ++m) {
#pragma unroll
        for (int r = 0; r < 4; ++r) {
            const long row = m0 + wr * 64 + m * 16 + r0 + r;
            __hip_bfloat16* hp = Hb + row * N + n0 + wc * 32 + cc;
#pragma unroll
            for (int n = 0; n < 2; ++n)
                hp[n * 16] = __float2bfloat16(silu_f(accg[m][n][r]) * accu[m][n][r]);
        }
    }
}

// ------- beta/alpha: inline rmsnorm (scale folds out of the dot) -------
__global__ __launch_bounds__(64) void ba_kernel(const float* __restrict__ x,
                                                const float* __restrict__ wb,
                                                const float* __restrict__ wg,
                                                float* __restrict__ beta,
                                                float* __restrict__ alpha) {
    const long row = blockIdx.x;
    const int tid = threadIdx.x;
    const int o = tid >> 2;
    const int p = tid & 3;
    const float* w = (o < 8) ? (wb + o) : (wg + (o - 8));
    const float* xr = x + row * DDIM + p * 256;
    const float* wr = w + (long)(p * 256) * HHEADS;
    float acc = 0.0f, ss = 0.0f;
#pragma unroll 8
    for (int i = 0; i < 256; ++i) {
        const float xv = xr[i];
        ss = fmaf(xv, xv, ss);
        acc = fmaf(xv, wr[(long)i * HHEADS], acc);
    }
    acc += __shfl_xor(acc, 1);
    acc += __shfl_xor(acc, 2);
    ss += __shfl_xor(ss, 1);
    ss += __shfl_xor(ss, 2);
    if (p == 0) {
        const float sc = rsqrtf(ss * (1.0f / (float)DDIM) + 1e-6f);
        const float val = 1.0f / (1.0f + expf(-acc * sc));
        if (o < 8) beta[row * HHEADS + o] = val;
        else       alpha[row * HHEADS + (o - 8)] = val;
    }
}

// ------- post-projection (bf16 in-place): silu + l2norm on q,k; silu on v ----
__global__ __launch_bounds__(64) void postqkv(__hip_bfloat16* __restrict__ q,
                                              __hip_bfloat16* __restrict__ k,
                                              __hip_bfloat16* __restrict__ v) {
    const long r = blockIdx.x;
    const int tid = threadIdx.x;
    {
        unsigned int* qp = (unsigned int*)(q + r * DHEAD + tid * 2);
        const unsigned int wbits = *qp;
        float y0 = silu_f(bfbits2f(wbits & 0xffff));
        float y1 = silu_f(bfbits2f(wbits >> 16));
        float ss = y0 * y0 + y1 * y1;
        ss += __shfl_xor(ss, 1);  ss += __shfl_xor(ss, 2);
        ss += __shfl_xor(ss, 4);  ss += __shfl_xor(ss, 8);
        ss += __shfl_xor(ss, 16); ss += __shfl_xor(ss, 32);
        const float sc = rsqrtf(ss + 1e-6f);
        *qp = (unsigned int)bf16_bits(y0 * sc) | ((unsigned int)bf16_bits(y1 * sc) << 16);
    }
    {
        unsigned int* kp = (unsigned int*)(k + r * DHEAD + tid * 2);
        const unsigned int wbits = *kp;
        float y0 = silu_f(bfbits2f(wbits & 0xffff));
        float y1 = silu_f(bfbits2f(wbits >> 16));
        float ss = y0 * y0 + y1 * y1;
        ss += __shfl_xor(ss, 1);  ss += __shfl_xor(ss, 2);
        ss += __shfl_xor(ss, 4);  ss += __shfl_xor(ss, 8);
        ss += __shfl_xor(ss, 16); ss += __shfl_xor(ss, 32);
        const float sc = rsqrtf(ss + 1e-6f);
        *kp = (unsigned int)bf16_bits(y0 * sc) | ((unsigned int)bf16_bits(y1 * sc) << 16);
    }
    {
        unsigned int* vp = (unsigned int*)(v + r * DHEAD + tid * 2);
        const unsigned int wbits = *vp;
        *vp = (unsigned int)bf16_bits(silu_f(bfbits2f(wbits & 0xffff)))
            | ((unsigned int)bf16_bits(silu_f(bfbits2f(wbits >> 16))) << 16);
    }
}

// ============ Chunked gated delta rule (log-space decay) ============
// G_t = sum_{s<=t} log(a_s) within chunk; ratio(t,s)=exp(G_t-G_s)<=1 for s<=t.
//   dv = dv0 + R @ S0,   R = -Tinv @ diag(b_s e^{G_s}) @ K   (precomputed)
//   dv0 = Tinv @ (b (.) v)                                    (precomputed)
//   o_t = e^{G_t} (S0^T q_t) + (M @ dv)_t                     (M precomputed)
//   S_end = e^{G63} S0 + K^T @ diag(e^{G63-G_t}) dv

// --------- Phase A (parallel over bh x chunk): G, M, R, K^T, dv0 ------------
__global__ __launch_bounds__(256) void chunk_prep(
    const __hip_bfloat16* __restrict__ kb, const __hip_bfloat16* __restrict__ qb,
    const __hip_bfloat16* __restrict__ vb, const float* __restrict__ betab,
    const float* __restrict__ alphab, float* __restrict__ Gcum,
    __hip_bfloat16* __restrict__ Rg, __hip_bfloat16* __restrict__ Ktg,
    __hip_bfloat16* __restrict__ dvX, __hip_bfloat16* __restrict__ Mmat)
{
    const int bh = blockIdx.x >> 5;
    const int c  = blockIdx.x & 31;
    const int b = bh >> 3, h = bh & 7;
    const int tid = threadIdx.x;

    __shared__ __align__(16) __hip_bfloat16 tA[64][136];   // k chunk
    __shared__ __align__(16) __hip_bfloat16 tB[64][136];   // q chunk, later b*v
    __shared__ __hip_bfloat16 Wl[64][66];
    __shared__ float Ti[64][65];
    __shared__ float sa[64], sb_[64], sG[64], swB[64];

    const long row0 = (long)b * TLEN + (long)c * CS;
    const long chnk = (long)bh * NC + c;

    if (tid < 64) {
        sa[tid]  = alphab[(row0 + tid) * HHEADS + h];
        sb_[tid] = betab[(row0 + tid) * HHEADS + h];
    }
    // load k,q chunks (bf16 direct copies)
    {
        const int r = tid >> 2;
        const int d0 = (tid & 3) * 32;
        const uint4* kp = (const uint4*)(kb + (row0 + r) * DDIM + h * DHEAD + d0);
        const uint4* qp = (const uint4*)(qb + (row0 + r) * DDIM + h * DHEAD + d0);
#pragma unroll
        for (int i = 0; i < 4; ++i) {
            *(uint4*)&tA[r][d0 + i * 8] = kp[i];
            *(uint4*)&tB[r][d0 + i * 8] = qp[i];
        }
    }
    __syncthreads();
    if (tid == 0) {
        float run = 0.0f;
        for (int t = 0; t < CS; ++t) { run += logf(sa[t]); sG[t] = run; }
    }
    __syncthreads();
    if (tid < 64) {
        Gcum[chnk * CS + tid] = sG[tid];
        swB[tid] = sb_[tid] * expf(sG[tid]);
    }
    __syncthreads();

    // W[t][s] (s<t) and M[t][s] (s<=t)
    {
        const int t = tid >> 2;
        const int s0 = (tid & 3) * 16;
        float accW[16], accM[16];
#pragma unroll
        for (int i = 0; i < 16; ++i) { accW[i] = 0.0f; accM[i] = 0.0f; }
        for (int d = 0; d < DHEAD; ++d) {
            const float at = __bfloat162float(tA[t][d]);
            const float bt = __bfloat162float(tB[t][d]);
#pragma unroll
            for (int i = 0; i < 16; ++i) {
                const float ks = __bfloat162float(tA[s0 + i][d]);
                accW[i] = fmaf(at, ks, accW[i]);
                accM[i] = fmaf(bt, ks, accM[i]);
            }
        }
        const float btc = sb_[t], Gt = sG[t];
        float mrow[16];
#pragma unroll
        for (int i = 0; i < 16; ++i) {
            const int s = s0 + i;
            const float ratio = (s <= t) ? expf(Gt - sG[s]) : 0.0f;  // <= 1
            Wl[t][s] = __float2bfloat16((s < t) ? btc * ratio * accW[i] : 0.0f);
            mrow[i] = ratio * accM[i];
        }
        __hip_bfloat16* mp = Mmat + (chnk * CS + t) * CS + s0;
        *(uint4*)(mp)     = pack8_bf16(&mrow[0]);
        *(uint4*)(mp + 8) = pack8_bf16(&mrow[8]);
    }
    __syncthreads();

    // Ti = (I+W)^-1 via forward elimination
    {
        const int t = tid >> 2, j0 = (tid & 3) * 16;
#pragma unroll
        for (int i = 0; i < 16; ++i) Ti[t][j0 + i] = (t == j0 + i) ? 1.0f : 0.0f;
    }
    __syncthreads();
    for (int s = 0; s < CS - 1; ++s) {
        const int t = tid & 63, jq = tid >> 6;
        if (t > s) {
            const float wt = -__bfloat162float(Wl[t][s]);
            const int jlo = jq * 16;
            const int jhi = min(s, jlo + 15);
            for (int j = jlo; j <= jhi; ++j)
                Ti[t][j] = fmaf(wt, Ti[s][j], Ti[t][j]);
        }
        __syncthreads();
    }

    // R[t][kk] = -sum_s Ti[t][s] * swB[s] * K[s][kk]   (bf16 out)
    {
        const int t = tid >> 2, j0 = (tid & 3) * 32;
        float acc[32];
#pragma unroll
        for (int j = 0; j < 32; ++j) acc[j] = 0.0f;
        for (int s = 0; s <= t; ++s) {
            const float cf = -Ti[t][s] * swB[s];
#pragma unroll
            for (int j = 0; j < 32; ++j)
                acc[j] = fmaf(cf, __bfloat162float(tA[s][j0 + j]), acc[j]);
        }
        __hip_bfloat16* rp = Rg + (chnk * CS + t) * DHEAD + j0;
#pragma unroll
        for (int i = 0; i < 4; ++i)
            *(uint4*)(rp + i * 8) = pack8_bf16(&acc[i * 8]);
    }

    // K^T: Ktg[kk][t] = K[t][kk]
    {
        const int kk = tid >> 1;
        const int t0 = (tid & 1) * 32;
        __hip_bfloat16* kp = Ktg + (chnk * DHEAD + kk) * CS + t0;
        float f[8];
#pragma unroll
        for (int i = 0; i < 4; ++i) {
#pragma unroll
            for (int j2 = 0; j2 < 8; ++j2)
                f[j2] = __bfloat162float(tA[t0 + i * 8 + j2][kk]);
            *(uint4*)(kp + i * 8) = pack8_bf16(f);
        }
    }

    // load b*v into tB
    {
        const int r = tid >> 2, d0 = (tid & 3) * 32;
        const float br = sb_[r];
        const uint4* vp = (const uint4*)(vb + (row0 + r) * DDIM + h * DHEAD + d0);
#pragma unroll
        for (int i = 0; i < 4; ++i) {
            const uint4 vv = vp[i];
            const unsigned short* u = (const unsigned short*)&vv;
            float f[8];
#pragma unroll
            for (int j = 0; j < 8; ++j) f[j] = br * bfbits2f(u[j]);
            *(uint4*)&tB[r][d0 + i * 8] = pack8_bf16(f);
        }
    }
    __syncthreads();

    // dv0 = Ti @ (b*v) -> dvX (bf16)
    {
        const int t = tid >> 2, j0 = (tid & 3) * 32;
        float acc[32];
#pragma unroll
        for (int j = 0; j < 32; ++j) acc[j] = 0.0f;
        for (int s = 0; s < CS; ++s) {
            const float ti = Ti[t][s];
#pragma unroll
            for (int j = 0; j < 32; ++j)
                acc[j] = fmaf(ti, __bfloat162float(tB[s][j0 + j]), acc[j]);
        }
        __hip_bfloat16* dp = dvX + (chnk * CS + t) * DHEAD + j0;
#pragma unroll
        for (int i = 0; i < 4; ++i)
            *(uint4*)(dp + i * 8) = pack8_bf16(&acc[i * 8]);
    }
}

// --------- Phase B: sequential over chunks; MFMA; 128 blocks ----------------
// Grid 16*SEQGV; bh = blockIdx.x & 15 (same-bh blocks share an XCD for L2
// reuse of R/Kt), g = blockIdx.x >> 4 selects 16 v-columns.
// Per block state: S[128 kk][16 j] as 2 MFMA C-fragments (8 f32/thread).
// LDS (bytes): R[2] 0/17408, Kt[2] 34816+18432*buf, dvT 71680 (16x72),
//              Stl 73984 (16x136, Stl[j][kk]), sG 78336 (2x64 f32). Total 78848.
#define SEQGV 8
#define SEQ_LDS_BYTES 78848

__global__ __launch_bounds__(256) void chunk_seq_mfma(
    const float* __restrict__ S0in, const float* __restrict__ Gcum,
    const __hip_bfloat16* __restrict__ Rg, const __hip_bfloat16* __restrict__ Ktg,
    __hip_bfloat16* __restrict__ dvX, __hip_bfloat16* __restrict__ Ssnap,
    float* __restrict__ Sout)
{
    const int bh = blockIdx.x & 15;
    const int g  = blockIdx.x >> 4;
    const int j0 = g * 16;
    const int tid = threadIdx.x;
    const int w = tid >> 6;
    const int l = tid & 63;
    const int fr = l & 15;
    const int fk8 = (l >> 4) * 8;
    const int rq = (l >> 4) * 4;

    __shared__ __align__(16) char smem[SEQ_LDS_BYTES];
    __hip_bfloat16* dvT = (__hip_bfloat16*)(smem + 71680);   // [16 j][72 t]
    __hip_bfloat16* Stl = (__hip_bfloat16*)(smem + 73984);   // [16 j][136 kk]
    float* sG = (float*)(smem + 78336);

    // ---- init: master S fragments (rows kk, cols j) + bf16 mirror S^T ----
    f32x4 SM[2];
#pragma unroll
    for (int mj = 0; mj < 2; ++mj) {
#pragma unroll
        for (int r = 0; r < 4; ++r) {
            const int kk = w * 32 + mj * 16 + rq + r;
            const float v = S0in[((long)bh * 128 + kk) * 128 + j0 + fr];
            SM[mj][r] = v;
            Stl[fr * 136 + kk] = __float2bfloat16(v);
        }
    }

    // ---- staging ----
    uint4 rreg[4], kreg[4];
    float greg = 0.0f;

#define SEQ_STAGE_LOAD(c_) do {                                                   \
        const long cb_ = (long)bh * NC + (c_);                                    \
        _Pragma("unroll")                                                         \
        for (int i_ = 0; i_ < 4; ++i_) {                                          \
            const int ur_ = (tid << 2) + i_;                                      \
            rreg[i_] = *(const uint4*)(Rg + (cb_ * CS + (ur_ >> 4)) * DHEAD + ((ur_ & 15) << 3)); \
            kreg[i_] = *(const uint4*)(Ktg + (cb_ * DHEAD + (ur_ >> 3)) * CS + ((ur_ & 7) << 3)); \
        }                                                                         \
        if (tid < 64) greg = Gcum[cb_ * CS + tid];                                \
    } while (0)

#define SEQ_STAGE_WRITE(bufi_) do {                                               \
        __hip_bfloat16* rb_ = (__hip_bfloat16*)(smem + (bufi_) * 17408);          \
        __hip_bfloat16* kb2_ = (__hip_bfloat16*)(smem + 34816 + (bufi_) * 18432); \
        _Pragma("unroll")                                                         \
        for (int i_ = 0; i_ < 4; ++i_) {                                          \
            const int ur_ = (tid << 2) + i_;                                      \
            *(uint4*)(rb_ + (ur_ >> 4) * 136 + ((ur_ & 15) << 3)) = rreg[i_];     \
            *(uint4*)(kb2_ + (ur_ >> 3) * 72 + ((ur_ & 7) << 3)) = kreg[i_];      \
        }                                                                         \
        if (tid < 64) sG[(bufi_) * 64 + tid] = greg;                              \
    } while (0)

    SEQ_STAGE_LOAD(0);
    SEQ_STAGE_WRITE(0);
    __syncthreads();

    for (int c = 0; c < NC; ++c) {
        const int cur = c & 1;
        const long chnk = (long)bh * NC + c;
        const __hip_bfloat16* Rl = (const __hip_bfloat16*)(smem + cur * 17408);
        const __hip_bfloat16* Ktl = (const __hip_bfloat16*)(smem + 34816 + cur * 18432);
        const float g63 = sG[cur * 64 + 63];
        const float a63 = expf(g63);

        // dv0 prefetch (this lane's 4 elements; same addresses overwritten below)
        unsigned short d0r[4];
#pragma unroll
        for (int r = 0; r < 4; ++r) {
            const int t = w * 16 + rq + r;
            d0r[r] = *(const unsigned short*)(dvX + (chnk * CS + t) * DHEAD + j0 + fr);
        }

        if (c + 1 < NC) SEQ_STAGE_LOAD(c + 1);

        // snapshot chunk-initial S^T slice -> Ssnap[chnk][j0+j][kk]
        {
            const int j = tid >> 4, k0 = (tid & 15) * 8;
            const uint4 v = *(const uint4*)&Stl[j * 136 + k0];
            *(uint4*)(Ssnap + (chnk * 128 + j0 + j) * 128 + k0) = v;
        }

        // ---- step A: dv[64 t][16 j] = dv0 + R @ S  (per wave: 1 t-tile) ----
        f32x4 acc = (f32x4)0.0f;
#pragma unroll
        for (int ks = 0; ks < 4; ++ks) {
            const bf16x8 bfrag = *(const bf16x8*)&Stl[fr * 136 + ks * 32 + fk8];
            const bf16x8 afrag = *(const bf16x8*)&Rl[(w * 16 + fr) * 136 + ks * 32 + fk8];
            acc = __builtin_amdgcn_mfma_f32_16x16x32_bf16(afrag, bfrag, acc, 0, 0, 0);
        }
        // epi A: add dv0, store dv (global), write scaled dv^T to LDS
#pragma unroll
        for (int r = 0; r < 4; ++r) {
            const int t = w * 16 + rq + r;
            const float rk = expf(g63 - sG[cur * 64 + t]);
            const float dv = acc[r] + bfbits2f(d0r[r]);
            *(unsigned short*)(dvX + (chnk * CS + t) * DHEAD + j0 + fr) = bf16_bits(dv);
            dvT[fr * 72 + t] = __float2bfloat16(rk * dv);
        }

        if (c + 1 < NC) SEQ_STAGE_WRITE(cur ^ 1);
        __syncthreads();   // dvT + next-chunk staging visible

        // ---- step B: S' = a63*S + K^T @ dvs  (per wave: 2 kk-tiles) ----
#pragma unroll
        for (int mj = 0; mj < 2; ++mj) SM[mj] *= a63;
#pragma unroll
        for (int ks = 0; ks < 2; ++ks) {
            const bf16x8 bfrag = *(const bf16x8*)&dvT[fr * 72 + ks * 32 + fk8];
#pragma unroll
            for (int mj = 0; mj < 2; ++mj) {
                const bf16x8 afrag = *(const bf16x8*)&Ktl[(w * 32 + mj * 16 + fr) * 72 + ks * 32 + fk8];
                SM[mj] = __builtin_amdgcn_mfma_f32_16x16x32_bf16(afrag, bfrag, SM[mj], 0, 0, 0);
            }
        }
        // epi B: refresh bf16 mirror
#pragma unroll
        for (int mj = 0; mj < 2; ++mj)
#pragma unroll
            for (int r = 0; r < 4; ++r) {
                const int kk = w * 32 + mj * 16 + rq + r;
                Stl[fr * 136 + kk] = __float2bfloat16(SM[mj][r]);
            }
        __syncthreads();   // Stl stable for next chunk's snapshot/step A
    }

    // ---- final state ----
#pragma unroll
    for (int mj = 0; mj < 2; ++mj)
#pragma unroll
        for (int r = 0; r < 4; ++r) {
            const int kk = w * 32 + mj * 16 + rq + r;
            Sout[((long)bh * 128 + kk) * 128 + j0 + fr] = SM[mj][r];
        }
#undef SEQ_STAGE_LOAD
#undef SEQ_STAGE_WRITE
}

// --------- Phase C (parallel): o = e^{G_t}*(q_t @ S0snap) + M @ dv ----------
// Ssnap layout: [chnk][j][kk] = S0^T
__global__ __launch_bounds__(256) void chunk_out(
    const __hip_bfloat16* __restrict__ qb, const float* __restrict__ Gcum,
    const __hip_bfloat16* __restrict__ dvX, const __hip_bfloat16* __restrict__ Ssnap,
    const __hip_bfloat16* __restrict__ Mmat, __hip_bfloat16* __restrict__ ob)
{
    const int bh = blockIdx.x >> 5;
    const int c  = blockIdx.x & 31;
    const int b = bh >> 3, h = bh & 7;
    const int tid = threadIdx.x;
    const long row0 = (long)b * TLEN + (long)c * CS;
    const long chnk = (long)bh * NC + c;

    __shared__ __align__(16) __hip_bfloat16 Ssn[128][136];   // [j][kk]
    __shared__ __align__(16) __hip_bfloat16 dvq[64][136];    // dv, later q
    __shared__ __align__(16) __hip_bfloat16 Ml[64][72];

    {
        const int j = tid >> 1;
        const int d0 = (tid & 1) * 64;
        const uint4* sp = (const uint4*)(Ssnap + (chnk * 128 + j) * 128 + d0);
#pragma unroll
        for (int i = 0; i < 8; ++i)
            *(uint4*)&Ssn[j][d0 + i * 8] = sp[i];
    }
    {
        const int t = tid >> 2;
        const int s0 = (tid & 3) * 32;
        const uint4* dp = (const uint4*)(dvX + (chnk * CS + t) * DHEAD + s0);
#pragma unroll
        for (int i = 0; i < 4; ++i)
            *(uint4*)&dvq[t][s0 + i * 8] = dp[i];
    }
    {
        const int t = tid >> 2;
        const int s0 = (tid & 3) * 16;
        const uint4* mp = (const uint4*)(Mmat + (chnk * CS + t) * CS + s0);
        *(uint4*)&Ml[t][s0]     = mp[0];
        *(uint4*)&Ml[t][s0 + 8] = mp[1];
    }
    __syncthreads();

    const int t = tid >> 2;
    const int j0l = (tid & 3) * 32;
    float acc[32];
#pragma unroll
    for (int j = 0; j < 32; ++j) acc[j] = 0.0f;

    // part 1: M @ dv
    for (int s = 0; s < CS; ++s) {
        const float m = __bfloat162float(Ml[t][s]);
#pragma unroll
        for (int j = 0; j < 32; ++j)
            acc[j] = fmaf(m, __bfloat162float(dvq[s][j0l + j]), acc[j]);
    }
    __syncthreads();

    // load q chunk into dvq
    {
        const int r = tid >> 2, d0 = (tid & 3) * 32;
        const uint4* qp = (const uint4*)(qb + (row0 + r) * DDIM + h * DHEAD + d0);
#pragma unroll
        for (int i = 0; i < 4; ++i)
            *(uint4*)&dvq[r][d0 + i * 8] = qp[i];
    }
    __syncthreads();

    // part 2: + e^{G_t} * (q_t @ S0)   with S0[kk][j] = Ssn[j][kk]
    const float At = expf(Gcum[chnk * CS + t]);
    for (int kk = 0; kk < 128; ++kk) {
        const float qv = At * __bfloat162float(dvq[t][kk]);
#pragma unroll
        for (int j = 0; j < 32; ++j)
            acc[j] = fmaf(qv, __bfloat162float(Ssn[j0l + j][kk]), acc[j]);
    }

    __hip_bfloat16* op = ob + (row0 + t) * DDIM + h * DHEAD + j0l;
#pragma unroll
    for (int i = 0; i < 4; ++i)
        *(uint4*)(op + i * 8) = pack8_bf16(&acc[i * 8]);
}

extern "C" void kernel_launch(void* const* d_in, const int* in_sizes, int n_in,
                              void* d_out, int out_size, void* d_ws, size_t ws_size,
                              hipStream_t stream) {
    const float* x     = (const float*)d_in[0];
    const float* S0    = (const float*)d_in[1];
    const float* wq    = (const float*)d_in[2];
    const float* wk    = (const float*)d_in[3];
    const float* wv    = (const float*)d_in[4];
    const float* wb    = (const float*)d_in[5];
    const float* wg    = (const float*)d_in[6];
    const float* wo    = (const float*)d_in[7];
    const float* wgate = (const float*)d_in[8];
    const float* wup   = (const float*)d_in[9];
    const float* wdown = (const float*)d_in[10];

    const int M = BSZ * TLEN;  // 4096 token rows

    float* out  = (float*)d_out;
    float* Sout = out + (long)M * DDIM;

    // Workspace layout, peak 76.5 MiB (proven budget: 81 MiB).
    char* w = (char*)d_ws;
    const size_t MB = 1u << 20;
    const size_t KB = 1u << 10;
    __hip_bfloat16* qbh   = (__hip_bfloat16*)(w + 0 * MB);             // QKV->chunk_out
    __hip_bfloat16* kbh   = (__hip_bfloat16*)(w + 8 * MB);             // QKV->chunk_prep
    __hip_bfloat16* vbh   = (__hip_bfloat16*)(w + 16 * MB);            // QKV->chunk_prep
    float*          beta  = (float*)(w + 24 * MB);                     // ->prep
    float*          alpha = (float*)(w + 24 * MB + 128 * KB);          // ->prep
    float*          Gcum  = (float*)(w + 24 * MB + 256 * KB);          // ->out
    __hip_bfloat16* Mmat  = (__hip_bfloat16*)(w + 24 * MB + 512 * KB); // prep->out (4MB)
    __hip_bfloat16* dvX   = (__hip_bfloat16*)(w + 28 * MB + 512 * KB); // prep->out (8MB)
    __hip_bfloat16* Rg    = (__hip_bfloat16*)(w + 36 * MB + 512 * KB); // prep->seq (8MB)
    __hip_bfloat16* xnb   = (__hip_bfloat16*)(w + 36 * MB + 512 * KB); // rms1->QKV (dead before Rg)
    __hip_bfloat16* Ktg   = (__hip_bfloat16*)(w + 44 * MB + 512 * KB); // prep->seq (8MB)
    __hip_bfloat16* Ssnap = (__hip_bfloat16*)(w + 52 * MB + 512 * KB); // seq->out (16MB)
    __hip_bfloat16* wqt   = (__hip_bfloat16*)(w + 68 * MB + 512 * KB); // ->QKV (2MB)
    __hip_bfloat16* wkt   = (__hip_bfloat16*)(w + 70 * MB + 512 * KB);
    __hip_bfloat16* wvt   = (__hip_bfloat16*)(w + 72 * MB + 512 * KB);
    __hip_bfloat16* wot   = (__hip_bfloat16*)(w + 74 * MB + 512 * KB); // ->GEMM4 (2MB), peak 76.5
    __hip_bfloat16* obufb = (__hip_bfloat16*)(w + 8 * MB);             // chunk_out->GEMM4 (kbh dead)
    __hip_bfloat16* xn2b  = (__hip_bfloat16*)(w + 8 * MB);             // rms2->gateup (obufb dead)
    __hip_bfloat16* wdt   = (__hip_bfloat16*)(w + 16 * MB);            // ->down (vbh dead)
    __hip_bfloat16* wgt   = (__hip_bfloat16*)(w + 24 * MB + 512 * KB); // after chunk_out (8MB)
    __hip_bfloat16* wut   = (__hip_bfloat16*)(w + 32 * MB + 512 * KB); // after chunk_out (8MB)
    __hip_bfloat16* Hb    = (__hip_bfloat16*)(w + 40 * MB + 512 * KB); // gateup->down (32MB)

    // 0) weight transpose+convert (W[K,N] -> Wt[N,K] bf16)
    transpose_cvt<<<dim3(DDIM / 32, DDIM / 32), 256, 0, stream>>>(wq, wqt, DDIM, DDIM);
    transpose_cvt<<<dim3(DDIM / 32, DDIM / 32), 256, 0, stream>>>(wk, wkt, DDIM, DDIM);
    transpose_cvt<<<dim3(DDIM / 32, DDIM / 32), 256, 0, stream>>>(wv, wvt, DDIM, DDIM);
    transpose_cvt<<<dim3(DDIM / 32, DDIM / 32), 256, 0, stream>>>(wo, wot, DDIM, DDIM);

    // 1) norms / gates
    rmsnorm_k<<<M, 256, 0, stream>>>(x, xnb);
    ba_kernel<<<M, 64, 0, stream>>>(x, wb, wg, beta, alpha);

    // 2) q/k/v projections (bf16 out)
    dim3 gP(DDIM / 128, M / 128);
    gemm_bf16<2><<<gP, 256, 0, stream>>>(xnb, wqt, nullptr, qbh, M, DDIM, DDIM);
    gemm_bf16<2><<<gP, 256, 0, stream>>>(xnb, wkt, nullptr, kbh, M, DDIM, DDIM);
    gemm_bf16<2><<<gP, 256, 0, stream>>>(xnb, wvt, nullptr, vbh, M, DDIM, DDIM);
    postqkv<<<M * HHEADS, 64, 0, stream>>>(qbh, kbh, vbh);

    // 3) chunked delta rule
    chunk_prep<<<16 * NC, 256, 0, stream>>>(kbh, qbh, vbh, beta, alpha, Gcum, Rg, Ktg, dvX, Mmat);
    chunk_seq_mfma<<<16 * SEQGV, 256, 0, stream>>>(S0, Gcum, Rg, Ktg, dvX, Ssnap, Sout);
    chunk_out<<<16 * NC, 256, 0, stream>>>(qbh, Gcum, dvX, Ssnap, Mmat, obufb);

    // 4) x1 = x + o @ wo
    gemm_bf16<1><<<gP, 256, 0, stream>>>(obufb, wot, x, out, M, DDIM, DDIM);

    // 4b) remaining weight transposes into now-dead regions
    transpose_cvt<<<dim3(DDIM / 32, FDIM / 32), 256, 0, stream>>>(wdown, wdt, FDIM, DDIM);
    transpose_cvt<<<dim3(FDIM / 32, DDIM / 32), 256, 0, stream>>>(wgate, wgt, DDIM, FDIM);
    transpose_cvt<<<dim3(FDIM / 32, DDIM / 32), 256, 0, stream>>>(wup, wut, DDIM, FDIM);

    // 5) xn2 = rms_norm(x1)
    rmsnorm_k<<<M, 256, 0, stream>>>(out, xn2b);

    // 6) H = silu(xn2 @ w_gate) * (xn2 @ w_up)  -- 128x64 tile
    dim3 gGU(FDIM / 64, M / 128);
    gemm_gateup_bf16<<<gGU, 256, 0, stream>>>(xn2b, wgt, wut, Hb, M, FDIM, DDIM);

    // 7) x_out = x1 + H @ w_down
    dim3 gDN(DDIM / 128, M / 128);
    gemm_bf16<1><<<gDN, 256, 0, stream>>>(Hb, wdt, out, out, M, DDIM, FDIM);
}

// Round 8
// 653.279 us; speedup vs baseline: 1.3987x; 1.0896x over previous
//
#include <hip/hip_runtime.h>
#include <hip/hip_bf16.h>
#include <math.h>

// Sizes fixed by the problem: B=2, T=2048, D=1024, F=4096, H=8, DH=128.
#define BSZ 2
#define TLEN 2048
#define DDIM 1024
#define FDIM 4096
#define HHEADS 8
#define DHEAD 128
#define NC 32   // chunks per sequence
#define CS 64   // chunk size (CS*NC == TLEN)

typedef __bf16 bf16x8 __attribute__((ext_vector_type(8)));
typedef float f32x4 __attribute__((ext_vector_type(4)));

__device__ __forceinline__ float silu_f(float x) {
    return x / (1.0f + expf(-x));
}

__device__ __forceinline__ void load_lds16(const void* g, void* l) {
    __builtin_amdgcn_global_load_lds(
        (const __attribute__((address_space(1))) void*)g,
        (__attribute__((address_space(3))) void*)l, 16, 0, 0);
}

__device__ __forceinline__ unsigned short bf16_bits(float f) {
    __hip_bfloat16 h = __float2bfloat16(f);
    return *reinterpret_cast<unsigned short*>(&h);
}

__device__ __forceinline__ float bfbits2f(unsigned short u) {
    union { unsigned int i; float f; } c;
    c.i = ((unsigned int)u) << 16;
    return c.f;
}

__device__ __forceinline__ uint4 pack8_bf16(const float* f) {
    union { unsigned short u[8]; uint4 v; } r;
#pragma unroll
    for (int i = 0; i < 8; ++i) r.u[i] = bf16_bits(f[i]);
    return r.v;
}

// ---------------- RMSNorm: one block (256 thr) per row of 1024; bf16 out -----
struct alignas(8) bh4 { __hip_bfloat16 a, b, c, d; };

__global__ __launch_bounds__(256) void rmsnorm_k(const float* __restrict__ in,
                                                 __hip_bfloat16* __restrict__ out) {
    const long row = blockIdx.x;
    const int tid = threadIdx.x;
    const float4 x = *(const float4*)(in + row * DDIM + tid * 4);
    float ss = x.x * x.x + x.y * x.y + x.z * x.z + x.w * x.w;
    ss += __shfl_xor(ss, 1);
    ss += __shfl_xor(ss, 2);
    ss += __shfl_xor(ss, 4);
    ss += __shfl_xor(ss, 8);
    ss += __shfl_xor(ss, 16);
    ss += __shfl_xor(ss, 32);
    __shared__ float wsum[4];
    if ((tid & 63) == 0) wsum[tid >> 6] = ss;
    __syncthreads();
    const float tot = wsum[0] + wsum[1] + wsum[2] + wsum[3];
    const float sc = rsqrtf(tot * (1.0f / (float)DDIM) + 1e-6f);
    bh4 y;
    y.a = __float2bfloat16(x.x * sc);
    y.b = __float2bfloat16(x.y * sc);
    y.c = __float2bfloat16(x.z * sc);
    y.d = __float2bfloat16(x.w * sc);
    *(bh4*)(out + row * DDIM + tid * 4) = y;
}

// ------------- transpose + f32->bf16: W[K,N] -> Wt[N,K] -------------
__global__ __launch_bounds__(256) void transpose_cvt(const float* __restrict__ W,
                                                     __hip_bfloat16* __restrict__ Wt,
                                                     int K, int N) {
    __shared__ float t[32][33];
    const int n0 = blockIdx.x * 32, k0 = blockIdx.y * 32;
    const int tx = threadIdx.x & 31, ty = threadIdx.x >> 5;  // ty 0..7
#pragma unroll
    for (int i = 0; i < 4; ++i)
        t[ty * 4 + i][tx] = W[(long)(k0 + ty * 4 + i) * N + n0 + tx];
    __syncthreads();
#pragma unroll
    for (int i = 0; i < 4; ++i)
        Wt[(long)(n0 + ty * 4 + i) * K + k0 + tx] = __float2bfloat16(t[tx][ty * 4 + i]);
}

// ---------------- bf16 MFMA GEMM: C[M,N] = A[M,K] @ Bt[N,K]^T -------
// MODE 0: f32 out. MODE 1: f32 out + f32 resid. MODE 2: bf16 out.
template <int MODE>
__global__ __launch_bounds__(256) void gemm_bf16(const __hip_bfloat16* __restrict__ A,
                                                 const __hip_bfloat16* __restrict__ Bt,
                                                 const float* __restrict__ resid,
                                                 void* __restrict__ Cout,
                                                 int M, int N, int K) {
    __shared__ __align__(16) short As[128 * 32];
    __shared__ __align__(16) short Bs[128 * 32];
    const int tid = threadIdx.x;
    const int w = tid >> 6, l = tid & 63;
    const int m0 = blockIdx.y * 128, n0 = blockIdx.x * 128;
    const int srow = (w << 4) + (l >> 2);
    const int skcol = (l & 3) * 8;
    const int wr = w >> 1, wc = w & 1;
    const int fr = l & 15;
    const int fkB = (l >> 4) * 16;

    f32x4 acc[4][4];
#pragma unroll
    for (int m = 0; m < 4; ++m)
#pragma unroll
        for (int n = 0; n < 4; ++n) acc[m][n] = (f32x4)0.0f;

    const __hip_bfloat16* Abase = A + (long)m0 * K + skcol;
    const __hip_bfloat16* Bbase = Bt + (long)n0 * K + skcol;

    for (int k0 = 0; k0 < K; k0 += 32) {
#pragma unroll
        for (int j = 0; j < 2; ++j) {
            const int row = srow + j * 64;
            load_lds16(Abase + (long)row * K + k0, (char*)As + w * 1024 + j * 4096);
            load_lds16(Bbase + (long)row * K + k0, (char*)Bs + w * 1024 + j * 4096);
        }
        __syncthreads();
        bf16x8 av[4], bv[4];
#pragma unroll
        for (int m = 0; m < 4; ++m) {
            av[m] = *(const bf16x8*)((char*)As + (wr * 64 + m * 16 + fr) * 64 + fkB);
            bv[m] = *(const bf16x8*)((char*)Bs + (wc * 64 + m * 16 + fr) * 64 + fkB);
        }
#pragma unroll
        for (int m = 0; m < 4; ++m)
#pragma unroll
            for (int n = 0; n < 4; ++n)
                acc[m][n] = __builtin_amdgcn_mfma_f32_16x16x32_bf16(av[m], bv[n], acc[m][n], 0, 0, 0);
        __syncthreads();
    }

    const int r0 = (l >> 4) * 4;
    const int cc = l & 15;
#pragma unroll
    for (int m = 0; m < 4; ++m) {
#pragma unroll
        for (int r = 0; r < 4; ++r) {
            const long row = m0 + wr * 64 + m * 16 + r0 + r;
            const long colb = n0 + wc * 64 + cc;
            if (MODE == 2) {
                __hip_bfloat16* cb = (__hip_bfloat16*)Cout + row * N + colb;
#pragma unroll
                for (int n = 0; n < 4; ++n)
                    cb[n * 16] = __float2bfloat16(acc[m][n][r]);
            } else {
                float* cp = (float*)Cout + row * N + colb;
                const float* rp = resid + row * N + colb;
#pragma unroll
                for (int n = 0; n < 4; ++n) {
                    float v = acc[m][n][r];
                    if (MODE == 1) v += rp[n * 16];
                    cp[n * 16] = v;
                }
            }
        }
    }
}

// ---- dual-B MFMA GEMM for SwiGLU: H = bf16( silu(A@Wg^T) * (A@Wu^T) ) ------
// Block tile 128x64, 4 waves (2x2), per wave 4x2 fragments per matrix.
__global__ __launch_bounds__(256) void gemm_gateup_bf16(const __hip_bfloat16* __restrict__ A,
                                                        const __hip_bfloat16* __restrict__ Bg,
                                                        const __hip_bfloat16* __restrict__ Bu,
                                                        __hip_bfloat16* __restrict__ Hb,
                                                        int M, int N, int K) {
    __shared__ __align__(16) short As[128 * 32];   // 8 KB
    __shared__ __align__(16) short Bgs[64 * 32];   // 4 KB
    __shared__ __align__(16) short Bus[64 * 32];   // 4 KB
    const int tid = threadIdx.x;
    const int w = tid >> 6, l = tid & 63;
    const int m0 = blockIdx.y * 128, n0 = blockIdx.x * 64;
    const int srow = (w << 4) + (l >> 2);
    const int skcol = (l & 3) * 8;
    const int wr = w >> 1, wc = w & 1;
    const int fr = l & 15;
    const int fkB = (l >> 4) * 16;

    f32x4 accg[4][2], accu[4][2];
#pragma unroll
    for (int m = 0; m < 4; ++m)
#pragma unroll
        for (int n = 0; n < 2; ++n) { accg[m][n] = (f32x4)0.0f; accu[m][n] = (f32x4)0.0f; }

    const __hip_bfloat16* Abase = A + (long)m0 * K + skcol;
    const __hip_bfloat16* Bgb = Bg + (long)n0 * K + skcol;
    const __hip_bfloat16* Bub = Bu + (long)n0 * K + skcol;

    for (int k0 = 0; k0 < K; k0 += 32) {
#pragma unroll
        for (int j = 0; j < 2; ++j)
            load_lds16(Abase + (long)(srow + j * 64) * K + k0, (char*)As + w * 1024 + j * 4096);
        load_lds16(Bgb + (long)srow * K + k0, (char*)Bgs + w * 1024);
        load_lds16(Bub + (long)srow * K + k0, (char*)Bus + w * 1024);
        __syncthreads();
        bf16x8 av[4], bgv[2], buv[2];
#pragma unroll
        for (int m = 0; m < 4; ++m)
            av[m] = *(const bf16x8*)((char*)As + (wr * 64 + m * 16 + fr) * 64 + fkB);
#pragma unroll
        for (int n = 0; n < 2; ++n) {
            bgv[n] = *(const bf16x8*)((char*)Bgs + (wc * 32 + n * 16 + fr) * 64 + fkB);
            buv[n] = *(const bf16x8*)((char*)Bus + (wc * 32 + n * 16 + fr) * 64 + fkB);
        }
#pragma unroll
        for (int m = 0; m < 4; ++m)
#pragma unroll
            for (int n = 0; n < 2; ++n) {
                accg[m][n] = __builtin_amdgcn_mfma_f32_16x16x32_bf16(av[m], bgv[n], accg[m][n], 0, 0, 0);
                accu[m][n] = __builtin_amdgcn_mfma_f32_16x16x32_bf16(av[m], buv[n], accu[m][n], 0, 0, 0);
            }
        __syncthreads();
    }

    const int r0 = (l >> 4) * 4;
    const int cc = l & 15;
#pragma unroll
    for (int m = 0; m < 4; ++m) {
#pragma unroll
        for (int r = 0; r < 4; ++r) {
            const long row = m0 + wr * 64 + m * 16 + r0 + r;
            __hip_bfloat16* hp = Hb + row * N + n0 + wc * 32 + cc;
#pragma unroll
            for (int n = 0; n < 2; ++n)
                hp[n * 16] = __float2bfloat16(silu_f(accg[m][n][r]) * accu[m][n][r]);
        }
    }
}

// ------- beta/alpha: inline rmsnorm (scale folds out of the dot) -------
__global__ __launch_bounds__(64) void ba_kernel(const float* __restrict__ x,
                                                const float* __restrict__ wb,
                                                const float* __restrict__ wg,
                                                float* __restrict__ beta,
                                                float* __restrict__ alpha) {
    const long row = blockIdx.x;
    const int tid = threadIdx.x;
    const int o = tid >> 2;
    const int p = tid & 3;
    const float* w = (o < 8) ? (wb + o) : (wg + (o - 8));
    const float* xr = x + row * DDIM + p * 256;
    const float* wr = w + (long)(p * 256) * HHEADS;
    float acc = 0.0f, ss = 0.0f;
#pragma unroll 8
    for (int i = 0; i < 256; ++i) {
        const float xv = xr[i];
        ss = fmaf(xv, xv, ss);
        acc = fmaf(xv, wr[(long)i * HHEADS], acc);
    }
    acc += __shfl_xor(acc, 1);
    acc += __shfl_xor(acc, 2);
    ss += __shfl_xor(ss, 1);
    ss += __shfl_xor(ss, 2);
    if (p == 0) {
        const float sc = rsqrtf(ss * (1.0f / (float)DDIM) + 1e-6f);
        const float val = 1.0f / (1.0f + expf(-acc * sc));
        if (o < 8) beta[row * HHEADS + o] = val;
        else       alpha[row * HHEADS + (o - 8)] = val;
    }
}

// ------- post-projection (bf16 in-place): silu + l2norm on q,k; silu on v ----
__global__ __launch_bounds__(64) void postqkv(__hip_bfloat16* __restrict__ q,
                                              __hip_bfloat16* __restrict__ k,
                                              __hip_bfloat16* __restrict__ v) {
    const long r = blockIdx.x;
    const int tid = threadIdx.x;
    {
        unsigned int* qp = (unsigned int*)(q + r * DHEAD + tid * 2);
        const unsigned int wbits = *qp;
        float y0 = silu_f(bfbits2f(wbits & 0xffff));
        float y1 = silu_f(bfbits2f(wbits >> 16));
        float ss = y0 * y0 + y1 * y1;
        ss += __shfl_xor(ss, 1);  ss += __shfl_xor(ss, 2);
        ss += __shfl_xor(ss, 4);  ss += __shfl_xor(ss, 8);
        ss += __shfl_xor(ss, 16); ss += __shfl_xor(ss, 32);
        const float sc = rsqrtf(ss + 1e-6f);
        *qp = (unsigned int)bf16_bits(y0 * sc) | ((unsigned int)bf16_bits(y1 * sc) << 16);
    }
    {
        unsigned int* kp = (unsigned int*)(k + r * DHEAD + tid * 2);
        const unsigned int wbits = *kp;
        float y0 = silu_f(bfbits2f(wbits & 0xffff));
        float y1 = silu_f(bfbits2f(wbits >> 16));
        float ss = y0 * y0 + y1 * y1;
        ss += __shfl_xor(ss, 1);  ss += __shfl_xor(ss, 2);
        ss += __shfl_xor(ss, 4);  ss += __shfl_xor(ss, 8);
        ss += __shfl_xor(ss, 16); ss += __shfl_xor(ss, 32);
        const float sc = rsqrtf(ss + 1e-6f);
        *kp = (unsigned int)bf16_bits(y0 * sc) | ((unsigned int)bf16_bits(y1 * sc) << 16);
    }
    {
        unsigned int* vp = (unsigned int*)(v + r * DHEAD + tid * 2);
        const unsigned int wbits = *vp;
        *vp = (unsigned int)bf16_bits(silu_f(bfbits2f(wbits & 0xffff)))
            | ((unsigned int)bf16_bits(silu_f(bfbits2f(wbits >> 16))) << 16);
    }
}

// ============ Chunked gated delta rule (log-space decay) ============
// G_t = sum_{s<=t} log(a_s) within chunk; ratio(t,s)=exp(G_t-G_s)<=1 for s<=t.
//   dv = dv0 + R @ S0,   R = -Tinv @ diag(b_s e^{G_s}) @ K   (precomputed)
//   dv0 = Tinv @ (b (.) v)                                    (precomputed)
//   o_t = e^{G_t} (S0^T q_t) + (M @ dv)_t                     (M precomputed)
//   S_end = e^{G63} S0 + K^T @ diag(e^{G63-G_t}) dv

// --------- Phase A (parallel over bh x chunk): G, M, R, K^T, dv0 ------------
// W_raw = K@K^T and M_raw = Q@K^T computed via MFMA (operands in LDS rows).
// Ti buffer [64][65] f32: lower+diag = Tinv (forward elimination);
// strictly-upper [s][t] = W[t][s] (packed transposed; disjoint cells).
__global__ __launch_bounds__(256) void chunk_prep(
    const __hip_bfloat16* __restrict__ kb, const __hip_bfloat16* __restrict__ qb,
    const __hip_bfloat16* __restrict__ vb, const float* __restrict__ betab,
    const float* __restrict__ alphab, float* __restrict__ Gcum,
    __hip_bfloat16* __restrict__ Rg, __hip_bfloat16* __restrict__ Ktg,
    __hip_bfloat16* __restrict__ dvX, __hip_bfloat16* __restrict__ Mmat)
{
    const int bh = blockIdx.x >> 5;
    const int c  = blockIdx.x & 31;
    const int b = bh >> 3, h = bh & 7;
    const int tid = threadIdx.x;
    const int w = tid >> 6, l = tid & 63;
    const int fr = l & 15;           // fragment col / A-row low
    const int fk8 = (l >> 4) * 8;    // fragment k base (bf16 elems)
    const int fr4 = (l >> 4) * 4;    // C-fragment row base

    __shared__ __align__(16) __hip_bfloat16 tA[64][136];   // k chunk
    __shared__ __align__(16) __hip_bfloat16 tB[64][136];   // q chunk, later b*v
    __shared__ float Ti[64][65];
    __shared__ float sa[64], sb_[64], sG[64], swB[64];

    const long row0 = (long)b * TLEN + (long)c * CS;
    const long chnk = (long)bh * NC + c;

    if (tid < 64) {
        sa[tid]  = alphab[(row0 + tid) * HHEADS + h];
        sb_[tid] = betab[(row0 + tid) * HHEADS + h];
    }
    // load k,q chunks (bf16 direct copies)
    {
        const int r = tid >> 2;
        const int d0 = (tid & 3) * 32;
        const uint4* kp = (const uint4*)(kb + (row0 + r) * DDIM + h * DHEAD + d0);
        const uint4* qp = (const uint4*)(qb + (row0 + r) * DDIM + h * DHEAD + d0);
#pragma unroll
        for (int i = 0; i < 4; ++i) {
            *(uint4*)&tA[r][d0 + i * 8] = kp[i];
            *(uint4*)&tB[r][d0 + i * 8] = qp[i];
        }
    }
    __syncthreads();
    if (tid == 0) {
        float run = 0.0f;
        for (int t = 0; t < CS; ++t) { run += logf(sa[t]); sG[t] = run; }
    }
    __syncthreads();
    if (tid < 64) {
        Gcum[chnk * CS + tid] = sG[tid];
        swB[tid] = sb_[tid] * expf(sG[tid]);
    }
    __syncthreads();

    // ---- MFMA: W_raw = K@K^T, M_raw = Q@K^T (wave w owns rows w*16..+15) ----
    f32x4 accW[4], accM[4];
#pragma unroll
    for (int n = 0; n < 4; ++n) { accW[n] = (f32x4)0.0f; accM[n] = (f32x4)0.0f; }
#pragma unroll
    for (int ks = 0; ks < 4; ++ks) {
        const bf16x8 aW = *(const bf16x8*)&tA[w * 16 + fr][ks * 32 + fk8];
        const bf16x8 aM = *(const bf16x8*)&tB[w * 16 + fr][ks * 32 + fk8];
#pragma unroll
        for (int n = 0; n < 4; ++n) {
            const bf16x8 bfr = *(const bf16x8*)&tA[n * 16 + fr][ks * 32 + fk8];
            accW[n] = __builtin_amdgcn_mfma_f32_16x16x32_bf16(aW, bfr, accW[n], 0, 0, 0);
            accM[n] = __builtin_amdgcn_mfma_f32_16x16x32_bf16(aM, bfr, accM[n], 0, 0, 0);
        }
    }
    // epilogue: M (masked+scaled) -> global; W (masked+scaled) -> Ti upper [s][t]
#pragma unroll
    for (int n = 0; n < 4; ++n) {
        const int s = n * 16 + fr;
        const float Gs = sG[s];
#pragma unroll
        for (int r = 0; r < 4; ++r) {
            const int t = w * 16 + fr4 + r;
            const float ratio = (s <= t) ? expf(sG[t] - Gs) : 0.0f;
            Mmat[(chnk * CS + t) * CS + s] = __float2bfloat16(ratio * accM[n][r]);
            if (s < t) Ti[s][t] = sb_[t] * ratio * accW[n][r];
        }
    }
    // init Ti lower+diag (upper holds W; disjoint cells)
    {
        const int t = tid >> 2, j0 = (tid & 3) * 16;
#pragma unroll
        for (int i = 0; i < 16; ++i) {
            const int j = j0 + i;
            if (j <= t) Ti[t][j] = (j == t) ? 1.0f : 0.0f;
        }
    }
    __syncthreads();   // all MFMA reads of tB done; Ti fully initialized

    // K^T: Ktg[kk][t] = K[t][kk]   (reads tA; independent of Ti)
    {
        const int kk = tid >> 1;
        const int t0 = (tid & 1) * 32;
        __hip_bfloat16* kp = Ktg + (chnk * DHEAD + kk) * CS + t0;
        float f[8];
#pragma unroll
        for (int i = 0; i < 4; ++i) {
#pragma unroll
            for (int j2 = 0; j2 < 8; ++j2)
                f[j2] = __bfloat162float(tA[t0 + i * 8 + j2][kk]);
            *(uint4*)(kp + i * 8) = pack8_bf16(f);
        }
    }
    // load b*v into tB (q dead)
    {
        const int r = tid >> 2, d0 = (tid & 3) * 32;
        const float br = sb_[r];
        const uint4* vp = (const uint4*)(vb + (row0 + r) * DDIM + h * DHEAD + d0);
#pragma unroll
        for (int i = 0; i < 4; ++i) {
            const uint4 vv = vp[i];
            const unsigned short* u = (const unsigned short*)&vv;
            float f[8];
#pragma unroll
            for (int j = 0; j < 8; ++j) f[j] = br * bfbits2f(u[j]);
            *(uint4*)&tB[r][d0 + i * 8] = pack8_bf16(f);
        }
    }
    __syncthreads();

    // Ti = (I+W)^-1 via forward elimination; W[t][s] read from Ti[s][t]
    for (int s = 0; s < CS - 1; ++s) {
        const int t = tid & 63, jq = tid >> 6;
        if (t > s) {
            const float wt = -Ti[s][t];
            const int jlo = jq * 16;
            const int jhi = min(s, jlo + 15);
            for (int j = jlo; j <= jhi; ++j)
                Ti[t][j] = fmaf(wt, Ti[s][j], Ti[t][j]);
        }
        __syncthreads();
    }

    // R[t][kk] = -sum_{s<=t} Ti[t][s] * swB[s] * K[s][kk]   (bf16 out)
    {
        const int t = tid >> 2, j0 = (tid & 3) * 32;
        float acc[32];
#pragma unroll
        for (int j = 0; j < 32; ++j) acc[j] = 0.0f;
        for (int s = 0; s <= t; ++s) {
            const float cf = -Ti[t][s] * swB[s];
#pragma unroll
            for (int j = 0; j < 32; ++j)
                acc[j] = fmaf(cf, __bfloat162float(tA[s][j0 + j]), acc[j]);
        }
        __hip_bfloat16* rp = Rg + (chnk * CS + t) * DHEAD + j0;
#pragma unroll
        for (int i = 0; i < 4; ++i)
            *(uint4*)(rp + i * 8) = pack8_bf16(&acc[i * 8]);
    }

    // dv0 = Ti @ (b*v) -> dvX (bf16); Ti lower-triangular so s<=t
    {
        const int t = tid >> 2, j0 = (tid & 3) * 32;
        float acc[32];
#pragma unroll
        for (int j = 0; j < 32; ++j) acc[j] = 0.0f;
        for (int s = 0; s <= t; ++s) {
            const float ti = Ti[t][s];
#pragma unroll
            for (int j = 0; j < 32; ++j)
                acc[j] = fmaf(ti, __bfloat162float(tB[s][j0 + j]), acc[j]);
        }
        __hip_bfloat16* dp = dvX + (chnk * CS + t) * DHEAD + j0;
#pragma unroll
        for (int i = 0; i < 4; ++i)
            *(uint4*)(dp + i * 8) = pack8_bf16(&acc[i * 8]);
    }
}

// --------- Phase B: sequential over chunks; MFMA; 128 blocks ----------------
#define SEQGV 8
#define SEQ_LDS_BYTES 78848

__global__ __launch_bounds__(256) void chunk_seq_mfma(
    const float* __restrict__ S0in, const float* __restrict__ Gcum,
    const __hip_bfloat16* __restrict__ Rg, const __hip_bfloat16* __restrict__ Ktg,
    __hip_bfloat16* __restrict__ dvX, __hip_bfloat16* __restrict__ Ssnap,
    float* __restrict__ Sout)
{
    const int bh = blockIdx.x & 15;
    const int g  = blockIdx.x >> 4;
    const int j0 = g * 16;
    const int tid = threadIdx.x;
    const int w = tid >> 6;
    const int l = tid & 63;
    const int fr = l & 15;
    const int fk8 = (l >> 4) * 8;
    const int rq = (l >> 4) * 4;

    __shared__ __align__(16) char smem[SEQ_LDS_BYTES];
    __hip_bfloat16* dvT = (__hip_bfloat16*)(smem + 71680);   // [16 j][72 t]
    __hip_bfloat16* Stl = (__hip_bfloat16*)(smem + 73984);   // [16 j][136 kk]
    float* sG = (float*)(smem + 78336);

    f32x4 SM[2];
#pragma unroll
    for (int mj = 0; mj < 2; ++mj) {
#pragma unroll
        for (int r = 0; r < 4; ++r) {
            const int kk = w * 32 + mj * 16 + rq + r;
            const float v = S0in[((long)bh * 128 + kk) * 128 + j0 + fr];
            SM[mj][r] = v;
            Stl[fr * 136 + kk] = __float2bfloat16(v);
        }
    }

    uint4 rreg[4], kreg[4];
    float greg = 0.0f;

#define SEQ_STAGE_LOAD(c_) do {                                                   \
        const long cb_ = (long)bh * NC + (c_);                                    \
        _Pragma("unroll")                                                         \
        for (int i_ = 0; i_ < 4; ++i_) {                                          \
            const int ur_ = (tid << 2) + i_;                                      \
            rreg[i_] = *(const uint4*)(Rg + (cb_ * CS + (ur_ >> 4)) * DHEAD + ((ur_ & 15) << 3)); \
            kreg[i_] = *(const uint4*)(Ktg + (cb_ * DHEAD + (ur_ >> 3)) * CS + ((ur_ & 7) << 3)); \
        }                                                                         \
        if (tid < 64) greg = Gcum[cb_ * CS + tid];                                \
    } while (0)

#define SEQ_STAGE_WRITE(bufi_) do {                                               \
        __hip_bfloat16* rb_ = (__hip_bfloat16*)(smem + (bufi_) * 17408);          \
        __hip_bfloat16* kb2_ = (__hip_bfloat16*)(smem + 34816 + (bufi_) * 18432); \
        _Pragma("unroll")                                                         \
        for (int i_ = 0; i_ < 4; ++i_) {                                          \
            const int ur_ = (tid << 2) + i_;                                      \
            *(uint4*)(rb_ + (ur_ >> 4) * 136 + ((ur_ & 15) << 3)) = rreg[i_];     \
            *(uint4*)(kb2_ + (ur_ >> 3) * 72 + ((ur_ & 7) << 3)) = kreg[i_];      \
        }                                                                         \
        if (tid < 64) sG[(bufi_) * 64 + tid] = greg;                              \
    } while (0)

    SEQ_STAGE_LOAD(0);
    SEQ_STAGE_WRITE(0);
    __syncthreads();

    for (int c = 0; c < NC; ++c) {
        const int cur = c & 1;
        const long chnk = (long)bh * NC + c;
        const __hip_bfloat16* Rl = (const __hip_bfloat16*)(smem + cur * 17408);
        const __hip_bfloat16* Ktl = (const __hip_bfloat16*)(smem + 34816 + cur * 18432);
        const float g63 = sG[cur * 64 + 63];
        const float a63 = expf(g63);

        unsigned short d0r[4];
#pragma unroll
        for (int r = 0; r < 4; ++r) {
            const int t = w * 16 + rq + r;
            d0r[r] = *(const unsigned short*)(dvX + (chnk * CS + t) * DHEAD + j0 + fr);
        }

        if (c + 1 < NC) SEQ_STAGE_LOAD(c + 1);

        {
            const int j = tid >> 4, k0 = (tid & 15) * 8;
            const uint4 v = *(const uint4*)&Stl[j * 136 + k0];
            *(uint4*)(Ssnap + (chnk * 128 + j0 + j) * 128 + k0) = v;
        }

        // step A: dv = dv0 + R @ S
        f32x4 acc = (f32x4)0.0f;
#pragma unroll
        for (int ks = 0; ks < 4; ++ks) {
            const bf16x8 bfrag = *(const bf16x8*)&Stl[fr * 136 + ks * 32 + fk8];
            const bf16x8 afrag = *(const bf16x8*)&Rl[(w * 16 + fr) * 136 + ks * 32 + fk8];
            acc = __builtin_amdgcn_mfma_f32_16x16x32_bf16(afrag, bfrag, acc, 0, 0, 0);
        }
#pragma unroll
        for (int r = 0; r < 4; ++r) {
            const int t = w * 16 + rq + r;
            const float rk = expf(g63 - sG[cur * 64 + t]);
            const float dv = acc[r] + bfbits2f(d0r[r]);
            *(unsigned short*)(dvX + (chnk * CS + t) * DHEAD + j0 + fr) = bf16_bits(dv);
            dvT[fr * 72 + t] = __float2bfloat16(rk * dv);
        }

        if (c + 1 < NC) SEQ_STAGE_WRITE(cur ^ 1);
        __syncthreads();

        // step B: S' = a63*S + K^T @ dvs
#pragma unroll
        for (int mj = 0; mj < 2; ++mj) SM[mj] *= a63;
#pragma unroll
        for (int ks = 0; ks < 2; ++ks) {
            const bf16x8 bfrag = *(const bf16x8*)&dvT[fr * 72 + ks * 32 + fk8];
#pragma unroll
            for (int mj = 0; mj < 2; ++mj) {
                const bf16x8 afrag = *(const bf16x8*)&Ktl[(w * 32 + mj * 16 + fr) * 72 + ks * 32 + fk8];
                SM[mj] = __builtin_amdgcn_mfma_f32_16x16x32_bf16(afrag, bfrag, SM[mj], 0, 0, 0);
            }
        }
#pragma unroll
        for (int mj = 0; mj < 2; ++mj)
#pragma unroll
            for (int r = 0; r < 4; ++r) {
                const int kk = w * 32 + mj * 16 + rq + r;
                Stl[fr * 136 + kk] = __float2bfloat16(SM[mj][r]);
            }
        __syncthreads();
    }

#pragma unroll
    for (int mj = 0; mj < 2; ++mj)
#pragma unroll
        for (int r = 0; r < 4; ++r) {
            const int kk = w * 32 + mj * 16 + rq + r;
            Sout[((long)bh * 128 + kk) * 128 + j0 + fr] = SM[mj][r];
        }
#undef SEQ_STAGE_LOAD
#undef SEQ_STAGE_WRITE
}

// --------- Phase C (parallel): o = e^{G_t}*(q_t @ S0snap) + M @ dv ----------
__global__ __launch_bounds__(256) void chunk_out(
    const __hip_bfloat16* __restrict__ qb, const float* __restrict__ Gcum,
    const __hip_bfloat16* __restrict__ dvX, const __hip_bfloat16* __restrict__ Ssnap,
    const __hip_bfloat16* __restrict__ Mmat, __hip_bfloat16* __restrict__ ob)
{
    const int bh = blockIdx.x >> 5;
    const int c  = blockIdx.x & 31;
    const int b = bh >> 3, h = bh & 7;
    const int tid = threadIdx.x;
    const long row0 = (long)b * TLEN + (long)c * CS;
    const long chnk = (long)bh * NC + c;

    __shared__ __align__(16) __hip_bfloat16 Ssn[128][136];   // [j][kk]
    __shared__ __align__(16) __hip_bfloat16 dvq[64][136];    // dv, later q
    __shared__ __align__(16) __hip_bfloat16 Ml[64][72];

    {
        const int j = tid >> 1;
        const int d0 = (tid & 1) * 64;
        const uint4* sp = (const uint4*)(Ssnap + (chnk * 128 + j) * 128 + d0);
#pragma unroll
        for (int i = 0; i < 8; ++i)
            *(uint4*)&Ssn[j][d0 + i * 8] = sp[i];
    }
    {
        const int t = tid >> 2;
        const int s0 = (tid & 3) * 32;
        const uint4* dp = (const uint4*)(dvX + (chnk * CS + t) * DHEAD + s0);
#pragma unroll
        for (int i = 0; i < 4; ++i)
            *(uint4*)&dvq[t][s0 + i * 8] = dp[i];
    }
    {
        const int t = tid >> 2;
        const int s0 = (tid & 3) * 16;
        const uint4* mp = (const uint4*)(Mmat + (chnk * CS + t) * CS + s0);
        *(uint4*)&Ml[t][s0]     = mp[0];
        *(uint4*)&Ml[t][s0 + 8] = mp[1];
    }
    __syncthreads();

    const int t = tid >> 2;
    const int j0l = (tid & 3) * 32;
    float acc[32];
#pragma unroll
    for (int j = 0; j < 32; ++j) acc[j] = 0.0f;

    for (int s = 0; s < CS; ++s) {
        const float m = __bfloat162float(Ml[t][s]);
#pragma unroll
        for (int j = 0; j < 32; ++j)
            acc[j] = fmaf(m, __bfloat162float(dvq[s][j0l + j]), acc[j]);
    }
    __syncthreads();

    {
        const int r = tid >> 2, d0 = (tid & 3) * 32;
        const uint4* qp = (const uint4*)(qb + (row0 + r) * DDIM + h * DHEAD + d0);
#pragma unroll
        for (int i = 0; i < 4; ++i)
            *(uint4*)&dvq[r][d0 + i * 8] = qp[i];
    }
    __syncthreads();

    const float At = expf(Gcum[chnk * CS + t]);
    for (int kk = 0; kk < 128; ++kk) {
        const float qv = At * __bfloat162float(dvq[t][kk]);
#pragma unroll
        for (int j = 0; j < 32; ++j)
            acc[j] = fmaf(qv, __bfloat162float(Ssn[j0l + j][kk]), acc[j]);
    }

    __hip_bfloat16* op = ob + (row0 + t) * DDIM + h * DHEAD + j0l;
#pragma unroll
    for (int i = 0; i < 4; ++i)
        *(uint4*)(op + i * 8) = pack8_bf16(&acc[i * 8]);
}

extern "C" void kernel_launch(void* const* d_in, const int* in_sizes, int n_in,
                              void* d_out, int out_size, void* d_ws, size_t ws_size,
                              hipStream_t stream) {
    const float* x     = (const float*)d_in[0];
    const float* S0    = (const float*)d_in[1];
    const float* wq    = (const float*)d_in[2];
    const float* wk    = (const float*)d_in[3];
    const float* wv    = (const float*)d_in[4];
    const float* wb    = (const float*)d_in[5];
    const float* wg    = (const float*)d_in[6];
    const float* wo    = (const float*)d_in[7];
    const float* wgate = (const float*)d_in[8];
    const float* wup   = (const float*)d_in[9];
    const float* wdown = (const float*)d_in[10];

    const int M = BSZ * TLEN;  // 4096 token rows

    float* out  = (float*)d_out;
    float* Sout = out + (long)M * DDIM;

    // Workspace layout, peak 76.5 MiB (proven budget: 81 MiB).
    char* w = (char*)d_ws;
    const size_t MB = 1u << 20;
    const size_t KB = 1u << 10;
    __hip_bfloat16* qbh   = (__hip_bfloat16*)(w + 0 * MB);
    __hip_bfloat16* kbh   = (__hip_bfloat16*)(w + 8 * MB);
    __hip_bfloat16* vbh   = (__hip_bfloat16*)(w + 16 * MB);
    float*          beta  = (float*)(w + 24 * MB);
    float*          alpha = (float*)(w + 24 * MB + 128 * KB);
    float*          Gcum  = (float*)(w + 24 * MB + 256 * KB);
    __hip_bfloat16* Mmat  = (__hip_bfloat16*)(w + 24 * MB + 512 * KB); // prep->out (4MB)
    __hip_bfloat16* dvX   = (__hip_bfloat16*)(w + 28 * MB + 512 * KB); // prep->out (8MB)
    __hip_bfloat16* Rg    = (__hip_bfloat16*)(w + 36 * MB + 512 * KB); // prep->seq (8MB)
    __hip_bfloat16* xnb   = (__hip_bfloat16*)(w + 36 * MB + 512 * KB); // rms1->QKV (dead before Rg)
    __hip_bfloat16* Ktg   = (__hip_bfloat16*)(w + 44 * MB + 512 * KB); // prep->seq (8MB)
    __hip_bfloat16* Ssnap = (__hip_bfloat16*)(w + 52 * MB + 512 * KB); // seq->out (16MB)
    __hip_bfloat16* wqt   = (__hip_bfloat16*)(w + 68 * MB + 512 * KB);
    __hip_bfloat16* wkt   = (__hip_bfloat16*)(w + 70 * MB + 512 * KB);
    __hip_bfloat16* wvt   = (__hip_bfloat16*)(w + 72 * MB + 512 * KB);
    __hip_bfloat16* wot   = (__hip_bfloat16*)(w + 74 * MB + 512 * KB);
    __hip_bfloat16* obufb = (__hip_bfloat16*)(w + 8 * MB);
    __hip_bfloat16* xn2b  = (__hip_bfloat16*)(w + 8 * MB);
    __hip_bfloat16* wdt   = (__hip_bfloat16*)(w + 16 * MB);
    __hip_bfloat16* wgt   = (__hip_bfloat16*)(w + 24 * MB + 512 * KB);
    __hip_bfloat16* wut   = (__hip_bfloat16*)(w + 32 * MB + 512 * KB);
    __hip_bfloat16* Hb    = (__hip_bfloat16*)(w + 40 * MB + 512 * KB);

    // 0) weight transpose+convert (W[K,N] -> Wt[N,K] bf16)
    transpose_cvt<<<dim3(DDIM / 32, DDIM / 32), 256, 0, stream>>>(wq, wqt, DDIM, DDIM);
    transpose_cvt<<<dim3(DDIM / 32, DDIM / 32), 256, 0, stream>>>(wk, wkt, DDIM, DDIM);
    transpose_cvt<<<dim3(DDIM / 32, DDIM / 32), 256, 0, stream>>>(wv, wvt, DDIM, DDIM);
    transpose_cvt<<<dim3(DDIM / 32, DDIM / 32), 256, 0, stream>>>(wo, wot, DDIM, DDIM);

    // 1) norms / gates
    rmsnorm_k<<<M, 256, 0, stream>>>(x, xnb);
    ba_kernel<<<M, 64, 0, stream>>>(x, wb, wg, beta, alpha);

    // 2) q/k/v projections (bf16 out)
    dim3 gP(DDIM / 128, M / 128);
    gemm_bf16<2><<<gP, 256, 0, stream>>>(xnb, wqt, nullptr, qbh, M, DDIM, DDIM);
    gemm_bf16<2><<<gP, 256, 0, stream>>>(xnb, wkt, nullptr, kbh, M, DDIM, DDIM);
    gemm_bf16<2><<<gP, 256, 0, stream>>>(xnb, wvt, nullptr, vbh, M, DDIM, DDIM);
    postqkv<<<M * HHEADS, 64, 0, stream>>>(qbh, kbh, vbh);

    // 3) chunked delta rule
    chunk_prep<<<16 * NC, 256, 0, stream>>>(kbh, qbh, vbh, beta, alpha, Gcum, Rg, Ktg, dvX, Mmat);
    chunk_seq_mfma<<<16 * SEQGV, 256, 0, stream>>>(S0, Gcum, Rg, Ktg, dvX, Ssnap, Sout);
    chunk_out<<<16 * NC, 256, 0, stream>>>(qbh, Gcum, dvX, Ssnap, Mmat, obufb);

    // 4) x1 = x + o @ wo
    gemm_bf16<1><<<gP, 256, 0, stream>>>(obufb, wot, x, out, M, DDIM, DDIM);

    // 4b) remaining weight transposes into now-dead regions
    transpose_cvt<<<dim3(DDIM / 32, FDIM / 32), 256, 0, stream>>>(wdown, wdt, FDIM, DDIM);
    transpose_cvt<<<dim3(FDIM / 32, DDIM / 32), 256, 0, stream>>>(wgate, wgt, DDIM, FDIM);
    transpose_cvt<<<dim3(FDIM / 32, DDIM / 32), 256, 0, stream>>>(wup, wut, DDIM, FDIM);

    // 5) xn2 = rms_norm(x1)
    rmsnorm_k<<<M, 256, 0, stream>>>(out, xn2b);

    // 6) H = silu(xn2 @ w_gate) * (xn2 @ w_up)  -- 128x64 tile
    dim3 gGU(FDIM / 64, M / 128);
    gemm_gateup_bf16<<<gGU, 256, 0, stream>>>(xn2b, wgt, wut, Hb, M, FDIM, DDIM);

    // 7) x_out = x1 + H @ w_down
    dim3 gDN(DDIM / 128, M / 128);
    gemm_bf16<1><<<gDN, 256, 0, stream>>>(Hb, wdt, out, out, M, DDIM, FDIM);
}

// Round 9
// 536.162 us; speedup vs baseline: 1.7042x; 1.2184x over previous
//
#include <hip/hip_runtime.h>
#include <hip/hip_bf16.h>
#include <math.h>

// Sizes fixed by the problem: B=2, T=2048, D=1024, F=4096, H=8, DH=128.
#define BSZ 2
#define TLEN 2048
#define DDIM 1024
#define FDIM 4096
#define HHEADS 8
#define DHEAD 128
#define NC 32   // chunks per sequence
#define CS 64   // chunk size (CS*NC == TLEN)

typedef __bf16 bf16x8 __attribute__((ext_vector_type(8)));
typedef float f32x4 __attribute__((ext_vector_type(4)));

__device__ __forceinline__ float silu_f(float x) {
    return x / (1.0f + expf(-x));
}

__device__ __forceinline__ void load_lds16(const void* g, void* l) {
    __builtin_amdgcn_global_load_lds(
        (const __attribute__((address_space(1))) void*)g,
        (__attribute__((address_space(3))) void*)l, 16, 0, 0);
}

__device__ __forceinline__ unsigned short bf16_bits(float f) {
    __hip_bfloat16 h = __float2bfloat16(f);
    return *reinterpret_cast<unsigned short*>(&h);
}

__device__ __forceinline__ float bfbits2f(unsigned short u) {
    union { unsigned int i; float f; } c;
    c.i = ((unsigned int)u) << 16;
    return c.f;
}

__device__ __forceinline__ uint4 pack8_bf16(const float* f) {
    union { unsigned short u[8]; uint4 v; } r;
#pragma unroll
    for (int i = 0; i < 8; ++i) r.u[i] = bf16_bits(f[i]);
    return r.v;
}

// ---------------- RMSNorm: one block (256 thr) per row of 1024; bf16 out -----
struct alignas(8) bh4 { __hip_bfloat16 a, b, c, d; };

__global__ __launch_bounds__(256) void rmsnorm_k(const float* __restrict__ in,
                                                 __hip_bfloat16* __restrict__ out) {
    const long row = blockIdx.x;
    const int tid = threadIdx.x;
    const float4 x = *(const float4*)(in + row * DDIM + tid * 4);
    float ss = x.x * x.x + x.y * x.y + x.z * x.z + x.w * x.w;
    ss += __shfl_xor(ss, 1);
    ss += __shfl_xor(ss, 2);
    ss += __shfl_xor(ss, 4);
    ss += __shfl_xor(ss, 8);
    ss += __shfl_xor(ss, 16);
    ss += __shfl_xor(ss, 32);
    __shared__ float wsum[4];
    if ((tid & 63) == 0) wsum[tid >> 6] = ss;
    __syncthreads();
    const float tot = wsum[0] + wsum[1] + wsum[2] + wsum[3];
    const float sc = rsqrtf(tot * (1.0f / (float)DDIM) + 1e-6f);
    bh4 y;
    y.a = __float2bfloat16(x.x * sc);
    y.b = __float2bfloat16(x.y * sc);
    y.c = __float2bfloat16(x.z * sc);
    y.d = __float2bfloat16(x.w * sc);
    *(bh4*)(out + row * DDIM + tid * 4) = y;
}

// ------------- transpose + f32->bf16: W[K,N] -> Wt[N,K] -------------
__global__ __launch_bounds__(256) void transpose_cvt(const float* __restrict__ W,
                                                     __hip_bfloat16* __restrict__ Wt,
                                                     int K, int N) {
    __shared__ float t[32][33];
    const int n0 = blockIdx.x * 32, k0 = blockIdx.y * 32;
    const int tx = threadIdx.x & 31, ty = threadIdx.x >> 5;  // ty 0..7
#pragma unroll
    for (int i = 0; i < 4; ++i)
        t[ty * 4 + i][tx] = W[(long)(k0 + ty * 4 + i) * N + n0 + tx];
    __syncthreads();
#pragma unroll
    for (int i = 0; i < 4; ++i)
        Wt[(long)(n0 + ty * 4 + i) * K + k0 + tx] = __float2bfloat16(t[tx][ty * 4 + i]);
}

// ---------------- bf16 MFMA GEMM: C[M,N] = A[M,K] @ Bt[N,K]^T -------
// MODE 0: f32 out. MODE 1: f32 out + f32 resid. MODE 2: bf16 out.
template <int MODE>
__global__ __launch_bounds__(256) void gemm_bf16(const __hip_bfloat16* __restrict__ A,
                                                 const __hip_bfloat16* __restrict__ Bt,
                                                 const float* __restrict__ resid,
                                                 void* __restrict__ Cout,
                                                 int M, int N, int K) {
    __shared__ __align__(16) short As[128 * 32];
    __shared__ __align__(16) short Bs[128 * 32];
    const int tid = threadIdx.x;
    const int w = tid >> 6, l = tid & 63;
    const int m0 = blockIdx.y * 128, n0 = blockIdx.x * 128;
    const int srow = (w << 4) + (l >> 2);
    const int skcol = (l & 3) * 8;
    const int wr = w >> 1, wc = w & 1;
    const int fr = l & 15;
    const int fkB = (l >> 4) * 16;

    f32x4 acc[4][4];
#pragma unroll
    for (int m = 0; m < 4; ++m)
#pragma unroll
        for (int n = 0; n < 4; ++n) acc[m][n] = (f32x4)0.0f;

    const __hip_bfloat16* Abase = A + (long)m0 * K + skcol;
    const __hip_bfloat16* Bbase = Bt + (long)n0 * K + skcol;

    for (int k0 = 0; k0 < K; k0 += 32) {
#pragma unroll
        for (int j = 0; j < 2; ++j) {
            const int row = srow + j * 64;
            load_lds16(Abase + (long)row * K + k0, (char*)As + w * 1024 + j * 4096);
            load_lds16(Bbase + (long)row * K + k0, (char*)Bs + w * 1024 + j * 4096);
        }
        __syncthreads();
        bf16x8 av[4], bv[4];
#pragma unroll
        for (int m = 0; m < 4; ++m) {
            av[m] = *(const bf16x8*)((char*)As + (wr * 64 + m * 16 + fr) * 64 + fkB);
            bv[m] = *(const bf16x8*)((char*)Bs + (wc * 64 + m * 16 + fr) * 64 + fkB);
        }
#pragma unroll
        for (int m = 0; m < 4; ++m)
#pragma unroll
            for (int n = 0; n < 4; ++n)
                acc[m][n] = __builtin_amdgcn_mfma_f32_16x16x32_bf16(av[m], bv[n], acc[m][n], 0, 0, 0);
        __syncthreads();
    }

    const int r0 = (l >> 4) * 4;
    const int cc = l & 15;
#pragma unroll
    for (int m = 0; m < 4; ++m) {
#pragma unroll
        for (int r = 0; r < 4; ++r) {
            const long row = m0 + wr * 64 + m * 16 + r0 + r;
            const long colb = n0 + wc * 64 + cc;
            if (MODE == 2) {
                __hip_bfloat16* cb = (__hip_bfloat16*)Cout + row * N + colb;
#pragma unroll
                for (int n = 0; n < 4; ++n)
                    cb[n * 16] = __float2bfloat16(acc[m][n][r]);
            } else {
                float* cp = (float*)Cout + row * N + colb;
                const float* rp = resid + row * N + colb;
#pragma unroll
                for (int n = 0; n < 4; ++n) {
                    float v = acc[m][n][r];
                    if (MODE == 1) v += rp[n * 16];
                    cp[n * 16] = v;
                }
            }
        }
    }
}

// ---- dual-B MFMA GEMM for SwiGLU: H = bf16( silu(A@Wg^T) * (A@Wu^T) ) ------
// Block tile 128x64, 4 waves (2x2), per wave 4x2 fragments per matrix.
__global__ __launch_bounds__(256) void gemm_gateup_bf16(const __hip_bfloat16* __restrict__ A,
                                                        const __hip_bfloat16* __restrict__ Bg,
                                                        const __hip_bfloat16* __restrict__ Bu,
                                                        __hip_bfloat16* __restrict__ Hb,
                                                        int M, int N, int K) {
    __shared__ __align__(16) short As[128 * 32];   // 8 KB
    __shared__ __align__(16) short Bgs[64 * 32];   // 4 KB
    __shared__ __align__(16) short Bus[64 * 32];   // 4 KB
    const int tid = threadIdx.x;
    const int w = tid >> 6, l = tid & 63;
    const int m0 = blockIdx.y * 128, n0 = blockIdx.x * 64;
    const int srow = (w << 4) + (l >> 2);
    const int skcol = (l & 3) * 8;
    const int wr = w >> 1, wc = w & 1;
    const int fr = l & 15;
    const int fkB = (l >> 4) * 16;

    f32x4 accg[4][2], accu[4][2];
#pragma unroll
    for (int m = 0; m < 4; ++m)
#pragma unroll
        for (int n = 0; n < 2; ++n) { accg[m][n] = (f32x4)0.0f; accu[m][n] = (f32x4)0.0f; }

    const __hip_bfloat16* Abase = A + (long)m0 * K + skcol;
    const __hip_bfloat16* Bgb = Bg + (long)n0 * K + skcol;
    const __hip_bfloat16* Bub = Bu + (long)n0 * K + skcol;

    for (int k0 = 0; k0 < K; k0 += 32) {
#pragma unroll
        for (int j = 0; j < 2; ++j)
            load_lds16(Abase + (long)(srow + j * 64) * K + k0, (char*)As + w * 1024 + j * 4096);
        load_lds16(Bgb + (long)srow * K + k0, (char*)Bgs + w * 1024);
        load_lds16(Bub + (long)srow * K + k0, (char*)Bus + w * 1024);
        __syncthreads();
        bf16x8 av[4], bgv[2], buv[2];
#pragma unroll
        for (int m = 0; m < 4; ++m)
            av[m] = *(const bf16x8*)((char*)As + (wr * 64 + m * 16 + fr) * 64 + fkB);
#pragma unroll
        for (int n = 0; n < 2; ++n) {
            bgv[n] = *(const bf16x8*)((char*)Bgs + (wc * 32 + n * 16 + fr) * 64 + fkB);
            buv[n] = *(const bf16x8*)((char*)Bus + (wc * 32 + n * 16 + fr) * 64 + fkB);
        }
#pragma unroll
        for (int m = 0; m < 4; ++m)
#pragma unroll
            for (int n = 0; n < 2; ++n) {
                accg[m][n] = __builtin_amdgcn_mfma_f32_16x16x32_bf16(av[m], bgv[n], accg[m][n], 0, 0, 0);
                accu[m][n] = __builtin_amdgcn_mfma_f32_16x16x32_bf16(av[m], buv[n], accu[m][n], 0, 0, 0);
            }
        __syncthreads();
    }

    const int r0 = (l >> 4) * 4;
    const int cc = l & 15;
#pragma unroll
    for (int m = 0; m < 4; ++m) {
#pragma unroll
        for (int r = 0; r < 4; ++r) {
            const long row = m0 + wr * 64 + m * 16 + r0 + r;
            __hip_bfloat16* hp = Hb + row * N + n0 + wc * 32 + cc;
#pragma unroll
            for (int n = 0; n < 2; ++n)
                hp[n * 16] = __float2bfloat16(silu_f(accg[m][n][r]) * accu[m][n][r]);
        }
    }
}

// ------- beta/alpha: inline rmsnorm (scale folds out of the dot) -------
__global__ __launch_bounds__(64) void ba_kernel(const float* __restrict__ x,
                                                const float* __restrict__ wb,
                                                const float* __restrict__ wg,
                                                float* __restrict__ beta,
                                                float* __restrict__ alpha) {
    const long row = blockIdx.x;
    const int tid = threadIdx.x;
    const int o = tid >> 2;
    const int p = tid & 3;
    const float* w = (o < 8) ? (wb + o) : (wg + (o - 8));
    const float* xr = x + row * DDIM + p * 256;
    const float* wr = w + (long)(p * 256) * HHEADS;
    float acc = 0.0f, ss = 0.0f;
#pragma unroll 8
    for (int i = 0; i < 256; ++i) {
        const float xv = xr[i];
        ss = fmaf(xv, xv, ss);
        acc = fmaf(xv, wr[(long)i * HHEADS], acc);
    }
    acc += __shfl_xor(acc, 1);
    acc += __shfl_xor(acc, 2);
    ss += __shfl_xor(ss, 1);
    ss += __shfl_xor(ss, 2);
    if (p == 0) {
        const float sc = rsqrtf(ss * (1.0f / (float)DDIM) + 1e-6f);
        const float val = 1.0f / (1.0f + expf(-acc * sc));
        if (o < 8) beta[row * HHEADS + o] = val;
        else       alpha[row * HHEADS + (o - 8)] = val;
    }
}

// ------- post-projection (bf16 in-place): silu + l2norm on q,k; silu on v ----
__global__ __launch_bounds__(64) void postqkv(__hip_bfloat16* __restrict__ q,
                                              __hip_bfloat16* __restrict__ k,
                                              __hip_bfloat16* __restrict__ v) {
    const long r = blockIdx.x;
    const int tid = threadIdx.x;
    {
        unsigned int* qp = (unsigned int*)(q + r * DHEAD + tid * 2);
        const unsigned int wbits = *qp;
        float y0 = silu_f(bfbits2f(wbits & 0xffff));
        float y1 = silu_f(bfbits2f(wbits >> 16));
        float ss = y0 * y0 + y1 * y1;
        ss += __shfl_xor(ss, 1);  ss += __shfl_xor(ss, 2);
        ss += __shfl_xor(ss, 4);  ss += __shfl_xor(ss, 8);
        ss += __shfl_xor(ss, 16); ss += __shfl_xor(ss, 32);
        const float sc = rsqrtf(ss + 1e-6f);
        *qp = (unsigned int)bf16_bits(y0 * sc) | ((unsigned int)bf16_bits(y1 * sc) << 16);
    }
    {
        unsigned int* kp = (unsigned int*)(k + r * DHEAD + tid * 2);
        const unsigned int wbits = *kp;
        float y0 = silu_f(bfbits2f(wbits & 0xffff));
        float y1 = silu_f(bfbits2f(wbits >> 16));
        float ss = y0 * y0 + y1 * y1;
        ss += __shfl_xor(ss, 1);  ss += __shfl_xor(ss, 2);
        ss += __shfl_xor(ss, 4);  ss += __shfl_xor(ss, 8);
        ss += __shfl_xor(ss, 16); ss += __shfl_xor(ss, 32);
        const float sc = rsqrtf(ss + 1e-6f);
        *kp = (unsigned int)bf16_bits(y0 * sc) | ((unsigned int)bf16_bits(y1 * sc) << 16);
    }
    {
        unsigned int* vp = (unsigned int*)(v + r * DHEAD + tid * 2);
        const unsigned int wbits = *vp;
        *vp = (unsigned int)bf16_bits(silu_f(bfbits2f(wbits & 0xffff)))
            | ((unsigned int)bf16_bits(silu_f(bfbits2f(wbits >> 16))) << 16);
    }
}

// ============ Chunked gated delta rule (log-space decay) ============
// G_t = sum_{s<=t} log(a_s) within chunk; ratio(t,s)=exp(G_t-G_s)<=1 for s<=t.
//   dv = dv0 + R @ S0,   R = -Tinv @ diag(b_s e^{G_s}) @ K   (precomputed)
//   dv0 = Tinv @ (b (.) v)                                    (precomputed)
//   o_t = e^{G_t} (S0^T q_t) + (M @ dv)_t                     (M precomputed)
//   S_end = e^{G63} S0 + K^T @ diag(e^{G63-G_t}) dv

// --------- Phase A (parallel over bh x chunk): G, M, R, K^T, dv0 ------------
__global__ __launch_bounds__(256) void chunk_prep(
    const __hip_bfloat16* __restrict__ kb, const __hip_bfloat16* __restrict__ qb,
    const __hip_bfloat16* __restrict__ vb, const float* __restrict__ betab,
    const float* __restrict__ alphab, float* __restrict__ Gcum,
    __hip_bfloat16* __restrict__ Rg, __hip_bfloat16* __restrict__ Ktg,
    __hip_bfloat16* __restrict__ dvX, __hip_bfloat16* __restrict__ Mmat)
{
    const int bh = blockIdx.x >> 5;
    const int c  = blockIdx.x & 31;
    const int b = bh >> 3, h = bh & 7;
    const int tid = threadIdx.x;
    const int w = tid >> 6, l = tid & 63;
    const int fr = l & 15;           // fragment col / A-row low
    const int fk8 = (l >> 4) * 8;    // fragment k base (bf16 elems)
    const int fr4 = (l >> 4) * 4;    // C-fragment row base

    __shared__ __align__(16) __hip_bfloat16 tA[64][136];   // k chunk
    __shared__ __align__(16) __hip_bfloat16 tB[64][136];   // q chunk, later b*v
    __shared__ float Ti[64][65];
    __shared__ float sa[64], sb_[64], sG[64], swB[64];

    const long row0 = (long)b * TLEN + (long)c * CS;
    const long chnk = (long)bh * NC + c;

    if (tid < 64) {
        sa[tid]  = alphab[(row0 + tid) * HHEADS + h];
        sb_[tid] = betab[(row0 + tid) * HHEADS + h];
    }
    // load k,q chunks (bf16 direct copies)
    {
        const int r = tid >> 2;
        const int d0 = (tid & 3) * 32;
        const uint4* kp = (const uint4*)(kb + (row0 + r) * DDIM + h * DHEAD + d0);
        const uint4* qp = (const uint4*)(qb + (row0 + r) * DDIM + h * DHEAD + d0);
#pragma unroll
        for (int i = 0; i < 4; ++i) {
            *(uint4*)&tA[r][d0 + i * 8] = kp[i];
            *(uint4*)&tB[r][d0 + i * 8] = qp[i];
        }
    }
    __syncthreads();
    if (tid == 0) {
        float run = 0.0f;
        for (int t = 0; t < CS; ++t) { run += logf(sa[t]); sG[t] = run; }
    }
    __syncthreads();
    if (tid < 64) {
        Gcum[chnk * CS + tid] = sG[tid];
        swB[tid] = sb_[tid] * expf(sG[tid]);
    }
    __syncthreads();

    // ---- MFMA: W_raw = K@K^T, M_raw = Q@K^T (wave w owns rows w*16..+15) ----
    f32x4 accW[4], accM[4];
#pragma unroll
    for (int n = 0; n < 4; ++n) { accW[n] = (f32x4)0.0f; accM[n] = (f32x4)0.0f; }
#pragma unroll
    for (int ks = 0; ks < 4; ++ks) {
        const bf16x8 aW = *(const bf16x8*)&tA[w * 16 + fr][ks * 32 + fk8];
        const bf16x8 aM = *(const bf16x8*)&tB[w * 16 + fr][ks * 32 + fk8];
#pragma unroll
        for (int n = 0; n < 4; ++n) {
            const bf16x8 bfr = *(const bf16x8*)&tA[n * 16 + fr][ks * 32 + fk8];
            accW[n] = __builtin_amdgcn_mfma_f32_16x16x32_bf16(aW, bfr, accW[n], 0, 0, 0);
            accM[n] = __builtin_amdgcn_mfma_f32_16x16x32_bf16(aM, bfr, accM[n], 0, 0, 0);
        }
    }
    // epilogue: M (masked+scaled) -> global; W (masked+scaled) -> Ti upper [s][t]
#pragma unroll
    for (int n = 0; n < 4; ++n) {
        const int s = n * 16 + fr;
        const float Gs = sG[s];
#pragma unroll
        for (int r = 0; r < 4; ++r) {
            const int t = w * 16 + fr4 + r;
            const float ratio = (s <= t) ? expf(sG[t] - Gs) : 0.0f;
            Mmat[(chnk * CS + t) * CS + s] = __float2bfloat16(ratio * accM[n][r]);
            if (s < t) Ti[s][t] = sb_[t] * ratio * accW[n][r];
        }
    }
    // init Ti lower+diag (upper holds W; disjoint cells)
    {
        const int t = tid >> 2, j0 = (tid & 3) * 16;
#pragma unroll
        for (int i = 0; i < 16; ++i) {
            const int j = j0 + i;
            if (j <= t) Ti[t][j] = (j == t) ? 1.0f : 0.0f;
        }
    }
    __syncthreads();   // all MFMA reads of tB done; Ti fully initialized

    // K^T: Ktg[kk][t] = K[t][kk]   (reads tA; independent of Ti)
    {
        const int kk = tid >> 1;
        const int t0 = (tid & 1) * 32;
        __hip_bfloat16* kp = Ktg + (chnk * DHEAD + kk) * CS + t0;
        float f[8];
#pragma unroll
        for (int i = 0; i < 4; ++i) {
#pragma unroll
            for (int j2 = 0; j2 < 8; ++j2)
                f[j2] = __bfloat162float(tA[t0 + i * 8 + j2][kk]);
            *(uint4*)(kp + i * 8) = pack8_bf16(f);
        }
    }
    // load b*v into tB (q dead)
    {
        const int r = tid >> 2, d0 = (tid & 3) * 32;
        const float br = sb_[r];
        const uint4* vp = (const uint4*)(vb + (row0 + r) * DDIM + h * DHEAD + d0);
#pragma unroll
        for (int i = 0; i < 4; ++i) {
            const uint4 vv = vp[i];
            const unsigned short* u = (const unsigned short*)&vv;
            float f[8];
#pragma unroll
            for (int j = 0; j < 8; ++j) f[j] = br * bfbits2f(u[j]);
            *(uint4*)&tB[r][d0 + i * 8] = pack8_bf16(f);
        }
    }
    __syncthreads();

    // Ti = (I+W)^-1 via forward elimination; W[t][s] read from Ti[s][t]
    for (int s = 0; s < CS - 1; ++s) {
        const int t = tid & 63, jq = tid >> 6;
        if (t > s) {
            const float wt = -Ti[s][t];
            const int jlo = jq * 16;
            const int jhi = min(s, jlo + 15);
            for (int j = jlo; j <= jhi; ++j)
                Ti[t][j] = fmaf(wt, Ti[s][j], Ti[t][j]);
        }
        __syncthreads();
    }

    // R[t][kk] = -sum_{s<=t} Ti[t][s] * swB[s] * K[s][kk]   (bf16 out)
    {
        const int t = tid >> 2, j0 = (tid & 3) * 32;
        float acc[32];
#pragma unroll
        for (int j = 0; j < 32; ++j) acc[j] = 0.0f;
        for (int s = 0; s <= t; ++s) {
            const float cf = -Ti[t][s] * swB[s];
#pragma unroll
            for (int j = 0; j < 32; ++j)
                acc[j] = fmaf(cf, __bfloat162float(tA[s][j0 + j]), acc[j]);
        }
        __hip_bfloat16* rp = Rg + (chnk * CS + t) * DHEAD + j0;
#pragma unroll
        for (int i = 0; i < 4; ++i)
            *(uint4*)(rp + i * 8) = pack8_bf16(&acc[i * 8]);
    }

    // dv0 = Ti @ (b*v) -> dvX (bf16); Ti lower-triangular so s<=t
    {
        const int t = tid >> 2, j0 = (tid & 3) * 32;
        float acc[32];
#pragma unroll
        for (int j = 0; j < 32; ++j) acc[j] = 0.0f;
        for (int s = 0; s <= t; ++s) {
            const float ti = Ti[t][s];
#pragma unroll
            for (int j = 0; j < 32; ++j)
                acc[j] = fmaf(ti, __bfloat162float(tB[s][j0 + j]), acc[j]);
        }
        __hip_bfloat16* dp = dvX + (chnk * CS + t) * DHEAD + j0;
#pragma unroll
        for (int i = 0; i < 4; ++i)
            *(uint4*)(dp + i * 8) = pack8_bf16(&acc[i * 8]);
    }
}

// --------- Phase B: sequential over chunks; MFMA; 128 blocks ----------------
#define SEQGV 8
#define SEQ_LDS_BYTES 78848

__global__ __launch_bounds__(256) void chunk_seq_mfma(
    const float* __restrict__ S0in, const float* __restrict__ Gcum,
    const __hip_bfloat16* __restrict__ Rg, const __hip_bfloat16* __restrict__ Ktg,
    __hip_bfloat16* __restrict__ dvX, __hip_bfloat16* __restrict__ Ssnap,
    float* __restrict__ Sout)
{
    const int bh = blockIdx.x & 15;
    const int g  = blockIdx.x >> 4;
    const int j0 = g * 16;
    const int tid = threadIdx.x;
    const int w = tid >> 6;
    const int l = tid & 63;
    const int fr = l & 15;
    const int fk8 = (l >> 4) * 8;
    const int rq = (l >> 4) * 4;

    __shared__ __align__(16) char smem[SEQ_LDS_BYTES];
    __hip_bfloat16* dvT = (__hip_bfloat16*)(smem + 71680);   // [16 j][72 t]
    __hip_bfloat16* Stl = (__hip_bfloat16*)(smem + 73984);   // [16 j][136 kk]
    float* sG = (float*)(smem + 78336);

    f32x4 SM[2];
#pragma unroll
    for (int mj = 0; mj < 2; ++mj) {
#pragma unroll
        for (int r = 0; r < 4; ++r) {
            const int kk = w * 32 + mj * 16 + rq + r;
            const float v = S0in[((long)bh * 128 + kk) * 128 + j0 + fr];
            SM[mj][r] = v;
            Stl[fr * 136 + kk] = __float2bfloat16(v);
        }
    }

    uint4 rreg[4], kreg[4];
    float greg = 0.0f;

#define SEQ_STAGE_LOAD(c_) do {                                                   \
        const long cb_ = (long)bh * NC + (c_);                                    \
        _Pragma("unroll")                                                         \
        for (int i_ = 0; i_ < 4; ++i_) {                                          \
            const int ur_ = (tid << 2) + i_;                                      \
            rreg[i_] = *(const uint4*)(Rg + (cb_ * CS + (ur_ >> 4)) * DHEAD + ((ur_ & 15) << 3)); \
            kreg[i_] = *(const uint4*)(Ktg + (cb_ * DHEAD + (ur_ >> 3)) * CS + ((ur_ & 7) << 3)); \
        }                                                                         \
        if (tid < 64) greg = Gcum[cb_ * CS + tid];                                \
    } while (0)

#define SEQ_STAGE_WRITE(bufi_) do {                                               \
        __hip_bfloat16* rb_ = (__hip_bfloat16*)(smem + (bufi_) * 17408);          \
        __hip_bfloat16* kb2_ = (__hip_bfloat16*)(smem + 34816 + (bufi_) * 18432); \
        _Pragma("unroll")                                                         \
        for (int i_ = 0; i_ < 4; ++i_) {                                          \
            const int ur_ = (tid << 2) + i_;                                      \
            *(uint4*)(rb_ + (ur_ >> 4) * 136 + ((ur_ & 15) << 3)) = rreg[i_];     \
            *(uint4*)(kb2_ + (ur_ >> 3) * 72 + ((ur_ & 7) << 3)) = kreg[i_];      \
        }                                                                         \
        if (tid < 64) sG[(bufi_) * 64 + tid] = greg;                              \
    } while (0)

    SEQ_STAGE_LOAD(0);
    SEQ_STAGE_WRITE(0);
    __syncthreads();

    for (int c = 0; c < NC; ++c) {
        const int cur = c & 1;
        const long chnk = (long)bh * NC + c;
        const __hip_bfloat16* Rl = (const __hip_bfloat16*)(smem + cur * 17408);
        const __hip_bfloat16* Ktl = (const __hip_bfloat16*)(smem + 34816 + cur * 18432);
        const float g63 = sG[cur * 64 + 63];
        const float a63 = expf(g63);

        unsigned short d0r[4];
#pragma unroll
        for (int r = 0; r < 4; ++r) {
            const int t = w * 16 + rq + r;
            d0r[r] = *(const unsigned short*)(dvX + (chnk * CS + t) * DHEAD + j0 + fr);
        }

        if (c + 1 < NC) SEQ_STAGE_LOAD(c + 1);

        {
            const int j = tid >> 4, k0 = (tid & 15) * 8;
            const uint4 v = *(const uint4*)&Stl[j * 136 + k0];
            *(uint4*)(Ssnap + (chnk * 128 + j0 + j) * 128 + k0) = v;
        }

        // step A: dv = dv0 + R @ S
        f32x4 acc = (f32x4)0.0f;
#pragma unroll
        for (int ks = 0; ks < 4; ++ks) {
            const bf16x8 bfrag = *(const bf16x8*)&Stl[fr * 136 + ks * 32 + fk8];
            const bf16x8 afrag = *(const bf16x8*)&Rl[(w * 16 + fr) * 136 + ks * 32 + fk8];
            acc = __builtin_amdgcn_mfma_f32_16x16x32_bf16(afrag, bfrag, acc, 0, 0, 0);
        }
#pragma unroll
        for (int r = 0; r < 4; ++r) {
            const int t = w * 16 + rq + r;
            const float rk = expf(g63 - sG[cur * 64 + t]);
            const float dv = acc[r] + bfbits2f(d0r[r]);
            *(unsigned short*)(dvX + (chnk * CS + t) * DHEAD + j0 + fr) = bf16_bits(dv);
            dvT[fr * 72 + t] = __float2bfloat16(rk * dv);
        }

        if (c + 1 < NC) SEQ_STAGE_WRITE(cur ^ 1);
        __syncthreads();

        // step B: S' = a63*S + K^T @ dvs
#pragma unroll
        for (int mj = 0; mj < 2; ++mj) SM[mj] *= a63;
#pragma unroll
        for (int ks = 0; ks < 2; ++ks) {
            const bf16x8 bfrag = *(const bf16x8*)&dvT[fr * 72 + ks * 32 + fk8];
#pragma unroll
            for (int mj = 0; mj < 2; ++mj) {
                const bf16x8 afrag = *(const bf16x8*)&Ktl[(w * 32 + mj * 16 + fr) * 72 + ks * 32 + fk8];
                SM[mj] = __builtin_amdgcn_mfma_f32_16x16x32_bf16(afrag, bfrag, SM[mj], 0, 0, 0);
            }
        }
#pragma unroll
        for (int mj = 0; mj < 2; ++mj)
#pragma unroll
            for (int r = 0; r < 4; ++r) {
                const int kk = w * 32 + mj * 16 + rq + r;
                Stl[fr * 136 + kk] = __float2bfloat16(SM[mj][r]);
            }
        __syncthreads();
    }

#pragma unroll
    for (int mj = 0; mj < 2; ++mj)
#pragma unroll
        for (int r = 0; r < 4; ++r) {
            const int kk = w * 32 + mj * 16 + rq + r;
            Sout[((long)bh * 128 + kk) * 128 + j0 + fr] = SM[mj][r];
        }
#undef SEQ_STAGE_LOAD
#undef SEQ_STAGE_WRITE
}

// --------- Phase C (parallel, MFMA): o = e^{G_t}*(q_t @ S0snap) + M @ dv ----
// O[64 t][128 j] = (At*q) @ Ssn^T-form + M @ dv.
// Wave w owns t-tile w (t = w*16+..); 8 j-tiles of 16.
// Part 1: A = M[t][s] (K=64), B = dvT[j][s] (LDS transpose of dv).
// Part 2: A = At*q[t][kk] (K=128), B = Ssn[j][kk] (Ssnap rows are j already).
__global__ __launch_bounds__(256) void chunk_out(
    const __hip_bfloat16* __restrict__ qb, const float* __restrict__ Gcum,
    const __hip_bfloat16* __restrict__ dvX, const __hip_bfloat16* __restrict__ Ssnap,
    const __hip_bfloat16* __restrict__ Mmat, __hip_bfloat16* __restrict__ ob)
{
    const int bh = blockIdx.x >> 5;
    const int c  = blockIdx.x & 31;
    const int b = bh >> 3, h = bh & 7;
    const int tid = threadIdx.x;
    const int w = tid >> 6, l = tid & 63;
    const int fr = l & 15;
    const int fk8 = (l >> 4) * 8;
    const int rq = (l >> 4) * 4;
    const long row0 = (long)b * TLEN + (long)c * CS;
    const long chnk = (long)bh * NC + c;

    // LDS: Ssn [128 j][136 kk] @0 (34816 B); Ml [64 t][72 s] @34816 (9216 B);
    //      dq @44032 (18432 B): first dvT [128 j][72 s], then qAt [64 t][136 kk]
    __shared__ __align__(16) char smem[62464];
    __hip_bfloat16* Ssn = (__hip_bfloat16*)(smem);
    __hip_bfloat16* Ml  = (__hip_bfloat16*)(smem + 34816);
    __hip_bfloat16* dq  = (__hip_bfloat16*)(smem + 44032);

    // load Ssn (rows j, kk contiguous — direct B-operand layout)
    {
        const int j = tid >> 1;
        const int d0 = (tid & 1) * 64;
        const uint4* sp = (const uint4*)(Ssnap + (chnk * 128 + j) * 128 + d0);
#pragma unroll
        for (int i = 0; i < 8; ++i)
            *(uint4*)&Ssn[j * 136 + d0 + i * 8] = sp[i];
    }
    // load Ml (rows t, s contiguous — A operand of part 1)
    {
        const int t = tid >> 2;
        const int s0 = (tid & 3) * 16;
        const uint4* mp = (const uint4*)(Mmat + (chnk * CS + t) * CS + s0);
        *(uint4*)&Ml[t * 72 + s0]     = mp[0];
        *(uint4*)&Ml[t * 72 + s0 + 8] = mp[1];
    }
    // load dv rows and transpose into dq = dvT[j][s]
    {
        const int t = tid >> 2, jb = (tid & 3) * 32;
        uint4 dvr[4];
#pragma unroll
        for (int i = 0; i < 4; ++i)
            dvr[i] = ((const uint4*)(dvX + (chnk * CS + t) * DHEAD + jb))[i];
        const unsigned short* u = (const unsigned short*)&dvr[0];
#pragma unroll
        for (int i = 0; i < 32; ++i)
            dq[(jb + i) * 72 + t] = *(const __hip_bfloat16*)&u[i];
    }
    __syncthreads();

    f32x4 acc[8];
#pragma unroll
    for (int n = 0; n < 8; ++n) acc[n] = (f32x4)0.0f;

    // part 1: O += M @ dv   (K = 64: 2 k-steps)
#pragma unroll
    for (int ks = 0; ks < 2; ++ks) {
        const bf16x8 afrag = *(const bf16x8*)&Ml[(w * 16 + fr) * 72 + ks * 32 + fk8];
#pragma unroll
        for (int n = 0; n < 8; ++n) {
            const bf16x8 bfrag = *(const bf16x8*)&dq[(n * 16 + fr) * 72 + ks * 32 + fk8];
            acc[n] = __builtin_amdgcn_mfma_f32_16x16x32_bf16(afrag, bfrag, acc[n], 0, 0, 0);
        }
    }
    __syncthreads();   // dvT reads done; reuse dq for qAt

    // load q rows scaled by e^{G_t} into dq = qAt[t][136]
    {
        const int t = tid >> 2, d0 = (tid & 3) * 32;
        const float At = expf(Gcum[chnk * CS + t]);
        const uint4* qp = (const uint4*)(qb + (row0 + t) * DDIM + h * DHEAD + d0);
#pragma unroll
        for (int i = 0; i < 4; ++i) {
            const uint4 qv = qp[i];
            const unsigned short* u = (const unsigned short*)&qv;
            float f[8];
#pragma unroll
            for (int j = 0; j < 8; ++j) f[j] = At * bfbits2f(u[j]);
            *(uint4*)&dq[t * 136 + d0 + i * 8] = pack8_bf16(f);
        }
    }
    __syncthreads();

    // part 2: O += (At*q) @ S0   (K = 128: 4 k-steps)
#pragma unroll
    for (int ks = 0; ks < 4; ++ks) {
        const bf16x8 afrag = *(const bf16x8*)&dq[(w * 16 + fr) * 136 + ks * 32 + fk8];
#pragma unroll
        for (int n = 0; n < 8; ++n) {
            const bf16x8 bfrag = *(const bf16x8*)&Ssn[(n * 16 + fr) * 136 + ks * 32 + fk8];
            acc[n] = __builtin_amdgcn_mfma_f32_16x16x32_bf16(afrag, bfrag, acc[n], 0, 0, 0);
        }
    }

    // epilogue: O[t][j] -> ob (col j = fr, row t = w*16 + rq + r)
#pragma unroll
    for (int r = 0; r < 4; ++r) {
        const int t = w * 16 + rq + r;
        __hip_bfloat16* op = ob + (row0 + t) * DDIM + h * DHEAD + fr;
#pragma unroll
        for (int n = 0; n < 8; ++n)
            op[n * 16] = __float2bfloat16(acc[n][r]);
    }
}

extern "C" void kernel_launch(void* const* d_in, const int* in_sizes, int n_in,
                              void* d_out, int out_size, void* d_ws, size_t ws_size,
                              hipStream_t stream) {
    const float* x     = (const float*)d_in[0];
    const float* S0    = (const float*)d_in[1];
    const float* wq    = (const float*)d_in[2];
    const float* wk    = (const float*)d_in[3];
    const float* wv    = (const float*)d_in[4];
    const float* wb    = (const float*)d_in[5];
    const float* wg    = (const float*)d_in[6];
    const float* wo    = (const float*)d_in[7];
    const float* wgate = (const float*)d_in[8];
    const float* wup   = (const float*)d_in[9];
    const float* wdown = (const float*)d_in[10];

    const int M = BSZ * TLEN;  // 4096 token rows

    float* out  = (float*)d_out;
    float* Sout = out + (long)M * DDIM;

    // Workspace layout, peak 76.5 MiB (proven budget: 81 MiB).
    char* w = (char*)d_ws;
    const size_t MB = 1u << 20;
    const size_t KB = 1u << 10;
    __hip_bfloat16* qbh   = (__hip_bfloat16*)(w + 0 * MB);
    __hip_bfloat16* kbh   = (__hip_bfloat16*)(w + 8 * MB);
    __hip_bfloat16* vbh   = (__hip_bfloat16*)(w + 16 * MB);
    float*          beta  = (float*)(w + 24 * MB);
    float*          alpha = (float*)(w + 24 * MB + 128 * KB);
    float*          Gcum  = (float*)(w + 24 * MB + 256 * KB);
    __hip_bfloat16* Mmat  = (__hip_bfloat16*)(w + 24 * MB + 512 * KB); // prep->out (4MB)
    __hip_bfloat16* dvX   = (__hip_bfloat16*)(w + 28 * MB + 512 * KB); // prep->out (8MB)
    __hip_bfloat16* Rg    = (__hip_bfloat16*)(w + 36 * MB + 512 * KB); // prep->seq (8MB)
    __hip_bfloat16* xnb   = (__hip_bfloat16*)(w + 36 * MB + 512 * KB); // rms1->QKV (dead before Rg)
    __hip_bfloat16* Ktg   = (__hip_bfloat16*)(w + 44 * MB + 512 * KB); // prep->seq (8MB)
    __hip_bfloat16* Ssnap = (__hip_bfloat16*)(w + 52 * MB + 512 * KB); // seq->out (16MB)
    __hip_bfloat16* wqt   = (__hip_bfloat16*)(w + 68 * MB + 512 * KB);
    __hip_bfloat16* wkt   = (__hip_bfloat16*)(w + 70 * MB + 512 * KB);
    __hip_bfloat16* wvt   = (__hip_bfloat16*)(w + 72 * MB + 512 * KB);
    __hip_bfloat16* wot   = (__hip_bfloat16*)(w + 74 * MB + 512 * KB);
    __hip_bfloat16* obufb = (__hip_bfloat16*)(w + 8 * MB);
    __hip_bfloat16* xn2b  = (__hip_bfloat16*)(w + 8 * MB);
    __hip_bfloat16* wdt   = (__hip_bfloat16*)(w + 16 * MB);
    __hip_bfloat16* wgt   = (__hip_bfloat16*)(w + 24 * MB + 512 * KB);
    __hip_bfloat16* wut   = (__hip_bfloat16*)(w + 32 * MB + 512 * KB);
    __hip_bfloat16* Hb    = (__hip_bfloat16*)(w + 40 * MB + 512 * KB);

    // 0) weight transpose+convert (W[K,N] -> Wt[N,K] bf16)
    transpose_cvt<<<dim3(DDIM / 32, DDIM / 32), 256, 0, stream>>>(wq, wqt, DDIM, DDIM);
    transpose_cvt<<<dim3(DDIM / 32, DDIM / 32), 256, 0, stream>>>(wk, wkt, DDIM, DDIM);
    transpose_cvt<<<dim3(DDIM / 32, DDIM / 32), 256, 0, stream>>>(wv, wvt, DDIM, DDIM);
    transpose_cvt<<<dim3(DDIM / 32, DDIM / 32), 256, 0, stream>>>(wo, wot, DDIM, DDIM);

    // 1) norms / gates
    rmsnorm_k<<<M, 256, 0, stream>>>(x, xnb);
    ba_kernel<<<M, 64, 0, stream>>>(x, wb, wg, beta, alpha);

    // 2) q/k/v projections (bf16 out)
    dim3 gP(DDIM / 128, M / 128);
    gemm_bf16<2><<<gP, 256, 0, stream>>>(xnb, wqt, nullptr, qbh, M, DDIM, DDIM);
    gemm_bf16<2><<<gP, 256, 0, stream>>>(xnb, wkt, nullptr, kbh, M, DDIM, DDIM);
    gemm_bf16<2><<<gP, 256, 0, stream>>>(xnb, wvt, nullptr, vbh, M, DDIM, DDIM);
    postqkv<<<M * HHEADS, 64, 0, stream>>>(qbh, kbh, vbh);

    // 3) chunked delta rule
    chunk_prep<<<16 * NC, 256, 0, stream>>>(kbh, qbh, vbh, beta, alpha, Gcum, Rg, Ktg, dvX, Mmat);
    chunk_seq_mfma<<<16 * SEQGV, 256, 0, stream>>>(S0, Gcum, Rg, Ktg, dvX, Ssnap, Sout);
    chunk_out<<<16 * NC, 256, 0, stream>>>(qbh, Gcum, dvX, Ssnap, Mmat, obufb);

    // 4) x1 = x + o @ wo
    gemm_bf16<1><<<gP, 256, 0, stream>>>(obufb, wot, x, out, M, DDIM, DDIM);

    // 4b) remaining weight transposes into now-dead regions
    transpose_cvt<<<dim3(DDIM / 32, FDIM / 32), 256, 0, stream>>>(wdown, wdt, FDIM, DDIM);
    transpose_cvt<<<dim3(FDIM / 32, DDIM / 32), 256, 0, stream>>>(wgate, wgt, DDIM, FDIM);
    transpose_cvt<<<dim3(FDIM / 32, DDIM / 32), 256, 0, stream>>>(wup, wut, DDIM, FDIM);

    // 5) xn2 = rms_norm(x1)
    rmsnorm_k<<<M, 256, 0, stream>>>(out, xn2b);

    // 6) H = silu(xn2 @ w_gate) * (xn2 @ w_up)  -- 128x64 tile
    dim3 gGU(FDIM / 64, M / 128);
    gemm_gateup_bf16<<<gGU, 256, 0, stream>>>(xn2b, wgt, wut, Hb, M, FDIM, DDIM);

    // 7) x_out = x1 + H @ w_down
    dim3 gDN(DDIM / 128, M / 128);
    gemm_bf16<1><<<gDN, 256, 0, stream>>>(Hb, wdt, out, out, M, DDIM, FDIM);
}

// Round 10
// 506.899 us; speedup vs baseline: 1.8026x; 1.0577x over previous
//
#include <hip/hip_runtime.h>
#include <hip/hip_bf16.h>
#include <math.h>

// Sizes fixed by the problem: B=2, T=2048, D=1024, F=4096, H=8, DH=128.
#define BSZ 2
#define TLEN 2048
#define DDIM 1024
#define FDIM 4096
#define HHEADS 8
#define DHEAD 128
#define NC 32   // chunks per sequence
#define CS 64   // chunk size (CS*NC == TLEN)

typedef __bf16 bf16x8 __attribute__((ext_vector_type(8)));
typedef float f32x4 __attribute__((ext_vector_type(4)));

__device__ __forceinline__ float silu_f(float x) {
    return x / (1.0f + expf(-x));
}

__device__ __forceinline__ void load_lds16(const void* g, void* l) {
    __builtin_amdgcn_global_load_lds(
        (const __attribute__((address_space(1))) void*)g,
        (__attribute__((address_space(3))) void*)l, 16, 0, 0);
}

__device__ __forceinline__ unsigned short bf16_bits(float f) {
    __hip_bfloat16 h = __float2bfloat16(f);
    return *reinterpret_cast<unsigned short*>(&h);
}

__device__ __forceinline__ float bfbits2f(unsigned short u) {
    union { unsigned int i; float f; } c;
    c.i = ((unsigned int)u) << 16;
    return c.f;
}

__device__ __forceinline__ uint4 pack8_bf16(const float* f) {
    union { unsigned short u[8]; uint4 v; } r;
#pragma unroll
    for (int i = 0; i < 8; ++i) r.u[i] = bf16_bits(f[i]);
    return r.v;
}

// ---------------- RMSNorm: one block (256 thr) per row of 1024; bf16 out -----
struct alignas(8) bh4 { __hip_bfloat16 a, b, c, d; };

__global__ __launch_bounds__(256) void rmsnorm_k(const float* __restrict__ in,
                                                 __hip_bfloat16* __restrict__ out) {
    const long row = blockIdx.x;
    const int tid = threadIdx.x;
    const float4 x = *(const float4*)(in + row * DDIM + tid * 4);
    float ss = x.x * x.x + x.y * x.y + x.z * x.z + x.w * x.w;
    ss += __shfl_xor(ss, 1);
    ss += __shfl_xor(ss, 2);
    ss += __shfl_xor(ss, 4);
    ss += __shfl_xor(ss, 8);
    ss += __shfl_xor(ss, 16);
    ss += __shfl_xor(ss, 32);
    __shared__ float wsum[4];
    if ((tid & 63) == 0) wsum[tid >> 6] = ss;
    __syncthreads();
    const float tot = wsum[0] + wsum[1] + wsum[2] + wsum[3];
    const float sc = rsqrtf(tot * (1.0f / (float)DDIM) + 1e-6f);
    bh4 y;
    y.a = __float2bfloat16(x.x * sc);
    y.b = __float2bfloat16(x.y * sc);
    y.c = __float2bfloat16(x.z * sc);
    y.d = __float2bfloat16(x.w * sc);
    *(bh4*)(out + row * DDIM + tid * 4) = y;
}

// ------------- transpose + f32->bf16: W[K,N] -> Wt[N,K] -------------
__global__ __launch_bounds__(256) void transpose_cvt(const float* __restrict__ W,
                                                     __hip_bfloat16* __restrict__ Wt,
                                                     int K, int N) {
    __shared__ float t[32][33];
    const int n0 = blockIdx.x * 32, k0 = blockIdx.y * 32;
    const int tx = threadIdx.x & 31, ty = threadIdx.x >> 5;  // ty 0..7
#pragma unroll
    for (int i = 0; i < 4; ++i)
        t[ty * 4 + i][tx] = W[(long)(k0 + ty * 4 + i) * N + n0 + tx];
    __syncthreads();
#pragma unroll
    for (int i = 0; i < 4; ++i)
        Wt[(long)(n0 + ty * 4 + i) * K + k0 + tx] = __float2bfloat16(t[tx][ty * 4 + i]);
}

// ---------------- bf16 MFMA GEMM (128x128): C = A @ Bt^T -------
// MODE 0: f32 out. MODE 1: f32 out + f32 resid. MODE 2: bf16 out.
template <int MODE>
__global__ __launch_bounds__(256) void gemm_bf16(const __hip_bfloat16* __restrict__ A,
                                                 const __hip_bfloat16* __restrict__ Bt,
                                                 const float* __restrict__ resid,
                                                 void* __restrict__ Cout,
                                                 int M, int N, int K) {
    __shared__ __align__(16) short As[128 * 32];
    __shared__ __align__(16) short Bs[128 * 32];
    const int tid = threadIdx.x;
    const int w = tid >> 6, l = tid & 63;
    const int m0 = blockIdx.y * 128, n0 = blockIdx.x * 128;
    const int srow = (w << 4) + (l >> 2);
    const int skcol = (l & 3) * 8;
    const int wr = w >> 1, wc = w & 1;
    const int fr = l & 15;
    const int fkB = (l >> 4) * 16;

    f32x4 acc[4][4];
#pragma unroll
    for (int m = 0; m < 4; ++m)
#pragma unroll
        for (int n = 0; n < 4; ++n) acc[m][n] = (f32x4)0.0f;

    const __hip_bfloat16* Abase = A + (long)m0 * K + skcol;
    const __hip_bfloat16* Bbase = Bt + (long)n0 * K + skcol;

    for (int k0 = 0; k0 < K; k0 += 32) {
#pragma unroll
        for (int j = 0; j < 2; ++j) {
            const int row = srow + j * 64;
            load_lds16(Abase + (long)row * K + k0, (char*)As + w * 1024 + j * 4096);
            load_lds16(Bbase + (long)row * K + k0, (char*)Bs + w * 1024 + j * 4096);
        }
        __syncthreads();
        bf16x8 av[4], bv[4];
#pragma unroll
        for (int m = 0; m < 4; ++m) {
            av[m] = *(const bf16x8*)((char*)As + (wr * 64 + m * 16 + fr) * 64 + fkB);
            bv[m] = *(const bf16x8*)((char*)Bs + (wc * 64 + m * 16 + fr) * 64 + fkB);
        }
#pragma unroll
        for (int m = 0; m < 4; ++m)
#pragma unroll
            for (int n = 0; n < 4; ++n)
                acc[m][n] = __builtin_amdgcn_mfma_f32_16x16x32_bf16(av[m], bv[n], acc[m][n], 0, 0, 0);
        __syncthreads();
    }

    const int r0 = (l >> 4) * 4;
    const int cc = l & 15;
#pragma unroll
    for (int m = 0; m < 4; ++m) {
#pragma unroll
        for (int r = 0; r < 4; ++r) {
            const long row = m0 + wr * 64 + m * 16 + r0 + r;
            const long colb = n0 + wc * 64 + cc;
            if (MODE == 2) {
                __hip_bfloat16* cb = (__hip_bfloat16*)Cout + row * N + colb;
#pragma unroll
                for (int n = 0; n < 4; ++n)
                    cb[n * 16] = __float2bfloat16(acc[m][n][r]);
            } else {
                float* cp = (float*)Cout + row * N + colb;
                const float* rp = resid + row * N + colb;
#pragma unroll
                for (int n = 0; n < 4; ++n) {
                    float v = acc[m][n][r];
                    if (MODE == 1) v += rp[n * 16];
                    cp[n * 16] = v;
                }
            }
        }
    }
}

// ---------------- bf16 MFMA GEMM (128x64): for N=1024 shapes ----------------
// Same structure as gateup minus the second B: 4 waves (2x2), 4x2 frags,
// 32 AGPR acc, 12 KB LDS -> ~5 blocks/CU; grid 512 blocks at N=1024.
// MODE 1: f32 out + f32 resid. MODE 2: bf16 out.
template <int MODE>
__global__ __launch_bounds__(256) void gemm_n64(const __hip_bfloat16* __restrict__ A,
                                                const __hip_bfloat16* __restrict__ Bt,
                                                const float* __restrict__ resid,
                                                void* __restrict__ Cout,
                                                int M, int N, int K) {
    __shared__ __align__(16) short As[128 * 32];   // 8 KB
    __shared__ __align__(16) short Bs[64 * 32];    // 4 KB
    const int tid = threadIdx.x;
    const int w = tid >> 6, l = tid & 63;
    const int m0 = blockIdx.y * 128, n0 = blockIdx.x * 64;
    const int srow = (w << 4) + (l >> 2);
    const int skcol = (l & 3) * 8;
    const int wr = w >> 1, wc = w & 1;
    const int fr = l & 15;
    const int fkB = (l >> 4) * 16;

    f32x4 acc[4][2];
#pragma unroll
    for (int m = 0; m < 4; ++m)
#pragma unroll
        for (int n = 0; n < 2; ++n) acc[m][n] = (f32x4)0.0f;

    const __hip_bfloat16* Abase = A + (long)m0 * K + skcol;
    const __hip_bfloat16* Bbase = Bt + (long)n0 * K + skcol;

    for (int k0 = 0; k0 < K; k0 += 32) {
#pragma unroll
        for (int j = 0; j < 2; ++j)
            load_lds16(Abase + (long)(srow + j * 64) * K + k0, (char*)As + w * 1024 + j * 4096);
        load_lds16(Bbase + (long)srow * K + k0, (char*)Bs + w * 1024);
        __syncthreads();
        bf16x8 av[4], bv[2];
#pragma unroll
        for (int m = 0; m < 4; ++m)
            av[m] = *(const bf16x8*)((char*)As + (wr * 64 + m * 16 + fr) * 64 + fkB);
#pragma unroll
        for (int n = 0; n < 2; ++n)
            bv[n] = *(const bf16x8*)((char*)Bs + (wc * 32 + n * 16 + fr) * 64 + fkB);
#pragma unroll
        for (int m = 0; m < 4; ++m)
#pragma unroll
            for (int n = 0; n < 2; ++n)
                acc[m][n] = __builtin_amdgcn_mfma_f32_16x16x32_bf16(av[m], bv[n], acc[m][n], 0, 0, 0);
        __syncthreads();
    }

    const int r0 = (l >> 4) * 4;
    const int cc = l & 15;
#pragma unroll
    for (int m = 0; m < 4; ++m) {
#pragma unroll
        for (int r = 0; r < 4; ++r) {
            const long row = m0 + wr * 64 + m * 16 + r0 + r;
            const long colb = n0 + wc * 32 + cc;
            if (MODE == 2) {
                __hip_bfloat16* cb = (__hip_bfloat16*)Cout + row * N + colb;
#pragma unroll
                for (int n = 0; n < 2; ++n)
                    cb[n * 16] = __float2bfloat16(acc[m][n][r]);
            } else {
                float* cp = (float*)Cout + row * N + colb;
                const float* rp = resid + row * N + colb;
#pragma unroll
                for (int n = 0; n < 2; ++n)
                    cp[n * 16] = acc[m][n][r] + rp[n * 16];
            }
        }
    }
}

// ---- dual-B MFMA GEMM for SwiGLU: H = bf16( silu(A@Wg^T) * (A@Wu^T) ) ------
__global__ __launch_bounds__(256) void gemm_gateup_bf16(const __hip_bfloat16* __restrict__ A,
                                                        const __hip_bfloat16* __restrict__ Bg,
                                                        const __hip_bfloat16* __restrict__ Bu,
                                                        __hip_bfloat16* __restrict__ Hb,
                                                        int M, int N, int K) {
    __shared__ __align__(16) short As[128 * 32];   // 8 KB
    __shared__ __align__(16) short Bgs[64 * 32];   // 4 KB
    __shared__ __align__(16) short Bus[64 * 32];   // 4 KB
    const int tid = threadIdx.x;
    const int w = tid >> 6, l = tid & 63;
    const int m0 = blockIdx.y * 128, n0 = blockIdx.x * 64;
    const int srow = (w << 4) + (l >> 2);
    const int skcol = (l & 3) * 8;
    const int wr = w >> 1, wc = w & 1;
    const int fr = l & 15;
    const int fkB = (l >> 4) * 16;

    f32x4 accg[4][2], accu[4][2];
#pragma unroll
    for (int m = 0; m < 4; ++m)
#pragma unroll
        for (int n = 0; n < 2; ++n) { accg[m][n] = (f32x4)0.0f; accu[m][n] = (f32x4)0.0f; }

    const __hip_bfloat16* Abase = A + (long)m0 * K + skcol;
    const __hip_bfloat16* Bgb = Bg + (long)n0 * K + skcol;
    const __hip_bfloat16* Bub = Bu + (long)n0 * K + skcol;

    for (int k0 = 0; k0 < K; k0 += 32) {
#pragma unroll
        for (int j = 0; j < 2; ++j)
            load_lds16(Abase + (long)(srow + j * 64) * K + k0, (char*)As + w * 1024 + j * 4096);
        load_lds16(Bgb + (long)srow * K + k0, (char*)Bgs + w * 1024);
        load_lds16(Bub + (long)srow * K + k0, (char*)Bus + w * 1024);
        __syncthreads();
        bf16x8 av[4], bgv[2], buv[2];
#pragma unroll
        for (int m = 0; m < 4; ++m)
            av[m] = *(const bf16x8*)((char*)As + (wr * 64 + m * 16 + fr) * 64 + fkB);
#pragma unroll
        for (int n = 0; n < 2; ++n) {
            bgv[n] = *(const bf16x8*)((char*)Bgs + (wc * 32 + n * 16 + fr) * 64 + fkB);
            buv[n] = *(const bf16x8*)((char*)Bus + (wc * 32 + n * 16 + fr) * 64 + fkB);
        }
#pragma unroll
        for (int m = 0; m < 4; ++m)
#pragma unroll
            for (int n = 0; n < 2; ++n) {
                accg[m][n] = __builtin_amdgcn_mfma_f32_16x16x32_bf16(av[m], bgv[n], accg[m][n], 0, 0, 0);
                accu[m][n] = __builtin_amdgcn_mfma_f32_16x16x32_bf16(av[m], buv[n], accu[m][n], 0, 0, 0);
            }
        __syncthreads();
    }

    const int r0 = (l >> 4) * 4;
    const int cc = l & 15;
#pragma unroll
    for (int m = 0; m < 4; ++m) {
#pragma unroll
        for (int r = 0; r < 4; ++r) {
            const long row = m0 + wr * 64 + m * 16 + r0 + r;
            __hip_bfloat16* hp = Hb + row * N + n0 + wc * 32 + cc;
#pragma unroll
            for (int n = 0; n < 2; ++n)
                hp[n * 16] = __float2bfloat16(silu_f(accg[m][n][r]) * accu[m][n][r]);
        }
    }
}

// ------- beta/alpha: inline rmsnorm (scale folds out of the dot) -------
__global__ __launch_bounds__(64) void ba_kernel(const float* __restrict__ x,
                                                const float* __restrict__ wb,
                                                const float* __restrict__ wg,
                                                float* __restrict__ beta,
                                                float* __restrict__ alpha) {
    const long row = blockIdx.x;
    const int tid = threadIdx.x;
    const int o = tid >> 2;
    const int p = tid & 3;
    const float* w = (o < 8) ? (wb + o) : (wg + (o - 8));
    const float* xr = x + row * DDIM + p * 256;
    const float* wr = w + (long)(p * 256) * HHEADS;
    float acc = 0.0f, ss = 0.0f;
#pragma unroll 8
    for (int i = 0; i < 256; ++i) {
        const float xv = xr[i];
        ss = fmaf(xv, xv, ss);
        acc = fmaf(xv, wr[(long)i * HHEADS], acc);
    }
    acc += __shfl_xor(acc, 1);
    acc += __shfl_xor(acc, 2);
    ss += __shfl_xor(ss, 1);
    ss += __shfl_xor(ss, 2);
    if (p == 0) {
        const float sc = rsqrtf(ss * (1.0f / (float)DDIM) + 1e-6f);
        const float val = 1.0f / (1.0f + expf(-acc * sc));
        if (o < 8) beta[row * HHEADS + o] = val;
        else       alpha[row * HHEADS + (o - 8)] = val;
    }
}

// ------- post-projection (bf16 in-place): silu + l2norm on q,k; silu on v ----
__global__ __launch_bounds__(64) void postqkv(__hip_bfloat16* __restrict__ q,
                                              __hip_bfloat16* __restrict__ k,
                                              __hip_bfloat16* __restrict__ v) {
    const long r = blockIdx.x;
    const int tid = threadIdx.x;
    {
        unsigned int* qp = (unsigned int*)(q + r * DHEAD + tid * 2);
        const unsigned int wbits = *qp;
        float y0 = silu_f(bfbits2f(wbits & 0xffff));
        float y1 = silu_f(bfbits2f(wbits >> 16));
        float ss = y0 * y0 + y1 * y1;
        ss += __shfl_xor(ss, 1);  ss += __shfl_xor(ss, 2);
        ss += __shfl_xor(ss, 4);  ss += __shfl_xor(ss, 8);
        ss += __shfl_xor(ss, 16); ss += __shfl_xor(ss, 32);
        const float sc = rsqrtf(ss + 1e-6f);
        *qp = (unsigned int)bf16_bits(y0 * sc) | ((unsigned int)bf16_bits(y1 * sc) << 16);
    }
    {
        unsigned int* kp = (unsigned int*)(k + r * DHEAD + tid * 2);
        const unsigned int wbits = *kp;
        float y0 = silu_f(bfbits2f(wbits & 0xffff));
        float y1 = silu_f(bfbits2f(wbits >> 16));
        float ss = y0 * y0 + y1 * y1;
        ss += __shfl_xor(ss, 1);  ss += __shfl_xor(ss, 2);
        ss += __shfl_xor(ss, 4);  ss += __shfl_xor(ss, 8);
        ss += __shfl_xor(ss, 16); ss += __shfl_xor(ss, 32);
        const float sc = rsqrtf(ss + 1e-6f);
        *kp = (unsigned int)bf16_bits(y0 * sc) | ((unsigned int)bf16_bits(y1 * sc) << 16);
    }
    {
        unsigned int* vp = (unsigned int*)(v + r * DHEAD + tid * 2);
        const unsigned int wbits = *vp;
        *vp = (unsigned int)bf16_bits(silu_f(bfbits2f(wbits & 0xffff)))
            | ((unsigned int)bf16_bits(silu_f(bfbits2f(wbits >> 16))) << 16);
    }
}

// ============ Chunked gated delta rule (log-space decay) ============
// G_t = sum_{s<=t} log(a_s) within chunk; ratio(t,s)=exp(G_t-G_s)<=1 for s<=t.
//   dv = dv0 + R @ S0,   R = -Tinv @ diag(b_s e^{G_s}) @ K   (precomputed)
//   dv0 = Tinv @ (b (.) v)                                    (precomputed)
//   o_t = e^{G_t} (S0^T q_t) + (M @ dv)_t                     (M precomputed)
//   S_end = e^{G63} S0 + K^T @ diag(e^{G63-G_t}) dv

// --------- Phase A (parallel over bh x chunk): G, M, R, K^T, dv0 ------------
__global__ __launch_bounds__(256) void chunk_prep(
    const __hip_bfloat16* __restrict__ kb, const __hip_bfloat16* __restrict__ qb,
    const __hip_bfloat16* __restrict__ vb, const float* __restrict__ betab,
    const float* __restrict__ alphab, float* __restrict__ Gcum,
    __hip_bfloat16* __restrict__ Rg, __hip_bfloat16* __restrict__ Ktg,
    __hip_bfloat16* __restrict__ dvX, __hip_bfloat16* __restrict__ Mmat)
{
    const int bh = blockIdx.x >> 5;
    const int c  = blockIdx.x & 31;
    const int b = bh >> 3, h = bh & 7;
    const int tid = threadIdx.x;
    const int w = tid >> 6, l = tid & 63;
    const int fr = l & 15;           // fragment col / A-row low
    const int fk8 = (l >> 4) * 8;    // fragment k base (bf16 elems)
    const int fr4 = (l >> 4) * 4;    // C-fragment row base

    __shared__ __align__(16) __hip_bfloat16 tA[64][136];   // k chunk
    __shared__ __align__(16) __hip_bfloat16 tB[64][136];   // q chunk, later b*v
    __shared__ float Ti[64][65];
    __shared__ float sa[64], sb_[64], sG[64], swB[64];

    const long row0 = (long)b * TLEN + (long)c * CS;
    const long chnk = (long)bh * NC + c;

    if (tid < 64) {
        sa[tid]  = alphab[(row0 + tid) * HHEADS + h];
        sb_[tid] = betab[(row0 + tid) * HHEADS + h];
    }
    // load k,q chunks (bf16 direct copies)
    {
        const int r = tid >> 2;
        const int d0 = (tid & 3) * 32;
        const uint4* kp = (const uint4*)(kb + (row0 + r) * DDIM + h * DHEAD + d0);
        const uint4* qp = (const uint4*)(qb + (row0 + r) * DDIM + h * DHEAD + d0);
#pragma unroll
        for (int i = 0; i < 4; ++i) {
            *(uint4*)&tA[r][d0 + i * 8] = kp[i];
            *(uint4*)&tB[r][d0 + i * 8] = qp[i];
        }
    }
    __syncthreads();
    if (tid == 0) {
        float run = 0.0f;
        for (int t = 0; t < CS; ++t) { run += logf(sa[t]); sG[t] = run; }
    }
    __syncthreads();
    if (tid < 64) {
        Gcum[chnk * CS + tid] = sG[tid];
        swB[tid] = sb_[tid] * expf(sG[tid]);
    }
    __syncthreads();

    // ---- MFMA: W_raw = K@K^T, M_raw = Q@K^T (wave w owns rows w*16..+15) ----
    f32x4 accW[4], accM[4];
#pragma unroll
    for (int n = 0; n < 4; ++n) { accW[n] = (f32x4)0.0f; accM[n] = (f32x4)0.0f; }
#pragma unroll
    for (int ks = 0; ks < 4; ++ks) {
        const bf16x8 aW = *(const bf16x8*)&tA[w * 16 + fr][ks * 32 + fk8];
        const bf16x8 aM = *(const bf16x8*)&tB[w * 16 + fr][ks * 32 + fk8];
#pragma unroll
        for (int n = 0; n < 4; ++n) {
            const bf16x8 bfr = *(const bf16x8*)&tA[n * 16 + fr][ks * 32 + fk8];
            accW[n] = __builtin_amdgcn_mfma_f32_16x16x32_bf16(aW, bfr, accW[n], 0, 0, 0);
            accM[n] = __builtin_amdgcn_mfma_f32_16x16x32_bf16(aM, bfr, accM[n], 0, 0, 0);
        }
    }
    // epilogue: M (masked+scaled) -> global; W (masked+scaled) -> Ti upper [s][t]
#pragma unroll
    for (int n = 0; n < 4; ++n) {
        const int s = n * 16 + fr;
        const float Gs = sG[s];
#pragma unroll
        for (int r = 0; r < 4; ++r) {
            const int t = w * 16 + fr4 + r;
            const float ratio = (s <= t) ? expf(sG[t] - Gs) : 0.0f;
            Mmat[(chnk * CS + t) * CS + s] = __float2bfloat16(ratio * accM[n][r]);
            if (s < t) Ti[s][t] = sb_[t] * ratio * accW[n][r];
        }
    }
    // init Ti lower+diag (upper holds W; disjoint cells)
    {
        const int t = tid >> 2, j0 = (tid & 3) * 16;
#pragma unroll
        for (int i = 0; i < 16; ++i) {
            const int j = j0 + i;
            if (j <= t) Ti[t][j] = (j == t) ? 1.0f : 0.0f;
        }
    }
    __syncthreads();   // all MFMA reads of tB done; Ti fully initialized

    // K^T: Ktg[kk][t] = K[t][kk]   (reads tA; independent of Ti)
    {
        const int kk = tid >> 1;
        const int t0 = (tid & 1) * 32;
        __hip_bfloat16* kp = Ktg + (chnk * DHEAD + kk) * CS + t0;
        float f[8];
#pragma unroll
        for (int i = 0; i < 4; ++i) {
#pragma unroll
            for (int j2 = 0; j2 < 8; ++j2)
                f[j2] = __bfloat162float(tA[t0 + i * 8 + j2][kk]);
            *(uint4*)(kp + i * 8) = pack8_bf16(f);
        }
    }
    // load b*v into tB (q dead)
    {
        const int r = tid >> 2, d0 = (tid & 3) * 32;
        const float br = sb_[r];
        const uint4* vp = (const uint4*)(vb + (row0 + r) * DDIM + h * DHEAD + d0);
#pragma unroll
        for (int i = 0; i < 4; ++i) {
            const uint4 vv = vp[i];
            const unsigned short* u = (const unsigned short*)&vv;
            float f[8];
#pragma unroll
            for (int j = 0; j < 8; ++j) f[j] = br * bfbits2f(u[j]);
            *(uint4*)&tB[r][d0 + i * 8] = pack8_bf16(f);
        }
    }
    __syncthreads();

    // Ti = (I+W)^-1 via forward elimination; W[t][s] read from Ti[s][t]
    for (int s = 0; s < CS - 1; ++s) {
        const int t = tid & 63, jq = tid >> 6;
        if (t > s) {
            const float wt = -Ti[s][t];
            const int jlo = jq * 16;
            const int jhi = min(s, jlo + 15);
            for (int j = jlo; j <= jhi; ++j)
                Ti[t][j] = fmaf(wt, Ti[s][j], Ti[t][j]);
        }
        __syncthreads();
    }

    // R[t][kk] = -sum_{s<=t} Ti[t][s] * swB[s] * K[s][kk]   (bf16 out)
    {
        const int t = tid >> 2, j0 = (tid & 3) * 32;
        float acc[32];
#pragma unroll
        for (int j = 0; j < 32; ++j) acc[j] = 0.0f;
        for (int s = 0; s <= t; ++s) {
            const float cf = -Ti[t][s] * swB[s];
#pragma unroll
            for (int j = 0; j < 32; ++j)
                acc[j] = fmaf(cf, __bfloat162float(tA[s][j0 + j]), acc[j]);
        }
        __hip_bfloat16* rp = Rg + (chnk * CS + t) * DHEAD + j0;
#pragma unroll
        for (int i = 0; i < 4; ++i)
            *(uint4*)(rp + i * 8) = pack8_bf16(&acc[i * 8]);
    }

    // dv0 = Ti @ (b*v) -> dvX (bf16); Ti lower-triangular so s<=t
    {
        const int t = tid >> 2, j0 = (tid & 3) * 32;
        float acc[32];
#pragma unroll
        for (int j = 0; j < 32; ++j) acc[j] = 0.0f;
        for (int s = 0; s <= t; ++s) {
            const float ti = Ti[t][s];
#pragma unroll
            for (int j = 0; j < 32; ++j)
                acc[j] = fmaf(ti, __bfloat162float(tB[s][j0 + j]), acc[j]);
        }
        __hip_bfloat16* dp = dvX + (chnk * CS + t) * DHEAD + j0;
#pragma unroll
        for (int i = 0; i < 4; ++i)
            *(uint4*)(dp + i * 8) = pack8_bf16(&acc[i * 8]);
    }
}

// --------- Phase B: sequential over chunks; MFMA; 128 blocks ----------------
#define SEQGV 8
#define SEQ_LDS_BYTES 78848

__global__ __launch_bounds__(256) void chunk_seq_mfma(
    const float* __restrict__ S0in, const float* __restrict__ Gcum,
    const __hip_bfloat16* __restrict__ Rg, const __hip_bfloat16* __restrict__ Ktg,
    __hip_bfloat16* __restrict__ dvX, __hip_bfloat16* __restrict__ Ssnap,
    float* __restrict__ Sout)
{
    const int bh = blockIdx.x & 15;
    const int g  = blockIdx.x >> 4;
    const int j0 = g * 16;
    const int tid = threadIdx.x;
    const int w = tid >> 6;
    const int l = tid & 63;
    const int fr = l & 15;
    const int fk8 = (l >> 4) * 8;
    const int rq = (l >> 4) * 4;

    __shared__ __align__(16) char smem[SEQ_LDS_BYTES];
    __hip_bfloat16* dvT = (__hip_bfloat16*)(smem + 71680);   // [16 j][72 t]
    __hip_bfloat16* Stl = (__hip_bfloat16*)(smem + 73984);   // [16 j][136 kk]
    float* sG = (float*)(smem + 78336);

    f32x4 SM[2];
#pragma unroll
    for (int mj = 0; mj < 2; ++mj) {
#pragma unroll
        for (int r = 0; r < 4; ++r) {
            const int kk = w * 32 + mj * 16 + rq + r;
            const float v = S0in[((long)bh * 128 + kk) * 128 + j0 + fr];
            SM[mj][r] = v;
            Stl[fr * 136 + kk] = __float2bfloat16(v);
        }
    }

    uint4 rreg[4], kreg[4];
    float greg = 0.0f;

#define SEQ_STAGE_LOAD(c_) do {                                                   \
        const long cb_ = (long)bh * NC + (c_);                                    \
        _Pragma("unroll")                                                         \
        for (int i_ = 0; i_ < 4; ++i_) {                                          \
            const int ur_ = (tid << 2) + i_;                                      \
            rreg[i_] = *(const uint4*)(Rg + (cb_ * CS + (ur_ >> 4)) * DHEAD + ((ur_ & 15) << 3)); \
            kreg[i_] = *(const uint4*)(Ktg + (cb_ * DHEAD + (ur_ >> 3)) * CS + ((ur_ & 7) << 3)); \
        }                                                                         \
        if (tid < 64) greg = Gcum[cb_ * CS + tid];                                \
    } while (0)

#define SEQ_STAGE_WRITE(bufi_) do {                                               \
        __hip_bfloat16* rb_ = (__hip_bfloat16*)(smem + (bufi_) * 17408);          \
        __hip_bfloat16* kb2_ = (__hip_bfloat16*)(smem + 34816 + (bufi_) * 18432); \
        _Pragma("unroll")                                                         \
        for (int i_ = 0; i_ < 4; ++i_) {                                          \
            const int ur_ = (tid << 2) + i_;                                      \
            *(uint4*)(rb_ + (ur_ >> 4) * 136 + ((ur_ & 15) << 3)) = rreg[i_];     \
            *(uint4*)(kb2_ + (ur_ >> 3) * 72 + ((ur_ & 7) << 3)) = kreg[i_];      \
        }                                                                         \
        if (tid < 64) sG[(bufi_) * 64 + tid] = greg;                              \
    } while (0)

    SEQ_STAGE_LOAD(0);
    SEQ_STAGE_WRITE(0);
    __syncthreads();

    for (int c = 0; c < NC; ++c) {
        const int cur = c & 1;
        const long chnk = (long)bh * NC + c;
        const __hip_bfloat16* Rl = (const __hip_bfloat16*)(smem + cur * 17408);
        const __hip_bfloat16* Ktl = (const __hip_bfloat16*)(smem + 34816 + cur * 18432);
        const float g63 = sG[cur * 64 + 63];
        const float a63 = expf(g63);

        unsigned short d0r[4];
#pragma unroll
        for (int r = 0; r < 4; ++r) {
            const int t = w * 16 + rq + r;
            d0r[r] = *(const unsigned short*)(dvX + (chnk * CS + t) * DHEAD + j0 + fr);
        }

        if (c + 1 < NC) SEQ_STAGE_LOAD(c + 1);

        {
            const int j = tid >> 4, k0 = (tid & 15) * 8;
            const uint4 v = *(const uint4*)&Stl[j * 136 + k0];
            *(uint4*)(Ssnap + (chnk * 128 + j0 + j) * 128 + k0) = v;
        }

        // step A: dv = dv0 + R @ S
        f32x4 acc = (f32x4)0.0f;
#pragma unroll
        for (int ks = 0; ks < 4; ++ks) {
            const bf16x8 bfrag = *(const bf16x8*)&Stl[fr * 136 + ks * 32 + fk8];
            const bf16x8 afrag = *(const bf16x8*)&Rl[(w * 16 + fr) * 136 + ks * 32 + fk8];
            acc = __builtin_amdgcn_mfma_f32_16x16x32_bf16(afrag, bfrag, acc, 0, 0, 0);
        }
#pragma unroll
        for (int r = 0; r < 4; ++r) {
            const int t = w * 16 + rq + r;
            const float rk = expf(g63 - sG[cur * 64 + t]);
            const float dv = acc[r] + bfbits2f(d0r[r]);
            *(unsigned short*)(dvX + (chnk * CS + t) * DHEAD + j0 + fr) = bf16_bits(dv);
            dvT[fr * 72 + t] = __float2bfloat16(rk * dv);
        }

        if (c + 1 < NC) SEQ_STAGE_WRITE(cur ^ 1);
        __syncthreads();

        // step B: S' = a63*S + K^T @ dvs
#pragma unroll
        for (int mj = 0; mj < 2; ++mj) SM[mj] *= a63;
#pragma unroll
        for (int ks = 0; ks < 2; ++ks) {
            const bf16x8 bfrag = *(const bf16x8*)&dvT[fr * 72 + ks * 32 + fk8];
#pragma unroll
            for (int mj = 0; mj < 2; ++mj) {
                const bf16x8 afrag = *(const bf16x8*)&Ktl[(w * 32 + mj * 16 + fr) * 72 + ks * 32 + fk8];
                SM[mj] = __builtin_amdgcn_mfma_f32_16x16x32_bf16(afrag, bfrag, SM[mj], 0, 0, 0);
            }
        }
#pragma unroll
        for (int mj = 0; mj < 2; ++mj)
#pragma unroll
            for (int r = 0; r < 4; ++r) {
                const int kk = w * 32 + mj * 16 + rq + r;
                Stl[fr * 136 + kk] = __float2bfloat16(SM[mj][r]);
            }
        __syncthreads();
    }

#pragma unroll
    for (int mj = 0; mj < 2; ++mj)
#pragma unroll
        for (int r = 0; r < 4; ++r) {
            const int kk = w * 32 + mj * 16 + rq + r;
            Sout[((long)bh * 128 + kk) * 128 + j0 + fr] = SM[mj][r];
        }
#undef SEQ_STAGE_LOAD
#undef SEQ_STAGE_WRITE
}

// --------- Phase C (parallel, MFMA): o = e^{G_t}*(q_t @ S0snap) + M @ dv ----
__global__ __launch_bounds__(256) void chunk_out(
    const __hip_bfloat16* __restrict__ qb, const float* __restrict__ Gcum,
    const __hip_bfloat16* __restrict__ dvX, const __hip_bfloat16* __restrict__ Ssnap,
    const __hip_bfloat16* __restrict__ Mmat, __hip_bfloat16* __restrict__ ob)
{
    const int bh = blockIdx.x >> 5;
    const int c  = blockIdx.x & 31;
    const int b = bh >> 3, h = bh & 7;
    const int tid = threadIdx.x;
    const int w = tid >> 6, l = tid & 63;
    const int fr = l & 15;
    const int fk8 = (l >> 4) * 8;
    const int rq = (l >> 4) * 4;
    const long row0 = (long)b * TLEN + (long)c * CS;
    const long chnk = (long)bh * NC + c;

    __shared__ __align__(16) char smem[62464];
    __hip_bfloat16* Ssn = (__hip_bfloat16*)(smem);
    __hip_bfloat16* Ml  = (__hip_bfloat16*)(smem + 34816);
    __hip_bfloat16* dq  = (__hip_bfloat16*)(smem + 44032);

    {
        const int j = tid >> 1;
        const int d0 = (tid & 1) * 64;
        const uint4* sp = (const uint4*)(Ssnap + (chnk * 128 + j) * 128 + d0);
#pragma unroll
        for (int i = 0; i < 8; ++i)
            *(uint4*)&Ssn[j * 136 + d0 + i * 8] = sp[i];
    }
    {
        const int t = tid >> 2;
        const int s0 = (tid & 3) * 16;
        const uint4* mp = (const uint4*)(Mmat + (chnk * CS + t) * CS + s0);
        *(uint4*)&Ml[t * 72 + s0]     = mp[0];
        *(uint4*)&Ml[t * 72 + s0 + 8] = mp[1];
    }
    {
        const int t = tid >> 2, jb = (tid & 3) * 32;
        uint4 dvr[4];
#pragma unroll
        for (int i = 0; i < 4; ++i)
            dvr[i] = ((const uint4*)(dvX + (chnk * CS + t) * DHEAD + jb))[i];
        const unsigned short* u = (const unsigned short*)&dvr[0];
#pragma unroll
        for (int i = 0; i < 32; ++i)
            dq[(jb + i) * 72 + t] = *(const __hip_bfloat16*)&u[i];
    }
    __syncthreads();

    f32x4 acc[8];
#pragma unroll
    for (int n = 0; n < 8; ++n) acc[n] = (f32x4)0.0f;

    // part 1: O += M @ dv   (K = 64)
#pragma unroll
    for (int ks = 0; ks < 2; ++ks) {
        const bf16x8 afrag = *(const bf16x8*)&Ml[(w * 16 + fr) * 72 + ks * 32 + fk8];
#pragma unroll
        for (int n = 0; n < 8; ++n) {
            const bf16x8 bfrag = *(const bf16x8*)&dq[(n * 16 + fr) * 72 + ks * 32 + fk8];
            acc[n] = __builtin_amdgcn_mfma_f32_16x16x32_bf16(afrag, bfrag, acc[n], 0, 0, 0);
        }
    }
    __syncthreads();

    {
        const int t = tid >> 2, d0 = (tid & 3) * 32;
        const float At = expf(Gcum[chnk * CS + t]);
        const uint4* qp = (const uint4*)(qb + (row0 + t) * DDIM + h * DHEAD + d0);
#pragma unroll
        for (int i = 0; i < 4; ++i) {
            const uint4 qv = qp[i];
            const unsigned short* u = (const unsigned short*)&qv;
            float f[8];
#pragma unroll
            for (int j = 0; j < 8; ++j) f[j] = At * bfbits2f(u[j]);
            *(uint4*)&dq[t * 136 + d0 + i * 8] = pack8_bf16(f);
        }
    }
    __syncthreads();

    // part 2: O += (At*q) @ S0   (K = 128)
#pragma unroll
    for (int ks = 0; ks < 4; ++ks) {
        const bf16x8 afrag = *(const bf16x8*)&dq[(w * 16 + fr) * 136 + ks * 32 + fk8];
#pragma unroll
        for (int n = 0; n < 8; ++n) {
            const bf16x8 bfrag = *(const bf16x8*)&Ssn[(n * 16 + fr) * 136 + ks * 32 + fk8];
            acc[n] = __builtin_amdgcn_mfma_f32_16x16x32_bf16(afrag, bfrag, acc[n], 0, 0, 0);
        }
    }

#pragma unroll
    for (int r = 0; r < 4; ++r) {
        const int t = w * 16 + rq + r;
        __hip_bfloat16* op = ob + (row0 + t) * DDIM + h * DHEAD + fr;
#pragma unroll
        for (int n = 0; n < 8; ++n)
            op[n * 16] = __float2bfloat16(acc[n][r]);
    }
}

extern "C" void kernel_launch(void* const* d_in, const int* in_sizes, int n_in,
                              void* d_out, int out_size, void* d_ws, size_t ws_size,
                              hipStream_t stream) {
    const float* x     = (const float*)d_in[0];
    const float* S0    = (const float*)d_in[1];
    const float* wq    = (const float*)d_in[2];
    const float* wk    = (const float*)d_in[3];
    const float* wv    = (const float*)d_in[4];
    const float* wb    = (const float*)d_in[5];
    const float* wg    = (const float*)d_in[6];
    const float* wo    = (const float*)d_in[7];
    const float* wgate = (const float*)d_in[8];
    const float* wup   = (const float*)d_in[9];
    const float* wdown = (const float*)d_in[10];

    const int M = BSZ * TLEN;  // 4096 token rows

    float* out  = (float*)d_out;
    float* Sout = out + (long)M * DDIM;

    // Workspace layout, peak 76.5 MiB (proven budget: 81 MiB).
    char* w = (char*)d_ws;
    const size_t MB = 1u << 20;
    const size_t KB = 1u << 10;
    __hip_bfloat16* qbh   = (__hip_bfloat16*)(w + 0 * MB);
    __hip_bfloat16* kbh   = (__hip_bfloat16*)(w + 8 * MB);
    __hip_bfloat16* vbh   = (__hip_bfloat16*)(w + 16 * MB);
    float*          beta  = (float*)(w + 24 * MB);
    float*          alpha = (float*)(w + 24 * MB + 128 * KB);
    float*          Gcum  = (float*)(w + 24 * MB + 256 * KB);
    __hip_bfloat16* Mmat  = (__hip_bfloat16*)(w + 24 * MB + 512 * KB); // prep->out (4MB)
    __hip_bfloat16* dvX   = (__hip_bfloat16*)(w + 28 * MB + 512 * KB); // prep->out (8MB)
    __hip_bfloat16* Rg    = (__hip_bfloat16*)(w + 36 * MB + 512 * KB); // prep->seq (8MB)
    __hip_bfloat16* xnb   = (__hip_bfloat16*)(w + 36 * MB + 512 * KB); // rms1->QKV (dead before Rg)
    __hip_bfloat16* Ktg   = (__hip_bfloat16*)(w + 44 * MB + 512 * KB); // prep->seq (8MB)
    __hip_bfloat16* Ssnap = (__hip_bfloat16*)(w + 52 * MB + 512 * KB); // seq->out (16MB)
    __hip_bfloat16* wqt   = (__hip_bfloat16*)(w + 68 * MB + 512 * KB);
    __hip_bfloat16* wkt   = (__hip_bfloat16*)(w + 70 * MB + 512 * KB);
    __hip_bfloat16* wvt   = (__hip_bfloat16*)(w + 72 * MB + 512 * KB);
    __hip_bfloat16* wot   = (__hip_bfloat16*)(w + 74 * MB + 512 * KB);
    __hip_bfloat16* obufb = (__hip_bfloat16*)(w + 8 * MB);
    __hip_bfloat16* xn2b  = (__hip_bfloat16*)(w + 8 * MB);
    __hip_bfloat16* wdt   = (__hip_bfloat16*)(w + 16 * MB);
    __hip_bfloat16* wgt   = (__hip_bfloat16*)(w + 24 * MB + 512 * KB);
    __hip_bfloat16* wut   = (__hip_bfloat16*)(w + 32 * MB + 512 * KB);
    __hip_bfloat16* Hb    = (__hip_bfloat16*)(w + 40 * MB + 512 * KB);

    // 0) weight transpose+convert (W[K,N] -> Wt[N,K] bf16)
    transpose_cvt<<<dim3(DDIM / 32, DDIM / 32), 256, 0, stream>>>(wq, wqt, DDIM, DDIM);
    transpose_cvt<<<dim3(DDIM / 32, DDIM / 32), 256, 0, stream>>>(wk, wkt, DDIM, DDIM);
    transpose_cvt<<<dim3(DDIM / 32, DDIM / 32), 256, 0, stream>>>(wv, wvt, DDIM, DDIM);
    transpose_cvt<<<dim3(DDIM / 32, DDIM / 32), 256, 0, stream>>>(wo, wot, DDIM, DDIM);

    // 1) norms / gates
    rmsnorm_k<<<M, 256, 0, stream>>>(x, xnb);
    ba_kernel<<<M, 64, 0, stream>>>(x, wb, wg, beta, alpha);

    // 2) q/k/v projections (bf16 out) — 128x64 tile, 512 blocks each
    dim3 gP64(DDIM / 64, M / 128);  // (16, 32)
    gemm_n64<2><<<gP64, 256, 0, stream>>>(xnb, wqt, nullptr, qbh, M, DDIM, DDIM);
    gemm_n64<2><<<gP64, 256, 0, stream>>>(xnb, wkt, nullptr, kbh, M, DDIM, DDIM);
    gemm_n64<2><<<gP64, 256, 0, stream>>>(xnb, wvt, nullptr, vbh, M, DDIM, DDIM);
    postqkv<<<M * HHEADS, 64, 0, stream>>>(qbh, kbh, vbh);

    // 3) chunked delta rule
    chunk_prep<<<16 * NC, 256, 0, stream>>>(kbh, qbh, vbh, beta, alpha, Gcum, Rg, Ktg, dvX, Mmat);
    chunk_seq_mfma<<<16 * SEQGV, 256, 0, stream>>>(S0, Gcum, Rg, Ktg, dvX, Ssnap, Sout);
    chunk_out<<<16 * NC, 256, 0, stream>>>(qbh, Gcum, dvX, Ssnap, Mmat, obufb);

    // 4) x1 = x + o @ wo — 128x64 tile
    gemm_n64<1><<<gP64, 256, 0, stream>>>(obufb, wot, x, out, M, DDIM, DDIM);

    // 4b) remaining weight transposes into now-dead regions
    transpose_cvt<<<dim3(DDIM / 32, FDIM / 32), 256, 0, stream>>>(wdown, wdt, FDIM, DDIM);
    transpose_cvt<<<dim3(FDIM / 32, DDIM / 32), 256, 0, stream>>>(wgate, wgt, DDIM, FDIM);
    transpose_cvt<<<dim3(FDIM / 32, DDIM / 32), 256, 0, stream>>>(wup, wut, DDIM, FDIM);

    // 5) xn2 = rms_norm(x1)
    rmsnorm_k<<<M, 256, 0, stream>>>(out, xn2b);

    // 6) H = silu(xn2 @ w_gate) * (xn2 @ w_up)  -- 128x64 tile
    dim3 gGU(FDIM / 64, M / 128);
    gemm_gateup_bf16<<<gGU, 256, 0, stream>>>(xn2b, wgt, wut, Hb, M, FDIM, DDIM);

    // 7) x_out = x1 + H @ w_down — 128x64 tile, K=4096
    gemm_n64<1><<<gP64, 256, 0, stream>>>(Hb, wdt, out, out, M, DDIM, FDIM);
}

// Round 11
// 438.972 us; speedup vs baseline: 2.0815x; 1.1547x over previous
//
#include <hip/hip_runtime.h>
#include <hip/hip_bf16.h>
#include <math.h>

// Sizes fixed by the problem: B=2, T=2048, D=1024, F=4096, H=8, DH=128.
#define BSZ 2
#define TLEN 2048
#define DDIM 1024
#define FDIM 4096
#define HHEADS 8
#define DHEAD 128
#define NC 32   // chunks per sequence
#define CS 64   // chunk size (CS*NC == TLEN)

typedef __bf16 bf16x8 __attribute__((ext_vector_type(8)));
typedef float f32x4 __attribute__((ext_vector_type(4)));

__device__ __forceinline__ float silu_f(float x) {
    return x / (1.0f + expf(-x));
}

__device__ __forceinline__ void load_lds16(const void* g, void* l) {
    __builtin_amdgcn_global_load_lds(
        (const __attribute__((address_space(1))) void*)g,
        (__attribute__((address_space(3))) void*)l, 16, 0, 0);
}

__device__ __forceinline__ unsigned short bf16_bits(float f) {
    __hip_bfloat16 h = __float2bfloat16(f);
    return *reinterpret_cast<unsigned short*>(&h);
}

__device__ __forceinline__ float bfbits2f(unsigned short u) {
    union { unsigned int i; float f; } c;
    c.i = ((unsigned int)u) << 16;
    return c.f;
}

__device__ __forceinline__ uint4 pack8_bf16(const float* f) {
    union { unsigned short u[8]; uint4 v; } r;
#pragma unroll
    for (int i = 0; i < 8; ++i) r.u[i] = bf16_bits(f[i]);
    return r.v;
}

// ---------------- RMSNorm: one block (256 thr) per row of 1024; bf16 out -----
struct alignas(8) bh4 { __hip_bfloat16 a, b, c, d; };

__global__ __launch_bounds__(256) void rmsnorm_k(const float* __restrict__ in,
                                                 __hip_bfloat16* __restrict__ out) {
    const long row = blockIdx.x;
    const int tid = threadIdx.x;
    const float4 x = *(const float4*)(in + row * DDIM + tid * 4);
    float ss = x.x * x.x + x.y * x.y + x.z * x.z + x.w * x.w;
    ss += __shfl_xor(ss, 1);
    ss += __shfl_xor(ss, 2);
    ss += __shfl_xor(ss, 4);
    ss += __shfl_xor(ss, 8);
    ss += __shfl_xor(ss, 16);
    ss += __shfl_xor(ss, 32);
    __shared__ float wsum[4];
    if ((tid & 63) == 0) wsum[tid >> 6] = ss;
    __syncthreads();
    const float tot = wsum[0] + wsum[1] + wsum[2] + wsum[3];
    const float sc = rsqrtf(tot * (1.0f / (float)DDIM) + 1e-6f);
    bh4 y;
    y.a = __float2bfloat16(x.x * sc);
    y.b = __float2bfloat16(x.y * sc);
    y.c = __float2bfloat16(x.z * sc);
    y.d = __float2bfloat16(x.w * sc);
    *(bh4*)(out + row * DDIM + tid * 4) = y;
}

// ------------- transpose + f32->bf16: W[K,N] -> Wt[N,K] -------------
__global__ __launch_bounds__(256) void transpose_cvt(const float* __restrict__ W,
                                                     __hip_bfloat16* __restrict__ Wt,
                                                     int K, int N) {
    __shared__ float t[32][33];
    const int n0 = blockIdx.x * 32, k0 = blockIdx.y * 32;
    const int tx = threadIdx.x & 31, ty = threadIdx.x >> 5;  // ty 0..7
#pragma unroll
    for (int i = 0; i < 4; ++i)
        t[ty * 4 + i][tx] = W[(long)(k0 + ty * 4 + i) * N + n0 + tx];
    __syncthreads();
#pragma unroll
    for (int i = 0; i < 4; ++i)
        Wt[(long)(n0 + ty * 4 + i) * K + k0 + tx] = __float2bfloat16(t[tx][ty * 4 + i]);
}

// ---------------- bf16 MFMA GEMM (128x64, BK=64 two-panel) ------------------
// Two 32-col K-panels with 64B rows (proven bank-free layout); halves barrier
// count vs BK=32. 4 waves (2x2), 4x2 frags, 32 AGPR acc, 24 KB LDS.
// MODE 1: f32 out + f32 resid. MODE 2: bf16 out.
template <int MODE>
__global__ __launch_bounds__(256) void gemm_n64(const __hip_bfloat16* __restrict__ A,
                                                const __hip_bfloat16* __restrict__ Bt,
                                                const float* __restrict__ resid,
                                                void* __restrict__ Cout,
                                                int M, int N, int K) {
    __shared__ __align__(16) short As[2 * 128 * 32];   // 16 KB (8 KB/panel)
    __shared__ __align__(16) short Bs[2 * 64 * 32];    // 8 KB (4 KB/panel)
    const int tid = threadIdx.x;
    const int w = tid >> 6, l = tid & 63;
    const int m0 = blockIdx.y * 128, n0 = blockIdx.x * 64;
    const int srow = (w << 4) + (l >> 2);
    const int skcol = (l & 3) * 8;
    const int wr = w >> 1, wc = w & 1;
    const int fr = l & 15;
    const int fkB = (l >> 4) * 16;

    f32x4 acc[4][2];
#pragma unroll
    for (int m = 0; m < 4; ++m)
#pragma unroll
        for (int n = 0; n < 2; ++n) acc[m][n] = (f32x4)0.0f;

    const __hip_bfloat16* Abase = A + (long)m0 * K + skcol;
    const __hip_bfloat16* Bbase = Bt + (long)n0 * K + skcol;

    for (int k0 = 0; k0 < K; k0 += 64) {
#pragma unroll
        for (int p = 0; p < 2; ++p) {
#pragma unroll
            for (int j = 0; j < 2; ++j)
                load_lds16(Abase + (long)(srow + j * 64) * K + k0 + p * 32,
                           (char*)As + p * 8192 + w * 1024 + j * 4096);
            load_lds16(Bbase + (long)srow * K + k0 + p * 32,
                       (char*)Bs + p * 4096 + w * 1024);
        }
        __syncthreads();
#pragma unroll
        for (int p = 0; p < 2; ++p) {
            bf16x8 av[4], bv[2];
#pragma unroll
            for (int m = 0; m < 4; ++m)
                av[m] = *(const bf16x8*)((char*)As + p * 8192 + (wr * 64 + m * 16 + fr) * 64 + fkB);
#pragma unroll
            for (int n = 0; n < 2; ++n)
                bv[n] = *(const bf16x8*)((char*)Bs + p * 4096 + (wc * 32 + n * 16 + fr) * 64 + fkB);
#pragma unroll
            for (int m = 0; m < 4; ++m)
#pragma unroll
                for (int n = 0; n < 2; ++n)
                    acc[m][n] = __builtin_amdgcn_mfma_f32_16x16x32_bf16(av[m], bv[n], acc[m][n], 0, 0, 0);
        }
        __syncthreads();
    }

    const int r0 = (l >> 4) * 4;
    const int cc = l & 15;
#pragma unroll
    for (int m = 0; m < 4; ++m) {
#pragma unroll
        for (int r = 0; r < 4; ++r) {
            const long row = m0 + wr * 64 + m * 16 + r0 + r;
            const long colb = n0 + wc * 32 + cc;
            if (MODE == 2) {
                __hip_bfloat16* cb = (__hip_bfloat16*)Cout + row * N + colb;
#pragma unroll
                for (int n = 0; n < 2; ++n)
                    cb[n * 16] = __float2bfloat16(acc[m][n][r]);
            } else {
                float* cp = (float*)Cout + row * N + colb;
                const float* rp = resid + row * N + colb;
#pragma unroll
                for (int n = 0; n < 2; ++n)
                    cp[n * 16] = acc[m][n][r] + rp[n * 16];
            }
        }
    }
}

// ---- dual-B MFMA GEMM for SwiGLU (BK=64 two-panel): ------------------------
// H = bf16( silu(A@Wg^T) * (A@Wu^T) ). 128x64 tile, 32 KB LDS.
__global__ __launch_bounds__(256) void gemm_gateup_bf16(const __hip_bfloat16* __restrict__ A,
                                                        const __hip_bfloat16* __restrict__ Bg,
                                                        const __hip_bfloat16* __restrict__ Bu,
                                                        __hip_bfloat16* __restrict__ Hb,
                                                        int M, int N, int K) {
    __shared__ __align__(16) short As[2 * 128 * 32];   // 16 KB
    __shared__ __align__(16) short Bgs[2 * 64 * 32];   // 8 KB
    __shared__ __align__(16) short Bus[2 * 64 * 32];   // 8 KB
    const int tid = threadIdx.x;
    const int w = tid >> 6, l = tid & 63;
    const int m0 = blockIdx.y * 128, n0 = blockIdx.x * 64;
    const int srow = (w << 4) + (l >> 2);
    const int skcol = (l & 3) * 8;
    const int wr = w >> 1, wc = w & 1;
    const int fr = l & 15;
    const int fkB = (l >> 4) * 16;

    f32x4 accg[4][2], accu[4][2];
#pragma unroll
    for (int m = 0; m < 4; ++m)
#pragma unroll
        for (int n = 0; n < 2; ++n) { accg[m][n] = (f32x4)0.0f; accu[m][n] = (f32x4)0.0f; }

    const __hip_bfloat16* Abase = A + (long)m0 * K + skcol;
    const __hip_bfloat16* Bgb = Bg + (long)n0 * K + skcol;
    const __hip_bfloat16* Bub = Bu + (long)n0 * K + skcol;

    for (int k0 = 0; k0 < K; k0 += 64) {
#pragma unroll
        for (int p = 0; p < 2; ++p) {
#pragma unroll
            for (int j = 0; j < 2; ++j)
                load_lds16(Abase + (long)(srow + j * 64) * K + k0 + p * 32,
                           (char*)As + p * 8192 + w * 1024 + j * 4096);
            load_lds16(Bgb + (long)srow * K + k0 + p * 32, (char*)Bgs + p * 4096 + w * 1024);
            load_lds16(Bub + (long)srow * K + k0 + p * 32, (char*)Bus + p * 4096 + w * 1024);
        }
        __syncthreads();
#pragma unroll
        for (int p = 0; p < 2; ++p) {
            bf16x8 av[4], bgv[2], buv[2];
#pragma unroll
            for (int m = 0; m < 4; ++m)
                av[m] = *(const bf16x8*)((char*)As + p * 8192 + (wr * 64 + m * 16 + fr) * 64 + fkB);
#pragma unroll
            for (int n = 0; n < 2; ++n) {
                bgv[n] = *(const bf16x8*)((char*)Bgs + p * 4096 + (wc * 32 + n * 16 + fr) * 64 + fkB);
                buv[n] = *(const bf16x8*)((char*)Bus + p * 4096 + (wc * 32 + n * 16 + fr) * 64 + fkB);
            }
#pragma unroll
            for (int m = 0; m < 4; ++m)
#pragma unroll
                for (int n = 0; n < 2; ++n) {
                    accg[m][n] = __builtin_amdgcn_mfma_f32_16x16x32_bf16(av[m], bgv[n], accg[m][n], 0, 0, 0);
                    accu[m][n] = __builtin_amdgcn_mfma_f32_16x16x32_bf16(av[m], buv[n], accu[m][n], 0, 0, 0);
                }
        }
        __syncthreads();
    }

    const int r0 = (l >> 4) * 4;
    const int cc = l & 15;
#pragma unroll
    for (int m = 0; m < 4; ++m) {
#pragma unroll
        for (int r = 0; r < 4; ++r) {
            const long row = m0 + wr * 64 + m * 16 + r0 + r;
            __hip_bfloat16* hp = Hb + row * N + n0 + wc * 32 + cc;
#pragma unroll
            for (int n = 0; n < 2; ++n)
                hp[n * 16] = __float2bfloat16(silu_f(accg[m][n][r]) * accu[m][n][r]);
        }
    }
}

// ------- beta/alpha: inline rmsnorm; x staged through LDS (coalesced) -------
__global__ __launch_bounds__(64) void ba_kernel(const float* __restrict__ x,
                                                const float* __restrict__ wb,
                                                const float* __restrict__ wg,
                                                float* __restrict__ beta,
                                                float* __restrict__ alpha) {
    __shared__ float xs[DDIM];
    const long row = blockIdx.x;
    const int tid = threadIdx.x;
    float ss = 0.0f;
#pragma unroll
    for (int j = 0; j < 4; ++j) {
        const int fi = tid + j * 64;                    // float4 index, coalesced
        const float4 v = *(const float4*)(x + row * DDIM + fi * 4);
        *(float4*)&xs[fi * 4] = v;
        ss += v.x * v.x + v.y * v.y + v.z * v.z + v.w * v.w;
    }
    ss += __shfl_xor(ss, 1);
    ss += __shfl_xor(ss, 2);
    ss += __shfl_xor(ss, 4);
    ss += __shfl_xor(ss, 8);
    ss += __shfl_xor(ss, 16);
    ss += __shfl_xor(ss, 32);
    __syncthreads();
    const int o = tid >> 2;   // 0..15 output (0..7 beta, 8..15 alpha)
    const int p = tid & 3;    // segment
    const float* wbase = (o < 8) ? (wb + o) : (wg + (o - 8));
    const float* wr = wbase + (long)(p * 256) * HHEADS;
    const float* xr = xs + p * 256;
    float acc = 0.0f;
#pragma unroll 8
    for (int i = 0; i < 256; ++i)
        acc = fmaf(xr[i], wr[(long)i * HHEADS], acc);
    acc += __shfl_xor(acc, 1);
    acc += __shfl_xor(acc, 2);
    if (p == 0) {
        const float sc = rsqrtf(ss * (1.0f / (float)DDIM) + 1e-6f);
        const float val = 1.0f / (1.0f + expf(-acc * sc));
        if (o < 8) beta[row * HHEADS + o] = val;
        else       alpha[row * HHEADS + (o - 8)] = val;
    }
}

// ------- post-projection (bf16 in-place): silu + l2norm on q,k; silu on v ----
__global__ __launch_bounds__(64) void postqkv(__hip_bfloat16* __restrict__ q,
                                              __hip_bfloat16* __restrict__ k,
                                              __hip_bfloat16* __restrict__ v) {
    const long r = blockIdx.x;
    const int tid = threadIdx.x;
    {
        unsigned int* qp = (unsigned int*)(q + r * DHEAD + tid * 2);
        const unsigned int wbits = *qp;
        float y0 = silu_f(bfbits2f(wbits & 0xffff));
        float y1 = silu_f(bfbits2f(wbits >> 16));
        float ss = y0 * y0 + y1 * y1;
        ss += __shfl_xor(ss, 1);  ss += __shfl_xor(ss, 2);
        ss += __shfl_xor(ss, 4);  ss += __shfl_xor(ss, 8);
        ss += __shfl_xor(ss, 16); ss += __shfl_xor(ss, 32);
        const float sc = rsqrtf(ss + 1e-6f);
        *qp = (unsigned int)bf16_bits(y0 * sc) | ((unsigned int)bf16_bits(y1 * sc) << 16);
    }
    {
        unsigned int* kp = (unsigned int*)(k + r * DHEAD + tid * 2);
        const unsigned int wbits = *kp;
        float y0 = silu_f(bfbits2f(wbits & 0xffff));
        float y1 = silu_f(bfbits2f(wbits >> 16));
        float ss = y0 * y0 + y1 * y1;
        ss += __shfl_xor(ss, 1);  ss += __shfl_xor(ss, 2);
        ss += __shfl_xor(ss, 4);  ss += __shfl_xor(ss, 8);
        ss += __shfl_xor(ss, 16); ss += __shfl_xor(ss, 32);
        const float sc = rsqrtf(ss + 1e-6f);
        *kp = (unsigned int)bf16_bits(y0 * sc) | ((unsigned int)bf16_bits(y1 * sc) << 16);
    }
    {
        unsigned int* vp = (unsigned int*)(v + r * DHEAD + tid * 2);
        const unsigned int wbits = *vp;
        *vp = (unsigned int)bf16_bits(silu_f(bfbits2f(wbits & 0xffff)))
            | ((unsigned int)bf16_bits(silu_f(bfbits2f(wbits >> 16))) << 16);
    }
}

// ============ Chunked gated delta rule (log-space decay) ============
// G_t = sum_{s<=t} log(a_s) within chunk; ratio(t,s)=exp(G_t-G_s)<=1 for s<=t.
//   dv = dv0 + R @ S0,   R = -Tinv @ diag(b_s e^{G_s}) @ K   (precomputed)
//   dv0 = Tinv @ (b (.) v)                                    (precomputed)
//   o_t = e^{G_t} (S0^T q_t) + (M @ dv)_t                     (M precomputed)
//   S_end = e^{G63} S0 + K^T @ diag(e^{G63-G_t}) dv

// --------- Phase A (parallel over bh x chunk): G, M, R, K^T, dv0 ------------
__global__ __launch_bounds__(256) void chunk_prep(
    const __hip_bfloat16* __restrict__ kb, const __hip_bfloat16* __restrict__ qb,
    const __hip_bfloat16* __restrict__ vb, const float* __restrict__ betab,
    const float* __restrict__ alphab, float* __restrict__ Gcum,
    __hip_bfloat16* __restrict__ Rg, __hip_bfloat16* __restrict__ Ktg,
    __hip_bfloat16* __restrict__ dvX, __hip_bfloat16* __restrict__ Mmat)
{
    const int bh = blockIdx.x >> 5;
    const int c  = blockIdx.x & 31;
    const int b = bh >> 3, h = bh & 7;
    const int tid = threadIdx.x;
    const int w = tid >> 6, l = tid & 63;
    const int fr = l & 15;           // fragment col / A-row low
    const int fk8 = (l >> 4) * 8;    // fragment k base (bf16 elems)
    const int fr4 = (l >> 4) * 4;    // C-fragment row base

    __shared__ __align__(16) __hip_bfloat16 tA[64][136];   // k chunk
    __shared__ __align__(16) __hip_bfloat16 tB[64][136];   // q chunk, later b*v
    __shared__ float Ti[64][65];
    __shared__ float sa[64], sb_[64], sG[64], swB[64];

    const long row0 = (long)b * TLEN + (long)c * CS;
    const long chnk = (long)bh * NC + c;

    if (tid < 64) {
        sa[tid]  = alphab[(row0 + tid) * HHEADS + h];
        sb_[tid] = betab[(row0 + tid) * HHEADS + h];
    }
    // load k,q chunks (bf16 direct copies)
    {
        const int r = tid >> 2;
        const int d0 = (tid & 3) * 32;
        const uint4* kp = (const uint4*)(kb + (row0 + r) * DDIM + h * DHEAD + d0);
        const uint4* qp = (const uint4*)(qb + (row0 + r) * DDIM + h * DHEAD + d0);
#pragma unroll
        for (int i = 0; i < 4; ++i) {
            *(uint4*)&tA[r][d0 + i * 8] = kp[i];
            *(uint4*)&tB[r][d0 + i * 8] = qp[i];
        }
    }
    __syncthreads();
    if (tid == 0) {
        float run = 0.0f;
        for (int t = 0; t < CS; ++t) { run += logf(sa[t]); sG[t] = run; }
    }
    __syncthreads();
    if (tid < 64) {
        Gcum[chnk * CS + tid] = sG[tid];
        swB[tid] = sb_[tid] * expf(sG[tid]);
    }
    __syncthreads();

    // ---- MFMA: W_raw = K@K^T, M_raw = Q@K^T (wave w owns rows w*16..+15) ----
    f32x4 accW[4], accM[4];
#pragma unroll
    for (int n = 0; n < 4; ++n) { accW[n] = (f32x4)0.0f; accM[n] = (f32x4)0.0f; }
#pragma unroll
    for (int ks = 0; ks < 4; ++ks) {
        const bf16x8 aW = *(const bf16x8*)&tA[w * 16 + fr][ks * 32 + fk8];
        const bf16x8 aM = *(const bf16x8*)&tB[w * 16 + fr][ks * 32 + fk8];
#pragma unroll
        for (int n = 0; n < 4; ++n) {
            const bf16x8 bfr = *(const bf16x8*)&tA[n * 16 + fr][ks * 32 + fk8];
            accW[n] = __builtin_amdgcn_mfma_f32_16x16x32_bf16(aW, bfr, accW[n], 0, 0, 0);
            accM[n] = __builtin_amdgcn_mfma_f32_16x16x32_bf16(aM, bfr, accM[n], 0, 0, 0);
        }
    }
    // epilogue: M (masked+scaled) -> global; W (masked+scaled) -> Ti upper [s][t]
#pragma unroll
    for (int n = 0; n < 4; ++n) {
        const int s = n * 16 + fr;
        const float Gs = sG[s];
#pragma unroll
        for (int r = 0; r < 4; ++r) {
            const int t = w * 16 + fr4 + r;
            const float ratio = (s <= t) ? expf(sG[t] - Gs) : 0.0f;
            Mmat[(chnk * CS + t) * CS + s] = __float2bfloat16(ratio * accM[n][r]);
            if (s < t) Ti[s][t] = sb_[t] * ratio * accW[n][r];
        }
    }
    // init Ti lower+diag (upper holds W; disjoint cells)
    {
        const int t = tid >> 2, j0 = (tid & 3) * 16;
#pragma unroll
        for (int i = 0; i < 16; ++i) {
            const int j = j0 + i;
            if (j <= t) Ti[t][j] = (j == t) ? 1.0f : 0.0f;
        }
    }
    __syncthreads();   // all MFMA reads of tB done; Ti fully initialized

    // K^T: Ktg[kk][t] = K[t][kk]   (reads tA; independent of Ti)
    {
        const int kk = tid >> 1;
        const int t0 = (tid & 1) * 32;
        __hip_bfloat16* kp = Ktg + (chnk * DHEAD + kk) * CS + t0;
        float f[8];
#pragma unroll
        for (int i = 0; i < 4; ++i) {
#pragma unroll
            for (int j2 = 0; j2 < 8; ++j2)
                f[j2] = __bfloat162float(tA[t0 + i * 8 + j2][kk]);
            *(uint4*)(kp + i * 8) = pack8_bf16(f);
        }
    }
    // load b*v into tB (q dead)
    {
        const int r = tid >> 2, d0 = (tid & 3) * 32;
        const float br = sb_[r];
        const uint4* vp = (const uint4*)(vb + (row0 + r) * DDIM + h * DHEAD + d0);
#pragma unroll
        for (int i = 0; i < 4; ++i) {
            const uint4 vv = vp[i];
            const unsigned short* u = (const unsigned short*)&vv;
            float f[8];
#pragma unroll
            for (int j = 0; j < 8; ++j) f[j] = br * bfbits2f(u[j]);
            *(uint4*)&tB[r][d0 + i * 8] = pack8_bf16(f);
        }
    }
    __syncthreads();

    // Ti = (I+W)^-1 via forward elimination; W[t][s] read from Ti[s][t]
    for (int s = 0; s < CS - 1; ++s) {
        const int t = tid & 63, jq = tid >> 6;
        if (t > s) {
            const float wt = -Ti[s][t];
            const int jlo = jq * 16;
            const int jhi = min(s, jlo + 15);
            for (int j = jlo; j <= jhi; ++j)
                Ti[t][j] = fmaf(wt, Ti[s][j], Ti[t][j]);
        }
        __syncthreads();
    }

    // R[t][kk] = -sum_{s<=t} Ti[t][s] * swB[s] * K[s][kk]   (bf16 out)
    {
        const int t = tid >> 2, j0 = (tid & 3) * 32;
        float acc[32];
#pragma unroll
        for (int j = 0; j < 32; ++j) acc[j] = 0.0f;
        for (int s = 0; s <= t; ++s) {
            const float cf = -Ti[t][s] * swB[s];
#pragma unroll
            for (int j = 0; j < 32; ++j)
                acc[j] = fmaf(cf, __bfloat162float(tA[s][j0 + j]), acc[j]);
        }
        __hip_bfloat16* rp = Rg + (chnk * CS + t) * DHEAD + j0;
#pragma unroll
        for (int i = 0; i < 4; ++i)
            *(uint4*)(rp + i * 8) = pack8_bf16(&acc[i * 8]);
    }

    // dv0 = Ti @ (b*v) -> dvX (bf16); Ti lower-triangular so s<=t
    {
        const int t = tid >> 2, j0 = (tid & 3) * 32;
        float acc[32];
#pragma unroll
        for (int j = 0; j < 32; ++j) acc[j] = 0.0f;
        for (int s = 0; s <= t; ++s) {
            const float ti = Ti[t][s];
#pragma unroll
            for (int j = 0; j < 32; ++j)
                acc[j] = fmaf(ti, __bfloat162float(tB[s][j0 + j]), acc[j]);
        }
        __hip_bfloat16* dp = dvX + (chnk * CS + t) * DHEAD + j0;
#pragma unroll
        for (int i = 0; i < 4; ++i)
            *(uint4*)(dp + i * 8) = pack8_bf16(&acc[i * 8]);
    }
}

// --------- Phase B: sequential over chunks; MFMA; 128 blocks ----------------
#define SEQGV 8
#define SEQ_LDS_BYTES 78848

__global__ __launch_bounds__(256) void chunk_seq_mfma(
    const float* __restrict__ S0in, const float* __restrict__ Gcum,
    const __hip_bfloat16* __restrict__ Rg, const __hip_bfloat16* __restrict__ Ktg,
    __hip_bfloat16* __restrict__ dvX, __hip_bfloat16* __restrict__ Ssnap,
    float* __restrict__ Sout)
{
    const int bh = blockIdx.x & 15;
    const int g  = blockIdx.x >> 4;
    const int j0 = g * 16;
    const int tid = threadIdx.x;
    const int w = tid >> 6;
    const int l = tid & 63;
    const int fr = l & 15;
    const int fk8 = (l >> 4) * 8;
    const int rq = (l >> 4) * 4;

    __shared__ __align__(16) char smem[SEQ_LDS_BYTES];
    __hip_bfloat16* dvT = (__hip_bfloat16*)(smem + 71680);   // [16 j][72 t]
    __hip_bfloat16* Stl = (__hip_bfloat16*)(smem + 73984);   // [16 j][136 kk]
    float* sG = (float*)(smem + 78336);

    f32x4 SM[2];
#pragma unroll
    for (int mj = 0; mj < 2; ++mj) {
#pragma unroll
        for (int r = 0; r < 4; ++r) {
            const int kk = w * 32 + mj * 16 + rq + r;
            const float v = S0in[((long)bh * 128 + kk) * 128 + j0 + fr];
            SM[mj][r] = v;
            Stl[fr * 136 + kk] = __float2bfloat16(v);
        }
    }

    uint4 rreg[4], kreg[4];
    float greg = 0.0f;

#define SEQ_STAGE_LOAD(c_) do {                                                   \
        const long cb_ = (long)bh * NC + (c_);                                    \
        _Pragma("unroll")                                                         \
        for (int i_ = 0; i_ < 4; ++i_) {                                          \
            const int ur_ = (tid << 2) + i_;                                      \
            rreg[i_] = *(const uint4*)(Rg + (cb_ * CS + (ur_ >> 4)) * DHEAD + ((ur_ & 15) << 3)); \
            kreg[i_] = *(const uint4*)(Ktg + (cb_ * DHEAD + (ur_ >> 3)) * CS + ((ur_ & 7) << 3)); \
        }                                                                         \
        if (tid < 64) greg = Gcum[cb_ * CS + tid];                                \
    } while (0)

#define SEQ_STAGE_WRITE(bufi_) do {                                               \
        __hip_bfloat16* rb_ = (__hip_bfloat16*)(smem + (bufi_) * 17408);          \
        __hip_bfloat16* kb2_ = (__hip_bfloat16*)(smem + 34816 + (bufi_) * 18432); \
        _Pragma("unroll")                                                         \
        for (int i_ = 0; i_ < 4; ++i_) {                                          \
            const int ur_ = (tid << 2) + i_;                                      \
            *(uint4*)(rb_ + (ur_ >> 4) * 136 + ((ur_ & 15) << 3)) = rreg[i_];     \
            *(uint4*)(kb2_ + (ur_ >> 3) * 72 + ((ur_ & 7) << 3)) = kreg[i_];      \
        }                                                                         \
        if (tid < 64) sG[(bufi_) * 64 + tid] = greg;                              \
    } while (0)

    SEQ_STAGE_LOAD(0);
    SEQ_STAGE_WRITE(0);
    __syncthreads();

    for (int c = 0; c < NC; ++c) {
        const int cur = c & 1;
        const long chnk = (long)bh * NC + c;
        const __hip_bfloat16* Rl = (const __hip_bfloat16*)(smem + cur * 17408);
        const __hip_bfloat16* Ktl = (const __hip_bfloat16*)(smem + 34816 + cur * 18432);
        const float g63 = sG[cur * 64 + 63];
        const float a63 = expf(g63);

        unsigned short d0r[4];
#pragma unroll
        for (int r = 0; r < 4; ++r) {
            const int t = w * 16 + rq + r;
            d0r[r] = *(const unsigned short*)(dvX + (chnk * CS + t) * DHEAD + j0 + fr);
        }

        if (c + 1 < NC) SEQ_STAGE_LOAD(c + 1);

        {
            const int j = tid >> 4, k0 = (tid & 15) * 8;
            const uint4 v = *(const uint4*)&Stl[j * 136 + k0];
            *(uint4*)(Ssnap + (chnk * 128 + j0 + j) * 128 + k0) = v;
        }

        // step A: dv = dv0 + R @ S
        f32x4 acc = (f32x4)0.0f;
#pragma unroll
        for (int ks = 0; ks < 4; ++ks) {
            const bf16x8 bfrag = *(const bf16x8*)&Stl[fr * 136 + ks * 32 + fk8];
            const bf16x8 afrag = *(const bf16x8*)&Rl[(w * 16 + fr) * 136 + ks * 32 + fk8];
            acc = __builtin_amdgcn_mfma_f32_16x16x32_bf16(afrag, bfrag, acc, 0, 0, 0);
        }
#pragma unroll
        for (int r = 0; r < 4; ++r) {
            const int t = w * 16 + rq + r;
            const float rk = expf(g63 - sG[cur * 64 + t]);
            const float dv = acc[r] + bfbits2f(d0r[r]);
            *(unsigned short*)(dvX + (chnk * CS + t) * DHEAD + j0 + fr) = bf16_bits(dv);
            dvT[fr * 72 + t] = __float2bfloat16(rk * dv);
        }

        if (c + 1 < NC) SEQ_STAGE_WRITE(cur ^ 1);
        __syncthreads();

        // step B: S' = a63*S + K^T @ dvs
#pragma unroll
        for (int mj = 0; mj < 2; ++mj) SM[mj] *= a63;
#pragma unroll
        for (int ks = 0; ks < 2; ++ks) {
            const bf16x8 bfrag = *(const bf16x8*)&dvT[fr * 72 + ks * 32 + fk8];
#pragma unroll
            for (int mj = 0; mj < 2; ++mj) {
                const bf16x8 afrag = *(const bf16x8*)&Ktl[(w * 32 + mj * 16 + fr) * 72 + ks * 32 + fk8];
                SM[mj] = __builtin_amdgcn_mfma_f32_16x16x32_bf16(afrag, bfrag, SM[mj], 0, 0, 0);
            }
        }
#pragma unroll
        for (int mj = 0; mj < 2; ++mj)
#pragma unroll
            for (int r = 0; r < 4; ++r) {
                const int kk = w * 32 + mj * 16 + rq + r;
                Stl[fr * 136 + kk] = __float2bfloat16(SM[mj][r]);
            }
        __syncthreads();
    }

#pragma unroll
    for (int mj = 0; mj < 2; ++mj)
#pragma unroll
        for (int r = 0; r < 4; ++r) {
            const int kk = w * 32 + mj * 16 + rq + r;
            Sout[((long)bh * 128 + kk) * 128 + j0 + fr] = SM[mj][r];
        }
#undef SEQ_STAGE_LOAD
#undef SEQ_STAGE_WRITE
}

// --------- Phase C (parallel, MFMA): o = e^{G_t}*(q_t @ S0snap) + M @ dv ----
__global__ __launch_bounds__(256) void chunk_out(
    const __hip_bfloat16* __restrict__ qb, const float* __restrict__ Gcum,
    const __hip_bfloat16* __restrict__ dvX, const __hip_bfloat16* __restrict__ Ssnap,
    const __hip_bfloat16* __restrict__ Mmat, __hip_bfloat16* __restrict__ ob)
{
    const int bh = blockIdx.x >> 5;
    const int c  = blockIdx.x & 31;
    const int b = bh >> 3, h = bh & 7;
    const int tid = threadIdx.x;
    const int w = tid >> 6, l = tid & 63;
    const int fr = l & 15;
    const int fk8 = (l >> 4) * 8;
    const int rq = (l >> 4) * 4;
    const long row0 = (long)b * TLEN + (long)c * CS;
    const long chnk = (long)bh * NC + c;

    __shared__ __align__(16) char smem[62464];
    __hip_bfloat16* Ssn = (__hip_bfloat16*)(smem);
    __hip_bfloat16* Ml  = (__hip_bfloat16*)(smem + 34816);
    __hip_bfloat16* dq  = (__hip_bfloat16*)(smem + 44032);

    {
        const int j = tid >> 1;
        const int d0 = (tid & 1) * 64;
        const uint4* sp = (const uint4*)(Ssnap + (chnk * 128 + j) * 128 + d0);
#pragma unroll
        for (int i = 0; i < 8; ++i)
            *(uint4*)&Ssn[j * 136 + d0 + i * 8] = sp[i];
    }
    {
        const int t = tid >> 2;
        const int s0 = (tid & 3) * 16;
        const uint4* mp = (const uint4*)(Mmat + (chnk * CS + t) * CS + s0);
        *(uint4*)&Ml[t * 72 + s0]     = mp[0];
        *(uint4*)&Ml[t * 72 + s0 + 8] = mp[1];
    }
    {
        const int t = tid >> 2, jb = (tid & 3) * 32;
        uint4 dvr[4];
#pragma unroll
        for (int i = 0; i < 4; ++i)
            dvr[i] = ((const uint4*)(dvX + (chnk * CS + t) * DHEAD + jb))[i];
        const unsigned short* u = (const unsigned short*)&dvr[0];
#pragma unroll
        for (int i = 0; i < 32; ++i)
            dq[(jb + i) * 72 + t] = *(const __hip_bfloat16*)&u[i];
    }
    __syncthreads();

    f32x4 acc[8];
#pragma unroll
    for (int n = 0; n < 8; ++n) acc[n] = (f32x4)0.0f;

    // part 1: O += M @ dv   (K = 64)
#pragma unroll
    for (int ks = 0; ks < 2; ++ks) {
        const bf16x8 afrag = *(const bf16x8*)&Ml[(w * 16 + fr) * 72 + ks * 32 + fk8];
#pragma unroll
        for (int n = 0; n < 8; ++n) {
            const bf16x8 bfrag = *(const bf16x8*)&dq[(n * 16 + fr) * 72 + ks * 32 + fk8];
            acc[n] = __builtin_amdgcn_mfma_f32_16x16x32_bf16(afrag, bfrag, acc[n], 0, 0, 0);
        }
    }
    __syncthreads();

    {
        const int t = tid >> 2, d0 = (tid & 3) * 32;
        const float At = expf(Gcum[chnk * CS + t]);
        const uint4* qp = (const uint4*)(qb + (row0 + t) * DDIM + h * DHEAD + d0);
#pragma unroll
        for (int i = 0; i < 4; ++i) {
            const uint4 qv = qp[i];
            const unsigned short* u = (const unsigned short*)&qv;
            float f[8];
#pragma unroll
            for (int j = 0; j < 8; ++j) f[j] = At * bfbits2f(u[j]);
            *(uint4*)&dq[t * 136 + d0 + i * 8] = pack8_bf16(f);
        }
    }
    __syncthreads();

    // part 2: O += (At*q) @ S0   (K = 128)
#pragma unroll
    for (int ks = 0; ks < 4; ++ks) {
        const bf16x8 afrag = *(const bf16x8*)&dq[(w * 16 + fr) * 136 + ks * 32 + fk8];
#pragma unroll
        for (int n = 0; n < 8; ++n) {
            const bf16x8 bfrag = *(const bf16x8*)&Ssn[(n * 16 + fr) * 136 + ks * 32 + fk8];
            acc[n] = __builtin_amdgcn_mfma_f32_16x16x32_bf16(afrag, bfrag, acc[n], 0, 0, 0);
        }
    }

#pragma unroll
    for (int r = 0; r < 4; ++r) {
        const int t = w * 16 + rq + r;
        __hip_bfloat16* op = ob + (row0 + t) * DDIM + h * DHEAD + fr;
#pragma unroll
        for (int n = 0; n < 8; ++n)
            op[n * 16] = __float2bfloat16(acc[n][r]);
    }
}

extern "C" void kernel_launch(void* const* d_in, const int* in_sizes, int n_in,
                              void* d_out, int out_size, void* d_ws, size_t ws_size,
                              hipStream_t stream) {
    const float* x     = (const float*)d_in[0];
    const float* S0    = (const float*)d_in[1];
    const float* wq    = (const float*)d_in[2];
    const float* wk    = (const float*)d_in[3];
    const float* wv    = (const float*)d_in[4];
    const float* wb    = (const float*)d_in[5];
    const float* wg    = (const float*)d_in[6];
    const float* wo    = (const float*)d_in[7];
    const float* wgate = (const float*)d_in[8];
    const float* wup   = (const float*)d_in[9];
    const float* wdown = (const float*)d_in[10];

    const int M = BSZ * TLEN;  // 4096 token rows

    float* out  = (float*)d_out;
    float* Sout = out + (long)M * DDIM;

    // Workspace layout, peak 76.5 MiB (proven budget: 81 MiB).
    char* w = (char*)d_ws;
    const size_t MB = 1u << 20;
    const size_t KB = 1u << 10;
    __hip_bfloat16* qbh   = (__hip_bfloat16*)(w + 0 * MB);
    __hip_bfloat16* kbh   = (__hip_bfloat16*)(w + 8 * MB);
    __hip_bfloat16* vbh   = (__hip_bfloat16*)(w + 16 * MB);
    float*          beta  = (float*)(w + 24 * MB);
    float*          alpha = (float*)(w + 24 * MB + 128 * KB);
    float*          Gcum  = (float*)(w + 24 * MB + 256 * KB);
    __hip_bfloat16* Mmat  = (__hip_bfloat16*)(w + 24 * MB + 512 * KB); // prep->out (4MB)
    __hip_bfloat16* dvX   = (__hip_bfloat16*)(w + 28 * MB + 512 * KB); // prep->out (8MB)
    __hip_bfloat16* Rg    = (__hip_bfloat16*)(w + 36 * MB + 512 * KB); // prep->seq (8MB)
    __hip_bfloat16* xnb   = (__hip_bfloat16*)(w + 36 * MB + 512 * KB); // rms1->QKV (dead before Rg)
    __hip_bfloat16* Ktg   = (__hip_bfloat16*)(w + 44 * MB + 512 * KB); // prep->seq (8MB)
    __hip_bfloat16* Ssnap = (__hip_bfloat16*)(w + 52 * MB + 512 * KB); // seq->out (16MB)
    __hip_bfloat16* wqt   = (__hip_bfloat16*)(w + 68 * MB + 512 * KB);
    __hip_bfloat16* wkt   = (__hip_bfloat16*)(w + 70 * MB + 512 * KB);
    __hip_bfloat16* wvt   = (__hip_bfloat16*)(w + 72 * MB + 512 * KB);
    __hip_bfloat16* wot   = (__hip_bfloat16*)(w + 74 * MB + 512 * KB);
    __hip_bfloat16* obufb = (__hip_bfloat16*)(w + 8 * MB);
    __hip_bfloat16* xn2b  = (__hip_bfloat16*)(w + 8 * MB);
    __hip_bfloat16* wdt   = (__hip_bfloat16*)(w + 16 * MB);
    __hip_bfloat16* wgt   = (__hip_bfloat16*)(w + 24 * MB + 512 * KB);
    __hip_bfloat16* wut   = (__hip_bfloat16*)(w + 32 * MB + 512 * KB);
    __hip_bfloat16* Hb    = (__hip_bfloat16*)(w + 40 * MB + 512 * KB);

    // 0) weight transpose+convert (W[K,N] -> Wt[N,K] bf16)
    transpose_cvt<<<dim3(DDIM / 32, DDIM / 32), 256, 0, stream>>>(wq, wqt, DDIM, DDIM);
    transpose_cvt<<<dim3(DDIM / 32, DDIM / 32), 256, 0, stream>>>(wk, wkt, DDIM, DDIM);
    transpose_cvt<<<dim3(DDIM / 32, DDIM / 32), 256, 0, stream>>>(wv, wvt, DDIM, DDIM);
    transpose_cvt<<<dim3(DDIM / 32, DDIM / 32), 256, 0, stream>>>(wo, wot, DDIM, DDIM);

    // 1) norms / gates
    rmsnorm_k<<<M, 256, 0, stream>>>(x, xnb);
    ba_kernel<<<M, 64, 0, stream>>>(x, wb, wg, beta, alpha);

    // 2) q/k/v projections (bf16 out) — 128x64 tile BK=64
    dim3 gP64(DDIM / 64, M / 128);  // (16, 32)
    gemm_n64<2><<<gP64, 256, 0, stream>>>(xnb, wqt, nullptr, qbh, M, DDIM, DDIM);
    gemm_n64<2><<<gP64, 256, 0, stream>>>(xnb, wkt, nullptr, kbh, M, DDIM, DDIM);
    gemm_n64<2><<<gP64, 256, 0, stream>>>(xnb, wvt, nullptr, vbh, M, DDIM, DDIM);
    postqkv<<<M * HHEADS, 64, 0, stream>>>(qbh, kbh, vbh);

    // 3) chunked delta rule
    chunk_prep<<<16 * NC, 256, 0, stream>>>(kbh, qbh, vbh, beta, alpha, Gcum, Rg, Ktg, dvX, Mmat);
    chunk_seq_mfma<<<16 * SEQGV, 256, 0, stream>>>(S0, Gcum, Rg, Ktg, dvX, Ssnap, Sout);
    chunk_out<<<16 * NC, 256, 0, stream>>>(qbh, Gcum, dvX, Ssnap, Mmat, obufb);

    // 4) x1 = x + o @ wo — 128x64 tile BK=64
    gemm_n64<1><<<gP64, 256, 0, stream>>>(obufb, wot, x, out, M, DDIM, DDIM);

    // 4b) remaining weight transposes into now-dead regions
    transpose_cvt<<<dim3(DDIM / 32, FDIM / 32), 256, 0, stream>>>(wdown, wdt, FDIM, DDIM);
    transpose_cvt<<<dim3(FDIM / 32, DDIM / 32), 256, 0, stream>>>(wgate, wgt, DDIM, FDIM);
    transpose_cvt<<<dim3(FDIM / 32, DDIM / 32), 256, 0, stream>>>(wup, wut, DDIM, FDIM);

    // 5) xn2 = rms_norm(x1)
    rmsnorm_k<<<M, 256, 0, stream>>>(out, xn2b);

    // 6) H = silu(xn2 @ w_gate) * (xn2 @ w_up)  -- 128x64 tile BK=64
    dim3 gGU(FDIM / 64, M / 128);
    gemm_gateup_bf16<<<gGU, 256, 0, stream>>>(xn2b, wgt, wut, Hb, M, FDIM, DDIM);

    // 7) x_out = x1 + H @ w_down — 128x64 tile BK=64, K=4096
    gemm_n64<1><<<gP64, 256, 0, stream>>>(Hb, wdt, out, out, M, DDIM, FDIM);
}

// Round 12
// 427.115 us; speedup vs baseline: 2.1393x; 1.0278x over previous
//
#include <hip/hip_runtime.h>
#include <hip/hip_bf16.h>
#include <math.h>

// Sizes fixed by the problem: B=2, T=2048, D=1024, F=4096, H=8, DH=128.
#define BSZ 2
#define TLEN 2048
#define DDIM 1024
#define FDIM 4096
#define HHEADS 8
#define DHEAD 128
#define NC 32   // chunks per sequence
#define CS 64   // chunk size (CS*NC == TLEN)

typedef __bf16 bf16x8 __attribute__((ext_vector_type(8)));
typedef float f32x4 __attribute__((ext_vector_type(4)));

__device__ __forceinline__ float silu_f(float x) {
    return x / (1.0f + expf(-x));
}

__device__ __forceinline__ void load_lds16(const void* g, void* l) {
    __builtin_amdgcn_global_load_lds(
        (const __attribute__((address_space(1))) void*)g,
        (__attribute__((address_space(3))) void*)l, 16, 0, 0);
}

__device__ __forceinline__ unsigned short bf16_bits(float f) {
    __hip_bfloat16 h = __float2bfloat16(f);
    return *reinterpret_cast<unsigned short*>(&h);
}

__device__ __forceinline__ float bfbits2f(unsigned short u) {
    union { unsigned int i; float f; } c;
    c.i = ((unsigned int)u) << 16;
    return c.f;
}

__device__ __forceinline__ uint4 pack8_bf16(const float* f) {
    union { unsigned short u[8]; uint4 v; } r;
#pragma unroll
    for (int i = 0; i < 8; ++i) r.u[i] = bf16_bits(f[i]);
    return r.v;
}

// ---------------- RMSNorm: one block (256 thr) per row of 1024; bf16 out -----
struct alignas(8) bh4 { __hip_bfloat16 a, b, c, d; };

__global__ __launch_bounds__(256) void rmsnorm_k(const float* __restrict__ in,
                                                 __hip_bfloat16* __restrict__ out) {
    const long row = blockIdx.x;
    const int tid = threadIdx.x;
    const float4 x = *(const float4*)(in + row * DDIM + tid * 4);
    float ss = x.x * x.x + x.y * x.y + x.z * x.z + x.w * x.w;
    ss += __shfl_xor(ss, 1);
    ss += __shfl_xor(ss, 2);
    ss += __shfl_xor(ss, 4);
    ss += __shfl_xor(ss, 8);
    ss += __shfl_xor(ss, 16);
    ss += __shfl_xor(ss, 32);
    __shared__ float wsum[4];
    if ((tid & 63) == 0) wsum[tid >> 6] = ss;
    __syncthreads();
    const float tot = wsum[0] + wsum[1] + wsum[2] + wsum[3];
    const float sc = rsqrtf(tot * (1.0f / (float)DDIM) + 1e-6f);
    bh4 y;
    y.a = __float2bfloat16(x.x * sc);
    y.b = __float2bfloat16(x.y * sc);
    y.c = __float2bfloat16(x.z * sc);
    y.d = __float2bfloat16(x.w * sc);
    *(bh4*)(out + row * DDIM + tid * 4) = y;
}

// ------------- transpose + f32->bf16: W[K,N] -> Wt[N,K] -------------
__global__ __launch_bounds__(256) void transpose_cvt(const float* __restrict__ W,
                                                     __hip_bfloat16* __restrict__ Wt,
                                                     int K, int N) {
    __shared__ float t[32][33];
    const int n0 = blockIdx.x * 32, k0 = blockIdx.y * 32;
    const int tx = threadIdx.x & 31, ty = threadIdx.x >> 5;  // ty 0..7
#pragma unroll
    for (int i = 0; i < 4; ++i)
        t[ty * 4 + i][tx] = W[(long)(k0 + ty * 4 + i) * N + n0 + tx];
    __syncthreads();
#pragma unroll
    for (int i = 0; i < 4; ++i)
        Wt[(long)(n0 + ty * 4 + i) * K + k0 + tx] = __float2bfloat16(t[tx][ty * 4 + i]);
}

// ---------------- bf16 MFMA GEMM (128x64, BK=64 two-panel) ------------------
// MODE 1: f32 out + f32 resid. MODE 2: bf16 out.
template <int MODE>
__global__ __launch_bounds__(256) void gemm_n64(const __hip_bfloat16* __restrict__ A,
                                                const __hip_bfloat16* __restrict__ Bt,
                                                const float* __restrict__ resid,
                                                void* __restrict__ Cout,
                                                int M, int N, int K) {
    __shared__ __align__(16) short As[2 * 128 * 32];   // 16 KB (8 KB/panel)
    __shared__ __align__(16) short Bs[2 * 64 * 32];    // 8 KB (4 KB/panel)
    const int tid = threadIdx.x;
    const int w = tid >> 6, l = tid & 63;
    const int m0 = blockIdx.y * 128, n0 = blockIdx.x * 64;
    const int srow = (w << 4) + (l >> 2);
    const int skcol = (l & 3) * 8;
    const int wr = w >> 1, wc = w & 1;
    const int fr = l & 15;
    const int fkB = (l >> 4) * 16;

    f32x4 acc[4][2];
#pragma unroll
    for (int m = 0; m < 4; ++m)
#pragma unroll
        for (int n = 0; n < 2; ++n) acc[m][n] = (f32x4)0.0f;

    const __hip_bfloat16* Abase = A + (long)m0 * K + skcol;
    const __hip_bfloat16* Bbase = Bt + (long)n0 * K + skcol;

    for (int k0 = 0; k0 < K; k0 += 64) {
#pragma unroll
        for (int p = 0; p < 2; ++p) {
#pragma unroll
            for (int j = 0; j < 2; ++j)
                load_lds16(Abase + (long)(srow + j * 64) * K + k0 + p * 32,
                           (char*)As + p * 8192 + w * 1024 + j * 4096);
            load_lds16(Bbase + (long)srow * K + k0 + p * 32,
                       (char*)Bs + p * 4096 + w * 1024);
        }
        __syncthreads();
#pragma unroll
        for (int p = 0; p < 2; ++p) {
            bf16x8 av[4], bv[2];
#pragma unroll
            for (int m = 0; m < 4; ++m)
                av[m] = *(const bf16x8*)((char*)As + p * 8192 + (wr * 64 + m * 16 + fr) * 64 + fkB);
#pragma unroll
            for (int n = 0; n < 2; ++n)
                bv[n] = *(const bf16x8*)((char*)Bs + p * 4096 + (wc * 32 + n * 16 + fr) * 64 + fkB);
#pragma unroll
            for (int m = 0; m < 4; ++m)
#pragma unroll
                for (int n = 0; n < 2; ++n)
                    acc[m][n] = __builtin_amdgcn_mfma_f32_16x16x32_bf16(av[m], bv[n], acc[m][n], 0, 0, 0);
        }
        __syncthreads();
    }

    const int r0 = (l >> 4) * 4;
    const int cc = l & 15;
#pragma unroll
    for (int m = 0; m < 4; ++m) {
#pragma unroll
        for (int r = 0; r < 4; ++r) {
            const long row = m0 + wr * 64 + m * 16 + r0 + r;
            const long colb = n0 + wc * 32 + cc;
            if (MODE == 2) {
                __hip_bfloat16* cb = (__hip_bfloat16*)Cout + row * N + colb;
#pragma unroll
                for (int n = 0; n < 2; ++n)
                    cb[n * 16] = __float2bfloat16(acc[m][n][r]);
            } else {
                float* cp = (float*)Cout + row * N + colb;
                const float* rp = resid + row * N + colb;
#pragma unroll
                for (int n = 0; n < 2; ++n)
                    cp[n * 16] = acc[m][n][r] + rp[n * 16];
            }
        }
    }
}

// ---- dual-B MFMA GEMM for SwiGLU (BK=64 two-panel) -------------------------
__global__ __launch_bounds__(256) void gemm_gateup_bf16(const __hip_bfloat16* __restrict__ A,
                                                        const __hip_bfloat16* __restrict__ Bg,
                                                        const __hip_bfloat16* __restrict__ Bu,
                                                        __hip_bfloat16* __restrict__ Hb,
                                                        int M, int N, int K) {
    __shared__ __align__(16) short As[2 * 128 * 32];   // 16 KB
    __shared__ __align__(16) short Bgs[2 * 64 * 32];   // 8 KB
    __shared__ __align__(16) short Bus[2 * 64 * 32];   // 8 KB
    const int tid = threadIdx.x;
    const int w = tid >> 6, l = tid & 63;
    const int m0 = blockIdx.y * 128, n0 = blockIdx.x * 64;
    const int srow = (w << 4) + (l >> 2);
    const int skcol = (l & 3) * 8;
    const int wr = w >> 1, wc = w & 1;
    const int fr = l & 15;
    const int fkB = (l >> 4) * 16;

    f32x4 accg[4][2], accu[4][2];
#pragma unroll
    for (int m = 0; m < 4; ++m)
#pragma unroll
        for (int n = 0; n < 2; ++n) { accg[m][n] = (f32x4)0.0f; accu[m][n] = (f32x4)0.0f; }

    const __hip_bfloat16* Abase = A + (long)m0 * K + skcol;
    const __hip_bfloat16* Bgb = Bg + (long)n0 * K + skcol;
    const __hip_bfloat16* Bub = Bu + (long)n0 * K + skcol;

    for (int k0 = 0; k0 < K; k0 += 64) {
#pragma unroll
        for (int p = 0; p < 2; ++p) {
#pragma unroll
            for (int j = 0; j < 2; ++j)
                load_lds16(Abase + (long)(srow + j * 64) * K + k0 + p * 32,
                           (char*)As + p * 8192 + w * 1024 + j * 4096);
            load_lds16(Bgb + (long)srow * K + k0 + p * 32, (char*)Bgs + p * 4096 + w * 1024);
            load_lds16(Bub + (long)srow * K + k0 + p * 32, (char*)Bus + p * 4096 + w * 1024);
        }
        __syncthreads();
#pragma unroll
        for (int p = 0; p < 2; ++p) {
            bf16x8 av[4], bgv[2], buv[2];
#pragma unroll
            for (int m = 0; m < 4; ++m)
                av[m] = *(const bf16x8*)((char*)As + p * 8192 + (wr * 64 + m * 16 + fr) * 64 + fkB);
#pragma unroll
            for (int n = 0; n < 2; ++n) {
                bgv[n] = *(const bf16x8*)((char*)Bgs + p * 4096 + (wc * 32 + n * 16 + fr) * 64 + fkB);
                buv[n] = *(const bf16x8*)((char*)Bus + p * 4096 + (wc * 32 + n * 16 + fr) * 64 + fkB);
            }
#pragma unroll
            for (int m = 0; m < 4; ++m)
#pragma unroll
                for (int n = 0; n < 2; ++n) {
                    accg[m][n] = __builtin_amdgcn_mfma_f32_16x16x32_bf16(av[m], bgv[n], accg[m][n], 0, 0, 0);
                    accu[m][n] = __builtin_amdgcn_mfma_f32_16x16x32_bf16(av[m], buv[n], accu[m][n], 0, 0, 0);
                }
        }
        __syncthreads();
    }

    const int r0 = (l >> 4) * 4;
    const int cc = l & 15;
#pragma unroll
    for (int m = 0; m < 4; ++m) {
#pragma unroll
        for (int r = 0; r < 4; ++r) {
            const long row = m0 + wr * 64 + m * 16 + r0 + r;
            __hip_bfloat16* hp = Hb + row * N + n0 + wc * 32 + cc;
#pragma unroll
            for (int n = 0; n < 2; ++n)
                hp[n * 16] = __float2bfloat16(silu_f(accg[m][n][r]) * accu[m][n][r]);
        }
    }
}

// ------- beta/alpha: inline rmsnorm; x staged through LDS (coalesced) -------
__global__ __launch_bounds__(64) void ba_kernel(const float* __restrict__ x,
                                                const float* __restrict__ wb,
                                                const float* __restrict__ wg,
                                                float* __restrict__ beta,
                                                float* __restrict__ alpha) {
    __shared__ float xs[DDIM];
    const long row = blockIdx.x;
    const int tid = threadIdx.x;
    float ss = 0.0f;
#pragma unroll
    for (int j = 0; j < 4; ++j) {
        const int fi = tid + j * 64;
        const float4 v = *(const float4*)(x + row * DDIM + fi * 4);
        *(float4*)&xs[fi * 4] = v;
        ss += v.x * v.x + v.y * v.y + v.z * v.z + v.w * v.w;
    }
    ss += __shfl_xor(ss, 1);
    ss += __shfl_xor(ss, 2);
    ss += __shfl_xor(ss, 4);
    ss += __shfl_xor(ss, 8);
    ss += __shfl_xor(ss, 16);
    ss += __shfl_xor(ss, 32);
    __syncthreads();
    const int o = tid >> 2;
    const int p = tid & 3;
    const float* wbase = (o < 8) ? (wb + o) : (wg + (o - 8));
    const float* wr = wbase + (long)(p * 256) * HHEADS;
    const float* xr = xs + p * 256;
    float acc = 0.0f;
#pragma unroll 8
    for (int i = 0; i < 256; ++i)
        acc = fmaf(xr[i], wr[(long)i * HHEADS], acc);
    acc += __shfl_xor(acc, 1);
    acc += __shfl_xor(acc, 2);
    if (p == 0) {
        const float sc = rsqrtf(ss * (1.0f / (float)DDIM) + 1e-6f);
        const float val = 1.0f / (1.0f + expf(-acc * sc));
        if (o < 8) beta[row * HHEADS + o] = val;
        else       alpha[row * HHEADS + (o - 8)] = val;
    }
}

// ------- post-projection (bf16 in-place): silu + l2norm on q,k; silu on v ----
__global__ __launch_bounds__(64) void postqkv(__hip_bfloat16* __restrict__ q,
                                              __hip_bfloat16* __restrict__ k,
                                              __hip_bfloat16* __restrict__ v) {
    const long r = blockIdx.x;
    const int tid = threadIdx.x;
    {
        unsigned int* qp = (unsigned int*)(q + r * DHEAD + tid * 2);
        const unsigned int wbits = *qp;
        float y0 = silu_f(bfbits2f(wbits & 0xffff));
        float y1 = silu_f(bfbits2f(wbits >> 16));
        float ss = y0 * y0 + y1 * y1;
        ss += __shfl_xor(ss, 1);  ss += __shfl_xor(ss, 2);
        ss += __shfl_xor(ss, 4);  ss += __shfl_xor(ss, 8);
        ss += __shfl_xor(ss, 16); ss += __shfl_xor(ss, 32);
        const float sc = rsqrtf(ss + 1e-6f);
        *qp = (unsigned int)bf16_bits(y0 * sc) | ((unsigned int)bf16_bits(y1 * sc) << 16);
    }
    {
        unsigned int* kp = (unsigned int*)(k + r * DHEAD + tid * 2);
        const unsigned int wbits = *kp;
        float y0 = silu_f(bfbits2f(wbits & 0xffff));
        float y1 = silu_f(bfbits2f(wbits >> 16));
        float ss = y0 * y0 + y1 * y1;
        ss += __shfl_xor(ss, 1);  ss += __shfl_xor(ss, 2);
        ss += __shfl_xor(ss, 4);  ss += __shfl_xor(ss, 8);
        ss += __shfl_xor(ss, 16); ss += __shfl_xor(ss, 32);
        const float sc = rsqrtf(ss + 1e-6f);
        *kp = (unsigned int)bf16_bits(y0 * sc) | ((unsigned int)bf16_bits(y1 * sc) << 16);
    }
    {
        unsigned int* vp = (unsigned int*)(v + r * DHEAD + tid * 2);
        const unsigned int wbits = *vp;
        *vp = (unsigned int)bf16_bits(silu_f(bfbits2f(wbits & 0xffff)))
            | ((unsigned int)bf16_bits(silu_f(bfbits2f(wbits >> 16))) << 16);
    }
}

// ============ Chunked gated delta rule (log-space decay) ============
// G_t = sum_{s<=t} log(a_s); ratio(t,s)=exp(G_t-G_s)<=1 for s<=t.
//   Tinv = (I+W)^-1 with W[t][s] = b_t ratio (k_t.k_s) (s<t)
//   dv = dv0 + R @ S0,   R = -Tinv @ diag(b_s e^{G_s}) @ K
//   dv0 = Tinv @ (b (.) v)
//   o_t = e^{G_t} (S0^T q_t) + (M @ dv)_t
//   S_end = e^{G63} S0 + K^T @ diag(e^{G63-G_t}) dv

// --------- Phase A (parallel over bh x chunk): G, M, Tinv, R, K^T, dv0 ------
// Tinv via Neumann doubling: X = -W nilpotent (X^64=0);
//   T=I; repeat 6x: { T <- T + T@X ; X <- X@X }  => T = sum X^k = (I+W)^-1.
// Maintains Xr (row-major) and Xt (=X^T row-major) so all MFMA operands are
// row reads. 3 matmuls/round: T@X (A=T,B=Xt), X@X (A=Xr,B=Xt), Xt@Xt (A=Xt,B=Xr).
// LDS carve (bytes): tA 0(17408) | tB 17408(17408) |
//   set i at 34816+i*27648: T(9216) Xr(9216) Xt(9216) | scalars @90112(1024).
__global__ __launch_bounds__(256) void chunk_prep(
    const __hip_bfloat16* __restrict__ kb, const __hip_bfloat16* __restrict__ qb,
    const __hip_bfloat16* __restrict__ vb, const float* __restrict__ betab,
    const float* __restrict__ alphab, float* __restrict__ Gcum,
    __hip_bfloat16* __restrict__ Rg, __hip_bfloat16* __restrict__ Ktg,
    __hip_bfloat16* __restrict__ dvX, __hip_bfloat16* __restrict__ Mmat)
{
    const int bh = blockIdx.x >> 5;
    const int c  = blockIdx.x & 31;
    const int b = bh >> 3, h = bh & 7;
    const int tid = threadIdx.x;
    const int w = tid >> 6, l = tid & 63;
    const int fr = l & 15;           // fragment col / A-row low
    const int fk8 = (l >> 4) * 8;    // fragment k base (bf16 elems)
    const int fr4 = (l >> 4) * 4;    // C-fragment row base

    __shared__ __align__(16) char smem[91136];
    __hip_bfloat16* tA = (__hip_bfloat16*)(smem);            // [64][136] k
    __hip_bfloat16* tB = (__hip_bfloat16*)(smem + 17408);    // [64][136] q -> b*v
    float* sa  = (float*)(smem + 90112);
    float* sb_ = sa + 64;
    float* sG  = sb_ + 64;
    float* swB = sG + 64;

    const long row0 = (long)b * TLEN + (long)c * CS;
    const long chnk = (long)bh * NC + c;

    if (tid < 64) {
        sa[tid]  = alphab[(row0 + tid) * HHEADS + h];
        sb_[tid] = betab[(row0 + tid) * HHEADS + h];
    }
    // load k,q chunks (bf16 direct copies)
    {
        const int r = tid >> 2;
        const int d0 = (tid & 3) * 32;
        const uint4* kp = (const uint4*)(kb + (row0 + r) * DDIM + h * DHEAD + d0);
        const uint4* qp = (const uint4*)(qb + (row0 + r) * DDIM + h * DHEAD + d0);
#pragma unroll
        for (int i = 0; i < 4; ++i) {
            *(uint4*)&tA[r * 136 + d0 + i * 8] = kp[i];
            *(uint4*)&tB[r * 136 + d0 + i * 8] = qp[i];
        }
    }
    __syncthreads();
    if (tid == 0) {
        float run = 0.0f;
        for (int t = 0; t < CS; ++t) { run += logf(sa[t]); sG[t] = run; }
    }
    __syncthreads();
    if (tid < 64) {
        Gcum[chnk * CS + tid] = sG[tid];
        swB[tid] = sb_[tid] * expf(sG[tid]);
    }
    __syncthreads();

    // ---- MFMA: W_raw = K@K^T, M_raw = Q@K^T (wave w owns rows w*16..+15) ----
    f32x4 accW[4], accM[4];
#pragma unroll
    for (int n = 0; n < 4; ++n) { accW[n] = (f32x4)0.0f; accM[n] = (f32x4)0.0f; }
#pragma unroll
    for (int ks = 0; ks < 4; ++ks) {
        const bf16x8 aW = *(const bf16x8*)&tA[(w * 16 + fr) * 136 + ks * 32 + fk8];
        const bf16x8 aM = *(const bf16x8*)&tB[(w * 16 + fr) * 136 + ks * 32 + fk8];
#pragma unroll
        for (int n = 0; n < 4; ++n) {
            const bf16x8 bfr = *(const bf16x8*)&tA[(n * 16 + fr) * 136 + ks * 32 + fk8];
            accW[n] = __builtin_amdgcn_mfma_f32_16x16x32_bf16(aW, bfr, accW[n], 0, 0, 0);
            accM[n] = __builtin_amdgcn_mfma_f32_16x16x32_bf16(aM, bfr, accM[n], 0, 0, 0);
        }
    }
    // epilogue: M -> global; X0 = -W (row + transposed); T0 = I
    {
        __hip_bfloat16* T0  = (__hip_bfloat16*)(smem + 34816);
        __hip_bfloat16* Xr0 = (__hip_bfloat16*)(smem + 34816 + 9216);
        __hip_bfloat16* Xt0 = (__hip_bfloat16*)(smem + 34816 + 18432);
#pragma unroll
        for (int n = 0; n < 4; ++n) {
            const int s = n * 16 + fr;
            const float Gs = sG[s];
#pragma unroll
            for (int r = 0; r < 4; ++r) {
                const int t = w * 16 + fr4 + r;
                const float ratio = (s <= t) ? expf(sG[t] - Gs) : 0.0f;
                Mmat[(chnk * CS + t) * CS + s] = __float2bfloat16(ratio * accM[n][r]);
                const float xv = (s < t) ? -(sb_[t] * ratio * accW[n][r]) : 0.0f;
                const __hip_bfloat16 xb = __float2bfloat16(xv);
                Xr0[t * 72 + s] = xb;
                Xt0[s * 72 + t] = xb;
                T0[t * 72 + s] = __float2bfloat16((s == t) ? 1.0f : 0.0f);
            }
        }
    }
    __syncthreads();   // tB (q) reads done; T0/Xr0/Xt0 visible

    // K^T: Ktg[kk][t] = K[t][kk]   (reads tA; independent of doubling bufs)
    {
        const int kk = tid >> 1;
        const int t0 = (tid & 1) * 32;
        __hip_bfloat16* kp = Ktg + (chnk * DHEAD + kk) * CS + t0;
        float f[8];
#pragma unroll
        for (int i = 0; i < 4; ++i) {
#pragma unroll
            for (int j2 = 0; j2 < 8; ++j2)
                f[j2] = __bfloat162float(tA[(t0 + i * 8 + j2) * 136 + kk]);
            *(uint4*)(kp + i * 8) = pack8_bf16(f);
        }
    }
    // load b*v into tB (q dead)
    {
        const int r = tid >> 2, d0 = (tid & 3) * 32;
        const float br = sb_[r];
        const uint4* vp = (const uint4*)(vb + (row0 + r) * DDIM + h * DHEAD + d0);
#pragma unroll
        for (int i = 0; i < 4; ++i) {
            const uint4 vv = vp[i];
            const unsigned short* u = (const unsigned short*)&vv;
            float f[8];
#pragma unroll
            for (int j = 0; j < 8; ++j) f[j] = br * bfbits2f(u[j]);
            *(uint4*)&tB[r * 136 + d0 + i * 8] = pack8_bf16(f);
        }
    }

    // ---- Neumann doubling: 6 rounds of {T += T@X; X = X@X} via MFMA --------
    int cur = 0;
    for (int rnd = 0; rnd < 6; ++rnd) {
        const int co = 34816 + cur * 27648;
        const int no = 34816 + (cur ^ 1) * 27648;
        const __hip_bfloat16* Tc  = (const __hip_bfloat16*)(smem + co);
        const __hip_bfloat16* Xrc = (const __hip_bfloat16*)(smem + co + 9216);
        const __hip_bfloat16* Xtc = (const __hip_bfloat16*)(smem + co + 18432);
        __hip_bfloat16* Tn  = (__hip_bfloat16*)(smem + no);
        __hip_bfloat16* Xrn = (__hip_bfloat16*)(smem + no + 9216);
        __hip_bfloat16* Xtn = (__hip_bfloat16*)(smem + no + 18432);

        f32x4 aT[4], aXr[4], aXt[4];
#pragma unroll
        for (int n = 0; n < 4; ++n) { aT[n] = (f32x4)0.0f; aXr[n] = (f32x4)0.0f; aXt[n] = (f32x4)0.0f; }
#pragma unroll
        for (int ks = 0; ks < 2; ++ks) {
            const bf16x8 fT  = *(const bf16x8*)&Tc [(w * 16 + fr) * 72 + ks * 32 + fk8];
            const bf16x8 fXr = *(const bf16x8*)&Xrc[(w * 16 + fr) * 72 + ks * 32 + fk8];
            const bf16x8 fXt = *(const bf16x8*)&Xtc[(w * 16 + fr) * 72 + ks * 32 + fk8];
#pragma unroll
            for (int n = 0; n < 4; ++n) {
                const bf16x8 bXt = *(const bf16x8*)&Xtc[(n * 16 + fr) * 72 + ks * 32 + fk8];
                const bf16x8 bXr = *(const bf16x8*)&Xrc[(n * 16 + fr) * 72 + ks * 32 + fk8];
                aT[n]  = __builtin_amdgcn_mfma_f32_16x16x32_bf16(fT,  bXt, aT[n], 0, 0, 0);
                aXr[n] = __builtin_amdgcn_mfma_f32_16x16x32_bf16(fXr, bXt, aXr[n], 0, 0, 0);
                aXt[n] = __builtin_amdgcn_mfma_f32_16x16x32_bf16(fXt, bXr, aXt[n], 0, 0, 0);
            }
        }
#pragma unroll
        for (int n = 0; n < 4; ++n) {
            const int col = n * 16 + fr;
#pragma unroll
            for (int r = 0; r < 4; ++r) {
                const int t = w * 16 + fr4 + r;
                Tn[t * 72 + col] = __float2bfloat16(aT[n][r] + __bfloat162float(Tc[t * 72 + col]));
                if (rnd < 5) {
                    Xrn[t * 72 + col] = __float2bfloat16(aXr[n][r]);
                    Xtn[t * 72 + col] = __float2bfloat16(aXt[n][r]);
                }
            }
        }
        __syncthreads();
        cur ^= 1;
    }
    const __hip_bfloat16* Tf = (const __hip_bfloat16*)(smem + 34816 + cur * 27648);

    // R[t][kk] = -sum_{s<=t} Tinv[t][s] * swB[s] * K[s][kk]   (bf16 out)
    {
        const int t = tid >> 2, j0 = (tid & 3) * 32;
        float acc[32];
#pragma unroll
        for (int j = 0; j < 32; ++j) acc[j] = 0.0f;
        for (int s = 0; s <= t; ++s) {
            const float cf = -__bfloat162float(Tf[t * 72 + s]) * swB[s];
#pragma unroll
            for (int j = 0; j < 32; ++j)
                acc[j] = fmaf(cf, __bfloat162float(tA[s * 136 + j0 + j]), acc[j]);
        }
        __hip_bfloat16* rp = Rg + (chnk * CS + t) * DHEAD + j0;
#pragma unroll
        for (int i = 0; i < 4; ++i)
            *(uint4*)(rp + i * 8) = pack8_bf16(&acc[i * 8]);
    }

    // dv0 = Tinv @ (b*v) -> dvX (bf16); Tinv lower-triangular so s<=t
    {
        const int t = tid >> 2, j0 = (tid & 3) * 32;
        float acc[32];
#pragma unroll
        for (int j = 0; j < 32; ++j) acc[j] = 0.0f;
        for (int s = 0; s <= t; ++s) {
            const float ti = __bfloat162float(Tf[t * 72 + s]);
#pragma unroll
            for (int j = 0; j < 32; ++j)
                acc[j] = fmaf(ti, __bfloat162float(tB[s * 136 + j0 + j]), acc[j]);
        }
        __hip_bfloat16* dp = dvX + (chnk * CS + t) * DHEAD + j0;
#pragma unroll
        for (int i = 0; i < 4; ++i)
            *(uint4*)(dp + i * 8) = pack8_bf16(&acc[i * 8]);
    }
}

// --------- Phase B: sequential over chunks; MFMA; 128 blocks ----------------
#define SEQGV 8
#define SEQ_LDS_BYTES 78848

__global__ __launch_bounds__(256) void chunk_seq_mfma(
    const float* __restrict__ S0in, const float* __restrict__ Gcum,
    const __hip_bfloat16* __restrict__ Rg, const __hip_bfloat16* __restrict__ Ktg,
    __hip_bfloat16* __restrict__ dvX, __hip_bfloat16* __restrict__ Ssnap,
    float* __restrict__ Sout)
{
    const int bh = blockIdx.x & 15;
    const int g  = blockIdx.x >> 4;
    const int j0 = g * 16;
    const int tid = threadIdx.x;
    const int w = tid >> 6;
    const int l = tid & 63;
    const int fr = l & 15;
    const int fk8 = (l >> 4) * 8;
    const int rq = (l >> 4) * 4;

    __shared__ __align__(16) char smem[SEQ_LDS_BYTES];
    __hip_bfloat16* dvT = (__hip_bfloat16*)(smem + 71680);   // [16 j][72 t]
    __hip_bfloat16* Stl = (__hip_bfloat16*)(smem + 73984);   // [16 j][136 kk]
    float* sG = (float*)(smem + 78336);

    f32x4 SM[2];
#pragma unroll
    for (int mj = 0; mj < 2; ++mj) {
#pragma unroll
        for (int r = 0; r < 4; ++r) {
            const int kk = w * 32 + mj * 16 + rq + r;
            const float v = S0in[((long)bh * 128 + kk) * 128 + j0 + fr];
            SM[mj][r] = v;
            Stl[fr * 136 + kk] = __float2bfloat16(v);
        }
    }

    uint4 rreg[4], kreg[4];
    float greg = 0.0f;

#define SEQ_STAGE_LOAD(c_) do {                                                   \
        const long cb_ = (long)bh * NC + (c_);                                    \
        _Pragma("unroll")                                                         \
        for (int i_ = 0; i_ < 4; ++i_) {                                          \
            const int ur_ = (tid << 2) + i_;                                      \
            rreg[i_] = *(const uint4*)(Rg + (cb_ * CS + (ur_ >> 4)) * DHEAD + ((ur_ & 15) << 3)); \
            kreg[i_] = *(const uint4*)(Ktg + (cb_ * DHEAD + (ur_ >> 3)) * CS + ((ur_ & 7) << 3)); \
        }                                                                         \
        if (tid < 64) greg = Gcum[cb_ * CS + tid];                                \
    } while (0)

#define SEQ_STAGE_WRITE(bufi_) do {                                               \
        __hip_bfloat16* rb_ = (__hip_bfloat16*)(smem + (bufi_) * 17408);          \
        __hip_bfloat16* kb2_ = (__hip_bfloat16*)(smem + 34816 + (bufi_) * 18432); \
        _Pragma("unroll")                                                         \
        for (int i_ = 0; i_ < 4; ++i_) {                                          \
            const int ur_ = (tid << 2) + i_;                                      \
            *(uint4*)(rb_ + (ur_ >> 4) * 136 + ((ur_ & 15) << 3)) = rreg[i_];     \
            *(uint4*)(kb2_ + (ur_ >> 3) * 72 + ((ur_ & 7) << 3)) = kreg[i_];      \
        }                                                                         \
        if (tid < 64) sG[(bufi_) * 64 + tid] = greg;                              \
    } while (0)

    SEQ_STAGE_LOAD(0);
    SEQ_STAGE_WRITE(0);
    __syncthreads();

    for (int c = 0; c < NC; ++c) {
        const int cur = c & 1;
        const long chnk = (long)bh * NC + c;
        const __hip_bfloat16* Rl = (const __hip_bfloat16*)(smem + cur * 17408);
        const __hip_bfloat16* Ktl = (const __hip_bfloat16*)(smem + 34816 + cur * 18432);
        const float g63 = sG[cur * 64 + 63];
        const float a63 = expf(g63);

        unsigned short d0r[4];
#pragma unroll
        for (int r = 0; r < 4; ++r) {
            const int t = w * 16 + rq + r;
            d0r[r] = *(const unsigned short*)(dvX + (chnk * CS + t) * DHEAD + j0 + fr);
        }

        if (c + 1 < NC) SEQ_STAGE_LOAD(c + 1);

        {
            const int j = tid >> 4, k0 = (tid & 15) * 8;
            const uint4 v = *(const uint4*)&Stl[j * 136 + k0];
            *(uint4*)(Ssnap + (chnk * 128 + j0 + j) * 128 + k0) = v;
        }

        // step A: dv = dv0 + R @ S
        f32x4 acc = (f32x4)0.0f;
#pragma unroll
        for (int ks = 0; ks < 4; ++ks) {
            const bf16x8 bfrag = *(const bf16x8*)&Stl[fr * 136 + ks * 32 + fk8];
            const bf16x8 afrag = *(const bf16x8*)&Rl[(w * 16 + fr) * 136 + ks * 32 + fk8];
            acc = __builtin_amdgcn_mfma_f32_16x16x32_bf16(afrag, bfrag, acc, 0, 0, 0);
        }
#pragma unroll
        for (int r = 0; r < 4; ++r) {
            const int t = w * 16 + rq + r;
            const float rk = expf(g63 - sG[cur * 64 + t]);
            const float dv = acc[r] + bfbits2f(d0r[r]);
            *(unsigned short*)(dvX + (chnk * CS + t) * DHEAD + j0 + fr) = bf16_bits(dv);
            dvT[fr * 72 + t] = __float2bfloat16(rk * dv);
        }

        if (c + 1 < NC) SEQ_STAGE_WRITE(cur ^ 1);
        __syncthreads();

        // step B: S' = a63*S + K^T @ dvs
#pragma unroll
        for (int mj = 0; mj < 2; ++mj) SM[mj] *= a63;
#pragma unroll
        for (int ks = 0; ks < 2; ++ks) {
            const bf16x8 bfrag = *(const bf16x8*)&dvT[fr * 72 + ks * 32 + fk8];
#pragma unroll
            for (int mj = 0; mj < 2; ++mj) {
                const bf16x8 afrag = *(const bf16x8*)&Ktl[(w * 32 + mj * 16 + fr) * 72 + ks * 32 + fk8];
                SM[mj] = __builtin_amdgcn_mfma_f32_16x16x32_bf16(afrag, bfrag, SM[mj], 0, 0, 0);
            }
        }
#pragma unroll
        for (int mj = 0; mj < 2; ++mj)
#pragma unroll
            for (int r = 0; r < 4; ++r) {
                const int kk = w * 32 + mj * 16 + rq + r;
                Stl[fr * 136 + kk] = __float2bfloat16(SM[mj][r]);
            }
        __syncthreads();
    }

#pragma unroll
    for (int mj = 0; mj < 2; ++mj)
#pragma unroll
        for (int r = 0; r < 4; ++r) {
            const int kk = w * 32 + mj * 16 + rq + r;
            Sout[((long)bh * 128 + kk) * 128 + j0 + fr] = SM[mj][r];
        }
#undef SEQ_STAGE_LOAD
#undef SEQ_STAGE_WRITE
}

// --------- Phase C (parallel, MFMA): o = e^{G_t}*(q_t @ S0snap) + M @ dv ----
__global__ __launch_bounds__(256) void chunk_out(
    const __hip_bfloat16* __restrict__ qb, const float* __restrict__ Gcum,
    const __hip_bfloat16* __restrict__ dvX, const __hip_bfloat16* __restrict__ Ssnap,
    const __hip_bfloat16* __restrict__ Mmat, __hip_bfloat16* __restrict__ ob)
{
    const int bh = blockIdx.x >> 5;
    const int c  = blockIdx.x & 31;
    const int b = bh >> 3, h = bh & 7;
    const int tid = threadIdx.x;
    const int w = tid >> 6, l = tid & 63;
    const int fr = l & 15;
    const int fk8 = (l >> 4) * 8;
    const int rq = (l >> 4) * 4;
    const long row0 = (long)b * TLEN + (long)c * CS;
    const long chnk = (long)bh * NC + c;

    __shared__ __align__(16) char smem[62464];
    __hip_bfloat16* Ssn = (__hip_bfloat16*)(smem);
    __hip_bfloat16* Ml  = (__hip_bfloat16*)(smem + 34816);
    __hip_bfloat16* dq  = (__hip_bfloat16*)(smem + 44032);

    {
        const int j = tid >> 1;
        const int d0 = (tid & 1) * 64;
        const uint4* sp = (const uint4*)(Ssnap + (chnk * 128 + j) * 128 + d0);
#pragma unroll
        for (int i = 0; i < 8; ++i)
            *(uint4*)&Ssn[j * 136 + d0 + i * 8] = sp[i];
    }
    {
        const int t = tid >> 2;
        const int s0 = (tid & 3) * 16;
        const uint4* mp = (const uint4*)(Mmat + (chnk * CS + t) * CS + s0);
        *(uint4*)&Ml[t * 72 + s0]     = mp[0];
        *(uint4*)&Ml[t * 72 + s0 + 8] = mp[1];
    }
    {
        const int t = tid >> 2, jb = (tid & 3) * 32;
        uint4 dvr[4];
#pragma unroll
        for (int i = 0; i < 4; ++i)
            dvr[i] = ((const uint4*)(dvX + (chnk * CS + t) * DHEAD + jb))[i];
        const unsigned short* u = (const unsigned short*)&dvr[0];
#pragma unroll
        for (int i = 0; i < 32; ++i)
            dq[(jb + i) * 72 + t] = *(const __hip_bfloat16*)&u[i];
    }
    __syncthreads();

    f32x4 acc[8];
#pragma unroll
    for (int n = 0; n < 8; ++n) acc[n] = (f32x4)0.0f;

    // part 1: O += M @ dv   (K = 64)
#pragma unroll
    for (int ks = 0; ks < 2; ++ks) {
        const bf16x8 afrag = *(const bf16x8*)&Ml[(w * 16 + fr) * 72 + ks * 32 + fk8];
#pragma unroll
        for (int n = 0; n < 8; ++n) {
            const bf16x8 bfrag = *(const bf16x8*)&dq[(n * 16 + fr) * 72 + ks * 32 + fk8];
            acc[n] = __builtin_amdgcn_mfma_f32_16x16x32_bf16(afrag, bfrag, acc[n], 0, 0, 0);
        }
    }
    __syncthreads();

    {
        const int t = tid >> 2, d0 = (tid & 3) * 32;
        const float At = expf(Gcum[chnk * CS + t]);
        const uint4* qp = (const uint4*)(qb + (row0 + t) * DDIM + h * DHEAD + d0);
#pragma unroll
        for (int i = 0; i < 4; ++i) {
            const uint4 qv = qp[i];
            const unsigned short* u = (const unsigned short*)&qv;
            float f[8];
#pragma unroll
            for (int j = 0; j < 8; ++j) f[j] = At * bfbits2f(u[j]);
            *(uint4*)&dq[t * 136 + d0 + i * 8] = pack8_bf16(f);
        }
    }
    __syncthreads();

    // part 2: O += (At*q) @ S0   (K = 128)
#pragma unroll
    for (int ks = 0; ks < 4; ++ks) {
        const bf16x8 afrag = *(const bf16x8*)&dq[(w * 16 + fr) * 136 + ks * 32 + fk8];
#pragma unroll
        for (int n = 0; n < 8; ++n) {
            const bf16x8 bfrag = *(const bf16x8*)&Ssn[(n * 16 + fr) * 136 + ks * 32 + fk8];
            acc[n] = __builtin_amdgcn_mfma_f32_16x16x32_bf16(afrag, bfrag, acc[n], 0, 0, 0);
        }
    }

#pragma unroll
    for (int r = 0; r < 4; ++r) {
        const int t = w * 16 + rq + r;
        __hip_bfloat16* op = ob + (row0 + t) * DDIM + h * DHEAD + fr;
#pragma unroll
        for (int n = 0; n < 8; ++n)
            op[n * 16] = __float2bfloat16(acc[n][r]);
    }
}

extern "C" void kernel_launch(void* const* d_in, const int* in_sizes, int n_in,
                              void* d_out, int out_size, void* d_ws, size_t ws_size,
                              hipStream_t stream) {
    const float* x     = (const float*)d_in[0];
    const float* S0    = (const float*)d_in[1];
    const float* wq    = (const float*)d_in[2];
    const float* wk    = (const float*)d_in[3];
    const float* wv    = (const float*)d_in[4];
    const float* wb    = (const float*)d_in[5];
    const float* wg    = (const float*)d_in[6];
    const float* wo    = (const float*)d_in[7];
    const float* wgate = (const float*)d_in[8];
    const float* wup   = (const float*)d_in[9];
    const float* wdown = (const float*)d_in[10];

    const int M = BSZ * TLEN;  // 4096 token rows

    float* out  = (float*)d_out;
    float* Sout = out + (long)M * DDIM;

    // Workspace layout, peak 76.5 MiB (proven budget: 81 MiB).
    char* w = (char*)d_ws;
    const size_t MB = 1u << 20;
    const size_t KB = 1u << 10;
    __hip_bfloat16* qbh   = (__hip_bfloat16*)(w + 0 * MB);
    __hip_bfloat16* kbh   = (__hip_bfloat16*)(w + 8 * MB);
    __hip_bfloat16* vbh   = (__hip_bfloat16*)(w + 16 * MB);
    float*          beta  = (float*)(w + 24 * MB);
    float*          alpha = (float*)(w + 24 * MB + 128 * KB);
    float*          Gcum  = (float*)(w + 24 * MB + 256 * KB);
    __hip_bfloat16* Mmat  = (__hip_bfloat16*)(w + 24 * MB + 512 * KB); // prep->out (4MB)
    __hip_bfloat16* dvX   = (__hip_bfloat16*)(w + 28 * MB + 512 * KB); // prep->out (8MB)
    __hip_bfloat16* Rg    = (__hip_bfloat16*)(w + 36 * MB + 512 * KB); // prep->seq (8MB)
    __hip_bfloat16* xnb   = (__hip_bfloat16*)(w + 36 * MB + 512 * KB); // rms1->QKV (dead before Rg)
    __hip_bfloat16* Ktg   = (__hip_bfloat16*)(w + 44 * MB + 512 * KB); // prep->seq (8MB)
    __hip_bfloat16* Ssnap = (__hip_bfloat16*)(w + 52 * MB + 512 * KB); // seq->out (16MB)
    __hip_bfloat16* wqt   = (__hip_bfloat16*)(w + 68 * MB + 512 * KB);
    __hip_bfloat16* wkt   = (__hip_bfloat16*)(w + 70 * MB + 512 * KB);
    __hip_bfloat16* wvt   = (__hip_bfloat16*)(w + 72 * MB + 512 * KB);
    __hip_bfloat16* wot   = (__hip_bfloat16*)(w + 74 * MB + 512 * KB);
    __hip_bfloat16* obufb = (__hip_bfloat16*)(w + 8 * MB);
    __hip_bfloat16* xn2b  = (__hip_bfloat16*)(w + 8 * MB);
    __hip_bfloat16* wdt   = (__hip_bfloat16*)(w + 16 * MB);
    __hip_bfloat16* wgt   = (__hip_bfloat16*)(w + 24 * MB + 512 * KB);
    __hip_bfloat16* wut   = (__hip_bfloat16*)(w + 32 * MB + 512 * KB);
    __hip_bfloat16* Hb    = (__hip_bfloat16*)(w + 40 * MB + 512 * KB);

    // 0) weight transpose+convert (W[K,N] -> Wt[N,K] bf16)
    transpose_cvt<<<dim3(DDIM / 32, DDIM / 32), 256, 0, stream>>>(wq, wqt, DDIM, DDIM);
    transpose_cvt<<<dim3(DDIM / 32, DDIM / 32), 256, 0, stream>>>(wk, wkt, DDIM, DDIM);
    transpose_cvt<<<dim3(DDIM / 32, DDIM / 32), 256, 0, stream>>>(wv, wvt, DDIM, DDIM);
    transpose_cvt<<<dim3(DDIM / 32, DDIM / 32), 256, 0, stream>>>(wo, wot, DDIM, DDIM);

    // 1) norms / gates
    rmsnorm_k<<<M, 256, 0, stream>>>(x, xnb);
    ba_kernel<<<M, 64, 0, stream>>>(x, wb, wg, beta, alpha);

    // 2) q/k/v projections (bf16 out) — 128x64 tile BK=64
    dim3 gP64(DDIM / 64, M / 128);  // (16, 32)
    gemm_n64<2><<<gP64, 256, 0, stream>>>(xnb, wqt, nullptr, qbh, M, DDIM, DDIM);
    gemm_n64<2><<<gP64, 256, 0, stream>>>(xnb, wkt, nullptr, kbh, M, DDIM, DDIM);
    gemm_n64<2><<<gP64, 256, 0, stream>>>(xnb, wvt, nullptr, vbh, M, DDIM, DDIM);
    postqkv<<<M * HHEADS, 64, 0, stream>>>(qbh, kbh, vbh);

    // 3) chunked delta rule
    chunk_prep<<<16 * NC, 256, 0, stream>>>(kbh, qbh, vbh, beta, alpha, Gcum, Rg, Ktg, dvX, Mmat);
    chunk_seq_mfma<<<16 * SEQGV, 256, 0, stream>>>(S0, Gcum, Rg, Ktg, dvX, Ssnap, Sout);
    chunk_out<<<16 * NC, 256, 0, stream>>>(qbh, Gcum, dvX, Ssnap, Mmat, obufb);

    // 4) x1 = x + o @ wo — 128x64 tile BK=64
    gemm_n64<1><<<gP64, 256, 0, stream>>>(obufb, wot, x, out, M, DDIM, DDIM);

    // 4b) remaining weight transposes into now-dead regions
    transpose_cvt<<<dim3(DDIM / 32, FDIM / 32), 256, 0, stream>>>(wdown, wdt, FDIM, DDIM);
    transpose_cvt<<<dim3(FDIM / 32, DDIM / 32), 256, 0, stream>>>(wgate, wgt, DDIM, FDIM);
    transpose_cvt<<<dim3(FDIM / 32, DDIM / 32), 256, 0, stream>>>(wup, wut, DDIM, FDIM);

    // 5) xn2 = rms_norm(x1)
    rmsnorm_k<<<M, 256, 0, stream>>>(out, xn2b);

    // 6) H = silu(xn2 @ w_gate) * (xn2 @ w_up)  -- 128x64 tile BK=64
    dim3 gGU(FDIM / 64, M / 128);
    gemm_gateup_bf16<<<gGU, 256, 0, stream>>>(xn2b, wgt, wut, Hb, M, FDIM, DDIM);

    // 7) x_out = x1 + H @ w_down — 128x64 tile BK=64, K=4096
    gemm_n64<1><<<gP64, 256, 0, stream>>>(Hb, wdt, out, out, M, DDIM, FDIM);
}

// Round 13
// 380.067 us; speedup vs baseline: 2.4041x; 1.1238x over previous
//
#include <hip/hip_runtime.h>
#include <hip/hip_bf16.h>
#include <math.h>

// Sizes fixed by the problem: B=2, T=2048, D=1024, F=4096, H=8, DH=128.
#define BSZ 2
#define TLEN 2048
#define DDIM 1024
#define FDIM 4096
#define HHEADS 8
#define DHEAD 128
#define NC 32   // chunks per sequence
#define CS 64   // chunk size (CS*NC == TLEN)

typedef __bf16 bf16x8 __attribute__((ext_vector_type(8)));
typedef float f32x4 __attribute__((ext_vector_type(4)));

__device__ __forceinline__ float silu_f(float x) {
    return x / (1.0f + expf(-x));
}

__device__ __forceinline__ void load_lds16(const void* g, void* l) {
    __builtin_amdgcn_global_load_lds(
        (const __attribute__((address_space(1))) void*)g,
        (__attribute__((address_space(3))) void*)l, 16, 0, 0);
}

__device__ __forceinline__ unsigned short bf16_bits(float f) {
    __hip_bfloat16 h = __float2bfloat16(f);
    return *reinterpret_cast<unsigned short*>(&h);
}

__device__ __forceinline__ float bfbits2f(unsigned short u) {
    union { unsigned int i; float f; } c;
    c.i = ((unsigned int)u) << 16;
    return c.f;
}

__device__ __forceinline__ uint4 pack8_bf16(const float* f) {
    union { unsigned short u[8]; uint4 v; } r;
#pragma unroll
    for (int i = 0; i < 8; ++i) r.u[i] = bf16_bits(f[i]);
    return r.v;
}

// ---------------- RMSNorm: one block (256 thr) per row of 1024; bf16 out -----
struct alignas(8) bh4 { __hip_bfloat16 a, b, c, d; };

__global__ __launch_bounds__(256) void rmsnorm_k(const float* __restrict__ in,
                                                 __hip_bfloat16* __restrict__ out) {
    const long row = blockIdx.x;
    const int tid = threadIdx.x;
    const float4 x = *(const float4*)(in + row * DDIM + tid * 4);
    float ss = x.x * x.x + x.y * x.y + x.z * x.z + x.w * x.w;
    ss += __shfl_xor(ss, 1);
    ss += __shfl_xor(ss, 2);
    ss += __shfl_xor(ss, 4);
    ss += __shfl_xor(ss, 8);
    ss += __shfl_xor(ss, 16);
    ss += __shfl_xor(ss, 32);
    __shared__ float wsum[4];
    if ((tid & 63) == 0) wsum[tid >> 6] = ss;
    __syncthreads();
    const float tot = wsum[0] + wsum[1] + wsum[2] + wsum[3];
    const float sc = rsqrtf(tot * (1.0f / (float)DDIM) + 1e-6f);
    bh4 y;
    y.a = __float2bfloat16(x.x * sc);
    y.b = __float2bfloat16(x.y * sc);
    y.c = __float2bfloat16(x.z * sc);
    y.d = __float2bfloat16(x.w * sc);
    *(bh4*)(out + row * DDIM + tid * 4) = y;
}

// ------------- transpose + f32->bf16: W[K,N] -> Wt[N,K] -------------
__global__ __launch_bounds__(256) void transpose_cvt(const float* __restrict__ W,
                                                     __hip_bfloat16* __restrict__ Wt,
                                                     int K, int N) {
    __shared__ float t[32][33];
    const int n0 = blockIdx.x * 32, k0 = blockIdx.y * 32;
    const int tx = threadIdx.x & 31, ty = threadIdx.x >> 5;  // ty 0..7
#pragma unroll
    for (int i = 0; i < 4; ++i)
        t[ty * 4 + i][tx] = W[(long)(k0 + ty * 4 + i) * N + n0 + tx];
    __syncthreads();
#pragma unroll
    for (int i = 0; i < 4; ++i)
        Wt[(long)(n0 + ty * 4 + i) * K + k0 + tx] = __float2bfloat16(t[tx][ty * 4 + i]);
}

// ---------------- bf16 MFMA GEMM (128x64, BK=64 two-panel) ------------------
// MODE 1: f32 out + f32 resid. MODE 2: bf16 out.
template <int MODE>
__global__ __launch_bounds__(256) void gemm_n64(const __hip_bfloat16* __restrict__ A,
                                                const __hip_bfloat16* __restrict__ Bt,
                                                const float* __restrict__ resid,
                                                void* __restrict__ Cout,
                                                int M, int N, int K) {
    __shared__ __align__(16) short As[2 * 128 * 32];   // 16 KB (8 KB/panel)
    __shared__ __align__(16) short Bs[2 * 64 * 32];    // 8 KB (4 KB/panel)
    const int tid = threadIdx.x;
    const int w = tid >> 6, l = tid & 63;
    const int m0 = blockIdx.y * 128, n0 = blockIdx.x * 64;
    const int srow = (w << 4) + (l >> 2);
    const int skcol = (l & 3) * 8;
    const int wr = w >> 1, wc = w & 1;
    const int fr = l & 15;
    const int fkB = (l >> 4) * 16;

    f32x4 acc[4][2];
#pragma unroll
    for (int m = 0; m < 4; ++m)
#pragma unroll
        for (int n = 0; n < 2; ++n) acc[m][n] = (f32x4)0.0f;

    const __hip_bfloat16* Abase = A + (long)m0 * K + skcol;
    const __hip_bfloat16* Bbase = Bt + (long)n0 * K + skcol;

    for (int k0 = 0; k0 < K; k0 += 64) {
#pragma unroll
        for (int p = 0; p < 2; ++p) {
#pragma unroll
            for (int j = 0; j < 2; ++j)
                load_lds16(Abase + (long)(srow + j * 64) * K + k0 + p * 32,
                           (char*)As + p * 8192 + w * 1024 + j * 4096);
            load_lds16(Bbase + (long)srow * K + k0 + p * 32,
                       (char*)Bs + p * 4096 + w * 1024);
        }
        __syncthreads();
#pragma unroll
        for (int p = 0; p < 2; ++p) {
            bf16x8 av[4], bv[2];
#pragma unroll
            for (int m = 0; m < 4; ++m)
                av[m] = *(const bf16x8*)((char*)As + p * 8192 + (wr * 64 + m * 16 + fr) * 64 + fkB);
#pragma unroll
            for (int n = 0; n < 2; ++n)
                bv[n] = *(const bf16x8*)((char*)Bs + p * 4096 + (wc * 32 + n * 16 + fr) * 64 + fkB);
#pragma unroll
            for (int m = 0; m < 4; ++m)
#pragma unroll
                for (int n = 0; n < 2; ++n)
                    acc[m][n] = __builtin_amdgcn_mfma_f32_16x16x32_bf16(av[m], bv[n], acc[m][n], 0, 0, 0);
        }
        __syncthreads();
    }

    const int r0 = (l >> 4) * 4;
    const int cc = l & 15;
#pragma unroll
    for (int m = 0; m < 4; ++m) {
#pragma unroll
        for (int r = 0; r < 4; ++r) {
            const long row = m0 + wr * 64 + m * 16 + r0 + r;
            const long colb = n0 + wc * 32 + cc;
            if (MODE == 2) {
                __hip_bfloat16* cb = (__hip_bfloat16*)Cout + row * N + colb;
#pragma unroll
                for (int n = 0; n < 2; ++n)
                    cb[n * 16] = __float2bfloat16(acc[m][n][r]);
            } else {
                float* cp = (float*)Cout + row * N + colb;
                const float* rp = resid + row * N + colb;
#pragma unroll
                for (int n = 0; n < 2; ++n)
                    cp[n * 16] = acc[m][n][r] + rp[n * 16];
            }
        }
    }
}

// ---- dual-B MFMA GEMM for SwiGLU (BK=64 two-panel) -------------------------
__global__ __launch_bounds__(256) void gemm_gateup_bf16(const __hip_bfloat16* __restrict__ A,
                                                        const __hip_bfloat16* __restrict__ Bg,
                                                        const __hip_bfloat16* __restrict__ Bu,
                                                        __hip_bfloat16* __restrict__ Hb,
                                                        int M, int N, int K) {
    __shared__ __align__(16) short As[2 * 128 * 32];   // 16 KB
    __shared__ __align__(16) short Bgs[2 * 64 * 32];   // 8 KB
    __shared__ __align__(16) short Bus[2 * 64 * 32];   // 8 KB
    const int tid = threadIdx.x;
    const int w = tid >> 6, l = tid & 63;
    const int m0 = blockIdx.y * 128, n0 = blockIdx.x * 64;
    const int srow = (w << 4) + (l >> 2);
    const int skcol = (l & 3) * 8;
    const int wr = w >> 1, wc = w & 1;
    const int fr = l & 15;
    const int fkB = (l >> 4) * 16;

    f32x4 accg[4][2], accu[4][2];
#pragma unroll
    for (int m = 0; m < 4; ++m)
#pragma unroll
        for (int n = 0; n < 2; ++n) { accg[m][n] = (f32x4)0.0f; accu[m][n] = (f32x4)0.0f; }

    const __hip_bfloat16* Abase = A + (long)m0 * K + skcol;
    const __hip_bfloat16* Bgb = Bg + (long)n0 * K + skcol;
    const __hip_bfloat16* Bub = Bu + (long)n0 * K + skcol;

    for (int k0 = 0; k0 < K; k0 += 64) {
#pragma unroll
        for (int p = 0; p < 2; ++p) {
#pragma unroll
            for (int j = 0; j < 2; ++j)
                load_lds16(Abase + (long)(srow + j * 64) * K + k0 + p * 32,
                           (char*)As + p * 8192 + w * 1024 + j * 4096);
            load_lds16(Bgb + (long)srow * K + k0 + p * 32, (char*)Bgs + p * 4096 + w * 1024);
            load_lds16(Bub + (long)srow * K + k0 + p * 32, (char*)Bus + p * 4096 + w * 1024);
        }
        __syncthreads();
#pragma unroll
        for (int p = 0; p < 2; ++p) {
            bf16x8 av[4], bgv[2], buv[2];
#pragma unroll
            for (int m = 0; m < 4; ++m)
                av[m] = *(const bf16x8*)((char*)As + p * 8192 + (wr * 64 + m * 16 + fr) * 64 + fkB);
#pragma unroll
            for (int n = 0; n < 2; ++n) {
                bgv[n] = *(const bf16x8*)((char*)Bgs + p * 4096 + (wc * 32 + n * 16 + fr) * 64 + fkB);
                buv[n] = *(const bf16x8*)((char*)Bus + p * 4096 + (wc * 32 + n * 16 + fr) * 64 + fkB);
            }
#pragma unroll
            for (int m = 0; m < 4; ++m)
#pragma unroll
                for (int n = 0; n < 2; ++n) {
                    accg[m][n] = __builtin_amdgcn_mfma_f32_16x16x32_bf16(av[m], bgv[n], accg[m][n], 0, 0, 0);
                    accu[m][n] = __builtin_amdgcn_mfma_f32_16x16x32_bf16(av[m], buv[n], accu[m][n], 0, 0, 0);
                }
        }
        __syncthreads();
    }

    const int r0 = (l >> 4) * 4;
    const int cc = l & 15;
#pragma unroll
    for (int m = 0; m < 4; ++m) {
#pragma unroll
        for (int r = 0; r < 4; ++r) {
            const long row = m0 + wr * 64 + m * 16 + r0 + r;
            __hip_bfloat16* hp = Hb + row * N + n0 + wc * 32 + cc;
#pragma unroll
            for (int n = 0; n < 2; ++n)
                hp[n * 16] = __float2bfloat16(silu_f(accg[m][n][r]) * accu[m][n][r]);
        }
    }
}

// ------- beta/alpha: inline rmsnorm; x staged through LDS (coalesced) -------
__global__ __launch_bounds__(64) void ba_kernel(const float* __restrict__ x,
                                                const float* __restrict__ wb,
                                                const float* __restrict__ wg,
                                                float* __restrict__ beta,
                                                float* __restrict__ alpha) {
    __shared__ float xs[DDIM];
    const long row = blockIdx.x;
    const int tid = threadIdx.x;
    float ss = 0.0f;
#pragma unroll
    for (int j = 0; j < 4; ++j) {
        const int fi = tid + j * 64;
        const float4 v = *(const float4*)(x + row * DDIM + fi * 4);
        *(float4*)&xs[fi * 4] = v;
        ss += v.x * v.x + v.y * v.y + v.z * v.z + v.w * v.w;
    }
    ss += __shfl_xor(ss, 1);
    ss += __shfl_xor(ss, 2);
    ss += __shfl_xor(ss, 4);
    ss += __shfl_xor(ss, 8);
    ss += __shfl_xor(ss, 16);
    ss += __shfl_xor(ss, 32);
    __syncthreads();
    const int o = tid >> 2;
    const int p = tid & 3;
    const float* wbase = (o < 8) ? (wb + o) : (wg + (o - 8));
    const float* wr = wbase + (long)(p * 256) * HHEADS;
    const float* xr = xs + p * 256;
    float acc = 0.0f;
#pragma unroll 8
    for (int i = 0; i < 256; ++i)
        acc = fmaf(xr[i], wr[(long)i * HHEADS], acc);
    acc += __shfl_xor(acc, 1);
    acc += __shfl_xor(acc, 2);
    if (p == 0) {
        const float sc = rsqrtf(ss * (1.0f / (float)DDIM) + 1e-6f);
        const float val = 1.0f / (1.0f + expf(-acc * sc));
        if (o < 8) beta[row * HHEADS + o] = val;
        else       alpha[row * HHEADS + (o - 8)] = val;
    }
}

// ------- post-projection (bf16 in-place): silu + l2norm on q,k; silu on v ----
__global__ __launch_bounds__(64) void postqkv(__hip_bfloat16* __restrict__ q,
                                              __hip_bfloat16* __restrict__ k,
                                              __hip_bfloat16* __restrict__ v) {
    const long r = blockIdx.x;
    const int tid = threadIdx.x;
    {
        unsigned int* qp = (unsigned int*)(q + r * DHEAD + tid * 2);
        const unsigned int wbits = *qp;
        float y0 = silu_f(bfbits2f(wbits & 0xffff));
        float y1 = silu_f(bfbits2f(wbits >> 16));
        float ss = y0 * y0 + y1 * y1;
        ss += __shfl_xor(ss, 1);  ss += __shfl_xor(ss, 2);
        ss += __shfl_xor(ss, 4);  ss += __shfl_xor(ss, 8);
        ss += __shfl_xor(ss, 16); ss += __shfl_xor(ss, 32);
        const float sc = rsqrtf(ss + 1e-6f);
        *qp = (unsigned int)bf16_bits(y0 * sc) | ((unsigned int)bf16_bits(y1 * sc) << 16);
    }
    {
        unsigned int* kp = (unsigned int*)(k + r * DHEAD + tid * 2);
        const unsigned int wbits = *kp;
        float y0 = silu_f(bfbits2f(wbits & 0xffff));
        float y1 = silu_f(bfbits2f(wbits >> 16));
        float ss = y0 * y0 + y1 * y1;
        ss += __shfl_xor(ss, 1);  ss += __shfl_xor(ss, 2);
        ss += __shfl_xor(ss, 4);  ss += __shfl_xor(ss, 8);
        ss += __shfl_xor(ss, 16); ss += __shfl_xor(ss, 32);
        const float sc = rsqrtf(ss + 1e-6f);
        *kp = (unsigned int)bf16_bits(y0 * sc) | ((unsigned int)bf16_bits(y1 * sc) << 16);
    }
    {
        unsigned int* vp = (unsigned int*)(v + r * DHEAD + tid * 2);
        const unsigned int wbits = *vp;
        *vp = (unsigned int)bf16_bits(silu_f(bfbits2f(wbits & 0xffff)))
            | ((unsigned int)bf16_bits(silu_f(bfbits2f(wbits >> 16))) << 16);
    }
}

// ============ Chunked gated delta rule (log-space decay) ============
// G_t = sum_{s<=t} log(a_s); ratio(t,s)=exp(G_t-G_s)<=1 for s<=t.
//   Tinv = (I+W)^-1 with W[t][s] = b_t ratio (k_t.k_s) (s<t)
//   dv = dv0 + R @ S0,   R = -Tinv @ diag(b_s e^{G_s}) @ K
//   dv0 = Tinv @ (b (.) v)
//   o_t = e^{G_t} (S0^T q_t) + (M @ dv)_t
//   S_end = e^{G63} S0 + K^T @ diag(e^{G63-G_t}) dv

// --------- Phase A (parallel over bh x chunk): G, M, Tinv, R, K^T, dv0 ------
// Tinv via IN-PLACE Neumann doubling (X=-W nilpotent):
//   T=I; 6x { T <- T + T@X ; X <- X@X } (2 barriers/round, single buffer).
// R and dv0 computed via MFMA against transposed B-operands built in LDS:
//   KtS[kk][s] = swB[s]*K[s][kk], bvT[j][s] = b_s*v[s][j].
// LDS carve (total 64512 B -> 2 blocks/CU):
//   tA  @0      [64][136] 17408  (K rows; whole kernel)
//   T   @17408  [64][72]   9216
//   Xr  @26624  [64][72]   9216  \ after doubling: bvT [128][72] 18432
//   Xt  @35840  [64][72]   9216  /   overlays @26624..45056
//   tB  @45056  [64][136] 17408  (Q rows; after M: KtS [128][72] 18432
//                                  overlays @45056..63488)
//   scalars @63488 (sa,sb,sG,swB) 1024
__global__ __launch_bounds__(256) void chunk_prep(
    const __hip_bfloat16* __restrict__ kb, const __hip_bfloat16* __restrict__ qb,
    const __hip_bfloat16* __restrict__ vb, const float* __restrict__ betab,
    const float* __restrict__ alphab, float* __restrict__ Gcum,
    __hip_bfloat16* __restrict__ Rg, __hip_bfloat16* __restrict__ Ktg,
    __hip_bfloat16* __restrict__ dvX, __hip_bfloat16* __restrict__ Mmat)
{
    const int bh = blockIdx.x >> 5;
    const int c  = blockIdx.x & 31;
    const int b = bh >> 3, h = bh & 7;
    const int tid = threadIdx.x;
    const int w = tid >> 6, l = tid & 63;
    const int fr = l & 15;           // fragment col / A-row low
    const int fk8 = (l >> 4) * 8;    // fragment k base (bf16 elems)
    const int fr4 = (l >> 4) * 4;    // C-fragment row base

    __shared__ __align__(16) char smem[64512];
    __hip_bfloat16* tA  = (__hip_bfloat16*)(smem);            // [64][136]
    __hip_bfloat16* Tm  = (__hip_bfloat16*)(smem + 17408);    // [64][72]
    __hip_bfloat16* Xr  = (__hip_bfloat16*)(smem + 26624);    // [64][72]
    __hip_bfloat16* Xt  = (__hip_bfloat16*)(smem + 35840);    // [64][72]
    __hip_bfloat16* bvT = (__hip_bfloat16*)(smem + 26624);    // [128][72] overlay
    __hip_bfloat16* tB  = (__hip_bfloat16*)(smem + 45056);    // [64][136]
    __hip_bfloat16* KtS = (__hip_bfloat16*)(smem + 45056);    // [128][72] overlay
    float* sa  = (float*)(smem + 63488);
    float* sb_ = sa + 64;
    float* sG  = sb_ + 64;
    float* swB = sG + 64;

    const long row0 = (long)b * TLEN + (long)c * CS;
    const long chnk = (long)bh * NC + c;

    if (tid < 64) {
        sa[tid]  = alphab[(row0 + tid) * HHEADS + h];
        sb_[tid] = betab[(row0 + tid) * HHEADS + h];
    }
    // load k,q chunks (bf16 direct copies)
    {
        const int r = tid >> 2;
        const int d0 = (tid & 3) * 32;
        const uint4* kp = (const uint4*)(kb + (row0 + r) * DDIM + h * DHEAD + d0);
        const uint4* qp = (const uint4*)(qb + (row0 + r) * DDIM + h * DHEAD + d0);
#pragma unroll
        for (int i = 0; i < 4; ++i) {
            *(uint4*)&tA[r * 136 + d0 + i * 8] = kp[i];
            *(uint4*)&tB[r * 136 + d0 + i * 8] = qp[i];
        }
    }
    __syncthreads();
    // lane-parallel log-prefix scan (wave 0)
    if (tid < 64) {
        float lv = logf(sa[tid]);
#pragma unroll
        for (int off = 1; off < 64; off <<= 1) {
            const float o = __shfl_up(lv, off, 64);
            if (tid >= off) lv += o;
        }
        sG[tid] = lv;
        Gcum[chnk * CS + tid] = lv;
        swB[tid] = sb_[tid] * expf(lv);
    }
    __syncthreads();

    // ---- MFMA: W_raw = K@K^T, M_raw = Q@K^T (wave w owns rows w*16..+15) ----
    f32x4 accW[4], accM[4];
#pragma unroll
    for (int n = 0; n < 4; ++n) { accW[n] = (f32x4)0.0f; accM[n] = (f32x4)0.0f; }
#pragma unroll
    for (int ks = 0; ks < 4; ++ks) {
        const bf16x8 aW = *(const bf16x8*)&tA[(w * 16 + fr) * 136 + ks * 32 + fk8];
        const bf16x8 aM = *(const bf16x8*)&tB[(w * 16 + fr) * 136 + ks * 32 + fk8];
#pragma unroll
        for (int n = 0; n < 4; ++n) {
            const bf16x8 bfr = *(const bf16x8*)&tA[(n * 16 + fr) * 136 + ks * 32 + fk8];
            accW[n] = __builtin_amdgcn_mfma_f32_16x16x32_bf16(aW, bfr, accW[n], 0, 0, 0);
            accM[n] = __builtin_amdgcn_mfma_f32_16x16x32_bf16(aM, bfr, accM[n], 0, 0, 0);
        }
    }
    // epilogue: M -> global; X0 = -W (row + transposed); T0 = I
#pragma unroll
    for (int n = 0; n < 4; ++n) {
        const int s = n * 16 + fr;
        const float Gs = sG[s];
#pragma unroll
        for (int r = 0; r < 4; ++r) {
            const int t = w * 16 + fr4 + r;
            const float ratio = (s <= t) ? expf(sG[t] - Gs) : 0.0f;
            Mmat[(chnk * CS + t) * CS + s] = __float2bfloat16(ratio * accM[n][r]);
            const float xv = (s < t) ? -(sb_[t] * ratio * accW[n][r]) : 0.0f;
            const __hip_bfloat16 xb = __float2bfloat16(xv);
            Xr[t * 72 + s] = xb;
            Xt[s * 72 + t] = xb;
            Tm[t * 72 + s] = __float2bfloat16((s == t) ? 1.0f : 0.0f);
        }
    }
    __syncthreads();   // tB (q) reads done; X/T visible

    // Ktg (unscaled K^T) -> global; KtS (swB-scaled K^T) -> LDS (overlays tB)
    {
        const int kk = tid >> 1;
        const int t0 = (tid & 1) * 32;
        __hip_bfloat16* kp = Ktg + (chnk * DHEAD + kk) * CS + t0;
        float f[8], fs[8];
#pragma unroll
        for (int i = 0; i < 4; ++i) {
#pragma unroll
            for (int j2 = 0; j2 < 8; ++j2) {
                const int t = t0 + i * 8 + j2;
                f[j2] = __bfloat162float(tA[t * 136 + kk]);
                fs[j2] = f[j2] * swB[t];
            }
            *(uint4*)(kp + i * 8) = pack8_bf16(f);
            *(uint4*)&KtS[kk * 72 + t0 + i * 8] = pack8_bf16(fs);
        }
    }
    __syncthreads();   // KtS visible; doubling may begin

    // ---- in-place Neumann doubling: 6 rounds {T += T@X; X = X@X} ----------
    for (int rnd = 0; rnd < 6; ++rnd) {
        f32x4 aT[4], aXr2[4], aXt2[4];
#pragma unroll
        for (int n = 0; n < 4; ++n) { aT[n] = (f32x4)0.0f; aXr2[n] = (f32x4)0.0f; aXt2[n] = (f32x4)0.0f; }
#pragma unroll
        for (int ks = 0; ks < 2; ++ks) {
            const bf16x8 fT  = *(const bf16x8*)&Tm[(w * 16 + fr) * 72 + ks * 32 + fk8];
            const bf16x8 fXr = *(const bf16x8*)&Xr[(w * 16 + fr) * 72 + ks * 32 + fk8];
            const bf16x8 fXt = *(const bf16x8*)&Xt[(w * 16 + fr) * 72 + ks * 32 + fk8];
#pragma unroll
            for (int n = 0; n < 4; ++n) {
                const bf16x8 bXt = *(const bf16x8*)&Xt[(n * 16 + fr) * 72 + ks * 32 + fk8];
                const bf16x8 bXr = *(const bf16x8*)&Xr[(n * 16 + fr) * 72 + ks * 32 + fk8];
                aT[n]   = __builtin_amdgcn_mfma_f32_16x16x32_bf16(fT,  bXt, aT[n], 0, 0, 0);
                aXr2[n] = __builtin_amdgcn_mfma_f32_16x16x32_bf16(fXr, bXt, aXr2[n], 0, 0, 0);
                aXt2[n] = __builtin_amdgcn_mfma_f32_16x16x32_bf16(fXt, bXr, aXt2[n], 0, 0, 0);
            }
        }
        float told[4][4];
#pragma unroll
        for (int n = 0; n < 4; ++n)
#pragma unroll
            for (int r = 0; r < 4; ++r)
                told[n][r] = __bfloat162float(Tm[(w * 16 + fr4 + r) * 72 + n * 16 + fr]);
        __syncthreads();   // all reads of T/Xr/Xt complete
#pragma unroll
        for (int n = 0; n < 4; ++n) {
            const int col = n * 16 + fr;
#pragma unroll
            for (int r = 0; r < 4; ++r) {
                const int t = w * 16 + fr4 + r;
                Tm[t * 72 + col] = __float2bfloat16(aT[n][r] + told[n][r]);
                if (rnd < 5) {
                    Xr[t * 72 + col] = __float2bfloat16(aXr2[n][r]);
                    Xt[t * 72 + col] = __float2bfloat16(aXt2[n][r]);
                }
            }
        }
        __syncthreads();   // writes visible
    }

    // ---- R = -(T @ KtS^T-form) via MFMA; scatter to global ----------------
    {
        f32x4 aR[8];
#pragma unroll
        for (int n = 0; n < 8; ++n) aR[n] = (f32x4)0.0f;
#pragma unroll
        for (int ks = 0; ks < 2; ++ks) {
            const bf16x8 aTf = *(const bf16x8*)&Tm[(w * 16 + fr) * 72 + ks * 32 + fk8];
#pragma unroll
            for (int n = 0; n < 8; ++n) {
                const bf16x8 bK = *(const bf16x8*)&KtS[(n * 16 + fr) * 72 + ks * 32 + fk8];
                aR[n] = __builtin_amdgcn_mfma_f32_16x16x32_bf16(aTf, bK, aR[n], 0, 0, 0);
            }
        }
#pragma unroll
        for (int n = 0; n < 8; ++n)
#pragma unroll
            for (int r = 0; r < 4; ++r) {
                const int t = w * 16 + fr4 + r;
                Rg[(chnk * CS + t) * DHEAD + n * 16 + fr] = __float2bfloat16(-aR[n][r]);
            }
    }

    // ---- bvT build (overlays Xr/Xt, dead after doubling) -------------------
    {
        const int r = tid >> 2, d0 = (tid & 3) * 32;
        const float br = sb_[r];
        const uint4* vp = (const uint4*)(vb + (row0 + r) * DDIM + h * DHEAD + d0);
#pragma unroll
        for (int i = 0; i < 4; ++i) {
            const uint4 vv = vp[i];
            const unsigned short* u = (const unsigned short*)&vv;
#pragma unroll
            for (int j2 = 0; j2 < 8; ++j2)
                bvT[(d0 + i * 8 + j2) * 72 + r] = __float2bfloat16(br * bfbits2f(u[j2]));
        }
    }
    __syncthreads();   // bvT visible

    // ---- dv0 = T @ bvT^T-form via MFMA; scatter to global ------------------
    {
        f32x4 aD[8];
#pragma unroll
        for (int n = 0; n < 8; ++n) aD[n] = (f32x4)0.0f;
#pragma unroll
        for (int ks = 0; ks < 2; ++ks) {
            const bf16x8 aTf = *(const bf16x8*)&Tm[(w * 16 + fr) * 72 + ks * 32 + fk8];
#pragma unroll
            for (int n = 0; n < 8; ++n) {
                const bf16x8 bV = *(const bf16x8*)&bvT[(n * 16 + fr) * 72 + ks * 32 + fk8];
                aD[n] = __builtin_amdgcn_mfma_f32_16x16x32_bf16(aTf, bV, aD[n], 0, 0, 0);
            }
        }
#pragma unroll
        for (int n = 0; n < 8; ++n)
#pragma unroll
            for (int r = 0; r < 4; ++r) {
                const int t = w * 16 + fr4 + r;
                dvX[(chnk * CS + t) * DHEAD + n * 16 + fr] = __float2bfloat16(aD[n][r]);
            }
    }
}

// --------- Phase B: sequential over chunks; MFMA; 128 blocks ----------------
#define SEQGV 8
#define SEQ_LDS_BYTES 78848

__global__ __launch_bounds__(256) void chunk_seq_mfma(
    const float* __restrict__ S0in, const float* __restrict__ Gcum,
    const __hip_bfloat16* __restrict__ Rg, const __hip_bfloat16* __restrict__ Ktg,
    __hip_bfloat16* __restrict__ dvX, __hip_bfloat16* __restrict__ Ssnap,
    float* __restrict__ Sout)
{
    const int bh = blockIdx.x & 15;
    const int g  = blockIdx.x >> 4;
    const int j0 = g * 16;
    const int tid = threadIdx.x;
    const int w = tid >> 6;
    const int l = tid & 63;
    const int fr = l & 15;
    const int fk8 = (l >> 4) * 8;
    const int rq = (l >> 4) * 4;

    __shared__ __align__(16) char smem[SEQ_LDS_BYTES];
    __hip_bfloat16* dvT = (__hip_bfloat16*)(smem + 71680);   // [16 j][72 t]
    __hip_bfloat16* Stl = (__hip_bfloat16*)(smem + 73984);   // [16 j][136 kk]
    float* sG = (float*)(smem + 78336);

    f32x4 SM[2];
#pragma unroll
    for (int mj = 0; mj < 2; ++mj) {
#pragma unroll
        for (int r = 0; r < 4; ++r) {
            const int kk = w * 32 + mj * 16 + rq + r;
            const float v = S0in[((long)bh * 128 + kk) * 128 + j0 + fr];
            SM[mj][r] = v;
            Stl[fr * 136 + kk] = __float2bfloat16(v);
        }
    }

    uint4 rreg[4], kreg[4];
    float greg = 0.0f;

#define SEQ_STAGE_LOAD(c_) do {                                                   \
        const long cb_ = (long)bh * NC + (c_);                                    \
        _Pragma("unroll")                                                         \
        for (int i_ = 0; i_ < 4; ++i_) {                                          \
            const int ur_ = (tid << 2) + i_;                                      \
            rreg[i_] = *(const uint4*)(Rg + (cb_ * CS + (ur_ >> 4)) * DHEAD + ((ur_ & 15) << 3)); \
            kreg[i_] = *(const uint4*)(Ktg + (cb_ * DHEAD + (ur_ >> 3)) * CS + ((ur_ & 7) << 3)); \
        }                                                                         \
        if (tid < 64) greg = Gcum[cb_ * CS + tid];                                \
    } while (0)

#define SEQ_STAGE_WRITE(bufi_) do {                                               \
        __hip_bfloat16* rb_ = (__hip_bfloat16*)(smem + (bufi_) * 17408);          \
        __hip_bfloat16* kb2_ = (__hip_bfloat16*)(smem + 34816 + (bufi_) * 18432); \
        _Pragma("unroll")                                                         \
        for (int i_ = 0; i_ < 4; ++i_) {                                          \
            const int ur_ = (tid << 2) + i_;                                      \
            *(uint4*)(rb_ + (ur_ >> 4) * 136 + ((ur_ & 15) << 3)) = rreg[i_];     \
            *(uint4*)(kb2_ + (ur_ >> 3) * 72 + ((ur_ & 7) << 3)) = kreg[i_];      \
        }                                                                         \
        if (tid < 64) sG[(bufi_) * 64 + tid] = greg;                              \
    } while (0)

    SEQ_STAGE_LOAD(0);
    SEQ_STAGE_WRITE(0);
    __syncthreads();

    for (int c = 0; c < NC; ++c) {
        const int cur = c & 1;
        const long chnk = (long)bh * NC + c;
        const __hip_bfloat16* Rl = (const __hip_bfloat16*)(smem + cur * 17408);
        const __hip_bfloat16* Ktl = (const __hip_bfloat16*)(smem + 34816 + cur * 18432);
        const float g63 = sG[cur * 64 + 63];
        const float a63 = expf(g63);

        unsigned short d0r[4];
#pragma unroll
        for (int r = 0; r < 4; ++r) {
            const int t = w * 16 + rq + r;
            d0r[r] = *(const unsigned short*)(dvX + (chnk * CS + t) * DHEAD + j0 + fr);
        }

        if (c + 1 < NC) SEQ_STAGE_LOAD(c + 1);

        {
            const int j = tid >> 4, k0 = (tid & 15) * 8;
            const uint4 v = *(const uint4*)&Stl[j * 136 + k0];
            *(uint4*)(Ssnap + (chnk * 128 + j0 + j) * 128 + k0) = v;
        }

        // step A: dv = dv0 + R @ S
        f32x4 acc = (f32x4)0.0f;
#pragma unroll
        for (int ks = 0; ks < 4; ++ks) {
            const bf16x8 bfrag = *(const bf16x8*)&Stl[fr * 136 + ks * 32 + fk8];
            const bf16x8 afrag = *(const bf16x8*)&Rl[(w * 16 + fr) * 136 + ks * 32 + fk8];
            acc = __builtin_amdgcn_mfma_f32_16x16x32_bf16(afrag, bfrag, acc, 0, 0, 0);
        }
#pragma unroll
        for (int r = 0; r < 4; ++r) {
            const int t = w * 16 + rq + r;
            const float rk = expf(g63 - sG[cur * 64 + t]);
            const float dv = acc[r] + bfbits2f(d0r[r]);
            *(unsigned short*)(dvX + (chnk * CS + t) * DHEAD + j0 + fr) = bf16_bits(dv);
            dvT[fr * 72 + t] = __float2bfloat16(rk * dv);
        }

        if (c + 1 < NC) SEQ_STAGE_WRITE(cur ^ 1);
        __syncthreads();

        // step B: S' = a63*S + K^T @ dvs
#pragma unroll
        for (int mj = 0; mj < 2; ++mj) SM[mj] *= a63;
#pragma unroll
        for (int ks = 0; ks < 2; ++ks) {
            const bf16x8 bfrag = *(const bf16x8*)&dvT[fr * 72 + ks * 32 + fk8];
#pragma unroll
            for (int mj = 0; mj < 2; ++mj) {
                const bf16x8 afrag = *(const bf16x8*)&Ktl[(w * 32 + mj * 16 + fr) * 72 + ks * 32 + fk8];
                SM[mj] = __builtin_amdgcn_mfma_f32_16x16x32_bf16(afrag, bfrag, SM[mj], 0, 0, 0);
            }
        }
#pragma unroll
        for (int mj = 0; mj < 2; ++mj)
#pragma unroll
            for (int r = 0; r < 4; ++r) {
                const int kk = w * 32 + mj * 16 + rq + r;
                Stl[fr * 136 + kk] = __float2bfloat16(SM[mj][r]);
            }
        __syncthreads();
    }

#pragma unroll
    for (int mj = 0; mj < 2; ++mj)
#pragma unroll
        for (int r = 0; r < 4; ++r) {
            const int kk = w * 32 + mj * 16 + rq + r;
            Sout[((long)bh * 128 + kk) * 128 + j0 + fr] = SM[mj][r];
        }
#undef SEQ_STAGE_LOAD
#undef SEQ_STAGE_WRITE
}

// --------- Phase C (parallel, MFMA): o = e^{G_t}*(q_t @ S0snap) + M @ dv ----
__global__ __launch_bounds__(256) void chunk_out(
    const __hip_bfloat16* __restrict__ qb, const float* __restrict__ Gcum,
    const __hip_bfloat16* __restrict__ dvX, const __hip_bfloat16* __restrict__ Ssnap,
    const __hip_bfloat16* __restrict__ Mmat, __hip_bfloat16* __restrict__ ob)
{
    const int bh = blockIdx.x >> 5;
    const int c  = blockIdx.x & 31;
    const int b = bh >> 3, h = bh & 7;
    const int tid = threadIdx.x;
    const int w = tid >> 6, l = tid & 63;
    const int fr = l & 15;
    const int fk8 = (l >> 4) * 8;
    const int rq = (l >> 4) * 4;
    const long row0 = (long)b * TLEN + (long)c * CS;
    const long chnk = (long)bh * NC + c;

    __shared__ __align__(16) char smem[62464];
    __hip_bfloat16* Ssn = (__hip_bfloat16*)(smem);
    __hip_bfloat16* Ml  = (__hip_bfloat16*)(smem + 34816);
    __hip_bfloat16* dq  = (__hip_bfloat16*)(smem + 44032);

    {
        const int j = tid >> 1;
        const int d0 = (tid & 1) * 64;
        const uint4* sp = (const uint4*)(Ssnap + (chnk * 128 + j) * 128 + d0);
#pragma unroll
        for (int i = 0; i < 8; ++i)
            *(uint4*)&Ssn[j * 136 + d0 + i * 8] = sp[i];
    }
    {
        const int t = tid >> 2;
        const int s0 = (tid & 3) * 16;
        const uint4* mp = (const uint4*)(Mmat + (chnk * CS + t) * CS + s0);
        *(uint4*)&Ml[t * 72 + s0]     = mp[0];
        *(uint4*)&Ml[t * 72 + s0 + 8] = mp[1];
    }
    {
        const int t = tid >> 2, jb = (tid & 3) * 32;
        uint4 dvr[4];
#pragma unroll
        for (int i = 0; i < 4; ++i)
            dvr[i] = ((const uint4*)(dvX + (chnk * CS + t) * DHEAD + jb))[i];
        const unsigned short* u = (const unsigned short*)&dvr[0];
#pragma unroll
        for (int i = 0; i < 32; ++i)
            dq[(jb + i) * 72 + t] = *(const __hip_bfloat16*)&u[i];
    }
    __syncthreads();

    f32x4 acc[8];
#pragma unroll
    for (int n = 0; n < 8; ++n) acc[n] = (f32x4)0.0f;

    // part 1: O += M @ dv   (K = 64)
#pragma unroll
    for (int ks = 0; ks < 2; ++ks) {
        const bf16x8 afrag = *(const bf16x8*)&Ml[(w * 16 + fr) * 72 + ks * 32 + fk8];
#pragma unroll
        for (int n = 0; n < 8; ++n) {
            const bf16x8 bfrag = *(const bf16x8*)&dq[(n * 16 + fr) * 72 + ks * 32 + fk8];
            acc[n] = __builtin_amdgcn_mfma_f32_16x16x32_bf16(afrag, bfrag, acc[n], 0, 0, 0);
        }
    }
    __syncthreads();

    {
        const int t = tid >> 2, d0 = (tid & 3) * 32;
        const float At = expf(Gcum[chnk * CS + t]);
        const uint4* qp = (const uint4*)(qb + (row0 + t) * DDIM + h * DHEAD + d0);
#pragma unroll
        for (int i = 0; i < 4; ++i) {
            const uint4 qv = qp[i];
            const unsigned short* u = (const unsigned short*)&qv;
            float f[8];
#pragma unroll
            for (int j = 0; j < 8; ++j) f[j] = At * bfbits2f(u[j]);
            *(uint4*)&dq[t * 136 + d0 + i * 8] = pack8_bf16(f);
        }
    }
    __syncthreads();

    // part 2: O += (At*q) @ S0   (K = 128)
#pragma unroll
    for (int ks = 0; ks < 4; ++ks) {
        const bf16x8 afrag = *(const bf16x8*)&dq[(w * 16 + fr) * 136 + ks * 32 + fk8];
#pragma unroll
        for (int n = 0; n < 8; ++n) {
            const bf16x8 bfrag = *(const bf16x8*)&Ssn[(n * 16 + fr) * 136 + ks * 32 + fk8];
            acc[n] = __builtin_amdgcn_mfma_f32_16x16x32_bf16(afrag, bfrag, acc[n], 0, 0, 0);
        }
    }

#pragma unroll
    for (int r = 0; r < 4; ++r) {
        const int t = w * 16 + rq + r;
        __hip_bfloat16* op = ob + (row0 + t) * DDIM + h * DHEAD + fr;
#pragma unroll
        for (int n = 0; n < 8; ++n)
            op[n * 16] = __float2bfloat16(acc[n][r]);
    }
}

extern "C" void kernel_launch(void* const* d_in, const int* in_sizes, int n_in,
                              void* d_out, int out_size, void* d_ws, size_t ws_size,
                              hipStream_t stream) {
    const float* x     = (const float*)d_in[0];
    const float* S0    = (const float*)d_in[1];
    const float* wq    = (const float*)d_in[2];
    const float* wk    = (const float*)d_in[3];
    const float* wv    = (const float*)d_in[4];
    const float* wb    = (const float*)d_in[5];
    const float* wg    = (const float*)d_in[6];
    const float* wo    = (const float*)d_in[7];
    const float* wgate = (const float*)d_in[8];
    const float* wup   = (const float*)d_in[9];
    const float* wdown = (const float*)d_in[10];

    const int M = BSZ * TLEN;  // 4096 token rows

    float* out  = (float*)d_out;
    float* Sout = out + (long)M * DDIM;

    // Workspace layout, peak 76.5 MiB (proven budget: 81 MiB).
    char* w = (char*)d_ws;
    const size_t MB = 1u << 20;
    const size_t KB = 1u << 10;
    __hip_bfloat16* qbh   = (__hip_bfloat16*)(w + 0 * MB);
    __hip_bfloat16* kbh   = (__hip_bfloat16*)(w + 8 * MB);
    __hip_bfloat16* vbh   = (__hip_bfloat16*)(w + 16 * MB);
    float*          beta  = (float*)(w + 24 * MB);
    float*          alpha = (float*)(w + 24 * MB + 128 * KB);
    float*          Gcum  = (float*)(w + 24 * MB + 256 * KB);
    __hip_bfloat16* Mmat  = (__hip_bfloat16*)(w + 24 * MB + 512 * KB); // prep->out (4MB)
    __hip_bfloat16* dvX   = (__hip_bfloat16*)(w + 28 * MB + 512 * KB); // prep->out (8MB)
    __hip_bfloat16* Rg    = (__hip_bfloat16*)(w + 36 * MB + 512 * KB); // prep->seq (8MB)
    __hip_bfloat16* xnb   = (__hip_bfloat16*)(w + 36 * MB + 512 * KB); // rms1->QKV (dead before Rg)
    __hip_bfloat16* Ktg   = (__hip_bfloat16*)(w + 44 * MB + 512 * KB); // prep->seq (8MB)
    __hip_bfloat16* Ssnap = (__hip_bfloat16*)(w + 52 * MB + 512 * KB); // seq->out (16MB)
    __hip_bfloat16* wqt   = (__hip_bfloat16*)(w + 68 * MB + 512 * KB);
    __hip_bfloat16* wkt   = (__hip_bfloat16*)(w + 70 * MB + 512 * KB);
    __hip_bfloat16* wvt   = (__hip_bfloat16*)(w + 72 * MB + 512 * KB);
    __hip_bfloat16* wot   = (__hip_bfloat16*)(w + 74 * MB + 512 * KB);
    __hip_bfloat16* obufb = (__hip_bfloat16*)(w + 8 * MB);
    __hip_bfloat16* xn2b  = (__hip_bfloat16*)(w + 8 * MB);
    __hip_bfloat16* wdt   = (__hip_bfloat16*)(w + 16 * MB);
    __hip_bfloat16* wgt   = (__hip_bfloat16*)(w + 24 * MB + 512 * KB);
    __hip_bfloat16* wut   = (__hip_bfloat16*)(w + 32 * MB + 512 * KB);
    __hip_bfloat16* Hb    = (__hip_bfloat16*)(w + 40 * MB + 512 * KB);

    // 0) weight transpose+convert (W[K,N] -> Wt[N,K] bf16)
    transpose_cvt<<<dim3(DDIM / 32, DDIM / 32), 256, 0, stream>>>(wq, wqt, DDIM, DDIM);
    transpose_cvt<<<dim3(DDIM / 32, DDIM / 32), 256, 0, stream>>>(wk, wkt, DDIM, DDIM);
    transpose_cvt<<<dim3(DDIM / 32, DDIM / 32), 256, 0, stream>>>(wv, wvt, DDIM, DDIM);
    transpose_cvt<<<dim3(DDIM / 32, DDIM / 32), 256, 0, stream>>>(wo, wot, DDIM, DDIM);

    // 1) norms / gates
    rmsnorm_k<<<M, 256, 0, stream>>>(x, xnb);
    ba_kernel<<<M, 64, 0, stream>>>(x, wb, wg, beta, alpha);

    // 2) q/k/v projections (bf16 out) — 128x64 tile BK=64
    dim3 gP64(DDIM / 64, M / 128);  // (16, 32)
    gemm_n64<2><<<gP64, 256, 0, stream>>>(xnb, wqt, nullptr, qbh, M, DDIM, DDIM);
    gemm_n64<2><<<gP64, 256, 0, stream>>>(xnb, wkt, nullptr, kbh, M, DDIM, DDIM);
    gemm_n64<2><<<gP64, 256, 0, stream>>>(xnb, wvt, nullptr, vbh, M, DDIM, DDIM);
    postqkv<<<M * HHEADS, 64, 0, stream>>>(qbh, kbh, vbh);

    // 3) chunked delta rule
    chunk_prep<<<16 * NC, 256, 0, stream>>>(kbh, qbh, vbh, beta, alpha, Gcum, Rg, Ktg, dvX, Mmat);
    chunk_seq_mfma<<<16 * SEQGV, 256, 0, stream>>>(S0, Gcum, Rg, Ktg, dvX, Ssnap, Sout);
    chunk_out<<<16 * NC, 256, 0, stream>>>(qbh, Gcum, dvX, Ssnap, Mmat, obufb);

    // 4) x1 = x + o @ wo — 128x64 tile BK=64
    gemm_n64<1><<<gP64, 256, 0, stream>>>(obufb, wot, x, out, M, DDIM, DDIM);

    // 4b) remaining weight transposes into now-dead regions
    transpose_cvt<<<dim3(DDIM / 32, FDIM / 32), 256, 0, stream>>>(wdown, wdt, FDIM, DDIM);
    transpose_cvt<<<dim3(FDIM / 32, DDIM / 32), 256, 0, stream>>>(wgate, wgt, DDIM, FDIM);
    transpose_cvt<<<dim3(FDIM / 32, DDIM / 32), 256, 0, stream>>>(wup, wut, DDIM, FDIM);

    // 5) xn2 = rms_norm(x1)
    rmsnorm_k<<<M, 256, 0, stream>>>(out, xn2b);

    // 6) H = silu(xn2 @ w_gate) * (xn2 @ w_up)  -- 128x64 tile BK=64
    dim3 gGU(FDIM / 64, M / 128);
    gemm_gateup_bf16<<<gGU, 256, 0, stream>>>(xn2b, wgt, wut, Hb, M, FDIM, DDIM);

    // 7) x_out = x1 + H @ w_down — 128x64 tile BK=64, K=4096
    gemm_n64<1><<<gP64, 256, 0, stream>>>(Hb, wdt, out, out, M, DDIM, FDIM);
}

// Round 14
// 364.993 us; speedup vs baseline: 2.5034x; 1.0413x over previous
//
#include <hip/hip_runtime.h>
#include <hip/hip_bf16.h>
#include <math.h>

// Sizes fixed by the problem: B=2, T=2048, D=1024, F=4096, H=8, DH=128.
#define BSZ 2
#define TLEN 2048
#define DDIM 1024
#define FDIM 4096
#define HHEADS 8
#define DHEAD 128
#define NC 32   // chunks per sequence
#define CS 64   // chunk size (CS*NC == TLEN)

typedef __bf16 bf16x8 __attribute__((ext_vector_type(8)));
typedef float f32x4 __attribute__((ext_vector_type(4)));

__device__ __forceinline__ float silu_f(float x) {
    return x / (1.0f + expf(-x));
}

__device__ __forceinline__ void load_lds16(const void* g, void* l) {
    __builtin_amdgcn_global_load_lds(
        (const __attribute__((address_space(1))) void*)g,
        (__attribute__((address_space(3))) void*)l, 16, 0, 0);
}

__device__ __forceinline__ unsigned short bf16_bits(float f) {
    __hip_bfloat16 h = __float2bfloat16(f);
    return *reinterpret_cast<unsigned short*>(&h);
}

__device__ __forceinline__ float bfbits2f(unsigned short u) {
    union { unsigned int i; float f; } c;
    c.i = ((unsigned int)u) << 16;
    return c.f;
}

__device__ __forceinline__ uint4 pack8_bf16(const float* f) {
    union { unsigned short u[8]; uint4 v; } r;
#pragma unroll
    for (int i = 0; i < 8; ++i) r.u[i] = bf16_bits(f[i]);
    return r.v;
}

// ---------------- RMSNorm: one block (256 thr) per row of 1024; bf16 out -----
struct alignas(8) bh4 { __hip_bfloat16 a, b, c, d; };

__global__ __launch_bounds__(256) void rmsnorm_k(const float* __restrict__ in,
                                                 __hip_bfloat16* __restrict__ out) {
    const long row = blockIdx.x;
    const int tid = threadIdx.x;
    const float4 x = *(const float4*)(in + row * DDIM + tid * 4);
    float ss = x.x * x.x + x.y * x.y + x.z * x.z + x.w * x.w;
    ss += __shfl_xor(ss, 1);
    ss += __shfl_xor(ss, 2);
    ss += __shfl_xor(ss, 4);
    ss += __shfl_xor(ss, 8);
    ss += __shfl_xor(ss, 16);
    ss += __shfl_xor(ss, 32);
    __shared__ float wsum[4];
    if ((tid & 63) == 0) wsum[tid >> 6] = ss;
    __syncthreads();
    const float tot = wsum[0] + wsum[1] + wsum[2] + wsum[3];
    const float sc = rsqrtf(tot * (1.0f / (float)DDIM) + 1e-6f);
    bh4 y;
    y.a = __float2bfloat16(x.x * sc);
    y.b = __float2bfloat16(x.y * sc);
    y.c = __float2bfloat16(x.z * sc);
    y.d = __float2bfloat16(x.w * sc);
    *(bh4*)(out + row * DDIM + tid * 4) = y;
}

// ------------- transpose + f32->bf16: W[K,N] -> Wt[N,K] -------------
__global__ __launch_bounds__(256) void transpose_cvt(const float* __restrict__ W,
                                                     __hip_bfloat16* __restrict__ Wt,
                                                     int K, int N) {
    __shared__ float t[32][33];
    const int n0 = blockIdx.x * 32, k0 = blockIdx.y * 32;
    const int tx = threadIdx.x & 31, ty = threadIdx.x >> 5;  // ty 0..7
#pragma unroll
    for (int i = 0; i < 4; ++i)
        t[ty * 4 + i][tx] = W[(long)(k0 + ty * 4 + i) * N + n0 + tx];
    __syncthreads();
#pragma unroll
    for (int i = 0; i < 4; ++i)
        Wt[(long)(n0 + ty * 4 + i) * K + k0 + tx] = __float2bfloat16(t[tx][ty * 4 + i]);
}

// ---------------- bf16 MFMA GEMM (128x64, BK=128 four-panel) ----------------
// Four 32-col K-panels with 64B rows (proven bank-free layout); halves barrier
// count vs BK=64. 4 waves (2x2), 4x2 frags, 32 AGPR acc, 48 KB LDS
// (3 blocks/CU by LDS; registers bind first so occupancy unchanged).
// MODE 1: f32 out + f32 resid. MODE 2: bf16 out.
template <int MODE>
__global__ __launch_bounds__(256) void gemm_n64(const __hip_bfloat16* __restrict__ A,
                                                const __hip_bfloat16* __restrict__ Bt,
                                                const float* __restrict__ resid,
                                                void* __restrict__ Cout,
                                                int M, int N, int K) {
    __shared__ __align__(16) short As[4 * 128 * 32];   // 32 KB (8 KB/panel)
    __shared__ __align__(16) short Bs[4 * 64 * 32];    // 16 KB (4 KB/panel)
    const int tid = threadIdx.x;
    const int w = tid >> 6, l = tid & 63;
    const int m0 = blockIdx.y * 128, n0 = blockIdx.x * 64;
    const int srow = (w << 4) + (l >> 2);
    const int skcol = (l & 3) * 8;
    const int wr = w >> 1, wc = w & 1;
    const int fr = l & 15;
    const int fkB = (l >> 4) * 16;

    f32x4 acc[4][2];
#pragma unroll
    for (int m = 0; m < 4; ++m)
#pragma unroll
        for (int n = 0; n < 2; ++n) acc[m][n] = (f32x4)0.0f;

    const __hip_bfloat16* Abase = A + (long)m0 * K + skcol;
    const __hip_bfloat16* Bbase = Bt + (long)n0 * K + skcol;

    for (int k0 = 0; k0 < K; k0 += 128) {
#pragma unroll
        for (int p = 0; p < 4; ++p) {
#pragma unroll
            for (int j = 0; j < 2; ++j)
                load_lds16(Abase + (long)(srow + j * 64) * K + k0 + p * 32,
                           (char*)As + p * 8192 + w * 1024 + j * 4096);
            load_lds16(Bbase + (long)srow * K + k0 + p * 32,
                       (char*)Bs + p * 4096 + w * 1024);
        }
        __syncthreads();
#pragma unroll
        for (int p = 0; p < 4; ++p) {
            bf16x8 av[4], bv[2];
#pragma unroll
            for (int m = 0; m < 4; ++m)
                av[m] = *(const bf16x8*)((char*)As + p * 8192 + (wr * 64 + m * 16 + fr) * 64 + fkB);
#pragma unroll
            for (int n = 0; n < 2; ++n)
                bv[n] = *(const bf16x8*)((char*)Bs + p * 4096 + (wc * 32 + n * 16 + fr) * 64 + fkB);
#pragma unroll
            for (int m = 0; m < 4; ++m)
#pragma unroll
                for (int n = 0; n < 2; ++n)
                    acc[m][n] = __builtin_amdgcn_mfma_f32_16x16x32_bf16(av[m], bv[n], acc[m][n], 0, 0, 0);
        }
        __syncthreads();
    }

    const int r0 = (l >> 4) * 4;
    const int cc = l & 15;
#pragma unroll
    for (int m = 0; m < 4; ++m) {
#pragma unroll
        for (int r = 0; r < 4; ++r) {
            const long row = m0 + wr * 64 + m * 16 + r0 + r;
            const long colb = n0 + wc * 32 + cc;
            if (MODE == 2) {
                __hip_bfloat16* cb = (__hip_bfloat16*)Cout + row * N + colb;
#pragma unroll
                for (int n = 0; n < 2; ++n)
                    cb[n * 16] = __float2bfloat16(acc[m][n][r]);
            } else {
                float* cp = (float*)Cout + row * N + colb;
                const float* rp = resid + row * N + colb;
#pragma unroll
                for (int n = 0; n < 2; ++n)
                    cp[n * 16] = acc[m][n][r] + rp[n * 16];
            }
        }
    }
}

// ---- dual-B MFMA GEMM for SwiGLU (BK=64 two-panel) -------------------------
__global__ __launch_bounds__(256) void gemm_gateup_bf16(const __hip_bfloat16* __restrict__ A,
                                                        const __hip_bfloat16* __restrict__ Bg,
                                                        const __hip_bfloat16* __restrict__ Bu,
                                                        __hip_bfloat16* __restrict__ Hb,
                                                        int M, int N, int K) {
    __shared__ __align__(16) short As[2 * 128 * 32];   // 16 KB
    __shared__ __align__(16) short Bgs[2 * 64 * 32];   // 8 KB
    __shared__ __align__(16) short Bus[2 * 64 * 32];   // 8 KB
    const int tid = threadIdx.x;
    const int w = tid >> 6, l = tid & 63;
    const int m0 = blockIdx.y * 128, n0 = blockIdx.x * 64;
    const int srow = (w << 4) + (l >> 2);
    const int skcol = (l & 3) * 8;
    const int wr = w >> 1, wc = w & 1;
    const int fr = l & 15;
    const int fkB = (l >> 4) * 16;

    f32x4 accg[4][2], accu[4][2];
#pragma unroll
    for (int m = 0; m < 4; ++m)
#pragma unroll
        for (int n = 0; n < 2; ++n) { accg[m][n] = (f32x4)0.0f; accu[m][n] = (f32x4)0.0f; }

    const __hip_bfloat16* Abase = A + (long)m0 * K + skcol;
    const __hip_bfloat16* Bgb = Bg + (long)n0 * K + skcol;
    const __hip_bfloat16* Bub = Bu + (long)n0 * K + skcol;

    for (int k0 = 0; k0 < K; k0 += 64) {
#pragma unroll
        for (int p = 0; p < 2; ++p) {
#pragma unroll
            for (int j = 0; j < 2; ++j)
                load_lds16(Abase + (long)(srow + j * 64) * K + k0 + p * 32,
                           (char*)As + p * 8192 + w * 1024 + j * 4096);
            load_lds16(Bgb + (long)srow * K + k0 + p * 32, (char*)Bgs + p * 4096 + w * 1024);
            load_lds16(Bub + (long)srow * K + k0 + p * 32, (char*)Bus + p * 4096 + w * 1024);
        }
        __syncthreads();
#pragma unroll
        for (int p = 0; p < 2; ++p) {
            bf16x8 av[4], bgv[2], buv[2];
#pragma unroll
            for (int m = 0; m < 4; ++m)
                av[m] = *(const bf16x8*)((char*)As + p * 8192 + (wr * 64 + m * 16 + fr) * 64 + fkB);
#pragma unroll
            for (int n = 0; n < 2; ++n) {
                bgv[n] = *(const bf16x8*)((char*)Bgs + p * 4096 + (wc * 32 + n * 16 + fr) * 64 + fkB);
                buv[n] = *(const bf16x8*)((char*)Bus + p * 4096 + (wc * 32 + n * 16 + fr) * 64 + fkB);
            }
#pragma unroll
            for (int m = 0; m < 4; ++m)
#pragma unroll
                for (int n = 0; n < 2; ++n) {
                    accg[m][n] = __builtin_amdgcn_mfma_f32_16x16x32_bf16(av[m], bgv[n], accg[m][n], 0, 0, 0);
                    accu[m][n] = __builtin_amdgcn_mfma_f32_16x16x32_bf16(av[m], buv[n], accu[m][n], 0, 0, 0);
                }
        }
        __syncthreads();
    }

    const int r0 = (l >> 4) * 4;
    const int cc = l & 15;
#pragma unroll
    for (int m = 0; m < 4; ++m) {
#pragma unroll
        for (int r = 0; r < 4; ++r) {
            const long row = m0 + wr * 64 + m * 16 + r0 + r;
            __hip_bfloat16* hp = Hb + row * N + n0 + wc * 32 + cc;
#pragma unroll
            for (int n = 0; n < 2; ++n)
                hp[n * 16] = __float2bfloat16(silu_f(accg[m][n][r]) * accu[m][n][r]);
        }
    }
}

// ------- beta/alpha: inline rmsnorm; x staged through LDS (coalesced) -------
__global__ __launch_bounds__(64) void ba_kernel(const float* __restrict__ x,
                                                const float* __restrict__ wb,
                                                const float* __restrict__ wg,
                                                float* __restrict__ beta,
                                                float* __restrict__ alpha) {
    __shared__ float xs[DDIM];
    const long row = blockIdx.x;
    const int tid = threadIdx.x;
    float ss = 0.0f;
#pragma unroll
    for (int j = 0; j < 4; ++j) {
        const int fi = tid + j * 64;
        const float4 v = *(const float4*)(x + row * DDIM + fi * 4);
        *(float4*)&xs[fi * 4] = v;
        ss += v.x * v.x + v.y * v.y + v.z * v.z + v.w * v.w;
    }
    ss += __shfl_xor(ss, 1);
    ss += __shfl_xor(ss, 2);
    ss += __shfl_xor(ss, 4);
    ss += __shfl_xor(ss, 8);
    ss += __shfl_xor(ss, 16);
    ss += __shfl_xor(ss, 32);
    __syncthreads();
    const int o = tid >> 2;
    const int p = tid & 3;
    const float* wbase = (o < 8) ? (wb + o) : (wg + (o - 8));
    const float* wr = wbase + (long)(p * 256) * HHEADS;
    const float* xr = xs + p * 256;
    float acc = 0.0f;
#pragma unroll 8
    for (int i = 0; i < 256; ++i)
        acc = fmaf(xr[i], wr[(long)i * HHEADS], acc);
    acc += __shfl_xor(acc, 1);
    acc += __shfl_xor(acc, 2);
    if (p == 0) {
        const float sc = rsqrtf(ss * (1.0f / (float)DDIM) + 1e-6f);
        const float val = 1.0f / (1.0f + expf(-acc * sc));
        if (o < 8) beta[row * HHEADS + o] = val;
        else       alpha[row * HHEADS + (o - 8)] = val;
    }
}

// ------- post-projection (bf16 in-place): silu + l2norm on q,k; silu on v ----
__global__ __launch_bounds__(64) void postqkv(__hip_bfloat16* __restrict__ q,
                                              __hip_bfloat16* __restrict__ k,
                                              __hip_bfloat16* __restrict__ v) {
    const long r = blockIdx.x;
    const int tid = threadIdx.x;
    {
        unsigned int* qp = (unsigned int*)(q + r * DHEAD + tid * 2);
        const unsigned int wbits = *qp;
        float y0 = silu_f(bfbits2f(wbits & 0xffff));
        float y1 = silu_f(bfbits2f(wbits >> 16));
        float ss = y0 * y0 + y1 * y1;
        ss += __shfl_xor(ss, 1);  ss += __shfl_xor(ss, 2);
        ss += __shfl_xor(ss, 4);  ss += __shfl_xor(ss, 8);
        ss += __shfl_xor(ss, 16); ss += __shfl_xor(ss, 32);
        const float sc = rsqrtf(ss + 1e-6f);
        *qp = (unsigned int)bf16_bits(y0 * sc) | ((unsigned int)bf16_bits(y1 * sc) << 16);
    }
    {
        unsigned int* kp = (unsigned int*)(k + r * DHEAD + tid * 2);
        const unsigned int wbits = *kp;
        float y0 = silu_f(bfbits2f(wbits & 0xffff));
        float y1 = silu_f(bfbits2f(wbits >> 16));
        float ss = y0 * y0 + y1 * y1;
        ss += __shfl_xor(ss, 1);  ss += __shfl_xor(ss, 2);
        ss += __shfl_xor(ss, 4);  ss += __shfl_xor(ss, 8);
        ss += __shfl_xor(ss, 16); ss += __shfl_xor(ss, 32);
        const float sc = rsqrtf(ss + 1e-6f);
        *kp = (unsigned int)bf16_bits(y0 * sc) | ((unsigned int)bf16_bits(y1 * sc) << 16);
    }
    {
        unsigned int* vp = (unsigned int*)(v + r * DHEAD + tid * 2);
        const unsigned int wbits = *vp;
        *vp = (unsigned int)bf16_bits(silu_f(bfbits2f(wbits & 0xffff)))
            | ((unsigned int)bf16_bits(silu_f(bfbits2f(wbits >> 16))) << 16);
    }
}

// ============ Chunked gated delta rule (log-space decay) ============
// G_t = sum_{s<=t} log(a_s); ratio(t,s)=exp(G_t-G_s)<=1 for s<=t.
//   Tinv = (I+W)^-1 with W[t][s] = b_t ratio (k_t.k_s) (s<t)
//   dv = dv0 + R @ S0,   R = -Tinv @ diag(b_s e^{G_s}) @ K
//   dv0 = Tinv @ (b (.) v)
//   o_t = e^{G_t} (S0^T q_t) + (M @ dv)_t
//   S_end = e^{G63} S0 + K^T @ diag(e^{G63-G_t}) dv

// --------- Phase A (parallel over bh x chunk): G, M, Tinv, R, K^T, dv0 ------
// Tinv via IN-PLACE Neumann doubling (X=-W nilpotent):
//   T=I; 6x { T <- T + T@X ; X <- X@X } (2 barriers/round, single buffer).
__global__ __launch_bounds__(256) void chunk_prep(
    const __hip_bfloat16* __restrict__ kb, const __hip_bfloat16* __restrict__ qb,
    const __hip_bfloat16* __restrict__ vb, const float* __restrict__ betab,
    const float* __restrict__ alphab, float* __restrict__ Gcum,
    __hip_bfloat16* __restrict__ Rg, __hip_bfloat16* __restrict__ Ktg,
    __hip_bfloat16* __restrict__ dvX, __hip_bfloat16* __restrict__ Mmat)
{
    const int bh = blockIdx.x >> 5;
    const int c  = blockIdx.x & 31;
    const int b = bh >> 3, h = bh & 7;
    const int tid = threadIdx.x;
    const int w = tid >> 6, l = tid & 63;
    const int fr = l & 15;           // fragment col / A-row low
    const int fk8 = (l >> 4) * 8;    // fragment k base (bf16 elems)
    const int fr4 = (l >> 4) * 4;    // C-fragment row base

    __shared__ __align__(16) char smem[64512];
    __hip_bfloat16* tA  = (__hip_bfloat16*)(smem);            // [64][136]
    __hip_bfloat16* Tm  = (__hip_bfloat16*)(smem + 17408);    // [64][72]
    __hip_bfloat16* Xr  = (__hip_bfloat16*)(smem + 26624);    // [64][72]
    __hip_bfloat16* Xt  = (__hip_bfloat16*)(smem + 35840);    // [64][72]
    __hip_bfloat16* bvT = (__hip_bfloat16*)(smem + 26624);    // [128][72] overlay
    __hip_bfloat16* tB  = (__hip_bfloat16*)(smem + 45056);    // [64][136]
    __hip_bfloat16* KtS = (__hip_bfloat16*)(smem + 45056);    // [128][72] overlay
    float* sa  = (float*)(smem + 63488);
    float* sb_ = sa + 64;
    float* sG  = sb_ + 64;
    float* swB = sG + 64;

    const long row0 = (long)b * TLEN + (long)c * CS;
    const long chnk = (long)bh * NC + c;

    if (tid < 64) {
        sa[tid]  = alphab[(row0 + tid) * HHEADS + h];
        sb_[tid] = betab[(row0 + tid) * HHEADS + h];
    }
    // load k,q chunks (bf16 direct copies)
    {
        const int r = tid >> 2;
        const int d0 = (tid & 3) * 32;
        const uint4* kp = (const uint4*)(kb + (row0 + r) * DDIM + h * DHEAD + d0);
        const uint4* qp = (const uint4*)(qb + (row0 + r) * DDIM + h * DHEAD + d0);
#pragma unroll
        for (int i = 0; i < 4; ++i) {
            *(uint4*)&tA[r * 136 + d0 + i * 8] = kp[i];
            *(uint4*)&tB[r * 136 + d0 + i * 8] = qp[i];
        }
    }
    __syncthreads();
    // lane-parallel log-prefix scan (wave 0)
    if (tid < 64) {
        float lv = logf(sa[tid]);
#pragma unroll
        for (int off = 1; off < 64; off <<= 1) {
            const float o = __shfl_up(lv, off, 64);
            if (tid >= off) lv += o;
        }
        sG[tid] = lv;
        Gcum[chnk * CS + tid] = lv;
        swB[tid] = sb_[tid] * expf(lv);
    }
    __syncthreads();

    // ---- MFMA: W_raw = K@K^T, M_raw = Q@K^T (wave w owns rows w*16..+15) ----
    f32x4 accW[4], accM[4];
#pragma unroll
    for (int n = 0; n < 4; ++n) { accW[n] = (f32x4)0.0f; accM[n] = (f32x4)0.0f; }
#pragma unroll
    for (int ks = 0; ks < 4; ++ks) {
        const bf16x8 aW = *(const bf16x8*)&tA[(w * 16 + fr) * 136 + ks * 32 + fk8];
        const bf16x8 aM = *(const bf16x8*)&tB[(w * 16 + fr) * 136 + ks * 32 + fk8];
#pragma unroll
        for (int n = 0; n < 4; ++n) {
            const bf16x8 bfr = *(const bf16x8*)&tA[(n * 16 + fr) * 136 + ks * 32 + fk8];
            accW[n] = __builtin_amdgcn_mfma_f32_16x16x32_bf16(aW, bfr, accW[n], 0, 0, 0);
            accM[n] = __builtin_amdgcn_mfma_f32_16x16x32_bf16(aM, bfr, accM[n], 0, 0, 0);
        }
    }
    // epilogue: M -> global; X0 = -W (row + transposed); T0 = I
#pragma unroll
    for (int n = 0; n < 4; ++n) {
        const int s = n * 16 + fr;
        const float Gs = sG[s];
#pragma unroll
        for (int r = 0; r < 4; ++r) {
            const int t = w * 16 + fr4 + r;
            const float ratio = (s <= t) ? expf(sG[t] - Gs) : 0.0f;
            Mmat[(chnk * CS + t) * CS + s] = __float2bfloat16(ratio * accM[n][r]);
            const float xv = (s < t) ? -(sb_[t] * ratio * accW[n][r]) : 0.0f;
            const __hip_bfloat16 xb = __float2bfloat16(xv);
            Xr[t * 72 + s] = xb;
            Xt[s * 72 + t] = xb;
            Tm[t * 72 + s] = __float2bfloat16((s == t) ? 1.0f : 0.0f);
        }
    }
    __syncthreads();   // tB (q) reads done; X/T visible

    // Ktg (unscaled K^T) -> global; KtS (swB-scaled K^T) -> LDS (overlays tB)
    {
        const int kk = tid >> 1;
        const int t0 = (tid & 1) * 32;
        __hip_bfloat16* kp = Ktg + (chnk * DHEAD + kk) * CS + t0;
        float f[8], fs[8];
#pragma unroll
        for (int i = 0; i < 4; ++i) {
#pragma unroll
            for (int j2 = 0; j2 < 8; ++j2) {
                const int t = t0 + i * 8 + j2;
                f[j2] = __bfloat162float(tA[t * 136 + kk]);
                fs[j2] = f[j2] * swB[t];
            }
            *(uint4*)(kp + i * 8) = pack8_bf16(f);
            *(uint4*)&KtS[kk * 72 + t0 + i * 8] = pack8_bf16(fs);
        }
    }
    __syncthreads();   // KtS visible; doubling may begin

    // ---- in-place Neumann doubling: 6 rounds {T += T@X; X = X@X} ----------
    for (int rnd = 0; rnd < 6; ++rnd) {
        f32x4 aT[4], aXr2[4], aXt2[4];
#pragma unroll
        for (int n = 0; n < 4; ++n) { aT[n] = (f32x4)0.0f; aXr2[n] = (f32x4)0.0f; aXt2[n] = (f32x4)0.0f; }
#pragma unroll
        for (int ks = 0; ks < 2; ++ks) {
            const bf16x8 fT  = *(const bf16x8*)&Tm[(w * 16 + fr) * 72 + ks * 32 + fk8];
            const bf16x8 fXr = *(const bf16x8*)&Xr[(w * 16 + fr) * 72 + ks * 32 + fk8];
            const bf16x8 fXt = *(const bf16x8*)&Xt[(w * 16 + fr) * 72 + ks * 32 + fk8];
#pragma unroll
            for (int n = 0; n < 4; ++n) {
                const bf16x8 bXt = *(const bf16x8*)&Xt[(n * 16 + fr) * 72 + ks * 32 + fk8];
                const bf16x8 bXr = *(const bf16x8*)&Xr[(n * 16 + fr) * 72 + ks * 32 + fk8];
                aT[n]   = __builtin_amdgcn_mfma_f32_16x16x32_bf16(fT,  bXt, aT[n], 0, 0, 0);
                aXr2[n] = __builtin_amdgcn_mfma_f32_16x16x32_bf16(fXr, bXt, aXr2[n], 0, 0, 0);
                aXt2[n] = __builtin_amdgcn_mfma_f32_16x16x32_bf16(fXt, bXr, aXt2[n], 0, 0, 0);
            }
        }
        float told[4][4];
#pragma unroll
        for (int n = 0; n < 4; ++n)
#pragma unroll
            for (int r = 0; r < 4; ++r)
                told[n][r] = __bfloat162float(Tm[(w * 16 + fr4 + r) * 72 + n * 16 + fr]);
        __syncthreads();   // all reads of T/Xr/Xt complete
#pragma unroll
        for (int n = 0; n < 4; ++n) {
            const int col = n * 16 + fr;
#pragma unroll
            for (int r = 0; r < 4; ++r) {
                const int t = w * 16 + fr4 + r;
                Tm[t * 72 + col] = __float2bfloat16(aT[n][r] + told[n][r]);
                if (rnd < 5) {
                    Xr[t * 72 + col] = __float2bfloat16(aXr2[n][r]);
                    Xt[t * 72 + col] = __float2bfloat16(aXt2[n][r]);
                }
            }
        }
        __syncthreads();   // writes visible
    }

    // ---- R = -(T @ KtS^T-form) via MFMA; scatter to global ----------------
    {
        f32x4 aR[8];
#pragma unroll
        for (int n = 0; n < 8; ++n) aR[n] = (f32x4)0.0f;
#pragma unroll
        for (int ks = 0; ks < 2; ++ks) {
            const bf16x8 aTf = *(const bf16x8*)&Tm[(w * 16 + fr) * 72 + ks * 32 + fk8];
#pragma unroll
            for (int n = 0; n < 8; ++n) {
                const bf16x8 bK = *(const bf16x8*)&KtS[(n * 16 + fr) * 72 + ks * 32 + fk8];
                aR[n] = __builtin_amdgcn_mfma_f32_16x16x32_bf16(aTf, bK, aR[n], 0, 0, 0);
            }
        }
#pragma unroll
        for (int n = 0; n < 8; ++n)
#pragma unroll
            for (int r = 0; r < 4; ++r) {
                const int t = w * 16 + fr4 + r;
                Rg[(chnk * CS + t) * DHEAD + n * 16 + fr] = __float2bfloat16(-aR[n][r]);
            }
    }

    // ---- bvT build (overlays Xr/Xt, dead after doubling) -------------------
    {
        const int r = tid >> 2, d0 = (tid & 3) * 32;
        const float br = sb_[r];
        const uint4* vp = (const uint4*)(vb + (row0 + r) * DDIM + h * DHEAD + d0);
#pragma unroll
        for (int i = 0; i < 4; ++i) {
            const uint4 vv = vp[i];
            const unsigned short* u = (const unsigned short*)&vv;
#pragma unroll
            for (int j2 = 0; j2 < 8; ++j2)
                bvT[(d0 + i * 8 + j2) * 72 + r] = __float2bfloat16(br * bfbits2f(u[j2]));
        }
    }
    __syncthreads();   // bvT visible

    // ---- dv0 = T @ bvT^T-form via MFMA; scatter to global ------------------
    {
        f32x4 aD[8];
#pragma unroll
        for (int n = 0; n < 8; ++n) aD[n] = (f32x4)0.0f;
#pragma unroll
        for (int ks = 0; ks < 2; ++ks) {
            const bf16x8 aTf = *(const bf16x8*)&Tm[(w * 16 + fr) * 72 + ks * 32 + fk8];
#pragma unroll
            for (int n = 0; n < 8; ++n) {
                const bf16x8 bV = *(const bf16x8*)&bvT[(n * 16 + fr) * 72 + ks * 32 + fk8];
                aD[n] = __builtin_amdgcn_mfma_f32_16x16x32_bf16(aTf, bV, aD[n], 0, 0, 0);
            }
        }
#pragma unroll
        for (int n = 0; n < 8; ++n)
#pragma unroll
            for (int r = 0; r < 4; ++r) {
                const int t = w * 16 + fr4 + r;
                dvX[(chnk * CS + t) * DHEAD + n * 16 + fr] = __float2bfloat16(aD[n][r]);
            }
    }
}

// --------- Phase B: sequential over chunks; MFMA; 128 blocks ----------------
#define SEQGV 8
#define SEQ_LDS_BYTES 78848

__global__ __launch_bounds__(256) void chunk_seq_mfma(
    const float* __restrict__ S0in, const float* __restrict__ Gcum,
    const __hip_bfloat16* __restrict__ Rg, const __hip_bfloat16* __restrict__ Ktg,
    __hip_bfloat16* __restrict__ dvX, __hip_bfloat16* __restrict__ Ssnap,
    float* __restrict__ Sout)
{
    const int bh = blockIdx.x & 15;
    const int g  = blockIdx.x >> 4;
    const int j0 = g * 16;
    const int tid = threadIdx.x;
    const int w = tid >> 6;
    const int l = tid & 63;
    const int fr = l & 15;
    const int fk8 = (l >> 4) * 8;
    const int rq = (l >> 4) * 4;

    __shared__ __align__(16) char smem[SEQ_LDS_BYTES];
    __hip_bfloat16* dvT = (__hip_bfloat16*)(smem + 71680);   // [16 j][72 t]
    __hip_bfloat16* Stl = (__hip_bfloat16*)(smem + 73984);   // [16 j][136 kk]
    float* sG = (float*)(smem + 78336);

    f32x4 SM[2];
#pragma unroll
    for (int mj = 0; mj < 2; ++mj) {
#pragma unroll
        for (int r = 0; r < 4; ++r) {
            const int kk = w * 32 + mj * 16 + rq + r;
            const float v = S0in[((long)bh * 128 + kk) * 128 + j0 + fr];
            SM[mj][r] = v;
            Stl[fr * 136 + kk] = __float2bfloat16(v);
        }
    }

    uint4 rreg[4], kreg[4];
    float greg = 0.0f;

#define SEQ_STAGE_LOAD(c_) do {                                                   \
        const long cb_ = (long)bh * NC + (c_);                                    \
        _Pragma("unroll")                                                         \
        for (int i_ = 0; i_ < 4; ++i_) {                                          \
            const int ur_ = (tid << 2) + i_;                                      \
            rreg[i_] = *(const uint4*)(Rg + (cb_ * CS + (ur_ >> 4)) * DHEAD + ((ur_ & 15) << 3)); \
            kreg[i_] = *(const uint4*)(Ktg + (cb_ * DHEAD + (ur_ >> 3)) * CS + ((ur_ & 7) << 3)); \
        }                                                                         \
        if (tid < 64) greg = Gcum[cb_ * CS + tid];                                \
    } while (0)

#define SEQ_STAGE_WRITE(bufi_) do {                                               \
        __hip_bfloat16* rb_ = (__hip_bfloat16*)(smem + (bufi_) * 17408);          \
        __hip_bfloat16* kb2_ = (__hip_bfloat16*)(smem + 34816 + (bufi_) * 18432); \
        _Pragma("unroll")                                                         \
        for (int i_ = 0; i_ < 4; ++i_) {                                          \
            const int ur_ = (tid << 2) + i_;                                      \
            *(uint4*)(rb_ + (ur_ >> 4) * 136 + ((ur_ & 15) << 3)) = rreg[i_];     \
            *(uint4*)(kb2_ + (ur_ >> 3) * 72 + ((ur_ & 7) << 3)) = kreg[i_];      \
        }                                                                         \
        if (tid < 64) sG[(bufi_) * 64 + tid] = greg;                              \
    } while (0)

    SEQ_STAGE_LOAD(0);
    SEQ_STAGE_WRITE(0);
    __syncthreads();

    for (int c = 0; c < NC; ++c) {
        const int cur = c & 1;
        const long chnk = (long)bh * NC + c;
        const __hip_bfloat16* Rl = (const __hip_bfloat16*)(smem + cur * 17408);
        const __hip_bfloat16* Ktl = (const __hip_bfloat16*)(smem + 34816 + cur * 18432);
        const float g63 = sG[cur * 64 + 63];
        const float a63 = expf(g63);

        unsigned short d0r[4];
#pragma unroll
        for (int r = 0; r < 4; ++r) {
            const int t = w * 16 + rq + r;
            d0r[r] = *(const unsigned short*)(dvX + (chnk * CS + t) * DHEAD + j0 + fr);
        }

        if (c + 1 < NC) SEQ_STAGE_LOAD(c + 1);

        {
            const int j = tid >> 4, k0 = (tid & 15) * 8;
            const uint4 v = *(const uint4*)&Stl[j * 136 + k0];
            *(uint4*)(Ssnap + (chnk * 128 + j0 + j) * 128 + k0) = v;
        }

        // step A: dv = dv0 + R @ S
        f32x4 acc = (f32x4)0.0f;
#pragma unroll
        for (int ks = 0; ks < 4; ++ks) {
            const bf16x8 bfrag = *(const bf16x8*)&Stl[fr * 136 + ks * 32 + fk8];
            const bf16x8 afrag = *(const bf16x8*)&Rl[(w * 16 + fr) * 136 + ks * 32 + fk8];
            acc = __builtin_amdgcn_mfma_f32_16x16x32_bf16(afrag, bfrag, acc, 0, 0, 0);
        }
#pragma unroll
        for (int r = 0; r < 4; ++r) {
            const int t = w * 16 + rq + r;
            const float rk = expf(g63 - sG[cur * 64 + t]);
            const float dv = acc[r] + bfbits2f(d0r[r]);
            *(unsigned short*)(dvX + (chnk * CS + t) * DHEAD + j0 + fr) = bf16_bits(dv);
            dvT[fr * 72 + t] = __float2bfloat16(rk * dv);
        }

        if (c + 1 < NC) SEQ_STAGE_WRITE(cur ^ 1);
        __syncthreads();

        // step B: S' = a63*S + K^T @ dvs
#pragma unroll
        for (int mj = 0; mj < 2; ++mj) SM[mj] *= a63;
#pragma unroll
        for (int ks = 0; ks < 2; ++ks) {
            const bf16x8 bfrag = *(const bf16x8*)&dvT[fr * 72 + ks * 32 + fk8];
#pragma unroll
            for (int mj = 0; mj < 2; ++mj) {
                const bf16x8 afrag = *(const bf16x8*)&Ktl[(w * 32 + mj * 16 + fr) * 72 + ks * 32 + fk8];
                SM[mj] = __builtin_amdgcn_mfma_f32_16x16x32_bf16(afrag, bfrag, SM[mj], 0, 0, 0);
            }
        }
#pragma unroll
        for (int mj = 0; mj < 2; ++mj)
#pragma unroll
            for (int r = 0; r < 4; ++r) {
                const int kk = w * 32 + mj * 16 + rq + r;
                Stl[fr * 136 + kk] = __float2bfloat16(SM[mj][r]);
            }
        __syncthreads();
    }

#pragma unroll
    for (int mj = 0; mj < 2; ++mj)
#pragma unroll
        for (int r = 0; r < 4; ++r) {
            const int kk = w * 32 + mj * 16 + rq + r;
            Sout[((long)bh * 128 + kk) * 128 + j0 + fr] = SM[mj][r];
        }
#undef SEQ_STAGE_LOAD
#undef SEQ_STAGE_WRITE
}

// --------- Phase C (parallel, MFMA): o = e^{G_t}*(q_t @ S0snap) + M @ dv ----
__global__ __launch_bounds__(256) void chunk_out(
    const __hip_bfloat16* __restrict__ qb, const float* __restrict__ Gcum,
    const __hip_bfloat16* __restrict__ dvX, const __hip_bfloat16* __restrict__ Ssnap,
    const __hip_bfloat16* __restrict__ Mmat, __hip_bfloat16* __restrict__ ob)
{
    const int bh = blockIdx.x >> 5;
    const int c  = blockIdx.x & 31;
    const int b = bh >> 3, h = bh & 7;
    const int tid = threadIdx.x;
    const int w = tid >> 6, l = tid & 63;
    const int fr = l & 15;
    const int fk8 = (l >> 4) * 8;
    const int rq = (l >> 4) * 4;
    const long row0 = (long)b * TLEN + (long)c * CS;
    const long chnk = (long)bh * NC + c;

    __shared__ __align__(16) char smem[62464];
    __hip_bfloat16* Ssn = (__hip_bfloat16*)(smem);
    __hip_bfloat16* Ml  = (__hip_bfloat16*)(smem + 34816);
    __hip_bfloat16* dq  = (__hip_bfloat16*)(smem + 44032);

    {
        const int j = tid >> 1;
        const int d0 = (tid & 1) * 64;
        const uint4* sp = (const uint4*)(Ssnap + (chnk * 128 + j) * 128 + d0);
#pragma unroll
        for (int i = 0; i < 8; ++i)
            *(uint4*)&Ssn[j * 136 + d0 + i * 8] = sp[i];
    }
    {
        const int t = tid >> 2;
        const int s0 = (tid & 3) * 16;
        const uint4* mp = (const uint4*)(Mmat + (chnk * CS + t) * CS + s0);
        *(uint4*)&Ml[t * 72 + s0]     = mp[0];
        *(uint4*)&Ml[t * 72 + s0 + 8] = mp[1];
    }
    {
        const int t = tid >> 2, jb = (tid & 3) * 32;
        uint4 dvr[4];
#pragma unroll
        for (int i = 0; i < 4; ++i)
            dvr[i] = ((const uint4*)(dvX + (chnk * CS + t) * DHEAD + jb))[i];
        const unsigned short* u = (const unsigned short*)&dvr[0];
#pragma unroll
        for (int i = 0; i < 32; ++i)
            dq[(jb + i) * 72 + t] = *(const __hip_bfloat16*)&u[i];
    }
    __syncthreads();

    f32x4 acc[8];
#pragma unroll
    for (int n = 0; n < 8; ++n) acc[n] = (f32x4)0.0f;

    // part 1: O += M @ dv   (K = 64)
#pragma unroll
    for (int ks = 0; ks < 2; ++ks) {
        const bf16x8 afrag = *(const bf16x8*)&Ml[(w * 16 + fr) * 72 + ks * 32 + fk8];
#pragma unroll
        for (int n = 0; n < 8; ++n) {
            const bf16x8 bfrag = *(const bf16x8*)&dq[(n * 16 + fr) * 72 + ks * 32 + fk8];
            acc[n] = __builtin_amdgcn_mfma_f32_16x16x32_bf16(afrag, bfrag, acc[n], 0, 0, 0);
        }
    }
    __syncthreads();

    {
        const int t = tid >> 2, d0 = (tid & 3) * 32;
        const float At = expf(Gcum[chnk * CS + t]);
        const uint4* qp = (const uint4*)(qb + (row0 + t) * DDIM + h * DHEAD + d0);
#pragma unroll
        for (int i = 0; i < 4; ++i) {
            const uint4 qv = qp[i];
            const unsigned short* u = (const unsigned short*)&qv;
            float f[8];
#pragma unroll
            for (int j = 0; j < 8; ++j) f[j] = At * bfbits2f(u[j]);
            *(uint4*)&dq[t * 136 + d0 + i * 8] = pack8_bf16(f);
        }
    }
    __syncthreads();

    // part 2: O += (At*q) @ S0   (K = 128)
#pragma unroll
    for (int ks = 0; ks < 4; ++ks) {
        const bf16x8 afrag = *(const bf16x8*)&dq[(w * 16 + fr) * 136 + ks * 32 + fk8];
#pragma unroll
        for (int n = 0; n < 8; ++n) {
            const bf16x8 bfrag = *(const bf16x8*)&Ssn[(n * 16 + fr) * 136 + ks * 32 + fk8];
            acc[n] = __builtin_amdgcn_mfma_f32_16x16x32_bf16(afrag, bfrag, acc[n], 0, 0, 0);
        }
    }

#pragma unroll
    for (int r = 0; r < 4; ++r) {
        const int t = w * 16 + rq + r;
        __hip_bfloat16* op = ob + (row0 + t) * DDIM + h * DHEAD + fr;
#pragma unroll
        for (int n = 0; n < 8; ++n)
            op[n * 16] = __float2bfloat16(acc[n][r]);
    }
}

extern "C" void kernel_launch(void* const* d_in, const int* in_sizes, int n_in,
                              void* d_out, int out_size, void* d_ws, size_t ws_size,
                              hipStream_t stream) {
    const float* x     = (const float*)d_in[0];
    const float* S0    = (const float*)d_in[1];
    const float* wq    = (const float*)d_in[2];
    const float* wk    = (const float*)d_in[3];
    const float* wv    = (const float*)d_in[4];
    const float* wb    = (const float*)d_in[5];
    const float* wg    = (const float*)d_in[6];
    const float* wo    = (const float*)d_in[7];
    const float* wgate = (const float*)d_in[8];
    const float* wup   = (const float*)d_in[9];
    const float* wdown = (const float*)d_in[10];

    const int M = BSZ * TLEN;  // 4096 token rows

    float* out  = (float*)d_out;
    float* Sout = out + (long)M * DDIM;

    // Workspace layout, peak 76.5 MiB (proven budget: 81 MiB).
    char* w = (char*)d_ws;
    const size_t MB = 1u << 20;
    const size_t KB = 1u << 10;
    __hip_bfloat16* qbh   = (__hip_bfloat16*)(w + 0 * MB);
    __hip_bfloat16* kbh   = (__hip_bfloat16*)(w + 8 * MB);
    __hip_bfloat16* vbh   = (__hip_bfloat16*)(w + 16 * MB);
    float*          beta  = (float*)(w + 24 * MB);
    float*          alpha = (float*)(w + 24 * MB + 128 * KB);
    float*          Gcum  = (float*)(w + 24 * MB + 256 * KB);
    __hip_bfloat16* Mmat  = (__hip_bfloat16*)(w + 24 * MB + 512 * KB); // prep->out (4MB)
    __hip_bfloat16* dvX   = (__hip_bfloat16*)(w + 28 * MB + 512 * KB); // prep->out (8MB)
    __hip_bfloat16* Rg    = (__hip_bfloat16*)(w + 36 * MB + 512 * KB); // prep->seq (8MB)
    __hip_bfloat16* xnb   = (__hip_bfloat16*)(w + 36 * MB + 512 * KB); // rms1->QKV (dead before Rg)
    __hip_bfloat16* Ktg   = (__hip_bfloat16*)(w + 44 * MB + 512 * KB); // prep->seq (8MB)
    __hip_bfloat16* Ssnap = (__hip_bfloat16*)(w + 52 * MB + 512 * KB); // seq->out (16MB)
    __hip_bfloat16* wqt   = (__hip_bfloat16*)(w + 68 * MB + 512 * KB);
    __hip_bfloat16* wkt   = (__hip_bfloat16*)(w + 70 * MB + 512 * KB);
    __hip_bfloat16* wvt   = (__hip_bfloat16*)(w + 72 * MB + 512 * KB);
    __hip_bfloat16* wot   = (__hip_bfloat16*)(w + 74 * MB + 512 * KB);
    __hip_bfloat16* obufb = (__hip_bfloat16*)(w + 8 * MB);
    __hip_bfloat16* xn2b  = (__hip_bfloat16*)(w + 8 * MB);
    __hip_bfloat16* wdt   = (__hip_bfloat16*)(w + 16 * MB);
    __hip_bfloat16* wgt   = (__hip_bfloat16*)(w + 24 * MB + 512 * KB);
    __hip_bfloat16* wut   = (__hip_bfloat16*)(w + 32 * MB + 512 * KB);
    __hip_bfloat16* Hb    = (__hip_bfloat16*)(w + 40 * MB + 512 * KB);

    // 0) weight transpose+convert (W[K,N] -> Wt[N,K] bf16)
    transpose_cvt<<<dim3(DDIM / 32, DDIM / 32), 256, 0, stream>>>(wq, wqt, DDIM, DDIM);
    transpose_cvt<<<dim3(DDIM / 32, DDIM / 32), 256, 0, stream>>>(wk, wkt, DDIM, DDIM);
    transpose_cvt<<<dim3(DDIM / 32, DDIM / 32), 256, 0, stream>>>(wv, wvt, DDIM, DDIM);
    transpose_cvt<<<dim3(DDIM / 32, DDIM / 32), 256, 0, stream>>>(wo, wot, DDIM, DDIM);

    // 1) norms / gates
    rmsnorm_k<<<M, 256, 0, stream>>>(x, xnb);
    ba_kernel<<<M, 64, 0, stream>>>(x, wb, wg, beta, alpha);

    // 2) q/k/v projections (bf16 out) — 128x64 tile BK=128
    dim3 gP64(DDIM / 64, M / 128);  // (16, 32)
    gemm_n64<2><<<gP64, 256, 0, stream>>>(xnb, wqt, nullptr, qbh, M, DDIM, DDIM);
    gemm_n64<2><<<gP64, 256, 0, stream>>>(xnb, wkt, nullptr, kbh, M, DDIM, DDIM);
    gemm_n64<2><<<gP64, 256, 0, stream>>>(xnb, wvt, nullptr, vbh, M, DDIM, DDIM);
    postqkv<<<M * HHEADS, 64, 0, stream>>>(qbh, kbh, vbh);

    // 3) chunked delta rule
    chunk_prep<<<16 * NC, 256, 0, stream>>>(kbh, qbh, vbh, beta, alpha, Gcum, Rg, Ktg, dvX, Mmat);
    chunk_seq_mfma<<<16 * SEQGV, 256, 0, stream>>>(S0, Gcum, Rg, Ktg, dvX, Ssnap, Sout);
    chunk_out<<<16 * NC, 256, 0, stream>>>(qbh, Gcum, dvX, Ssnap, Mmat, obufb);

    // 4) x1 = x + o @ wo — 128x64 tile BK=128
    gemm_n64<1><<<gP64, 256, 0, stream>>>(obufb, wot, x, out, M, DDIM, DDIM);

    // 4b) remaining weight transposes into now-dead regions
    transpose_cvt<<<dim3(DDIM / 32, FDIM / 32), 256, 0, stream>>>(wdown, wdt, FDIM, DDIM);
    transpose_cvt<<<dim3(FDIM / 32, DDIM / 32), 256, 0, stream>>>(wgate, wgt, DDIM, FDIM);
    transpose_cvt<<<dim3(FDIM / 32, DDIM / 32), 256, 0, stream>>>(wup, wut, DDIM, FDIM);

    // 5) xn2 = rms_norm(x1)
    rmsnorm_k<<<M, 256, 0, stream>>>(out, xn2b);

    // 6) H = silu(xn2 @ w_gate) * (xn2 @ w_up)  -- 128x64 tile BK=64
    dim3 gGU(FDIM / 64, M / 128);
    gemm_gateup_bf16<<<gGU, 256, 0, stream>>>(xn2b, wgt, wut, Hb, M, FDIM, DDIM);

    // 7) x_out = x1 + H @ w_down — 128x64 tile BK=128, K=4096
    gemm_n64<1><<<gP64, 256, 0, stream>>>(Hb, wdt, out, out, M, DDIM, FDIM);
}

// Round 15
// 348.713 us; speedup vs baseline: 2.6203x; 1.0467x over previous
//
#include <hip/hip_runtime.h>
#include <hip/hip_bf16.h>
#include <math.h>

// Sizes fixed by the problem: B=2, T=2048, D=1024, F=4096, H=8, DH=128.
#define BSZ 2
#define TLEN 2048
#define DDIM 1024
#define FDIM 4096
#define HHEADS 8
#define DHEAD 128
#define NC 32   // chunks per sequence
#define CS 64   // chunk size (CS*NC == TLEN)

typedef __bf16 bf16x8 __attribute__((ext_vector_type(8)));
typedef float f32x4 __attribute__((ext_vector_type(4)));

__device__ __forceinline__ float silu_f(float x) {
    return x / (1.0f + expf(-x));
}

__device__ __forceinline__ void load_lds16(const void* g, void* l) {
    __builtin_amdgcn_global_load_lds(
        (const __attribute__((address_space(1))) void*)g,
        (__attribute__((address_space(3))) void*)l, 16, 0, 0);
}

__device__ __forceinline__ unsigned short bf16_bits(float f) {
    __hip_bfloat16 h = __float2bfloat16(f);
    return *reinterpret_cast<unsigned short*>(&h);
}

__device__ __forceinline__ float bfbits2f(unsigned short u) {
    union { unsigned int i; float f; } c;
    c.i = ((unsigned int)u) << 16;
    return c.f;
}

__device__ __forceinline__ uint4 pack8_bf16(const float* f) {
    union { unsigned short u[8]; uint4 v; } r;
#pragma unroll
    for (int i = 0; i < 8; ++i) r.u[i] = bf16_bits(f[i]);
    return r.v;
}

// ---------------- RMSNorm: one block (256 thr) per row of 1024; bf16 out -----
struct alignas(8) bh4 { __hip_bfloat16 a, b, c, d; };

__global__ __launch_bounds__(256) void rmsnorm_k(const float* __restrict__ in,
                                                 __hip_bfloat16* __restrict__ out) {
    const long row = blockIdx.x;
    const int tid = threadIdx.x;
    const float4 x = *(const float4*)(in + row * DDIM + tid * 4);
    float ss = x.x * x.x + x.y * x.y + x.z * x.z + x.w * x.w;
    ss += __shfl_xor(ss, 1);
    ss += __shfl_xor(ss, 2);
    ss += __shfl_xor(ss, 4);
    ss += __shfl_xor(ss, 8);
    ss += __shfl_xor(ss, 16);
    ss += __shfl_xor(ss, 32);
    __shared__ float wsum[4];
    if ((tid & 63) == 0) wsum[tid >> 6] = ss;
    __syncthreads();
    const float tot = wsum[0] + wsum[1] + wsum[2] + wsum[3];
    const float sc = rsqrtf(tot * (1.0f / (float)DDIM) + 1e-6f);
    bh4 y;
    y.a = __float2bfloat16(x.x * sc);
    y.b = __float2bfloat16(x.y * sc);
    y.c = __float2bfloat16(x.z * sc);
    y.d = __float2bfloat16(x.w * sc);
    *(bh4*)(out + row * DDIM + tid * 4) = y;
}

// ------------- transpose + f32->bf16: W[K,N] -> Wt[N,K] -------------
__global__ __launch_bounds__(256) void transpose_cvt(const float* __restrict__ W,
                                                     __hip_bfloat16* __restrict__ Wt,
                                                     int K, int N) {
    __shared__ float t[32][33];
    const int n0 = blockIdx.x * 32, k0 = blockIdx.y * 32;
    const int tx = threadIdx.x & 31, ty = threadIdx.x >> 5;  // ty 0..7
#pragma unroll
    for (int i = 0; i < 4; ++i)
        t[ty * 4 + i][tx] = W[(long)(k0 + ty * 4 + i) * N + n0 + tx];
    __syncthreads();
#pragma unroll
    for (int i = 0; i < 4; ++i)
        Wt[(long)(n0 + ty * 4 + i) * K + k0 + tx] = __float2bfloat16(t[tx][ty * 4 + i]);
}

// ---------------- bf16 MFMA GEMM (128x64, BK=128 four-panel) ----------------
// MODE 1: f32 out + f32 resid. MODE 2: bf16 out.
// MODE 3: bf16 out, split-QKV routing: logical col c -> buffer (c>>10) at
//         stride 4194304 elems (8 MiB), col c&1023 (row stride 1024).
template <int MODE>
__global__ __launch_bounds__(256) void gemm_n64(const __hip_bfloat16* __restrict__ A,
                                                const __hip_bfloat16* __restrict__ Bt,
                                                const float* __restrict__ resid,
                                                void* __restrict__ Cout,
                                                int M, int N, int K) {
    __shared__ __align__(16) short As[4 * 128 * 32];   // 32 KB (8 KB/panel)
    __shared__ __align__(16) short Bs[4 * 64 * 32];    // 16 KB (4 KB/panel)
    const int tid = threadIdx.x;
    const int w = tid >> 6, l = tid & 63;
    const int m0 = blockIdx.y * 128, n0 = blockIdx.x * 64;
    const int srow = (w << 4) + (l >> 2);
    const int skcol = (l & 3) * 8;
    const int wr = w >> 1, wc = w & 1;
    const int fr = l & 15;
    const int fkB = (l >> 4) * 16;

    f32x4 acc[4][2];
#pragma unroll
    for (int m = 0; m < 4; ++m)
#pragma unroll
        for (int n = 0; n < 2; ++n) acc[m][n] = (f32x4)0.0f;

    const __hip_bfloat16* Abase = A + (long)m0 * K + skcol;
    const __hip_bfloat16* Bbase = Bt + (long)n0 * K + skcol;

    for (int k0 = 0; k0 < K; k0 += 128) {
#pragma unroll
        for (int p = 0; p < 4; ++p) {
#pragma unroll
            for (int j = 0; j < 2; ++j)
                load_lds16(Abase + (long)(srow + j * 64) * K + k0 + p * 32,
                           (char*)As + p * 8192 + w * 1024 + j * 4096);
            load_lds16(Bbase + (long)srow * K + k0 + p * 32,
                       (char*)Bs + p * 4096 + w * 1024);
        }
        __syncthreads();
#pragma unroll
        for (int p = 0; p < 4; ++p) {
            bf16x8 av[4], bv[2];
#pragma unroll
            for (int m = 0; m < 4; ++m)
                av[m] = *(const bf16x8*)((char*)As + p * 8192 + (wr * 64 + m * 16 + fr) * 64 + fkB);
#pragma unroll
            for (int n = 0; n < 2; ++n)
                bv[n] = *(const bf16x8*)((char*)Bs + p * 4096 + (wc * 32 + n * 16 + fr) * 64 + fkB);
#pragma unroll
            for (int m = 0; m < 4; ++m)
#pragma unroll
                for (int n = 0; n < 2; ++n)
                    acc[m][n] = __builtin_amdgcn_mfma_f32_16x16x32_bf16(av[m], bv[n], acc[m][n], 0, 0, 0);
        }
        __syncthreads();
    }

    const int r0 = (l >> 4) * 4;
    const int cc = l & 15;
#pragma unroll
    for (int m = 0; m < 4; ++m) {
#pragma unroll
        for (int r = 0; r < 4; ++r) {
            const long row = m0 + wr * 64 + m * 16 + r0 + r;
            const long colb = n0 + wc * 32 + cc;
            if (MODE == 2) {
                __hip_bfloat16* cb = (__hip_bfloat16*)Cout + row * N + colb;
#pragma unroll
                for (int n = 0; n < 2; ++n)
                    cb[n * 16] = __float2bfloat16(acc[m][n][r]);
            } else if (MODE == 3) {
                // 64-wide block never crosses a 1024 boundary -> n0>>10 uniform
                __hip_bfloat16* cb = (__hip_bfloat16*)Cout
                    + (long)(n0 >> 10) * 4194304 + row * 1024 + (colb & 1023);
#pragma unroll
                for (int n = 0; n < 2; ++n)
                    cb[n * 16] = __float2bfloat16(acc[m][n][r]);
            } else {
                float* cp = (float*)Cout + row * N + colb;
                const float* rp = resid + row * N + colb;
#pragma unroll
                for (int n = 0; n < 2; ++n)
                    cp[n * 16] = acc[m][n][r] + rp[n * 16];
            }
        }
    }
}

// ---- dual-B MFMA GEMM for SwiGLU (BK=64 two-panel, 512 thr / 8 waves) ------
// Same 128x64 tile; 8 waves (4 wr x 2 wc), per wave 2x2 frags per matrix
// (32 acc regs -> ~100 unified -> 4 waves/SIMD tier; 32 KB LDS).
__global__ __launch_bounds__(512) void gemm_gateup_bf16(const __hip_bfloat16* __restrict__ A,
                                                        const __hip_bfloat16* __restrict__ Bg,
                                                        const __hip_bfloat16* __restrict__ Bu,
                                                        __hip_bfloat16* __restrict__ Hb,
                                                        int M, int N, int K) {
    __shared__ __align__(16) short As[2 * 128 * 32];   // 16 KB
    __shared__ __align__(16) short Bgs[2 * 64 * 32];   // 8 KB
    __shared__ __align__(16) short Bus[2 * 64 * 32];   // 8 KB
    const int tid = threadIdx.x;
    const int w = tid >> 6, l = tid & 63;              // w 0..7
    const int m0 = blockIdx.y * 128, n0 = blockIdx.x * 64;
    const int srow = (w << 4) + (l >> 2);              // 0..127
    const int skcol = (l & 3) * 8;
    const int wr = w >> 1, wc = w & 1;                 // wr 0..3, wc 0..1
    const int fr = l & 15;
    const int fkB = (l >> 4) * 16;

    f32x4 accg[2][2], accu[2][2];
#pragma unroll
    for (int m = 0; m < 2; ++m)
#pragma unroll
        for (int n = 0; n < 2; ++n) { accg[m][n] = (f32x4)0.0f; accu[m][n] = (f32x4)0.0f; }

    const __hip_bfloat16* Abase = A + (long)m0 * K + skcol;
    const __hip_bfloat16* Bgb = Bg + (long)n0 * K + skcol;
    const __hip_bfloat16* Bub = Bu + (long)n0 * K + skcol;

    for (int k0 = 0; k0 < K; k0 += 64) {
#pragma unroll
        for (int p = 0; p < 2; ++p) {
            // A: 128 rows, one per thread (srow 0..127)
            load_lds16(Abase + (long)srow * K + k0 + p * 32,
                       (char*)As + p * 8192 + w * 1024);
            // Bg: waves 0..3 (rows 0..63); Bu: waves 4..7 (rows 0..63)
            if (w < 4)
                load_lds16(Bgb + (long)srow * K + k0 + p * 32,
                           (char*)Bgs + p * 4096 + w * 1024);
            else
                load_lds16(Bub + (long)(srow - 64) * K + k0 + p * 32,
                           (char*)Bus + p * 4096 + (w - 4) * 1024);
        }
        __syncthreads();
#pragma unroll
        for (int p = 0; p < 2; ++p) {
            bf16x8 av[2], bgv[2], buv[2];
#pragma unroll
            for (int m = 0; m < 2; ++m)
                av[m] = *(const bf16x8*)((char*)As + p * 8192 + (wr * 32 + m * 16 + fr) * 64 + fkB);
#pragma unroll
            for (int n = 0; n < 2; ++n) {
                bgv[n] = *(const bf16x8*)((char*)Bgs + p * 4096 + (wc * 32 + n * 16 + fr) * 64 + fkB);
                buv[n] = *(const bf16x8*)((char*)Bus + p * 4096 + (wc * 32 + n * 16 + fr) * 64 + fkB);
            }
#pragma unroll
            for (int m = 0; m < 2; ++m)
#pragma unroll
                for (int n = 0; n < 2; ++n) {
                    accg[m][n] = __builtin_amdgcn_mfma_f32_16x16x32_bf16(av[m], bgv[n], accg[m][n], 0, 0, 0);
                    accu[m][n] = __builtin_amdgcn_mfma_f32_16x16x32_bf16(av[m], buv[n], accu[m][n], 0, 0, 0);
                }
        }
        __syncthreads();
    }

    const int r0 = (l >> 4) * 4;
    const int cc = l & 15;
#pragma unroll
    for (int m = 0; m < 2; ++m) {
#pragma unroll
        for (int r = 0; r < 4; ++r) {
            const long row = m0 + wr * 32 + m * 16 + r0 + r;
            __hip_bfloat16* hp = Hb + row * N + n0 + wc * 32 + cc;
#pragma unroll
            for (int n = 0; n < 2; ++n)
                hp[n * 16] = __float2bfloat16(silu_f(accg[m][n][r]) * accu[m][n][r]);
        }
    }
}

// ------- beta/alpha + rmsnorm fused: x staged once through LDS --------------
__global__ __launch_bounds__(64) void ba_kernel(const float* __restrict__ x,
                                                const float* __restrict__ wb,
                                                const float* __restrict__ wg,
                                                float* __restrict__ beta,
                                                float* __restrict__ alpha,
                                                __hip_bfloat16* __restrict__ xout) {
    __shared__ float xs[DDIM];
    const long row = blockIdx.x;
    const int tid = threadIdx.x;
    float ss = 0.0f;
#pragma unroll
    for (int j = 0; j < 4; ++j) {
        const int fi = tid + j * 64;
        const float4 v = *(const float4*)(x + row * DDIM + fi * 4);
        *(float4*)&xs[fi * 4] = v;
        ss += v.x * v.x + v.y * v.y + v.z * v.z + v.w * v.w;
    }
    ss += __shfl_xor(ss, 1);
    ss += __shfl_xor(ss, 2);
    ss += __shfl_xor(ss, 4);
    ss += __shfl_xor(ss, 8);
    ss += __shfl_xor(ss, 16);
    ss += __shfl_xor(ss, 32);
    const float sc = rsqrtf(ss * (1.0f / (float)DDIM) + 1e-6f);
    // rmsnorm output (replaces the separate rmsnorm_k dispatch)
#pragma unroll
    for (int j = 0; j < 4; ++j) {
        const int fi = tid + j * 64;
        const float4 v = *(const float4*)&xs[fi * 4];   // registers, pre-barrier ok
        bh4 y;
        y.a = __float2bfloat16(v.x * sc);
        y.b = __float2bfloat16(v.y * sc);
        y.c = __float2bfloat16(v.z * sc);
        y.d = __float2bfloat16(v.w * sc);
        *(bh4*)(xout + row * DDIM + fi * 4) = y;
    }
    __syncthreads();
    const int o = tid >> 2;
    const int p = tid & 3;
    const float* wbase = (o < 8) ? (wb + o) : (wg + (o - 8));
    const float* wr = wbase + (long)(p * 256) * HHEADS;
    const float* xr = xs + p * 256;
    float acc = 0.0f;
#pragma unroll 8
    for (int i = 0; i < 256; ++i)
        acc = fmaf(xr[i], wr[(long)i * HHEADS], acc);
    acc += __shfl_xor(acc, 1);
    acc += __shfl_xor(acc, 2);
    if (p == 0) {
        const float val = 1.0f / (1.0f + expf(-acc * sc));
        if (o < 8) beta[row * HHEADS + o] = val;
        else       alpha[row * HHEADS + (o - 8)] = val;
    }
}

// ------- post-projection (bf16 in-place): silu + l2norm on q,k; silu on v ----
__global__ __launch_bounds__(64) void postqkv(__hip_bfloat16* __restrict__ q,
                                              __hip_bfloat16* __restrict__ k,
                                              __hip_bfloat16* __restrict__ v) {
    const long r = blockIdx.x;
    const int tid = threadIdx.x;
    {
        unsigned int* qp = (unsigned int*)(q + r * DHEAD + tid * 2);
        const unsigned int wbits = *qp;
        float y0 = silu_f(bfbits2f(wbits & 0xffff));
        float y1 = silu_f(bfbits2f(wbits >> 16));
        float ss = y0 * y0 + y1 * y1;
        ss += __shfl_xor(ss, 1);  ss += __shfl_xor(ss, 2);
        ss += __shfl_xor(ss, 4);  ss += __shfl_xor(ss, 8);
        ss += __shfl_xor(ss, 16); ss += __shfl_xor(ss, 32);
        const float sc = rsqrtf(ss + 1e-6f);
        *qp = (unsigned int)bf16_bits(y0 * sc) | ((unsigned int)bf16_bits(y1 * sc) << 16);
    }
    {
        unsigned int* kp = (unsigned int*)(k + r * DHEAD + tid * 2);
        const unsigned int wbits = *kp;
        float y0 = silu_f(bfbits2f(wbits & 0xffff));
        float y1 = silu_f(bfbits2f(wbits >> 16));
        float ss = y0 * y0 + y1 * y1;
        ss += __shfl_xor(ss, 1);  ss += __shfl_xor(ss, 2);
        ss += __shfl_xor(ss, 4);  ss += __shfl_xor(ss, 8);
        ss += __shfl_xor(ss, 16); ss += __shfl_xor(ss, 32);
        const float sc = rsqrtf(ss + 1e-6f);
        *kp = (unsigned int)bf16_bits(y0 * sc) | ((unsigned int)bf16_bits(y1 * sc) << 16);
    }
    {
        unsigned int* vp = (unsigned int*)(v + r * DHEAD + tid * 2);
        const unsigned int wbits = *vp;
        *vp = (unsigned int)bf16_bits(silu_f(bfbits2f(wbits & 0xffff)))
            | ((unsigned int)bf16_bits(silu_f(bfbits2f(wbits >> 16))) << 16);
    }
}

// ============ Chunked gated delta rule (log-space decay) ============
// G_t = sum_{s<=t} log(a_s); ratio(t,s)=exp(G_t-G_s)<=1 for s<=t.
//   Tinv = (I+W)^-1 with W[t][s] = b_t ratio (k_t.k_s) (s<t)
//   dv = dv0 + R @ S0,   R = -Tinv @ diag(b_s e^{G_s}) @ K
//   dv0 = Tinv @ (b (.) v)
//   o_t = e^{G_t} (S0^T q_t) + (M @ dv)_t
//   S_end = e^{G63} S0 + K^T @ diag(e^{G63-G_t}) dv

// --------- Phase A (parallel over bh x chunk): G, M, Tinv, R, K^T, dv0 ------
__global__ __launch_bounds__(256) void chunk_prep(
    const __hip_bfloat16* __restrict__ kb, const __hip_bfloat16* __restrict__ qb,
    const __hip_bfloat16* __restrict__ vb, const float* __restrict__ betab,
    const float* __restrict__ alphab, float* __restrict__ Gcum,
    __hip_bfloat16* __restrict__ Rg, __hip_bfloat16* __restrict__ Ktg,
    __hip_bfloat16* __restrict__ dvX, __hip_bfloat16* __restrict__ Mmat)
{
    const int bh = blockIdx.x >> 5;
    const int c  = blockIdx.x & 31;
    const int b = bh >> 3, h = bh & 7;
    const int tid = threadIdx.x;
    const int w = tid >> 6, l = tid & 63;
    const int fr = l & 15;           // fragment col / A-row low
    const int fk8 = (l >> 4) * 8;    // fragment k base (bf16 elems)
    const int fr4 = (l >> 4) * 4;    // C-fragment row base

    __shared__ __align__(16) char smem[64512];
    __hip_bfloat16* tA  = (__hip_bfloat16*)(smem);            // [64][136]
    __hip_bfloat16* Tm  = (__hip_bfloat16*)(smem + 17408);    // [64][72]
    __hip_bfloat16* Xr  = (__hip_bfloat16*)(smem + 26624);    // [64][72]
    __hip_bfloat16* Xt  = (__hip_bfloat16*)(smem + 35840);    // [64][72]
    __hip_bfloat16* bvT = (__hip_bfloat16*)(smem + 26624);    // [128][72] overlay
    __hip_bfloat16* tB  = (__hip_bfloat16*)(smem + 45056);    // [64][136]
    __hip_bfloat16* KtS = (__hip_bfloat16*)(smem + 45056);    // [128][72] overlay
    float* sa  = (float*)(smem + 63488);
    float* sb_ = sa + 64;
    float* sG  = sb_ + 64;
    float* swB = sG + 64;

    const long row0 = (long)b * TLEN + (long)c * CS;
    const long chnk = (long)bh * NC + c;

    if (tid < 64) {
        sa[tid]  = alphab[(row0 + tid) * HHEADS + h];
        sb_[tid] = betab[(row0 + tid) * HHEADS + h];
    }
    // load k,q chunks (bf16 direct copies)
    {
        const int r = tid >> 2;
        const int d0 = (tid & 3) * 32;
        const uint4* kp = (const uint4*)(kb + (row0 + r) * DDIM + h * DHEAD + d0);
        const uint4* qp = (const uint4*)(qb + (row0 + r) * DDIM + h * DHEAD + d0);
#pragma unroll
        for (int i = 0; i < 4; ++i) {
            *(uint4*)&tA[r * 136 + d0 + i * 8] = kp[i];
            *(uint4*)&tB[r * 136 + d0 + i * 8] = qp[i];
        }
    }
    __syncthreads();
    // lane-parallel log-prefix scan (wave 0)
    if (tid < 64) {
        float lv = logf(sa[tid]);
#pragma unroll
        for (int off = 1; off < 64; off <<= 1) {
            const float o = __shfl_up(lv, off, 64);
            if (tid >= off) lv += o;
        }
        sG[tid] = lv;
        Gcum[chnk * CS + tid] = lv;
        swB[tid] = sb_[tid] * expf(lv);
    }
    __syncthreads();

    // ---- MFMA: W_raw = K@K^T, M_raw = Q@K^T (wave w owns rows w*16..+15) ----
    f32x4 accW[4], accM[4];
#pragma unroll
    for (int n = 0; n < 4; ++n) { accW[n] = (f32x4)0.0f; accM[n] = (f32x4)0.0f; }
#pragma unroll
    for (int ks = 0; ks < 4; ++ks) {
        const bf16x8 aW = *(const bf16x8*)&tA[(w * 16 + fr) * 136 + ks * 32 + fk8];
        const bf16x8 aM = *(const bf16x8*)&tB[(w * 16 + fr) * 136 + ks * 32 + fk8];
#pragma unroll
        for (int n = 0; n < 4; ++n) {
            const bf16x8 bfr = *(const bf16x8*)&tA[(n * 16 + fr) * 136 + ks * 32 + fk8];
            accW[n] = __builtin_amdgcn_mfma_f32_16x16x32_bf16(aW, bfr, accW[n], 0, 0, 0);
            accM[n] = __builtin_amdgcn_mfma_f32_16x16x32_bf16(aM, bfr, accM[n], 0, 0, 0);
        }
    }
    // epilogue: M -> global; X0 = -W (row + transposed); T0 = I
#pragma unroll
    for (int n = 0; n < 4; ++n) {
        const int s = n * 16 + fr;
        const float Gs = sG[s];
#pragma unroll
        for (int r = 0; r < 4; ++r) {
            const int t = w * 16 + fr4 + r;
            const float ratio = (s <= t) ? expf(sG[t] - Gs) : 0.0f;
            Mmat[(chnk * CS + t) * CS + s] = __float2bfloat16(ratio * accM[n][r]);
            const float xv = (s < t) ? -(sb_[t] * ratio * accW[n][r]) : 0.0f;
            const __hip_bfloat16 xb = __float2bfloat16(xv);
            Xr[t * 72 + s] = xb;
            Xt[s * 72 + t] = xb;
            Tm[t * 72 + s] = __float2bfloat16((s == t) ? 1.0f : 0.0f);
        }
    }
    __syncthreads();   // tB (q) reads done; X/T visible

    // Ktg (unscaled K^T) -> global; KtS (swB-scaled K^T) -> LDS (overlays tB)
    {
        const int kk = tid >> 1;
        const int t0 = (tid & 1) * 32;
        __hip_bfloat16* kp = Ktg + (chnk * DHEAD + kk) * CS + t0;
        float f[8], fs[8];
#pragma unroll
        for (int i = 0; i < 4; ++i) {
#pragma unroll
            for (int j2 = 0; j2 < 8; ++j2) {
                const int t = t0 + i * 8 + j2;
                f[j2] = __bfloat162float(tA[t * 136 + kk]);
                fs[j2] = f[j2] * swB[t];
            }
            *(uint4*)(kp + i * 8) = pack8_bf16(f);
            *(uint4*)&KtS[kk * 72 + t0 + i * 8] = pack8_bf16(fs);
        }
    }
    __syncthreads();   // KtS visible; doubling may begin

    // ---- in-place Neumann doubling: 6 rounds {T += T@X; X = X@X} ----------
    for (int rnd = 0; rnd < 6; ++rnd) {
        f32x4 aT[4], aXr2[4], aXt2[4];
#pragma unroll
        for (int n = 0; n < 4; ++n) { aT[n] = (f32x4)0.0f; aXr2[n] = (f32x4)0.0f; aXt2[n] = (f32x4)0.0f; }
#pragma unroll
        for (int ks = 0; ks < 2; ++ks) {
            const bf16x8 fT  = *(const bf16x8*)&Tm[(w * 16 + fr) * 72 + ks * 32 + fk8];
            const bf16x8 fXr = *(const bf16x8*)&Xr[(w * 16 + fr) * 72 + ks * 32 + fk8];
            const bf16x8 fXt = *(const bf16x8*)&Xt[(w * 16 + fr) * 72 + ks * 32 + fk8];
#pragma unroll
            for (int n = 0; n < 4; ++n) {
                const bf16x8 bXt = *(const bf16x8*)&Xt[(n * 16 + fr) * 72 + ks * 32 + fk8];
                const bf16x8 bXr = *(const bf16x8*)&Xr[(n * 16 + fr) * 72 + ks * 32 + fk8];
                aT[n]   = __builtin_amdgcn_mfma_f32_16x16x32_bf16(fT,  bXt, aT[n], 0, 0, 0);
                aXr2[n] = __builtin_amdgcn_mfma_f32_16x16x32_bf16(fXr, bXt, aXr2[n], 0, 0, 0);
                aXt2[n] = __builtin_amdgcn_mfma_f32_16x16x32_bf16(fXt, bXr, aXt2[n], 0, 0, 0);
            }
        }
        float told[4][4];
#pragma unroll
        for (int n = 0; n < 4; ++n)
#pragma unroll
            for (int r = 0; r < 4; ++r)
                told[n][r] = __bfloat162float(Tm[(w * 16 + fr4 + r) * 72 + n * 16 + fr]);
        __syncthreads();   // all reads of T/Xr/Xt complete
#pragma unroll
        for (int n = 0; n < 4; ++n) {
            const int col = n * 16 + fr;
#pragma unroll
            for (int r = 0; r < 4; ++r) {
                const int t = w * 16 + fr4 + r;
                Tm[t * 72 + col] = __float2bfloat16(aT[n][r] + told[n][r]);
                if (rnd < 5) {
                    Xr[t * 72 + col] = __float2bfloat16(aXr2[n][r]);
                    Xt[t * 72 + col] = __float2bfloat16(aXt2[n][r]);
                }
            }
        }
        __syncthreads();   // writes visible
    }

    // ---- R = -(T @ KtS^T-form) via MFMA; scatter to global ----------------
    {
        f32x4 aR[8];
#pragma unroll
        for (int n = 0; n < 8; ++n) aR[n] = (f32x4)0.0f;
#pragma unroll
        for (int ks = 0; ks < 2; ++ks) {
            const bf16x8 aTf = *(const bf16x8*)&Tm[(w * 16 + fr) * 72 + ks * 32 + fk8];
#pragma unroll
            for (int n = 0; n < 8; ++n) {
                const bf16x8 bK = *(const bf16x8*)&KtS[(n * 16 + fr) * 72 + ks * 32 + fk8];
                aR[n] = __builtin_amdgcn_mfma_f32_16x16x32_bf16(aTf, bK, aR[n], 0, 0, 0);
            }
        }
#pragma unroll
        for (int n = 0; n < 8; ++n)
#pragma unroll
            for (int r = 0; r < 4; ++r) {
                const int t = w * 16 + fr4 + r;
                Rg[(chnk * CS + t) * DHEAD + n * 16 + fr] = __float2bfloat16(-aR[n][r]);
            }
    }

    // ---- bvT build (overlays Xr/Xt, dead after doubling) -------------------
    {
        const int r = tid >> 2, d0 = (tid & 3) * 32;
        const float br = sb_[r];
        const uint4* vp = (const uint4*)(vb + (row0 + r) * DDIM + h * DHEAD + d0);
#pragma unroll
        for (int i = 0; i < 4; ++i) {
            const uint4 vv = vp[i];
            const unsigned short* u = (const unsigned short*)&vv;
#pragma unroll
            for (int j2 = 0; j2 < 8; ++j2)
                bvT[(d0 + i * 8 + j2) * 72 + r] = __float2bfloat16(br * bfbits2f(u[j2]));
        }
    }
    __syncthreads();   // bvT visible

    // ---- dv0 = T @ bvT^T-form via MFMA; scatter to global ------------------
    {
        f32x4 aD[8];
#pragma unroll
        for (int n = 0; n < 8; ++n) aD[n] = (f32x4)0.0f;
#pragma unroll
        for (int ks = 0; ks < 2; ++ks) {
            const bf16x8 aTf = *(const bf16x8*)&Tm[(w * 16 + fr) * 72 + ks * 32 + fk8];
#pragma unroll
            for (int n = 0; n < 8; ++n) {
                const bf16x8 bV = *(const bf16x8*)&bvT[(n * 16 + fr) * 72 + ks * 32 + fk8];
                aD[n] = __builtin_amdgcn_mfma_f32_16x16x32_bf16(aTf, bV, aD[n], 0, 0, 0);
            }
        }
#pragma unroll
        for (int n = 0; n < 8; ++n)
#pragma unroll
            for (int r = 0; r < 4; ++r) {
                const int t = w * 16 + fr4 + r;
                dvX[(chnk * CS + t) * DHEAD + n * 16 + fr] = __float2bfloat16(aD[n][r]);
            }
    }
}

// --------- Phase B: sequential over chunks; MFMA; 128 blocks ----------------
#define SEQGV 8
#define SEQ_LDS_BYTES 78848

__global__ __launch_bounds__(256) void chunk_seq_mfma(
    const float* __restrict__ S0in, const float* __restrict__ Gcum,
    const __hip_bfloat16* __restrict__ Rg, const __hip_bfloat16* __restrict__ Ktg,
    __hip_bfloat16* __restrict__ dvX, __hip_bfloat16* __restrict__ Ssnap,
    float* __restrict__ Sout)
{
    const int bh = blockIdx.x & 15;
    const int g  = blockIdx.x >> 4;
    const int j0 = g * 16;
    const int tid = threadIdx.x;
    const int w = tid >> 6;
    const int l = tid & 63;
    const int fr = l & 15;
    const int fk8 = (l >> 4) * 8;
    const int rq = (l >> 4) * 4;

    __shared__ __align__(16) char smem[SEQ_LDS_BYTES];
    __hip_bfloat16* dvT = (__hip_bfloat16*)(smem + 71680);   // [16 j][72 t]
    __hip_bfloat16* Stl = (__hip_bfloat16*)(smem + 73984);   // [16 j][136 kk]
    float* sG = (float*)(smem + 78336);

    f32x4 SM[2];
#pragma unroll
    for (int mj = 0; mj < 2; ++mj) {
#pragma unroll
        for (int r = 0; r < 4; ++r) {
            const int kk = w * 32 + mj * 16 + rq + r;
            const float v = S0in[((long)bh * 128 + kk) * 128 + j0 + fr];
            SM[mj][r] = v;
            Stl[fr * 136 + kk] = __float2bfloat16(v);
        }
    }

    uint4 rreg[4], kreg[4];
    float greg = 0.0f;

#define SEQ_STAGE_LOAD(c_) do {                                                   \
        const long cb_ = (long)bh * NC + (c_);                                    \
        _Pragma("unroll")                                                         \
        for (int i_ = 0; i_ < 4; ++i_) {                                          \
            const int ur_ = (tid << 2) + i_;                                      \
            rreg[i_] = *(const uint4*)(Rg + (cb_ * CS + (ur_ >> 4)) * DHEAD + ((ur_ & 15) << 3)); \
            kreg[i_] = *(const uint4*)(Ktg + (cb_ * DHEAD + (ur_ >> 3)) * CS + ((ur_ & 7) << 3)); \
        }                                                                         \
        if (tid < 64) greg = Gcum[cb_ * CS + tid];                                \
    } while (0)

#define SEQ_STAGE_WRITE(bufi_) do {                                               \
        __hip_bfloat16* rb_ = (__hip_bfloat16*)(smem + (bufi_) * 17408);          \
        __hip_bfloat16* kb2_ = (__hip_bfloat16*)(smem + 34816 + (bufi_) * 18432); \
        _Pragma("unroll")                                                         \
        for (int i_ = 0; i_ < 4; ++i_) {                                          \
            const int ur_ = (tid << 2) + i_;                                      \
            *(uint4*)(rb_ + (ur_ >> 4) * 136 + ((ur_ & 15) << 3)) = rreg[i_];     \
            *(uint4*)(kb2_ + (ur_ >> 3) * 72 + ((ur_ & 7) << 3)) = kreg[i_];      \
        }                                                                         \
        if (tid < 64) sG[(bufi_) * 64 + tid] = greg;                              \
    } while (0)

    SEQ_STAGE_LOAD(0);
    SEQ_STAGE_WRITE(0);
    __syncthreads();

    for (int c = 0; c < NC; ++c) {
        const int cur = c & 1;
        const long chnk = (long)bh * NC + c;
        const __hip_bfloat16* Rl = (const __hip_bfloat16*)(smem + cur * 17408);
        const __hip_bfloat16* Ktl = (const __hip_bfloat16*)(smem + 34816 + cur * 18432);
        const float g63 = sG[cur * 64 + 63];
        const float a63 = expf(g63);

        unsigned short d0r[4];
#pragma unroll
        for (int r = 0; r < 4; ++r) {
            const int t = w * 16 + rq + r;
            d0r[r] = *(const unsigned short*)(dvX + (chnk * CS + t) * DHEAD + j0 + fr);
        }

        if (c + 1 < NC) SEQ_STAGE_LOAD(c + 1);

        {
            const int j = tid >> 4, k0 = (tid & 15) * 8;
            const uint4 v = *(const uint4*)&Stl[j * 136 + k0];
            *(uint4*)(Ssnap + (chnk * 128 + j0 + j) * 128 + k0) = v;
        }

        // step A: dv = dv0 + R @ S
        f32x4 acc = (f32x4)0.0f;
#pragma unroll
        for (int ks = 0; ks < 4; ++ks) {
            const bf16x8 bfrag = *(const bf16x8*)&Stl[fr * 136 + ks * 32 + fk8];
            const bf16x8 afrag = *(const bf16x8*)&Rl[(w * 16 + fr) * 136 + ks * 32 + fk8];
            acc = __builtin_amdgcn_mfma_f32_16x16x32_bf16(afrag, bfrag, acc, 0, 0, 0);
        }
#pragma unroll
        for (int r = 0; r < 4; ++r) {
            const int t = w * 16 + rq + r;
            const float rk = expf(g63 - sG[cur * 64 + t]);
            const float dv = acc[r] + bfbits2f(d0r[r]);
            *(unsigned short*)(dvX + (chnk * CS + t) * DHEAD + j0 + fr) = bf16_bits(dv);
            dvT[fr * 72 + t] = __float2bfloat16(rk * dv);
        }

        if (c + 1 < NC) SEQ_STAGE_WRITE(cur ^ 1);
        __syncthreads();

        // step B: S' = a63*S + K^T @ dvs
#pragma unroll
        for (int mj = 0; mj < 2; ++mj) SM[mj] *= a63;
#pragma unroll
        for (int ks = 0; ks < 2; ++ks) {
            const bf16x8 bfrag = *(const bf16x8*)&dvT[fr * 72 + ks * 32 + fk8];
#pragma unroll
            for (int mj = 0; mj < 2; ++mj) {
                const bf16x8 afrag = *(const bf16x8*)&Ktl[(w * 32 + mj * 16 + fr) * 72 + ks * 32 + fk8];
                SM[mj] = __builtin_amdgcn_mfma_f32_16x16x32_bf16(afrag, bfrag, SM[mj], 0, 0, 0);
            }
        }
#pragma unroll
        for (int mj = 0; mj < 2; ++mj)
#pragma unroll
            for (int r = 0; r < 4; ++r) {
                const int kk = w * 32 + mj * 16 + rq + r;
                Stl[fr * 136 + kk] = __float2bfloat16(SM[mj][r]);
            }
        __syncthreads();
    }

#pragma unroll
    for (int mj = 0; mj < 2; ++mj)
#pragma unroll
        for (int r = 0; r < 4; ++r) {
            const int kk = w * 32 + mj * 16 + rq + r;
            Sout[((long)bh * 128 + kk) * 128 + j0 + fr] = SM[mj][r];
        }
#undef SEQ_STAGE_LOAD
#undef SEQ_STAGE_WRITE
}

// --------- Phase C (parallel, MFMA): o = e^{G_t}*(q_t @ S0snap) + M @ dv ----
__global__ __launch_bounds__(256) void chunk_out(
    const __hip_bfloat16* __restrict__ qb, const float* __restrict__ Gcum,
    const __hip_bfloat16* __restrict__ dvX, const __hip_bfloat16* __restrict__ Ssnap,
    const __hip_bfloat16* __restrict__ Mmat, __hip_bfloat16* __restrict__ ob)
{
    const int bh = blockIdx.x >> 5;
    const int c  = blockIdx.x & 31;
    const int b = bh >> 3, h = bh & 7;
    const int tid = threadIdx.x;
    const int w = tid >> 6, l = tid & 63;
    const int fr = l & 15;
    const int fk8 = (l >> 4) * 8;
    const int rq = (l >> 4) * 4;
    const long row0 = (long)b * TLEN + (long)c * CS;
    const long chnk = (long)bh * NC + c;

    __shared__ __align__(16) char smem[62464];
    __hip_bfloat16* Ssn = (__hip_bfloat16*)(smem);
    __hip_bfloat16* Ml  = (__hip_bfloat16*)(smem + 34816);
    __hip_bfloat16* dq  = (__hip_bfloat16*)(smem + 44032);

    {
        const int j = tid >> 1;
        const int d0 = (tid & 1) * 64;
        const uint4* sp = (const uint4*)(Ssnap + (chnk * 128 + j) * 128 + d0);
#pragma unroll
        for (int i = 0; i < 8; ++i)
            *(uint4*)&Ssn[j * 136 + d0 + i * 8] = sp[i];
    }
    {
        const int t = tid >> 2;
        const int s0 = (tid & 3) * 16;
        const uint4* mp = (const uint4*)(Mmat + (chnk * CS + t) * CS + s0);
        *(uint4*)&Ml[t * 72 + s0]     = mp[0];
        *(uint4*)&Ml[t * 72 + s0 + 8] = mp[1];
    }
    {
        const int t = tid >> 2, jb = (tid & 3) * 32;
        uint4 dvr[4];
#pragma unroll
        for (int i = 0; i < 4; ++i)
            dvr[i] = ((const uint4*)(dvX + (chnk * CS + t) * DHEAD + jb))[i];
        const unsigned short* u = (const unsigned short*)&dvr[0];
#pragma unroll
        for (int i = 0; i < 32; ++i)
            dq[(jb + i) * 72 + t] = *(const __hip_bfloat16*)&u[i];
    }
    __syncthreads();

    f32x4 acc[8];
#pragma unroll
    for (int n = 0; n < 8; ++n) acc[n] = (f32x4)0.0f;

    // part 1: O += M @ dv   (K = 64)
#pragma unroll
    for (int ks = 0; ks < 2; ++ks) {
        const bf16x8 afrag = *(const bf16x8*)&Ml[(w * 16 + fr) * 72 + ks * 32 + fk8];
#pragma unroll
        for (int n = 0; n < 8; ++n) {
            const bf16x8 bfrag = *(const bf16x8*)&dq[(n * 16 + fr) * 72 + ks * 32 + fk8];
            acc[n] = __builtin_amdgcn_mfma_f32_16x16x32_bf16(afrag, bfrag, acc[n], 0, 0, 0);
        }
    }
    __syncthreads();

    {
        const int t = tid >> 2, d0 = (tid & 3) * 32;
        const float At = expf(Gcum[chnk * CS + t]);
        const uint4* qp = (const uint4*)(qb + (row0 + t) * DDIM + h * DHEAD + d0);
#pragma unroll
        for (int i = 0; i < 4; ++i) {
            const uint4 qv = qp[i];
            const unsigned short* u = (const unsigned short*)&qv;
            float f[8];
#pragma unroll
            for (int j = 0; j < 8; ++j) f[j] = At * bfbits2f(u[j]);
            *(uint4*)&dq[t * 136 + d0 + i * 8] = pack8_bf16(f);
        }
    }
    __syncthreads();

    // part 2: O += (At*q) @ S0   (K = 128)
#pragma unroll
    for (int ks = 0; ks < 4; ++ks) {
        const bf16x8 afrag = *(const bf16x8*)&dq[(w * 16 + fr) * 136 + ks * 32 + fk8];
#pragma unroll
        for (int n = 0; n < 8; ++n) {
            const bf16x8 bfrag = *(const bf16x8*)&Ssn[(n * 16 + fr) * 136 + ks * 32 + fk8];
            acc[n] = __builtin_amdgcn_mfma_f32_16x16x32_bf16(afrag, bfrag, acc[n], 0, 0, 0);
        }
    }

#pragma unroll
    for (int r = 0; r < 4; ++r) {
        const int t = w * 16 + rq + r;
        __hip_bfloat16* op = ob + (row0 + t) * DDIM + h * DHEAD + fr;
#pragma unroll
        for (int n = 0; n < 8; ++n)
            op[n * 16] = __float2bfloat16(acc[n][r]);
    }
}

extern "C" void kernel_launch(void* const* d_in, const int* in_sizes, int n_in,
                              void* d_out, int out_size, void* d_ws, size_t ws_size,
                              hipStream_t stream) {
    const float* x     = (const float*)d_in[0];
    const float* S0    = (const float*)d_in[1];
    const float* wq    = (const float*)d_in[2];
    const float* wk    = (const float*)d_in[3];
    const float* wv    = (const float*)d_in[4];
    const float* wb    = (const float*)d_in[5];
    const float* wg    = (const float*)d_in[6];
    const float* wo    = (const float*)d_in[7];
    const float* wgate = (const float*)d_in[8];
    const float* wup   = (const float*)d_in[9];
    const float* wdown = (const float*)d_in[10];

    const int M = BSZ * TLEN;  // 4096 token rows

    float* out  = (float*)d_out;
    float* Sout = out + (long)M * DDIM;

    // Workspace layout, peak 76.5 MiB (proven budget: 81 MiB).
    char* w = (char*)d_ws;
    const size_t MB = 1u << 20;
    const size_t KB = 1u << 10;
    __hip_bfloat16* qbh   = (__hip_bfloat16*)(w + 0 * MB);
    __hip_bfloat16* kbh   = (__hip_bfloat16*)(w + 8 * MB);
    __hip_bfloat16* vbh   = (__hip_bfloat16*)(w + 16 * MB);
    float*          beta  = (float*)(w + 24 * MB);
    float*          alpha = (float*)(w + 24 * MB + 128 * KB);
    float*          Gcum  = (float*)(w + 24 * MB + 256 * KB);
    __hip_bfloat16* Mmat  = (__hip_bfloat16*)(w + 24 * MB + 512 * KB); // prep->out (4MB)
    __hip_bfloat16* dvX   = (__hip_bfloat16*)(w + 28 * MB + 512 * KB); // prep->out (8MB)
    __hip_bfloat16* Rg    = (__hip_bfloat16*)(w + 36 * MB + 512 * KB); // prep->seq (8MB)
    __hip_bfloat16* xnb   = (__hip_bfloat16*)(w + 36 * MB + 512 * KB); // ba->QKV (dead before Rg)
    __hip_bfloat16* Ktg   = (__hip_bfloat16*)(w + 44 * MB + 512 * KB); // prep->seq (8MB)
    __hip_bfloat16* Ssnap = (__hip_bfloat16*)(w + 52 * MB + 512 * KB); // seq->out (16MB)
    __hip_bfloat16* wqt   = (__hip_bfloat16*)(w + 68 * MB + 512 * KB); // wqt|wkt|wvt contiguous
    __hip_bfloat16* wkt   = (__hip_bfloat16*)(w + 70 * MB + 512 * KB);
    __hip_bfloat16* wvt   = (__hip_bfloat16*)(w + 72 * MB + 512 * KB);
    __hip_bfloat16* wot   = (__hip_bfloat16*)(w + 74 * MB + 512 * KB);
    __hip_bfloat16* obufb = (__hip_bfloat16*)(w + 8 * MB);
    __hip_bfloat16* xn2b  = (__hip_bfloat16*)(w + 8 * MB);
    __hip_bfloat16* wdt   = (__hip_bfloat16*)(w + 16 * MB);
    __hip_bfloat16* wgt   = (__hip_bfloat16*)(w + 24 * MB + 512 * KB);
    __hip_bfloat16* wut   = (__hip_bfloat16*)(w + 32 * MB + 512 * KB);
    __hip_bfloat16* Hb    = (__hip_bfloat16*)(w + 40 * MB + 512 * KB);

    // 0) weight transpose+convert (W[K,N] -> Wt[N,K] bf16)
    transpose_cvt<<<dim3(DDIM / 32, DDIM / 32), 256, 0, stream>>>(wq, wqt, DDIM, DDIM);
    transpose_cvt<<<dim3(DDIM / 32, DDIM / 32), 256, 0, stream>>>(wk, wkt, DDIM, DDIM);
    transpose_cvt<<<dim3(DDIM / 32, DDIM / 32), 256, 0, stream>>>(wv, wvt, DDIM, DDIM);
    transpose_cvt<<<dim3(DDIM / 32, DDIM / 32), 256, 0, stream>>>(wo, wot, DDIM, DDIM);

    // 1) fused rmsnorm + gates: xnb (bf16) + beta/alpha from one pass over x
    ba_kernel<<<M, 64, 0, stream>>>(x, wb, wg, beta, alpha, xnb);

    // 2) q/k/v projections merged: one GEMM over [3072][1024] weights,
    //    MODE 3 routes output blocks to qbh/kbh/vbh (8 MiB apart).
    gemm_n64<3><<<dim3(3072 / 64, M / 128), 256, 0, stream>>>(xnb, wqt, nullptr, qbh, M, 3072, DDIM);
    postqkv<<<M * HHEADS, 64, 0, stream>>>(qbh, kbh, vbh);

    // 3) chunked delta rule
    chunk_prep<<<16 * NC, 256, 0, stream>>>(kbh, qbh, vbh, beta, alpha, Gcum, Rg, Ktg, dvX, Mmat);
    chunk_seq_mfma<<<16 * SEQGV, 256, 0, stream>>>(S0, Gcum, Rg, Ktg, dvX, Ssnap, Sout);
    chunk_out<<<16 * NC, 256, 0, stream>>>(qbh, Gcum, dvX, Ssnap, Mmat, obufb);

    // 4) x1 = x + o @ wo — 128x64 tile BK=128
    dim3 gP64(DDIM / 64, M / 128);  // (16, 32)
    gemm_n64<1><<<gP64, 256, 0, stream>>>(obufb, wot, x, out, M, DDIM, DDIM);

    // 4b) remaining weight transposes into now-dead regions
    transpose_cvt<<<dim3(DDIM / 32, FDIM / 32), 256, 0, stream>>>(wdown, wdt, FDIM, DDIM);
    transpose_cvt<<<dim3(FDIM / 32, DDIM / 32), 256, 0, stream>>>(wgate, wgt, DDIM, FDIM);
    transpose_cvt<<<dim3(FDIM / 32, DDIM / 32), 256, 0, stream>>>(wup, wut, DDIM, FDIM);

    // 5) xn2 = rms_norm(x1)
    rmsnorm_k<<<M, 256, 0, stream>>>(out, xn2b);

    // 6) H = silu(xn2 @ w_gate) * (xn2 @ w_up)  -- 128x64 tile, 512 threads
    dim3 gGU(FDIM / 64, M / 128);
    gemm_gateup_bf16<<<gGU, 512, 0, stream>>>(xn2b, wgt, wut, Hb, M, FDIM, DDIM);

    // 7) x_out = x1 + H @ w_down — 128x64 tile BK=128, K=4096
    gemm_n64<1><<<gP64, 256, 0, stream>>>(Hb, wdt, out, out, M, DDIM, FDIM);
}